// Round 1
// baseline (881.826 us; speedup 1.0000x reference)
//
#include <hip/hip_runtime.h>

#define XDIM 134
#define FEAT 128
#define AUGN 6
#define NH 8
#define HD 16
#define OUTD 40

__device__ __forceinline__ float rlf(float v, int lane) {
  return __int_as_float(__builtin_amdgcn_readlane(__float_as_int(v), lane));
}
__device__ __forceinline__ float sel8(const float v[8], int h) {
  float r = v[0];
  r = (h == 1) ? v[1] : r; r = (h == 2) ? v[2] : r; r = (h == 3) ? v[3] : r;
  r = (h == 4) ? v[4] : r; r = (h == 5) ? v[5] : r; r = (h == 6) ? v[6] : r;
  r = (h == 7) ? v[7] : r;
  return r;
}

// ---------------- K0: column sums/sumsq of the 6 aug columns ----------------
__global__ __launch_bounds__(256) void k_stats(const float* __restrict__ x,
                                               float* __restrict__ stats, int N) {
  float s[AUGN] = {0, 0, 0, 0, 0, 0}, q[AUGN] = {0, 0, 0, 0, 0, 0};
  for (int n = blockIdx.x * blockDim.x + threadIdx.x; n < N;
       n += gridDim.x * blockDim.x) {
    const float* r = x + (size_t)n * XDIM + FEAT;
#pragma unroll
    for (int i = 0; i < AUGN; i++) {
      float v = r[i];
      s[i] += v;
      q[i] += v * v;
    }
  }
#pragma unroll
  for (int i = 0; i < AUGN; i++) {
    for (int m = 1; m < 64; m <<= 1) {
      s[i] += __shfl_xor(s[i], m);
      q[i] += __shfl_xor(q[i], m);
    }
  }
  if ((threadIdx.x & 63) == 0) {
#pragma unroll
    for (int i = 0; i < AUGN; i++) {
      atomicAdd(&stats[i], s[i]);
      atomicAdd(&stats[8 + i], q[i]);
    }
  }
}

// ---------------- K1: per-node scale = 1 + sigmoid(MLP(norm(aug))) ----------
__global__ __launch_bounds__(256) void k_scale(
    const float* __restrict__ x, const float* __restrict__ stats,
    const float* __restrict__ w1, const float* __restrict__ b1,
    const float* __restrict__ w2, const float* __restrict__ b2,
    float* __restrict__ scl, int N) {
  int n = blockIdx.x * blockDim.x + threadIdx.x;
  if (n >= N) return;
  const float* r = x + (size_t)n * XDIM + FEAT;
  float a[AUGN];
  float invN = 1.0f / (float)N;
#pragma unroll
  for (int i = 0; i < AUGN; i++) {
    float sum = stats[i], sq = stats[8 + i];
    float mean = sum * invN;
    float var = (sq - sum * mean) / (float)(N - 1);
    a[i] = (r[i] - mean) / sqrtf(var);
  }
  float s2 = b2[0];
#pragma unroll
  for (int j = 0; j < 16; j++) {
    float z = b1[j];
#pragma unroll
    for (int i = 0; i < AUGN; i++) z = fmaf(a[i], w1[i * 16 + j], z);
    z = fmaxf(z, 0.0f);
    s2 = fmaf(z, w2[j], s2);
  }
  float sig = 1.0f / (1.0f + __expf(-s2));
  scl[n] = 1.0f + sig;
}

// ---------------- K2a: in-degree histogram (real edges only) ---------------
__global__ __launch_bounds__(256) void k_hist(const int* __restrict__ ei,
                                              int* __restrict__ deg, int E) {
  for (int e = blockIdx.x * blockDim.x + threadIdx.x; e < E;
       e += gridDim.x * blockDim.x)
    atomicAdd(&deg[ei[E + e]], 1);
}

// ---------------- K2b: exclusive scan of (deg+1), init cursors, self-loops -
__global__ __launch_bounds__(1024) void k_scan(const int* __restrict__ deg,
                                               int* __restrict__ offs,
                                               int* __restrict__ cur,
                                               int* __restrict__ csr, int N) {
  __shared__ int ps[1024];
  int t = threadIdx.x;
  int chunk = (N + 1023) >> 10;
  int lo = t * chunk, hi = min(lo + chunk, N);
  int sum = 0;
  for (int i = lo; i < hi; i++) sum += deg[i] + 1;
  ps[t] = sum;
  __syncthreads();
  for (int d = 1; d < 1024; d <<= 1) {
    int v = (t >= d) ? ps[t - d] : 0;
    __syncthreads();
    ps[t] += v;
    __syncthreads();
  }
  int run = (t == 0) ? 0 : ps[t - 1];
  for (int i = lo; i < hi; i++) {
    offs[i] = run;
    cur[i] = run + 1;  // slot run is the self-loop
    csr[run] = i;
    run += deg[i] + 1;
  }
  if (t == 1023) offs[N] = ps[1023];
}

// ---------------- K2c: scatter src indices into CSR ------------------------
__global__ __launch_bounds__(256) void k_scatter(const int* __restrict__ ei,
                                                 int* __restrict__ cur,
                                                 int* __restrict__ csr, int E) {
  for (int e = blockIdx.x * blockDim.x + threadIdx.x; e < E;
       e += gridDim.x * blockDim.x) {
    int d = ei[E + e];
    int p = atomicAdd(&cur[d], 1);
    csr[p] = ei[e];
  }
}

// ---------------- K3: h1 = (x*scale) @ W1 ; a_src1/a_dst1 ------------------
__global__ __launch_bounds__(256) void k_gemm1(
    const float* __restrict__ x, const float* __restrict__ scl,
    const float* __restrict__ W, const float* __restrict__ asv,
    const float* __restrict__ adv, float* __restrict__ h1,
    float* __restrict__ a_src, float* __restrict__ a_dst, int N) {
  __shared__ float WL[128 * 128];
  int tid = threadIdx.x;
#pragma unroll
  for (int i = 0; i < 16; i++)
    ((float4*)WL)[tid + i * 256] = ((const float4*)W)[tid + i * 256];
  __syncthreads();
  int wv = tid >> 6, l = tid & 63;
  int ngroups = gridDim.x * 4;
  for (int gI = blockIdx.x * 4 + wv; gI * 4 < N; gI += ngroups) {
    int base = gI * 4;
    float h0[4], h1r[4];
#pragma unroll
    for (int n = 0; n < 4; n++) {
      int node = base + n;
      if (node < N) {
        float2 v = *(const float2*)(x + (size_t)node * XDIM + 2 * l);
        h0[n] = v.x;
        h1r[n] = v.y;
      } else {
        h0[n] = 0.0f;
        h1r[n] = 0.0f;
      }
    }
    float a0[4] = {0, 0, 0, 0}, a1[4] = {0, 0, 0, 0};
#pragma unroll 8
    for (int k2 = 0; k2 < 64; k2++) {
      float2 we = *(const float2*)&WL[(2 * k2) * 128 + 2 * l];
      float2 wo = *(const float2*)&WL[(2 * k2 + 1) * 128 + 2 * l];
#pragma unroll
      for (int n = 0; n < 4; n++) {
        float he = rlf(h0[n], k2);
        float ho = rlf(h1r[n], k2);
        a0[n] = fmaf(he, we.x, fmaf(ho, wo.x, a0[n]));
        a1[n] = fmaf(he, we.y, fmaf(ho, wo.y, a1[n]));
      }
    }
    float asw0 = asv[2 * l], asw1 = asv[2 * l + 1];
    float adw0 = adv[2 * l], adw1 = adv[2 * l + 1];
#pragma unroll
    for (int n = 0; n < 4; n++) {
      int node = base + n;
      if (node >= N) break;
      float s = scl[node];
      float y0 = a0[n] * s, y1 = a1[n] * s;
      *(float2*)(h1 + (size_t)node * FEAT + 2 * l) = make_float2(y0, y1);
      float ps = y0 * asw0 + y1 * asw1;
      float pd = y0 * adw0 + y1 * adw1;
      ps += __shfl_xor(ps, 1); ps += __shfl_xor(ps, 2); ps += __shfl_xor(ps, 4);
      pd += __shfl_xor(pd, 1); pd += __shfl_xor(pd, 2); pd += __shfl_xor(pd, 4);
      if ((l & 7) == 0) {
        a_src[node * NH + (l >> 3)] = ps;
        a_dst[node * NH + (l >> 3)] = pd;
      }
    }
  }
}

// ---------------- K4: layer-1 softmax-aggregate; h2 = relu(out+bias) -------
__global__ __launch_bounds__(256) void k_agg1(
    const int* __restrict__ offs, const int* __restrict__ csr,
    const float* __restrict__ a_src, const float* __restrict__ a_dst,
    const float* __restrict__ h1, const float* __restrict__ bias,
    float* __restrict__ h2, int N) {
  __shared__ float plds[4][8 * 68];
  int wv = threadIdx.x >> 6, l = threadIdx.x & 63;
  int n = blockIdx.x * 4 + wv;
  if (n >= N) return;
  int beg = offs[n], end = offs[n + 1];
  int deg = end - beg;
  float ad[8];
#pragma unroll
  for (int h = 0; h < 8; h++) ad[h] = a_dst[(size_t)n * NH + h];
  // pass 1: max per head
  float em[8];
#pragma unroll
  for (int h = 0; h < 8; h++) em[h] = -INFINITY;
  float e0[8];
  int s0 = 0;
  for (int j0 = 0; j0 < deg; j0 += 64) {
    int j = j0 + l;
    bool act = j < deg;
    int s = act ? csr[beg + j] : 0;
    float e[8];
    if (act) {
      float4 v0 = *(const float4*)(a_src + (size_t)s * NH);
      float4 v1 = *(const float4*)(a_src + (size_t)s * NH + 4);
      float vs[8] = {v0.x, v0.y, v0.z, v0.w, v1.x, v1.y, v1.z, v1.w};
#pragma unroll
      for (int h = 0; h < 8; h++) {
        float t = vs[h] + ad[h];
        e[h] = t > 0.0f ? t : 0.2f * t;
        em[h] = fmaxf(em[h], e[h]);
      }
    } else {
#pragma unroll
      for (int h = 0; h < 8; h++) e[h] = -INFINITY;
    }
    if (j0 == 0) {
      s0 = s;
#pragma unroll
      for (int h = 0; h < 8; h++) e0[h] = e[h];
    }
  }
#pragma unroll
  for (int h = 0; h < 8; h++)
    for (int m = 1; m < 64; m <<= 1) em[h] = fmaxf(em[h], __shfl_xor(em[h], m));
  // pass 2: p and denom
  float sm[8] = {0, 0, 0, 0, 0, 0, 0, 0};
  for (int j0 = 0; j0 < deg; j0 += 64) {
    int j = j0 + l;
    bool act = j < deg;
    float p[8];
    if (act) {
      if (j0 == 0) {
#pragma unroll
        for (int h = 0; h < 8; h++) p[h] = __expf(e0[h] - em[h]);
      } else {
        int s = csr[beg + j];
        float4 v0 = *(const float4*)(a_src + (size_t)s * NH);
        float4 v1 = *(const float4*)(a_src + (size_t)s * NH + 4);
        float vs[8] = {v0.x, v0.y, v0.z, v0.w, v1.x, v1.y, v1.z, v1.w};
#pragma unroll
        for (int h = 0; h < 8; h++) {
          float t = vs[h] + ad[h];
          t = t > 0.0f ? t : 0.2f * t;
          p[h] = __expf(t - em[h]);
        }
      }
    } else {
#pragma unroll
      for (int h = 0; h < 8; h++) p[h] = 0.0f;
    }
#pragma unroll
    for (int h = 0; h < 8; h++) sm[h] += p[h];
    if (j0 == 0) {
#pragma unroll
      for (int h = 0; h < 8; h++) plds[wv][h * 68 + l] = p[h];
    }
  }
#pragma unroll
  for (int h = 0; h < 8; h++)
    for (int m = 1; m < 64; m <<= 1) sm[h] += __shfl_xor(sm[h], m);
  int myh = l >> 3;
  float mm = sel8(em, myh);
  float admine = sel8(ad, myh);
  float rd = 1.0f / sel8(sm, myh);
  // pass 3: accumulate messages (serial over edges, lanes = channels)
  float acc0 = 0.0f, acc1 = 0.0f;
  for (int j0 = 0; j0 < deg; j0 += 64) {
    int cnt = min(64, deg - j0);
    int sreg = (j0 == 0) ? s0 : ((j0 + l < deg) ? csr[beg + j0 + l] : 0);
    for (int jj = 0; jj < cnt; jj++) {
      int s = __builtin_amdgcn_readlane(sreg, jj);
      float alpha;
      if (j0 == 0) {
        alpha = plds[wv][myh * 68 + jj] * rd;
      } else {
        float av = a_src[(size_t)s * NH + myh];
        float t = av + admine;
        t = t > 0.0f ? t : 0.2f * t;
        alpha = __expf(t - mm) * rd;
      }
      float2 hv = *(const float2*)(h1 + (size_t)s * FEAT + 2 * l);
      acc0 = fmaf(alpha, hv.x, acc0);
      acc1 = fmaf(alpha, hv.y, acc1);
    }
  }
  float b0 = bias[2 * l], b1v = bias[2 * l + 1];
  float o0 = fmaxf(acc0 + b0, 0.0f), o1 = fmaxf(acc1 + b1v, 0.0f);
  *(float2*)(h2 + (size_t)n * FEAT + 2 * l) = make_float2(o0, o1);
}

// ---------------- K5: g = h2 @ W2 ; a_src2/a_dst2 --------------------------
__global__ __launch_bounds__(256) void k_gemm2(
    const float* __restrict__ h2, const float* __restrict__ W,
    const float* __restrict__ asv, const float* __restrict__ adv,
    float* __restrict__ g, float* __restrict__ a_src, float* __restrict__ a_dst,
    int N) {
  __shared__ float WL[128 * OUTD];
  int tid = threadIdx.x;
  for (int i = tid; i < 128 * OUTD; i += 256) WL[i] = W[i];
  __syncthreads();
  int wv = tid >> 6, l = tid & 63;
  int cw = min(l, OUTD - 1);
  int ngroups = gridDim.x * 4;
  for (int gI = blockIdx.x * 4 + wv; gI * 4 < N; gI += ngroups) {
    int base = gI * 4;
    float h0[4], h1r[4];
#pragma unroll
    for (int n = 0; n < 4; n++) {
      int node = base + n;
      if (node < N) {
        float2 v = *(const float2*)(h2 + (size_t)node * FEAT + 2 * l);
        h0[n] = v.x;
        h1r[n] = v.y;
      } else {
        h0[n] = 0.0f;
        h1r[n] = 0.0f;
      }
    }
    float acc[4] = {0, 0, 0, 0};
#pragma unroll 8
    for (int k2 = 0; k2 < 64; k2++) {
      float we = WL[(2 * k2) * OUTD + cw];
      float wo = WL[(2 * k2 + 1) * OUTD + cw];
#pragma unroll
      for (int n = 0; n < 4; n++) {
        float he = rlf(h0[n], k2);
        float ho = rlf(h1r[n], k2);
        acc[n] = fmaf(he, we, fmaf(ho, wo, acc[n]));
      }
    }
    float asw = asv[cw], adw = adv[cw];
#pragma unroll
    for (int n = 0; n < 4; n++) {
      int node = base + n;
      if (node >= N) break;
      if (l < OUTD) g[(size_t)node * OUTD + l] = acc[n];
      float ps = (l < OUTD) ? acc[n] * asw : 0.0f;
      float pd = (l < OUTD) ? acc[n] * adw : 0.0f;
      for (int m = 1; m < 64; m <<= 1) {
        ps += __shfl_xor(ps, m);
        pd += __shfl_xor(pd, m);
      }
      if (l == 0) {
        a_src[node] = ps;
        a_dst[node] = pd;
      }
    }
  }
}

// ---------------- K6: layer-2 softmax-aggregate + log_softmax --------------
__global__ __launch_bounds__(256) void k_agg2(
    const int* __restrict__ offs, const int* __restrict__ csr,
    const float* __restrict__ a_src, const float* __restrict__ a_dst,
    const float* __restrict__ g, const float* __restrict__ bias,
    float* __restrict__ out, int N) {
  int wv = threadIdx.x >> 6, l = threadIdx.x & 63;
  int n = blockIdx.x * 4 + wv;
  if (n >= N) return;
  int beg = offs[n], end = offs[n + 1];
  int deg = end - beg;
  float adn = a_dst[n];
  float em = -INFINITY, e0 = 0.0f;
  int s0 = 0;
  for (int j0 = 0; j0 < deg; j0 += 64) {
    int j = j0 + l;
    bool act = j < deg;
    int s = act ? csr[beg + j] : 0;
    float e = -INFINITY;
    if (act) {
      float t = a_src[s] + adn;
      e = t > 0.0f ? t : 0.2f * t;
    }
    em = fmaxf(em, e);
    if (j0 == 0) {
      e0 = e;
      s0 = s;
    }
  }
  for (int m = 1; m < 64; m <<= 1) em = fmaxf(em, __shfl_xor(em, m));
  float smv = 0.0f, p0 = 0.0f;
  for (int j0 = 0; j0 < deg; j0 += 64) {
    int j = j0 + l;
    bool act = j < deg;
    float p = 0.0f;
    if (act) {
      if (j0 == 0)
        p = __expf(e0 - em);
      else {
        int s = csr[beg + j];
        float t = a_src[s] + adn;
        t = t > 0.0f ? t : 0.2f * t;
        p = __expf(t - em);
      }
    }
    if (j0 == 0) p0 = p;
    smv += p;
  }
  for (int m = 1; m < 64; m <<= 1) smv += __shfl_xor(smv, m);
  float rd = 1.0f / smv;
  float acc = 0.0f;
  bool cact = l < OUTD;
  for (int j0 = 0; j0 < deg; j0 += 64) {
    int cnt = min(64, deg - j0);
    int sreg;
    float preg;
    if (j0 == 0) {
      sreg = s0;
      preg = p0;
    } else {
      int j = j0 + l;
      if (j < deg) {
        sreg = csr[beg + j];
        float t = a_src[sreg] + adn;
        t = t > 0.0f ? t : 0.2f * t;
        preg = __expf(t - em);
      } else {
        sreg = 0;
        preg = 0.0f;
      }
    }
    for (int jj = 0; jj < cnt; jj++) {
      int s = __builtin_amdgcn_readlane(sreg, jj);
      float alpha = rlf(preg, jj) * rd;
      if (cact) {
        float gv = g[(size_t)s * OUTD + l];
        acc = fmaf(alpha, gv, acc);
      }
    }
  }
  float v = cact ? acc + bias[l] : -INFINITY;
  float mx = v;
  for (int m = 1; m < 64; m <<= 1) mx = fmaxf(mx, __shfl_xor(mx, m));
  float pe = cact ? __expf(v - mx) : 0.0f;
  float se = pe;
  for (int m = 1; m < 64; m <<= 1) se += __shfl_xor(se, m);
  float ls = logf(se);
  if (cact) out[(size_t)n * OUTD + l] = v - mx - ls;
}

// ---------------------------------------------------------------------------
extern "C" void kernel_launch(void* const* d_in, const int* in_sizes, int n_in,
                              void* d_out, int out_size, void* d_ws,
                              size_t ws_size, hipStream_t stream) {
  const float* x = (const float*)d_in[0];
  const int* ei = (const int*)d_in[1];
  const float* mw1 = (const float*)d_in[2];
  const float* mb1 = (const float*)d_in[3];
  const float* mw2 = (const float*)d_in[4];
  const float* mb2 = (const float*)d_in[5];
  const float* W1 = (const float*)d_in[6];
  const float* as1w = (const float*)d_in[7];
  const float* ad1w = (const float*)d_in[8];
  const float* b1 = (const float*)d_in[9];
  const float* W2 = (const float*)d_in[10];
  const float* as2w = (const float*)d_in[11];
  const float* ad2w = (const float*)d_in[12];
  const float* b2 = (const float*)d_in[13];
  float* out = (float*)d_out;

  int N = in_sizes[0] / XDIM;
  int E = in_sizes[1] / 2;
  int ET = E + N;

  char* ws = (char*)d_ws;
  size_t off = 0;
  auto carve = [&](size_t bytes) -> void* {
    void* p = ws + off;
    off = (off + bytes + 255) & ~(size_t)255;
    return p;
  };
  float* stats = (float*)carve(64);
  int* deg = (int*)carve((size_t)N * 4);
  int* offs = (int*)carve((size_t)(N + 1) * 4);
  int* cur = (int*)carve((size_t)N * 4);
  int* csr = (int*)carve((size_t)ET * 4);
  float* scl = (float*)carve((size_t)N * 4);
  float* as1 = (float*)carve((size_t)N * NH * 4);
  float* ad1 = (float*)carve((size_t)N * NH * 4);
  float* h1 = (float*)carve((size_t)N * FEAT * 4);
  float* h2 = (float*)carve((size_t)N * FEAT * 4);
  float* gm = (float*)carve((size_t)N * OUTD * 4);
  float* as2 = (float*)carve((size_t)N * 4);
  float* ad2 = (float*)carve((size_t)N * 4);

  // zero stats + deg (adjacent at the start of ws)
  hipMemsetAsync(d_ws, 0, 256 + (size_t)N * 4, stream);

  k_stats<<<256, 256, 0, stream>>>(x, stats, N);
  k_scale<<<(N + 255) / 256, 256, 0, stream>>>(x, stats, mw1, mb1, mw2, mb2,
                                               scl, N);
  int hb = (E + 255) / 256;
  if (hb > 4096) hb = 4096;
  k_hist<<<hb, 256, 0, stream>>>(ei, deg, E);
  k_scan<<<1, 1024, 0, stream>>>(deg, offs, cur, csr, N);
  k_scatter<<<hb, 256, 0, stream>>>(ei, cur, csr, E);
  k_gemm1<<<1280, 256, 0, stream>>>(x, scl, W1, as1w, ad1w, h1, as1, ad1, N);
  k_agg1<<<(N + 3) / 4, 256, 0, stream>>>(offs, csr, as1, ad1, h1, b1, h2, N);
  k_gemm2<<<1280, 256, 0, stream>>>(h2, W2, as2w, ad2w, gm, as2, ad2, N);
  k_agg2<<<(N + 3) / 4, 256, 0, stream>>>(offs, csr, as2, ad2, gm, b2, out, N);
}

// Round 2
// 763.710 us; speedup vs baseline: 1.1547x; 1.1547x over previous
//
#include <hip/hip_runtime.h>

#define XDIM 134
#define FEAT 128
#define AUGN 6
#define NH 8
#define HD 16
#define OUTD 40
#define PS 132       // per-head stride in plds (132 mod 32 = 4 -> conflict-free)
#define NCHUNK 1024

__device__ __forceinline__ float sel8(const float v[8], int h) {
  float r = v[0];
  r = (h == 1) ? v[1] : r; r = (h == 2) ? v[2] : r; r = (h == 3) ? v[3] : r;
  r = (h == 4) ? v[4] : r; r = (h == 5) ? v[5] : r; r = (h == 6) ? v[6] : r;
  r = (h == 7) ? v[7] : r;
  return r;
}
__device__ __forceinline__ float rlf(float v, int lane) {
  return __int_as_float(__builtin_amdgcn_readlane(__float_as_int(v), lane));
}

// ---------------- K0: column sums/sumsq of the 6 aug columns ----------------
__global__ __launch_bounds__(256) void k_stats(const float* __restrict__ x,
                                               float* __restrict__ stats, int N) {
  float s[AUGN] = {0, 0, 0, 0, 0, 0}, q[AUGN] = {0, 0, 0, 0, 0, 0};
  for (int n = blockIdx.x * blockDim.x + threadIdx.x; n < N;
       n += gridDim.x * blockDim.x) {
    const float* r = x + (size_t)n * XDIM + FEAT;
#pragma unroll
    for (int i = 0; i < AUGN; i++) {
      float v = r[i];
      s[i] += v;
      q[i] += v * v;
    }
  }
#pragma unroll
  for (int i = 0; i < AUGN; i++) {
    for (int m = 1; m < 64; m <<= 1) {
      s[i] += __shfl_xor(s[i], m);
      q[i] += __shfl_xor(q[i], m);
    }
  }
  if ((threadIdx.x & 63) == 0) {
#pragma unroll
    for (int i = 0; i < AUGN; i++) {
      atomicAdd(&stats[i], s[i]);
      atomicAdd(&stats[8 + i], q[i]);
    }
  }
}

// ---------------- K1: per-node scale = 1 + sigmoid(MLP(norm(aug))) ----------
__global__ __launch_bounds__(256) void k_scale(
    const float* __restrict__ x, const float* __restrict__ stats,
    const float* __restrict__ w1, const float* __restrict__ b1,
    const float* __restrict__ w2, const float* __restrict__ b2,
    float* __restrict__ scl, int N) {
  int n = blockIdx.x * blockDim.x + threadIdx.x;
  if (n >= N) return;
  const float* r = x + (size_t)n * XDIM + FEAT;
  float a[AUGN];
  float invN = 1.0f / (float)N;
#pragma unroll
  for (int i = 0; i < AUGN; i++) {
    float sum = stats[i], sq = stats[8 + i];
    float mean = sum * invN;
    float var = (sq - sum * mean) / (float)(N - 1);
    a[i] = (r[i] - mean) / sqrtf(var);
  }
  float s2 = b2[0];
#pragma unroll
  for (int j = 0; j < 16; j++) {
    float z = b1[j];
#pragma unroll
    for (int i = 0; i < AUGN; i++) z = fmaf(a[i], w1[i * 16 + j], z);
    z = fmaxf(z, 0.0f);
    s2 = fmaf(z, w2[j], s2);
  }
  float sig = 1.0f / (1.0f + __expf(-s2));
  scl[n] = 1.0f + sig;
}

// ---------------- K2a: in-degree histogram (real edges only) ---------------
__global__ __launch_bounds__(256) void k_hist(const int* __restrict__ ei,
                                              int* __restrict__ deg, int E) {
  for (int e = blockIdx.x * blockDim.x + threadIdx.x; e < E;
       e += gridDim.x * blockDim.x)
    atomicAdd(&deg[ei[E + e]], 1);
}

// ---------------- K2b: 3-kernel deterministic scan of (deg+1) --------------
__global__ __launch_bounds__(128) void k_csum1(const int* __restrict__ deg,
                                               int* __restrict__ csum, int N) {
  int t = blockIdx.x * 128 + threadIdx.x;  // 8 blocks x 128 = 1024 chunks
  int chunk = (N + NCHUNK - 1) / NCHUNK;
  int lo = t * chunk, hi = min(lo + chunk, N);
  int sum = 0;
  for (int i = lo; i < hi; i++) sum += deg[i] + 1;
  csum[t] = sum;
}
__global__ __launch_bounds__(1024) void k_csum2(int* __restrict__ csum) {
  __shared__ int ps[NCHUNK];
  int t = threadIdx.x;
  ps[t] = csum[t];
  __syncthreads();
  for (int d = 1; d < NCHUNK; d <<= 1) {
    int v = (t >= d) ? ps[t - d] : 0;
    __syncthreads();
    ps[t] += v;
    __syncthreads();
  }
  csum[t] = (t == 0) ? 0 : ps[t - 1];  // exclusive
}
__global__ __launch_bounds__(128) void k_csum3(const int* __restrict__ deg,
                                               const int* __restrict__ csum,
                                               int* __restrict__ offs,
                                               int* __restrict__ cur,
                                               int* __restrict__ csr, int N,
                                               int ET) {
  int t = blockIdx.x * 128 + threadIdx.x;
  int chunk = (N + NCHUNK - 1) / NCHUNK;
  int lo = t * chunk, hi = min(lo + chunk, N);
  int run = csum[t];
  for (int i = lo; i < hi; i++) {
    offs[i] = run;
    cur[i] = run + 1;  // slot run is the self-loop
    csr[run] = i;
    run += deg[i] + 1;
  }
  if (t == 0) offs[N] = ET;
}

// ---------------- K2c: scatter src indices into CSR ------------------------
__global__ __launch_bounds__(256) void k_scatter(const int* __restrict__ ei,
                                                 int* __restrict__ cur,
                                                 int* __restrict__ csr, int E) {
  for (int e = blockIdx.x * blockDim.x + threadIdx.x; e < E;
       e += gridDim.x * blockDim.x) {
    int d = ei[E + e];
    int p = atomicAdd(&cur[d], 1);
    csr[p] = ei[e];
  }
}

// ---------------- K3: h1 = (x*scale) @ W1 ; a_src1/a_dst1 ------------------
__global__ __launch_bounds__(256) void k_gemm1(
    const float* __restrict__ x, const float* __restrict__ scl,
    const float* __restrict__ W, const float* __restrict__ asv,
    const float* __restrict__ adv, float* __restrict__ h1,
    float* __restrict__ a_src, float* __restrict__ a_dst, int N) {
  __shared__ float WL[128 * 128];
  int tid = threadIdx.x;
#pragma unroll
  for (int i = 0; i < 16; i++)
    ((float4*)WL)[tid + i * 256] = ((const float4*)W)[tid + i * 256];
  __syncthreads();
  int wv = tid >> 6, l = tid & 63;
  int ngroups = gridDim.x * 4;
  for (int gI = blockIdx.x * 4 + wv; gI * 4 < N; gI += ngroups) {
    int base = gI * 4;
    float h0[4], h1r[4];
#pragma unroll
    for (int n = 0; n < 4; n++) {
      int node = base + n;
      if (node < N) {
        float2 v = *(const float2*)(x + (size_t)node * XDIM + 2 * l);
        h0[n] = v.x;
        h1r[n] = v.y;
      } else {
        h0[n] = 0.0f;
        h1r[n] = 0.0f;
      }
    }
    float a0[4] = {0, 0, 0, 0}, a1[4] = {0, 0, 0, 0};
#pragma unroll 8
    for (int k2 = 0; k2 < 64; k2++) {
      float2 we = *(const float2*)&WL[(2 * k2) * 128 + 2 * l];
      float2 wo = *(const float2*)&WL[(2 * k2 + 1) * 128 + 2 * l];
#pragma unroll
      for (int n = 0; n < 4; n++) {
        float he = rlf(h0[n], k2);
        float ho = rlf(h1r[n], k2);
        a0[n] = fmaf(he, we.x, fmaf(ho, wo.x, a0[n]));
        a1[n] = fmaf(he, we.y, fmaf(ho, wo.y, a1[n]));
      }
    }
    float asw0 = asv[2 * l], asw1 = asv[2 * l + 1];
    float adw0 = adv[2 * l], adw1 = adv[2 * l + 1];
#pragma unroll
    for (int n = 0; n < 4; n++) {
      int node = base + n;
      if (node >= N) break;
      float s = scl[node];
      float y0 = a0[n] * s, y1 = a1[n] * s;
      *(float2*)(h1 + (size_t)node * FEAT + 2 * l) = make_float2(y0, y1);
      float ps = y0 * asw0 + y1 * asw1;
      float pd = y0 * adw0 + y1 * adw1;
      ps += __shfl_xor(ps, 1); ps += __shfl_xor(ps, 2); ps += __shfl_xor(ps, 4);
      pd += __shfl_xor(pd, 1); pd += __shfl_xor(pd, 2); pd += __shfl_xor(pd, 4);
      if ((l & 7) == 0) {
        a_src[node * NH + (l >> 3)] = ps;
        a_dst[node * NH + (l >> 3)] = pd;
      }
    }
  }
}

// ---------------- K4: layer-1 softmax-aggregate; h2 = relu(out+bias) -------
// wave = 1 dst node. pass1: e->LDS, max. pass2: p->LDS, denom.
// pass3: 4 edges/step, 16-lane channel slices, parallel float4 row gathers.
__global__ __launch_bounds__(256) void k_agg1(
    const int* __restrict__ offs, const int* __restrict__ csr,
    const float* __restrict__ a_src, const float* __restrict__ a_dst,
    const float* __restrict__ h1, const float* __restrict__ bias,
    float* __restrict__ h2, int N) {
  __shared__ float plds[4][8 * PS];
  __shared__ int slds[4][128];
  int wv = threadIdx.x >> 6, l = threadIdx.x & 63;
  int n = blockIdx.x * 4 + wv;
  if (n >= N) return;
  int beg = offs[n], end = offs[n + 1];
  int deg = end - beg;
  float ad[8];
#pragma unroll
  for (int h = 0; h < 8; h++) ad[h] = a_dst[(size_t)n * NH + h];
  // pass 1: e -> LDS (j<128), per-head max
  float em[8];
#pragma unroll
  for (int h = 0; h < 8; h++) em[h] = -INFINITY;
  for (int j0 = 0; j0 < deg; j0 += 64) {
    int j = j0 + l;
    if (j < deg) {
      int s = csr[beg + j];
      float4 v0 = *(const float4*)(a_src + (size_t)s * NH);
      float4 v1 = *(const float4*)(a_src + (size_t)s * NH + 4);
      float vs[8] = {v0.x, v0.y, v0.z, v0.w, v1.x, v1.y, v1.z, v1.w};
#pragma unroll
      for (int h = 0; h < 8; h++) {
        float t = vs[h] + ad[h];
        t = t > 0.0f ? t : 0.2f * t;
        em[h] = fmaxf(em[h], t);
        if (j < 128) plds[wv][h * PS + j] = t;
      }
      if (j < 128) slds[wv][j] = s;
    }
  }
#pragma unroll
  for (int h = 0; h < 8; h++)
    for (int m = 1; m < 64; m <<= 1) em[h] = fmaxf(em[h], __shfl_xor(em[h], m));
  // pass 2: p -> LDS, denom
  float sm[8] = {0, 0, 0, 0, 0, 0, 0, 0};
  for (int j0 = 0; j0 < deg; j0 += 64) {
    int j = j0 + l;
    if (j < deg) {
      if (j < 128) {
#pragma unroll
        for (int h = 0; h < 8; h++) {
          float p = __expf(plds[wv][h * PS + j] - em[h]);
          plds[wv][h * PS + j] = p;
          sm[h] += p;
        }
      } else {
        int s = csr[beg + j];
        float4 v0 = *(const float4*)(a_src + (size_t)s * NH);
        float4 v1 = *(const float4*)(a_src + (size_t)s * NH + 4);
        float vs[8] = {v0.x, v0.y, v0.z, v0.w, v1.x, v1.y, v1.z, v1.w};
#pragma unroll
        for (int h = 0; h < 8; h++) {
          float t = vs[h] + ad[h];
          t = t > 0.0f ? t : 0.2f * t;
          sm[h] += __expf(t - em[h]);
        }
      }
    }
  }
#pragma unroll
  for (int h = 0; h < 8; h++)
    for (int m = 1; m < 64; m <<= 1) sm[h] += __shfl_xor(sm[h], m);
  // pass 3: 4 edges in parallel; lane = (eg, li): edge-group eg, 8-ch slice li
  int li = l & 15, eg = l >> 4;
  int hl = li >> 1;
  float rd = 1.0f / sel8(sm, hl);
  float emh = sel8(em, hl), adh = sel8(ad, hl);
  float4 accA = {0, 0, 0, 0}, accB = {0, 0, 0, 0};
  for (int j0 = 0; j0 < deg; j0 += 4) {
    int j = j0 + eg;
    if (j < deg) {
      int s;
      float alpha;
      if (j < 128) {
        s = slds[wv][j];
        alpha = plds[wv][hl * PS + j] * rd;
      } else {
        s = csr[beg + j];
        float t = a_src[(size_t)s * NH + hl] + adh;
        t = t > 0.0f ? t : 0.2f * t;
        alpha = __expf(t - emh) * rd;
      }
      const float* hp = h1 + (size_t)s * FEAT + li * 8;
      float4 v0 = *(const float4*)hp;
      float4 v1 = *(const float4*)(hp + 4);
      accA.x = fmaf(alpha, v0.x, accA.x);
      accA.y = fmaf(alpha, v0.y, accA.y);
      accA.z = fmaf(alpha, v0.z, accA.z);
      accA.w = fmaf(alpha, v0.w, accA.w);
      accB.x = fmaf(alpha, v1.x, accB.x);
      accB.y = fmaf(alpha, v1.y, accB.y);
      accB.z = fmaf(alpha, v1.z, accB.z);
      accB.w = fmaf(alpha, v1.w, accB.w);
    }
  }
#pragma unroll
  for (int m = 16; m < 64; m <<= 1) {
    accA.x += __shfl_xor(accA.x, m);
    accA.y += __shfl_xor(accA.y, m);
    accA.z += __shfl_xor(accA.z, m);
    accA.w += __shfl_xor(accA.w, m);
    accB.x += __shfl_xor(accB.x, m);
    accB.y += __shfl_xor(accB.y, m);
    accB.z += __shfl_xor(accB.z, m);
    accB.w += __shfl_xor(accB.w, m);
  }
  if (l < 16) {
    float4 b0 = *(const float4*)(bias + l * 8);
    float4 b1v = *(const float4*)(bias + l * 8 + 4);
    float4 o0, o1;
    o0.x = fmaxf(accA.x + b0.x, 0.0f);
    o0.y = fmaxf(accA.y + b0.y, 0.0f);
    o0.z = fmaxf(accA.z + b0.z, 0.0f);
    o0.w = fmaxf(accA.w + b0.w, 0.0f);
    o1.x = fmaxf(accB.x + b1v.x, 0.0f);
    o1.y = fmaxf(accB.y + b1v.y, 0.0f);
    o1.z = fmaxf(accB.z + b1v.z, 0.0f);
    o1.w = fmaxf(accB.w + b1v.w, 0.0f);
    float* op = h2 + (size_t)n * FEAT + l * 8;
    *(float4*)op = o0;
    *(float4*)(op + 4) = o1;
  }
}

// ---------------- K5: g64 = h2 @ W2 (padded to 64 cols); a_src2/a_dst2 -----
__global__ __launch_bounds__(256) void k_gemm2(
    const float* __restrict__ h2, const float* __restrict__ W,
    const float* __restrict__ asv, const float* __restrict__ adv,
    float* __restrict__ g64, float* __restrict__ a_src,
    float* __restrict__ a_dst, int N) {
  __shared__ float WL[128 * OUTD];
  int tid = threadIdx.x;
  for (int i = tid; i < 128 * OUTD; i += 256) WL[i] = W[i];
  __syncthreads();
  int wv = tid >> 6, l = tid & 63;
  int cw = min(l, OUTD - 1);
  int ngroups = gridDim.x * 4;
  for (int gI = blockIdx.x * 4 + wv; gI * 4 < N; gI += ngroups) {
    int base = gI * 4;
    float h0[4], h1r[4];
#pragma unroll
    for (int n = 0; n < 4; n++) {
      int node = base + n;
      if (node < N) {
        float2 v = *(const float2*)(h2 + (size_t)node * FEAT + 2 * l);
        h0[n] = v.x;
        h1r[n] = v.y;
      } else {
        h0[n] = 0.0f;
        h1r[n] = 0.0f;
      }
    }
    float acc[4] = {0, 0, 0, 0};
#pragma unroll 8
    for (int k2 = 0; k2 < 64; k2++) {
      float we = WL[(2 * k2) * OUTD + cw];
      float wo = WL[(2 * k2 + 1) * OUTD + cw];
#pragma unroll
      for (int n = 0; n < 4; n++) {
        float he = rlf(h0[n], k2);
        float ho = rlf(h1r[n], k2);
        acc[n] = fmaf(he, we, fmaf(ho, wo, acc[n]));
      }
    }
    float asw = asv[cw], adw = adv[cw];
#pragma unroll
    for (int n = 0; n < 4; n++) {
      int node = base + n;
      if (node >= N) break;
      g64[(size_t)node * 64 + l] = (l < OUTD) ? acc[n] : 0.0f;
      float ps = (l < OUTD) ? acc[n] * asw : 0.0f;
      float pd = (l < OUTD) ? acc[n] * adw : 0.0f;
      for (int m = 1; m < 64; m <<= 1) {
        ps += __shfl_xor(ps, m);
        pd += __shfl_xor(pd, m);
      }
      if (l == 0) {
        a_src[node] = ps;
        a_dst[node] = pd;
      }
    }
  }
}

// ---------------- K6: layer-2 softmax-aggregate + log_softmax --------------
// wave = 1 dst node. pass3: 8 edges/step, 8-lane 8-ch slices of padded g64.
__global__ __launch_bounds__(256) void k_agg2(
    const int* __restrict__ offs, const int* __restrict__ csr,
    const float* __restrict__ a_src, const float* __restrict__ a_dst,
    const float* __restrict__ g64, const float* __restrict__ bias,
    float* __restrict__ out, int N) {
  __shared__ float plds[4][PS];
  __shared__ int slds[4][128];
  __shared__ float olds[4][64];
  int wv = threadIdx.x >> 6, l = threadIdx.x & 63;
  int n = blockIdx.x * 4 + wv;
  if (n >= N) return;
  int beg = offs[n], end = offs[n + 1];
  int deg = end - beg;
  float adn = a_dst[n];
  float em = -INFINITY;
  for (int j0 = 0; j0 < deg; j0 += 64) {
    int j = j0 + l;
    if (j < deg) {
      int s = csr[beg + j];
      float t = a_src[s] + adn;
      t = t > 0.0f ? t : 0.2f * t;
      em = fmaxf(em, t);
      if (j < 128) {
        plds[wv][j] = t;
        slds[wv][j] = s;
      }
    }
  }
  for (int m = 1; m < 64; m <<= 1) em = fmaxf(em, __shfl_xor(em, m));
  float sm = 0.0f;
  for (int j0 = 0; j0 < deg; j0 += 64) {
    int j = j0 + l;
    if (j < deg) {
      float p;
      if (j < 128) {
        p = __expf(plds[wv][j] - em);
        plds[wv][j] = p;
      } else {
        int s = csr[beg + j];
        float t = a_src[s] + adn;
        t = t > 0.0f ? t : 0.2f * t;
        p = __expf(t - em);
      }
      sm += p;
    }
  }
  for (int m = 1; m < 64; m <<= 1) sm += __shfl_xor(sm, m);
  float rd = 1.0f / sm;
  int li = l & 7, eg = l >> 3;
  float4 accA = {0, 0, 0, 0}, accB = {0, 0, 0, 0};
  for (int j0 = 0; j0 < deg; j0 += 8) {
    int j = j0 + eg;
    if (j < deg) {
      int s;
      float alpha;
      if (j < 128) {
        s = slds[wv][j];
        alpha = plds[wv][j] * rd;
      } else {
        s = csr[beg + j];
        float t = a_src[s] + adn;
        t = t > 0.0f ? t : 0.2f * t;
        alpha = __expf(t - em) * rd;
      }
      const float* gp = g64 + (size_t)s * 64 + li * 8;
      float4 v0 = *(const float4*)gp;
      float4 v1 = *(const float4*)(gp + 4);
      accA.x = fmaf(alpha, v0.x, accA.x);
      accA.y = fmaf(alpha, v0.y, accA.y);
      accA.z = fmaf(alpha, v0.z, accA.z);
      accA.w = fmaf(alpha, v0.w, accA.w);
      accB.x = fmaf(alpha, v1.x, accB.x);
      accB.y = fmaf(alpha, v1.y, accB.y);
      accB.z = fmaf(alpha, v1.z, accB.z);
      accB.w = fmaf(alpha, v1.w, accB.w);
    }
  }
#pragma unroll
  for (int m = 8; m < 64; m <<= 1) {
    accA.x += __shfl_xor(accA.x, m);
    accA.y += __shfl_xor(accA.y, m);
    accA.z += __shfl_xor(accA.z, m);
    accA.w += __shfl_xor(accA.w, m);
    accB.x += __shfl_xor(accB.x, m);
    accB.y += __shfl_xor(accB.y, m);
    accB.z += __shfl_xor(accB.z, m);
    accB.w += __shfl_xor(accB.w, m);
  }
  if (l < 8) {
    float* op = &olds[wv][l * 8];
    *(float4*)op = accA;
    *(float4*)(op + 4) = accB;
  }
  float v = (l < OUTD) ? olds[wv][l] + bias[l] : -INFINITY;
  float mx = v;
  for (int m = 1; m < 64; m <<= 1) mx = fmaxf(mx, __shfl_xor(mx, m));
  float pe = (l < OUTD) ? __expf(v - mx) : 0.0f;
  float se = pe;
  for (int m = 1; m < 64; m <<= 1) se += __shfl_xor(se, m);
  float ls = logf(se);
  if (l < OUTD) out[(size_t)n * OUTD + l] = v - mx - ls;
}

// ---------------------------------------------------------------------------
extern "C" void kernel_launch(void* const* d_in, const int* in_sizes, int n_in,
                              void* d_out, int out_size, void* d_ws,
                              size_t ws_size, hipStream_t stream) {
  const float* x = (const float*)d_in[0];
  const int* ei = (const int*)d_in[1];
  const float* mw1 = (const float*)d_in[2];
  const float* mb1 = (const float*)d_in[3];
  const float* mw2 = (const float*)d_in[4];
  const float* mb2 = (const float*)d_in[5];
  const float* W1 = (const float*)d_in[6];
  const float* as1w = (const float*)d_in[7];
  const float* ad1w = (const float*)d_in[8];
  const float* b1 = (const float*)d_in[9];
  const float* W2 = (const float*)d_in[10];
  const float* as2w = (const float*)d_in[11];
  const float* ad2w = (const float*)d_in[12];
  const float* b2 = (const float*)d_in[13];
  float* out = (float*)d_out;

  int N = in_sizes[0] / XDIM;
  int E = in_sizes[1] / 2;
  int ET = E + N;

  char* ws = (char*)d_ws;
  size_t off = 0;
  auto carve = [&](size_t bytes) -> void* {
    void* p = ws + off;
    off = (off + bytes + 255) & ~(size_t)255;
    return p;
  };
  float* stats = (float*)carve(64);
  int* deg = (int*)carve((size_t)N * 4);
  int* csum = (int*)carve((size_t)NCHUNK * 4);
  int* offs = (int*)carve((size_t)(N + 1) * 4);
  int* cur = (int*)carve((size_t)N * 4);
  int* csr = (int*)carve((size_t)ET * 4);
  float* scl = (float*)carve((size_t)N * 4);
  float* as1 = (float*)carve((size_t)N * NH * 4);
  float* ad1 = (float*)carve((size_t)N * NH * 4);
  float* h1 = (float*)carve((size_t)N * FEAT * 4);
  float* h2 = (float*)carve((size_t)N * FEAT * 4);
  float* gm = (float*)carve((size_t)N * 64 * 4);
  float* as2 = (float*)carve((size_t)N * 4);
  float* ad2 = (float*)carve((size_t)N * 4);

  // zero stats + deg (adjacent at the start of ws)
  hipMemsetAsync(d_ws, 0, 256 + (size_t)N * 4, stream);

  k_stats<<<256, 256, 0, stream>>>(x, stats, N);
  k_scale<<<(N + 255) / 256, 256, 0, stream>>>(x, stats, mw1, mb1, mw2, mb2,
                                               scl, N);
  int hb = (E + 255) / 256;
  if (hb > 4096) hb = 4096;
  k_hist<<<hb, 256, 0, stream>>>(ei, deg, E);
  k_csum1<<<NCHUNK / 128, 128, 0, stream>>>(deg, csum, N);
  k_csum2<<<1, NCHUNK, 0, stream>>>(csum);
  k_csum3<<<NCHUNK / 128, 128, 0, stream>>>(deg, csum, offs, cur, csr, N, ET);
  k_scatter<<<hb, 256, 0, stream>>>(ei, cur, csr, E);
  k_gemm1<<<1280, 256, 0, stream>>>(x, scl, W1, as1w, ad1w, h1, as1, ad1, N);
  k_agg1<<<(N + 3) / 4, 256, 0, stream>>>(offs, csr, as1, ad1, h1, b1, h2, N);
  k_gemm2<<<1280, 256, 0, stream>>>(h2, W2, as2w, ad2w, gm, as2, ad2, N);
  k_agg2<<<(N + 3) / 4, 256, 0, stream>>>(offs, csr, as2, ad2, gm, b2, out, N);
}

// Round 3
// 710.377 us; speedup vs baseline: 1.2413x; 1.0751x over previous
//
#include <hip/hip_runtime.h>

#define XDIM 134
#define FEAT 128
#define AUGN 6
#define NH 8
#define HD 16
#define OUTD 40
#define PS 132       // per-head stride in plds (132 mod 32 = 4 -> conflict-free)
#define NCHUNK 1024

__device__ __forceinline__ float sel8(const float v[8], int h) {
  float r = v[0];
  r = (h == 1) ? v[1] : r; r = (h == 2) ? v[2] : r; r = (h == 3) ? v[3] : r;
  r = (h == 4) ? v[4] : r; r = (h == 5) ? v[5] : r; r = (h == 6) ? v[6] : r;
  r = (h == 7) ? v[7] : r;
  return r;
}
__device__ __forceinline__ float rlf(float v, int lane) {
  return __int_as_float(__builtin_amdgcn_readlane(__float_as_int(v), lane));
}

// ---------------- K0: column sums/sumsq of the 6 aug columns ----------------
__global__ __launch_bounds__(256) void k_stats(const float* __restrict__ x,
                                               float* __restrict__ stats, int N) {
  float s[AUGN] = {0, 0, 0, 0, 0, 0}, q[AUGN] = {0, 0, 0, 0, 0, 0};
  for (int n = blockIdx.x * blockDim.x + threadIdx.x; n < N;
       n += gridDim.x * blockDim.x) {
    const float* r = x + (size_t)n * XDIM + FEAT;
#pragma unroll
    for (int i = 0; i < AUGN; i++) {
      float v = r[i];
      s[i] += v;
      q[i] += v * v;
    }
  }
#pragma unroll
  for (int i = 0; i < AUGN; i++) {
    for (int m = 1; m < 64; m <<= 1) {
      s[i] += __shfl_xor(s[i], m);
      q[i] += __shfl_xor(q[i], m);
    }
  }
  if ((threadIdx.x & 63) == 0) {
#pragma unroll
    for (int i = 0; i < AUGN; i++) {
      atomicAdd(&stats[i], s[i]);
      atomicAdd(&stats[8 + i], q[i]);
    }
  }
}

// ---------------- K1: per-node scale = 1 + sigmoid(MLP(norm(aug))) ----------
__global__ __launch_bounds__(256) void k_scale(
    const float* __restrict__ x, const float* __restrict__ stats,
    const float* __restrict__ w1, const float* __restrict__ b1,
    const float* __restrict__ w2, const float* __restrict__ b2,
    float* __restrict__ scl, int N) {
  int n = blockIdx.x * blockDim.x + threadIdx.x;
  if (n >= N) return;
  const float* r = x + (size_t)n * XDIM + FEAT;
  float a[AUGN];
  float invN = 1.0f / (float)N;
#pragma unroll
  for (int i = 0; i < AUGN; i++) {
    float sum = stats[i], sq = stats[8 + i];
    float mean = sum * invN;
    float var = (sq - sum * mean) / (float)(N - 1);
    a[i] = (r[i] - mean) / sqrtf(var);
  }
  float s2 = b2[0];
#pragma unroll
  for (int j = 0; j < 16; j++) {
    float z = b1[j];
#pragma unroll
    for (int i = 0; i < AUGN; i++) z = fmaf(a[i], w1[i * 16 + j], z);
    z = fmaxf(z, 0.0f);
    s2 = fmaf(z, w2[j], s2);
  }
  float sig = 1.0f / (1.0f + __expf(-s2));
  scl[n] = 1.0f + sig;
}

// ---------------- K2a: in-degree histogram (real edges only) ---------------
__global__ __launch_bounds__(256) void k_hist(const int* __restrict__ ei,
                                              int* __restrict__ deg, int E) {
  for (int e = blockIdx.x * blockDim.x + threadIdx.x; e < E;
       e += gridDim.x * blockDim.x)
    atomicAdd(&deg[ei[E + e]], 1);
}

// ---------------- K2b: 3-kernel deterministic scan of (deg+1) --------------
__global__ __launch_bounds__(128) void k_csum1(const int* __restrict__ deg,
                                               int* __restrict__ csum, int N) {
  int t = blockIdx.x * 128 + threadIdx.x;  // 8 blocks x 128 = 1024 chunks
  int chunk = (N + NCHUNK - 1) / NCHUNK;
  int lo = t * chunk, hi = min(lo + chunk, N);
  int sum = 0;
  for (int i = lo; i < hi; i++) sum += deg[i] + 1;
  csum[t] = sum;
}
__global__ __launch_bounds__(1024) void k_csum2(int* __restrict__ csum) {
  __shared__ int ps[NCHUNK];
  int t = threadIdx.x;
  ps[t] = csum[t];
  __syncthreads();
  for (int d = 1; d < NCHUNK; d <<= 1) {
    int v = (t >= d) ? ps[t - d] : 0;
    __syncthreads();
    ps[t] += v;
    __syncthreads();
  }
  csum[t] = (t == 0) ? 0 : ps[t - 1];  // exclusive
}
__global__ __launch_bounds__(128) void k_csum3(const int* __restrict__ deg,
                                               const int* __restrict__ csum,
                                               int* __restrict__ offs,
                                               int* __restrict__ cur,
                                               int* __restrict__ csr, int N,
                                               int ET) {
  int t = blockIdx.x * 128 + threadIdx.x;
  int chunk = (N + NCHUNK - 1) / NCHUNK;
  int lo = t * chunk, hi = min(lo + chunk, N);
  int run = csum[t];
  for (int i = lo; i < hi; i++) {
    offs[i] = run;
    cur[i] = run + 1;  // slot run is the self-loop
    csr[run] = i;
    run += deg[i] + 1;
  }
  if (t == 0) offs[N] = ET;
}

// ---------------- K2c: scatter src indices into CSR ------------------------
__global__ __launch_bounds__(256) void k_scatter(const int* __restrict__ ei,
                                                 int* __restrict__ cur,
                                                 int* __restrict__ csr, int E) {
  for (int e = blockIdx.x * blockDim.x + threadIdx.x; e < E;
       e += gridDim.x * blockDim.x) {
    int d = ei[E + e];
    int p = atomicAdd(&cur[d], 1);
    csr[p] = ei[e];
  }
}

// ---------------- K3: h1 = (x*scale) @ W1 ; a_src1/a_dst1 ------------------
__global__ __launch_bounds__(256) void k_gemm1(
    const float* __restrict__ x, const float* __restrict__ scl,
    const float* __restrict__ W, const float* __restrict__ asv,
    const float* __restrict__ adv, float* __restrict__ h1,
    float* __restrict__ a_src, float* __restrict__ a_dst, int N) {
  __shared__ float WL[128 * 128];
  int tid = threadIdx.x;
#pragma unroll
  for (int i = 0; i < 16; i++)
    ((float4*)WL)[tid + i * 256] = ((const float4*)W)[tid + i * 256];
  __syncthreads();
  int wv = tid >> 6, l = tid & 63;
  int ngroups = gridDim.x * 4;
  for (int gI = blockIdx.x * 4 + wv; gI * 4 < N; gI += ngroups) {
    int base = gI * 4;
    float h0[4], h1r[4];
#pragma unroll
    for (int n = 0; n < 4; n++) {
      int node = base + n;
      if (node < N) {
        float2 v = *(const float2*)(x + (size_t)node * XDIM + 2 * l);
        h0[n] = v.x;
        h1r[n] = v.y;
      } else {
        h0[n] = 0.0f;
        h1r[n] = 0.0f;
      }
    }
    float a0[4] = {0, 0, 0, 0}, a1[4] = {0, 0, 0, 0};
#pragma unroll 8
    for (int k2 = 0; k2 < 64; k2++) {
      float2 we = *(const float2*)&WL[(2 * k2) * 128 + 2 * l];
      float2 wo = *(const float2*)&WL[(2 * k2 + 1) * 128 + 2 * l];
#pragma unroll
      for (int n = 0; n < 4; n++) {
        float he = rlf(h0[n], k2);
        float ho = rlf(h1r[n], k2);
        a0[n] = fmaf(he, we.x, fmaf(ho, wo.x, a0[n]));
        a1[n] = fmaf(he, we.y, fmaf(ho, wo.y, a1[n]));
      }
    }
    float asw0 = asv[2 * l], asw1 = asv[2 * l + 1];
    float adw0 = adv[2 * l], adw1 = adv[2 * l + 1];
#pragma unroll
    for (int n = 0; n < 4; n++) {
      int node = base + n;
      if (node >= N) break;
      float s = scl[node];
      float y0 = a0[n] * s, y1 = a1[n] * s;
      *(float2*)(h1 + (size_t)node * FEAT + 2 * l) = make_float2(y0, y1);
      float ps = y0 * asw0 + y1 * asw1;
      float pd = y0 * adw0 + y1 * adw1;
      ps += __shfl_xor(ps, 1); ps += __shfl_xor(ps, 2); ps += __shfl_xor(ps, 4);
      pd += __shfl_xor(pd, 1); pd += __shfl_xor(pd, 2); pd += __shfl_xor(pd, 4);
      if ((l & 7) == 0) {
        a_src[node * NH + (l >> 3)] = ps;
        a_dst[node * NH + (l >> 3)] = pd;
      }
    }
  }
}

// ---------------- K4: layer-1 softmax-aggregate; h2 = relu(out+bias) -------
// wave = 1 dst node. pass1: e->LDS, max. pass2: raw p->LDS, denom.
// pass3: whole-wave row gathers (lane = channel pair), 4-deep prefetch,
//        normalize once at the end (no cross-lane reduce needed).
__global__ __launch_bounds__(256) void k_agg1(
    const int* __restrict__ offs, const int* __restrict__ csr,
    const float* __restrict__ a_src, const float* __restrict__ a_dst,
    const float* __restrict__ h1, const float* __restrict__ bias,
    float* __restrict__ h2, int N) {
  __shared__ float plds[4][8 * PS];
  __shared__ int slds[4][128];
  int wv = threadIdx.x >> 6, l = threadIdx.x & 63;
  int n = blockIdx.x * 4 + wv;
  if (n >= N) return;
  int beg = offs[n], end = offs[n + 1];
  int deg = end - beg;
  float ad[8];
#pragma unroll
  for (int h = 0; h < 8; h++) ad[h] = a_dst[(size_t)n * NH + h];
  // pass 1: e -> LDS (j<128), per-head max
  float em[8];
#pragma unroll
  for (int h = 0; h < 8; h++) em[h] = -INFINITY;
  for (int j0 = 0; j0 < deg; j0 += 64) {
    int j = j0 + l;
    if (j < deg) {
      int s = csr[beg + j];
      float4 v0 = *(const float4*)(a_src + (size_t)s * NH);
      float4 v1 = *(const float4*)(a_src + (size_t)s * NH + 4);
      float vs[8] = {v0.x, v0.y, v0.z, v0.w, v1.x, v1.y, v1.z, v1.w};
#pragma unroll
      for (int h = 0; h < 8; h++) {
        float t = vs[h] + ad[h];
        t = t > 0.0f ? t : 0.2f * t;
        em[h] = fmaxf(em[h], t);
        if (j < 128) plds[wv][h * PS + j] = t;
      }
      if (j < 128) slds[wv][j] = s;
    }
  }
#pragma unroll
  for (int h = 0; h < 8; h++)
    for (int m = 1; m < 64; m <<= 1) em[h] = fmaxf(em[h], __shfl_xor(em[h], m));
  // pass 2: raw p -> LDS, denom
  float sm[8] = {0, 0, 0, 0, 0, 0, 0, 0};
  for (int j0 = 0; j0 < deg; j0 += 64) {
    int j = j0 + l;
    if (j < deg) {
      if (j < 128) {
#pragma unroll
        for (int h = 0; h < 8; h++) {
          float p = __expf(plds[wv][h * PS + j] - em[h]);
          plds[wv][h * PS + j] = p;
          sm[h] += p;
        }
      } else {
        int s = csr[beg + j];
        float4 v0 = *(const float4*)(a_src + (size_t)s * NH);
        float4 v1 = *(const float4*)(a_src + (size_t)s * NH + 4);
        float vs[8] = {v0.x, v0.y, v0.z, v0.w, v1.x, v1.y, v1.z, v1.w};
#pragma unroll
        for (int h = 0; h < 8; h++) {
          float t = vs[h] + ad[h];
          t = t > 0.0f ? t : 0.2f * t;
          sm[h] += __expf(t - em[h]);
        }
      }
    }
  }
#pragma unroll
  for (int h = 0; h < 8; h++)
    for (int m = 1; m < 64; m <<= 1) sm[h] += __shfl_xor(sm[h], m);
  // pass 3: whole-wave rows, lane l owns channels {2l, 2l+1}, head = l>>3
  int hl = l >> 3;
  float rd = 1.0f / sel8(sm, hl);
  const int* sp = slds[wv];
  const float* pp = &plds[wv][hl * PS];
  const float* hb = h1 + 2 * l;
  float acc0 = 0.0f, acc1 = 0.0f;
  int jb = 0;
  if (deg <= 128) {
    if (deg >= 8) {
      int s0 = sp[0], s1 = sp[1], s2 = sp[2], s3 = sp[3];
      float2 c0 = *(const float2*)(hb + (size_t)s0 * FEAT);
      float2 c1 = *(const float2*)(hb + (size_t)s1 * FEAT);
      float2 c2 = *(const float2*)(hb + (size_t)s2 * FEAT);
      float2 c3 = *(const float2*)(hb + (size_t)s3 * FEAT);
      for (; jb + 8 <= deg; jb += 4) {
        int t0 = sp[jb + 4], t1 = sp[jb + 5], t2 = sp[jb + 6], t3 = sp[jb + 7];
        float2 n0 = *(const float2*)(hb + (size_t)t0 * FEAT);
        float2 n1 = *(const float2*)(hb + (size_t)t1 * FEAT);
        float2 n2 = *(const float2*)(hb + (size_t)t2 * FEAT);
        float2 n3 = *(const float2*)(hb + (size_t)t3 * FEAT);
        float a0 = pp[jb], a1 = pp[jb + 1], a2 = pp[jb + 2], a3 = pp[jb + 3];
        acc0 = fmaf(a0, c0.x, acc0); acc1 = fmaf(a0, c0.y, acc1);
        acc0 = fmaf(a1, c1.x, acc0); acc1 = fmaf(a1, c1.y, acc1);
        acc0 = fmaf(a2, c2.x, acc0); acc1 = fmaf(a2, c2.y, acc1);
        acc0 = fmaf(a3, c3.x, acc0); acc1 = fmaf(a3, c3.y, acc1);
        c0 = n0; c1 = n1; c2 = n2; c3 = n3;
      }
      float a0 = pp[jb], a1 = pp[jb + 1], a2 = pp[jb + 2], a3 = pp[jb + 3];
      acc0 = fmaf(a0, c0.x, acc0); acc1 = fmaf(a0, c0.y, acc1);
      acc0 = fmaf(a1, c1.x, acc0); acc1 = fmaf(a1, c1.y, acc1);
      acc0 = fmaf(a2, c2.x, acc0); acc1 = fmaf(a2, c2.y, acc1);
      acc0 = fmaf(a3, c3.x, acc0); acc1 = fmaf(a3, c3.y, acc1);
      jb += 4;
    }
    for (; jb < deg; jb++) {
      int s = sp[jb];
      float2 v = *(const float2*)(hb + (size_t)s * FEAT);
      float a = pp[jb];
      acc0 = fmaf(a, v.x, acc0);
      acc1 = fmaf(a, v.y, acc1);
    }
  } else {
    float emh = sel8(em, hl), adh = sel8(ad, hl);
    for (int j = 0; j < deg; j++) {
      int s;
      float p;
      if (j < 128) {
        s = sp[j];
        p = pp[j];
      } else {
        s = csr[beg + j];
        float t = a_src[(size_t)s * NH + hl] + adh;
        t = t > 0.0f ? t : 0.2f * t;
        p = __expf(t - emh);
      }
      float2 v = *(const float2*)(hb + (size_t)s * FEAT);
      acc0 = fmaf(p, v.x, acc0);
      acc1 = fmaf(p, v.y, acc1);
    }
  }
  acc0 *= rd;
  acc1 *= rd;
  float2 bv = *(const float2*)(bias + 2 * l);
  float o0 = fmaxf(acc0 + bv.x, 0.0f), o1 = fmaxf(acc1 + bv.y, 0.0f);
  *(float2*)(h2 + (size_t)n * FEAT + 2 * l) = make_float2(o0, o1);
}

// ---------------- K5: g64 = h2 @ W2 (padded to 64 cols); a_src2/a_dst2 -----
__global__ __launch_bounds__(256) void k_gemm2(
    const float* __restrict__ h2, const float* __restrict__ W,
    const float* __restrict__ asv, const float* __restrict__ adv,
    float* __restrict__ g64, float* __restrict__ a_src,
    float* __restrict__ a_dst, int N) {
  __shared__ float WL[128 * OUTD];
  int tid = threadIdx.x;
  for (int i = tid; i < 128 * OUTD; i += 256) WL[i] = W[i];
  __syncthreads();
  int wv = tid >> 6, l = tid & 63;
  int cw = min(l, OUTD - 1);
  int ngroups = gridDim.x * 4;
  for (int gI = blockIdx.x * 4 + wv; gI * 4 < N; gI += ngroups) {
    int base = gI * 4;
    float h0[4], h1r[4];
#pragma unroll
    for (int n = 0; n < 4; n++) {
      int node = base + n;
      if (node < N) {
        float2 v = *(const float2*)(h2 + (size_t)node * FEAT + 2 * l);
        h0[n] = v.x;
        h1r[n] = v.y;
      } else {
        h0[n] = 0.0f;
        h1r[n] = 0.0f;
      }
    }
    float acc[4] = {0, 0, 0, 0};
#pragma unroll 8
    for (int k2 = 0; k2 < 64; k2++) {
      float we = WL[(2 * k2) * OUTD + cw];
      float wo = WL[(2 * k2 + 1) * OUTD + cw];
#pragma unroll
      for (int n = 0; n < 4; n++) {
        float he = rlf(h0[n], k2);
        float ho = rlf(h1r[n], k2);
        acc[n] = fmaf(he, we, fmaf(ho, wo, acc[n]));
      }
    }
    float asw = asv[cw], adw = adv[cw];
#pragma unroll
    for (int n = 0; n < 4; n++) {
      int node = base + n;
      if (node >= N) break;
      g64[(size_t)node * 64 + l] = (l < OUTD) ? acc[n] : 0.0f;
      float ps = (l < OUTD) ? acc[n] * asw : 0.0f;
      float pd = (l < OUTD) ? acc[n] * adw : 0.0f;
      for (int m = 1; m < 64; m <<= 1) {
        ps += __shfl_xor(ps, m);
        pd += __shfl_xor(pd, m);
      }
      if (l == 0) {
        a_src[node] = ps;
        a_dst[node] = pd;
      }
    }
  }
}

// ---------------- K6: layer-2 softmax-aggregate + log_softmax --------------
// wave = 1 dst node. pass3: whole-wave rows of padded g64 (lane = column),
// wave-uniform alpha broadcast, 4-deep prefetch, normalize at end.
__global__ __launch_bounds__(256) void k_agg2(
    const int* __restrict__ offs, const int* __restrict__ csr,
    const float* __restrict__ a_src, const float* __restrict__ a_dst,
    const float* __restrict__ g64, const float* __restrict__ bias,
    float* __restrict__ out, int N) {
  __shared__ float plds[4][132];
  __shared__ int slds[4][128];
  int wv = threadIdx.x >> 6, l = threadIdx.x & 63;
  int n = blockIdx.x * 4 + wv;
  if (n >= N) return;
  int beg = offs[n], end = offs[n + 1];
  int deg = end - beg;
  float adn = a_dst[n];
  float em = -INFINITY;
  for (int j0 = 0; j0 < deg; j0 += 64) {
    int j = j0 + l;
    if (j < deg) {
      int s = csr[beg + j];
      float t = a_src[s] + adn;
      t = t > 0.0f ? t : 0.2f * t;
      em = fmaxf(em, t);
      if (j < 128) {
        plds[wv][j] = t;
        slds[wv][j] = s;
      }
    }
  }
  for (int m = 1; m < 64; m <<= 1) em = fmaxf(em, __shfl_xor(em, m));
  float sm = 0.0f;
  for (int j0 = 0; j0 < deg; j0 += 64) {
    int j = j0 + l;
    if (j < deg) {
      float p;
      if (j < 128) {
        p = __expf(plds[wv][j] - em);
        plds[wv][j] = p;
      } else {
        int s = csr[beg + j];
        float t = a_src[s] + adn;
        t = t > 0.0f ? t : 0.2f * t;
        p = __expf(t - em);
      }
      sm += p;
    }
  }
  for (int m = 1; m < 64; m <<= 1) sm += __shfl_xor(sm, m);
  float rd = 1.0f / sm;
  const int* sp = slds[wv];
  const float* pp = plds[wv];
  const float* gb = g64 + l;
  float acc = 0.0f;
  int jb = 0;
  if (deg <= 128) {
    if (deg >= 8) {
      int s0 = sp[0], s1 = sp[1], s2 = sp[2], s3 = sp[3];
      float c0 = gb[(size_t)s0 * 64];
      float c1 = gb[(size_t)s1 * 64];
      float c2 = gb[(size_t)s2 * 64];
      float c3 = gb[(size_t)s3 * 64];
      for (; jb + 8 <= deg; jb += 4) {
        int t0 = sp[jb + 4], t1 = sp[jb + 5], t2 = sp[jb + 6], t3 = sp[jb + 7];
        float n0 = gb[(size_t)t0 * 64];
        float n1 = gb[(size_t)t1 * 64];
        float n2 = gb[(size_t)t2 * 64];
        float n3 = gb[(size_t)t3 * 64];
        float a0 = pp[jb], a1 = pp[jb + 1], a2 = pp[jb + 2], a3 = pp[jb + 3];
        acc = fmaf(a0, c0, acc);
        acc = fmaf(a1, c1, acc);
        acc = fmaf(a2, c2, acc);
        acc = fmaf(a3, c3, acc);
        c0 = n0; c1 = n1; c2 = n2; c3 = n3;
      }
      float a0 = pp[jb], a1 = pp[jb + 1], a2 = pp[jb + 2], a3 = pp[jb + 3];
      acc = fmaf(a0, c0, acc);
      acc = fmaf(a1, c1, acc);
      acc = fmaf(a2, c2, acc);
      acc = fmaf(a3, c3, acc);
      jb += 4;
    }
    for (; jb < deg; jb++) {
      int s = sp[jb];
      acc = fmaf(pp[jb], gb[(size_t)s * 64], acc);
    }
  } else {
    for (int j = 0; j < deg; j++) {
      int s;
      float p;
      if (j < 128) {
        s = sp[j];
        p = pp[j];
      } else {
        s = csr[beg + j];
        float t = a_src[s] + adn;
        t = t > 0.0f ? t : 0.2f * t;
        p = __expf(t - em);
      }
      acc = fmaf(p, gb[(size_t)s * 64], acc);
    }
  }
  acc *= rd;
  float v = (l < OUTD) ? acc + bias[l] : -INFINITY;
  float mx = v;
  for (int m = 1; m < 64; m <<= 1) mx = fmaxf(mx, __shfl_xor(mx, m));
  float pe = (l < OUTD) ? __expf(v - mx) : 0.0f;
  float se = pe;
  for (int m = 1; m < 64; m <<= 1) se += __shfl_xor(se, m);
  float ls = logf(se);
  if (l < OUTD) out[(size_t)n * OUTD + l] = v - mx - ls;
}

// ---------------------------------------------------------------------------
extern "C" void kernel_launch(void* const* d_in, const int* in_sizes, int n_in,
                              void* d_out, int out_size, void* d_ws,
                              size_t ws_size, hipStream_t stream) {
  const float* x = (const float*)d_in[0];
  const int* ei = (const int*)d_in[1];
  const float* mw1 = (const float*)d_in[2];
  const float* mb1 = (const float*)d_in[3];
  const float* mw2 = (const float*)d_in[4];
  const float* mb2 = (const float*)d_in[5];
  const float* W1 = (const float*)d_in[6];
  const float* as1w = (const float*)d_in[7];
  const float* ad1w = (const float*)d_in[8];
  const float* b1 = (const float*)d_in[9];
  const float* W2 = (const float*)d_in[10];
  const float* as2w = (const float*)d_in[11];
  const float* ad2w = (const float*)d_in[12];
  const float* b2 = (const float*)d_in[13];
  float* out = (float*)d_out;

  int N = in_sizes[0] / XDIM;
  int E = in_sizes[1] / 2;
  int ET = E + N;

  char* ws = (char*)d_ws;
  size_t off = 0;
  auto carve = [&](size_t bytes) -> void* {
    void* p = ws + off;
    off = (off + bytes + 255) & ~(size_t)255;
    return p;
  };
  float* stats = (float*)carve(64);
  int* deg = (int*)carve((size_t)N * 4);
  int* csum = (int*)carve((size_t)NCHUNK * 4);
  int* offs = (int*)carve((size_t)(N + 1) * 4);
  int* cur = (int*)carve((size_t)N * 4);
  int* csr = (int*)carve((size_t)ET * 4);
  float* scl = (float*)carve((size_t)N * 4);
  float* as1 = (float*)carve((size_t)N * NH * 4);
  float* ad1 = (float*)carve((size_t)N * NH * 4);
  float* h1 = (float*)carve((size_t)N * FEAT * 4);
  float* h2 = (float*)carve((size_t)N * FEAT * 4);
  float* gm = (float*)carve((size_t)N * 64 * 4);
  float* as2 = (float*)carve((size_t)N * 4);
  float* ad2 = (float*)carve((size_t)N * 4);

  // zero stats + deg (adjacent at the start of ws)
  hipMemsetAsync(d_ws, 0, 256 + (size_t)N * 4, stream);

  k_stats<<<256, 256, 0, stream>>>(x, stats, N);
  k_scale<<<(N + 255) / 256, 256, 0, stream>>>(x, stats, mw1, mb1, mw2, mb2,
                                               scl, N);
  int hb = (E + 255) / 256;
  if (hb > 4096) hb = 4096;
  k_hist<<<hb, 256, 0, stream>>>(ei, deg, E);
  k_csum1<<<NCHUNK / 128, 128, 0, stream>>>(deg, csum, N);
  k_csum2<<<1, NCHUNK, 0, stream>>>(csum);
  k_csum3<<<NCHUNK / 128, 128, 0, stream>>>(deg, csum, offs, cur, csr, N, ET);
  k_scatter<<<hb, 256, 0, stream>>>(ei, cur, csr, E);
  k_gemm1<<<1280, 256, 0, stream>>>(x, scl, W1, as1w, ad1w, h1, as1, ad1, N);
  k_agg1<<<(N + 3) / 4, 256, 0, stream>>>(offs, csr, as1, ad1, h1, b1, h2, N);
  k_gemm2<<<1280, 256, 0, stream>>>(h2, W2, as2w, ad2w, gm, as2, ad2, N);
  k_agg2<<<(N + 3) / 4, 256, 0, stream>>>(offs, csr, as2, ad2, gm, b2, out, N);
}

// Round 4
// 649.558 us; speedup vs baseline: 1.3576x; 1.0936x over previous
//
#include <hip/hip_runtime.h>
#include <hip/hip_fp16.h>

#define XDIM 134
#define FEAT 128
#define AUGN 6
#define NH 8
#define HD 16
#define OUTD 40
#define PS 132       // per-head stride in plds (132 mod 32 = 4 -> conflict-free)
#define NCHUNK 1024

__device__ __forceinline__ float sel8(const float v[8], int h) {
  float r = v[0];
  r = (h == 1) ? v[1] : r; r = (h == 2) ? v[2] : r; r = (h == 3) ? v[3] : r;
  r = (h == 4) ? v[4] : r; r = (h == 5) ? v[5] : r; r = (h == 6) ? v[6] : r;
  r = (h == 7) ? v[7] : r;
  return r;
}
__device__ __forceinline__ float rlf(float v, int lane) {
  return __int_as_float(__builtin_amdgcn_readlane(__float_as_int(v), lane));
}

// ---------------- K0: column sums/sumsq of the 6 aug columns ----------------
__global__ __launch_bounds__(256) void k_stats(const float* __restrict__ x,
                                               float* __restrict__ stats, int N) {
  float s[AUGN] = {0, 0, 0, 0, 0, 0}, q[AUGN] = {0, 0, 0, 0, 0, 0};
  for (int n = blockIdx.x * blockDim.x + threadIdx.x; n < N;
       n += gridDim.x * blockDim.x) {
    const float* r = x + (size_t)n * XDIM + FEAT;
#pragma unroll
    for (int i = 0; i < AUGN; i++) {
      float v = r[i];
      s[i] += v;
      q[i] += v * v;
    }
  }
#pragma unroll
  for (int i = 0; i < AUGN; i++) {
    for (int m = 1; m < 64; m <<= 1) {
      s[i] += __shfl_xor(s[i], m);
      q[i] += __shfl_xor(q[i], m);
    }
  }
  if ((threadIdx.x & 63) == 0) {
#pragma unroll
    for (int i = 0; i < AUGN; i++) {
      atomicAdd(&stats[i], s[i]);
      atomicAdd(&stats[8 + i], q[i]);
    }
  }
}

// ---------------- K1: per-node scale = 1 + sigmoid(MLP(norm(aug))) ----------
__global__ __launch_bounds__(256) void k_scale(
    const float* __restrict__ x, const float* __restrict__ stats,
    const float* __restrict__ w1, const float* __restrict__ b1,
    const float* __restrict__ w2, const float* __restrict__ b2,
    float* __restrict__ scl, int N) {
  int n = blockIdx.x * blockDim.x + threadIdx.x;
  if (n >= N) return;
  const float* r = x + (size_t)n * XDIM + FEAT;
  float a[AUGN];
  float invN = 1.0f / (float)N;
#pragma unroll
  for (int i = 0; i < AUGN; i++) {
    float sum = stats[i], sq = stats[8 + i];
    float mean = sum * invN;
    float var = (sq - sum * mean) / (float)(N - 1);
    a[i] = (r[i] - mean) / sqrtf(var);
  }
  float s2 = b2[0];
#pragma unroll
  for (int j = 0; j < 16; j++) {
    float z = b1[j];
#pragma unroll
    for (int i = 0; i < AUGN; i++) z = fmaf(a[i], w1[i * 16 + j], z);
    z = fmaxf(z, 0.0f);
    s2 = fmaf(z, w2[j], s2);
  }
  float sig = 1.0f / (1.0f + __expf(-s2));
  scl[n] = 1.0f + sig;
}

// ---------------- K2a: in-degree histogram (real edges only) ---------------
__global__ __launch_bounds__(256) void k_hist(const int* __restrict__ ei,
                                              int* __restrict__ deg, int E) {
  for (int e = blockIdx.x * blockDim.x + threadIdx.x; e < E;
       e += gridDim.x * blockDim.x)
    atomicAdd(&deg[ei[E + e]], 1);
}

// ---------------- K2b: 3-kernel deterministic scan of (deg+1) --------------
__global__ __launch_bounds__(128) void k_csum1(const int* __restrict__ deg,
                                               int* __restrict__ csum, int N) {
  int t = blockIdx.x * 128 + threadIdx.x;  // 8 blocks x 128 = 1024 chunks
  int chunk = (N + NCHUNK - 1) / NCHUNK;
  int lo = t * chunk, hi = min(lo + chunk, N);
  int sum = 0;
  for (int i = lo; i < hi; i++) sum += deg[i] + 1;
  csum[t] = sum;
}
__global__ __launch_bounds__(1024) void k_csum2(int* __restrict__ csum) {
  __shared__ int ps[NCHUNK];
  int t = threadIdx.x;
  ps[t] = csum[t];
  __syncthreads();
  for (int d = 1; d < NCHUNK; d <<= 1) {
    int v = (t >= d) ? ps[t - d] : 0;
    __syncthreads();
    ps[t] += v;
    __syncthreads();
  }
  csum[t] = (t == 0) ? 0 : ps[t - 1];  // exclusive
}
__global__ __launch_bounds__(128) void k_csum3(const int* __restrict__ deg,
                                               const int* __restrict__ csum,
                                               int* __restrict__ offs,
                                               int* __restrict__ cur,
                                               int* __restrict__ csr, int N,
                                               int ET) {
  int t = blockIdx.x * 128 + threadIdx.x;
  int chunk = (N + NCHUNK - 1) / NCHUNK;
  int lo = t * chunk, hi = min(lo + chunk, N);
  int run = csum[t];
  for (int i = lo; i < hi; i++) {
    offs[i] = run;
    cur[i] = run + 1;  // slot run is the self-loop
    csr[run] = i;
    run += deg[i] + 1;
  }
  if (t == 0) offs[N] = ET;
}

// ---------------- K2c: scatter src indices into CSR ------------------------
__global__ __launch_bounds__(256) void k_scatter(const int* __restrict__ ei,
                                                 int* __restrict__ cur,
                                                 int* __restrict__ csr, int E) {
  for (int e = blockIdx.x * blockDim.x + threadIdx.x; e < E;
       e += gridDim.x * blockDim.x) {
    int d = ei[E + e];
    int p = atomicAdd(&cur[d], 1);
    csr[p] = ei[e];
  }
}

// ---------------- K3: h1(fp16) = (x*scale) @ W1 ; a_src1/a_dst1 (fp32) -----
__global__ __launch_bounds__(256) void k_gemm1(
    const float* __restrict__ x, const float* __restrict__ scl,
    const float* __restrict__ W, const float* __restrict__ asv,
    const float* __restrict__ adv, __half* __restrict__ h1h,
    float* __restrict__ a_src, float* __restrict__ a_dst, int N) {
  __shared__ float WL[128 * 128];
  int tid = threadIdx.x;
#pragma unroll
  for (int i = 0; i < 16; i++)
    ((float4*)WL)[tid + i * 256] = ((const float4*)W)[tid + i * 256];
  __syncthreads();
  int wv = tid >> 6, l = tid & 63;
  int ngroups = gridDim.x * 4;
  for (int gI = blockIdx.x * 4 + wv; gI * 4 < N; gI += ngroups) {
    int base = gI * 4;
    float h0[4], h1r[4];
#pragma unroll
    for (int n = 0; n < 4; n++) {
      int node = base + n;
      if (node < N) {
        float2 v = *(const float2*)(x + (size_t)node * XDIM + 2 * l);
        h0[n] = v.x;
        h1r[n] = v.y;
      } else {
        h0[n] = 0.0f;
        h1r[n] = 0.0f;
      }
    }
    float a0[4] = {0, 0, 0, 0}, a1[4] = {0, 0, 0, 0};
#pragma unroll 8
    for (int k2 = 0; k2 < 64; k2++) {
      float2 we = *(const float2*)&WL[(2 * k2) * 128 + 2 * l];
      float2 wo = *(const float2*)&WL[(2 * k2 + 1) * 128 + 2 * l];
#pragma unroll
      for (int n = 0; n < 4; n++) {
        float he = rlf(h0[n], k2);
        float ho = rlf(h1r[n], k2);
        a0[n] = fmaf(he, we.x, fmaf(ho, wo.x, a0[n]));
        a1[n] = fmaf(he, we.y, fmaf(ho, wo.y, a1[n]));
      }
    }
    float asw0 = asv[2 * l], asw1 = asv[2 * l + 1];
    float adw0 = adv[2 * l], adw1 = adv[2 * l + 1];
#pragma unroll
    for (int n = 0; n < 4; n++) {
      int node = base + n;
      if (node >= N) break;
      float s = scl[node];
      float y0 = a0[n] * s, y1 = a1[n] * s;
      *(__half2*)(h1h + (size_t)node * FEAT + 2 * l) =
          __float22half2_rn(make_float2(y0, y1));
      float ps = y0 * asw0 + y1 * asw1;
      float pd = y0 * adw0 + y1 * adw1;
      ps += __shfl_xor(ps, 1); ps += __shfl_xor(ps, 2); ps += __shfl_xor(ps, 4);
      pd += __shfl_xor(pd, 1); pd += __shfl_xor(pd, 2); pd += __shfl_xor(pd, 4);
      if ((l & 7) == 0) {
        a_src[node * NH + (l >> 3)] = ps;
        a_dst[node * NH + (l >> 3)] = pd;
      }
    }
  }
}

// ---------------- K4: layer-1 softmax-aggregate; h2 = relu(out+bias) -------
// No max-subtraction (|e| bounded): sweep1 computes raw p=exp(e)->LDS + denom.
// sweep2 gathers fp16 h1 rows whole-wave (lane = ch pair), 4-deep clamped
// prefetch, normalize once at the end.
__global__ __launch_bounds__(256) void k_agg1(
    const int* __restrict__ offs, const int* __restrict__ csr,
    const float* __restrict__ a_src, const float* __restrict__ a_dst,
    const __half* __restrict__ h1h, const float* __restrict__ bias,
    float* __restrict__ h2, int N) {
  __shared__ float plds[4][8 * PS];
  __shared__ int slds[4][128];
  int wv = threadIdx.x >> 6, l = threadIdx.x & 63;
  int n = blockIdx.x * 4 + wv;
  if (n >= N) return;
  int beg = offs[n], end = offs[n + 1];
  int deg = end - beg;
  float ad[8];
#pragma unroll
  for (int h = 0; h < 8; h++) ad[h] = a_dst[(size_t)n * NH + h];
  // sweep 1: raw p = exp(leaky(e)) -> LDS (j<128), denom accumulate
  float sm[8] = {0, 0, 0, 0, 0, 0, 0, 0};
  for (int j0 = 0; j0 < deg; j0 += 64) {
    int j = j0 + l;
    if (j < deg) {
      int s = csr[beg + j];
      float4 v0 = *(const float4*)(a_src + (size_t)s * NH);
      float4 v1 = *(const float4*)(a_src + (size_t)s * NH + 4);
      float vs[8] = {v0.x, v0.y, v0.z, v0.w, v1.x, v1.y, v1.z, v1.w};
#pragma unroll
      for (int h = 0; h < 8; h++) {
        float t = vs[h] + ad[h];
        t = t > 0.0f ? t : 0.2f * t;
        float p = __expf(t);
        sm[h] += p;
        if (j < 128) plds[wv][h * PS + j] = p;
      }
      if (j < 128) slds[wv][j] = s;
    }
  }
#pragma unroll
  for (int h = 0; h < 8; h++)
    for (int m = 1; m < 64; m <<= 1) sm[h] += __shfl_xor(sm[h], m);
  // sweep 2: whole-wave fp16 rows, lane l owns channels {2l, 2l+1}
  int hl = l >> 3;
  float rd = 1.0f / sel8(sm, hl);
  const int* sp = slds[wv];
  const float* pp = &plds[wv][hl * PS];
  const __half* hb = h1h + 2 * l;
  float acc0 = 0.0f, acc1 = 0.0f;
  if (deg <= 128) {
    __half2 c0, c1, c2, c3;
#define LD1(J) (*(const __half2*)(hb + (size_t)sp[min((J), deg - 1)] * FEAT))
#define AL1(J) (((J) < deg) ? pp[(J)] : 0.0f)
    c0 = LD1(0); c1 = LD1(1); c2 = LD1(2); c3 = LD1(3);
    for (int jb = 0; jb < deg; jb += 4) {
      __half2 n0 = LD1(jb + 4), n1 = LD1(jb + 5), n2 = LD1(jb + 6),
              n3 = LD1(jb + 7);
      float a0 = AL1(jb), a1 = AL1(jb + 1), a2 = AL1(jb + 2), a3 = AL1(jb + 3);
      float2 f0 = __half22float2(c0);
      float2 f1 = __half22float2(c1);
      float2 f2 = __half22float2(c2);
      float2 f3 = __half22float2(c3);
      acc0 = fmaf(a0, f0.x, acc0); acc1 = fmaf(a0, f0.y, acc1);
      acc0 = fmaf(a1, f1.x, acc0); acc1 = fmaf(a1, f1.y, acc1);
      acc0 = fmaf(a2, f2.x, acc0); acc1 = fmaf(a2, f2.y, acc1);
      acc0 = fmaf(a3, f3.x, acc0); acc1 = fmaf(a3, f3.y, acc1);
      c0 = n0; c1 = n1; c2 = n2; c3 = n3;
    }
#undef LD1
#undef AL1
  } else {
    float adh = sel8(ad, hl);
    for (int j = 0; j < deg; j++) {
      int s;
      float p;
      if (j < 128) {
        s = sp[j];
        p = pp[j];
      } else {
        s = csr[beg + j];
        float t = a_src[(size_t)s * NH + hl] + adh;
        t = t > 0.0f ? t : 0.2f * t;
        p = __expf(t);
      }
      float2 v = __half22float2(*(const __half2*)(hb + (size_t)s * FEAT));
      acc0 = fmaf(p, v.x, acc0);
      acc1 = fmaf(p, v.y, acc1);
    }
  }
  acc0 *= rd;
  acc1 *= rd;
  float2 bv = *(const float2*)(bias + 2 * l);
  float o0 = fmaxf(acc0 + bv.x, 0.0f), o1 = fmaxf(acc1 + bv.y, 0.0f);
  *(float2*)(h2 + (size_t)n * FEAT + 2 * l) = make_float2(o0, o1);
}

// ---------------- K5: g16 = h2 @ W2 (fp16, padded 64); a_src2/a_dst2 -------
__global__ __launch_bounds__(256) void k_gemm2(
    const float* __restrict__ h2, const float* __restrict__ W,
    const float* __restrict__ asv, const float* __restrict__ adv,
    __half* __restrict__ g16, float* __restrict__ a_src,
    float* __restrict__ a_dst, int N) {
  __shared__ float WL[128 * OUTD];
  int tid = threadIdx.x;
  for (int i = tid; i < 128 * OUTD; i += 256) WL[i] = W[i];
  __syncthreads();
  int wv = tid >> 6, l = tid & 63;
  int cw = min(l, OUTD - 1);
  int ngroups = gridDim.x * 4;
  for (int gI = blockIdx.x * 4 + wv; gI * 4 < N; gI += ngroups) {
    int base = gI * 4;
    float h0[4], h1r[4];
#pragma unroll
    for (int n = 0; n < 4; n++) {
      int node = base + n;
      if (node < N) {
        float2 v = *(const float2*)(h2 + (size_t)node * FEAT + 2 * l);
        h0[n] = v.x;
        h1r[n] = v.y;
      } else {
        h0[n] = 0.0f;
        h1r[n] = 0.0f;
      }
    }
    float acc[4] = {0, 0, 0, 0};
#pragma unroll 8
    for (int k2 = 0; k2 < 64; k2++) {
      float we = WL[(2 * k2) * OUTD + cw];
      float wo = WL[(2 * k2 + 1) * OUTD + cw];
#pragma unroll
      for (int n = 0; n < 4; n++) {
        float he = rlf(h0[n], k2);
        float ho = rlf(h1r[n], k2);
        acc[n] = fmaf(he, we, fmaf(ho, wo, acc[n]));
      }
    }
    float asw = asv[cw], adw = adv[cw];
#pragma unroll
    for (int n = 0; n < 4; n++) {
      int node = base + n;
      if (node >= N) break;
      g16[(size_t)node * 64 + l] =
          (l < OUTD) ? __float2half(acc[n]) : __float2half(0.0f);
      float ps = (l < OUTD) ? acc[n] * asw : 0.0f;
      float pd = (l < OUTD) ? acc[n] * adw : 0.0f;
      for (int m = 1; m < 64; m <<= 1) {
        ps += __shfl_xor(ps, m);
        pd += __shfl_xor(pd, m);
      }
      if (l == 0) {
        a_src[node] = ps;
        a_dst[node] = pd;
      }
    }
  }
}

// ---------------- K6: layer-2 softmax-aggregate + log_softmax --------------
// No max-subtraction. Gather: 2 edges/wave (eg = l>>5), lanes li=l&31 own
// col pair {2li,2li+1} of fp16 g rows; xor-32 reduce; log_softmax in-wave.
__global__ __launch_bounds__(256) void k_agg2(
    const int* __restrict__ offs, const int* __restrict__ csr,
    const float* __restrict__ a_src, const float* __restrict__ a_dst,
    const __half* __restrict__ g16, const float* __restrict__ bias,
    float* __restrict__ out, int N) {
  __shared__ float plds[4][PS];
  __shared__ int slds[4][128];
  int wv = threadIdx.x >> 6, l = threadIdx.x & 63;
  int n = blockIdx.x * 4 + wv;
  if (n >= N) return;
  int beg = offs[n], end = offs[n + 1];
  int deg = end - beg;
  float adn = a_dst[n];
  float sm = 0.0f;
  for (int j0 = 0; j0 < deg; j0 += 64) {
    int j = j0 + l;
    if (j < deg) {
      int s = csr[beg + j];
      float t = a_src[s] + adn;
      t = t > 0.0f ? t : 0.2f * t;
      float p = __expf(t);
      sm += p;
      if (j < 128) {
        plds[wv][j] = p;
        slds[wv][j] = s;
      }
    }
  }
  for (int m = 1; m < 64; m <<= 1) sm += __shfl_xor(sm, m);
  float rd = 1.0f / sm;
  const int* sp = slds[wv];
  const float* pp = plds[wv];
  int li = l & 31, eg = l >> 5;
  const __half* gb = g16 + 2 * li;
  float acc0 = 0.0f, acc1 = 0.0f;
  if (deg <= 128) {
    int ng = (deg + 1) >> 1;
    __half2 c0, c1, c2, c3;
#define LD2(G) \
  (*(const __half2*)(gb + (size_t)sp[min(2 * (G) + eg, deg - 1)] * 64))
#define AL2(G) ((2 * (G) + eg < deg) ? pp[2 * (G) + eg] : 0.0f)
    c0 = LD2(0); c1 = LD2(1); c2 = LD2(2); c3 = LD2(3);
    for (int g = 0; g < ng; g += 4) {
      __half2 n0 = LD2(g + 4), n1 = LD2(g + 5), n2 = LD2(g + 6),
              n3 = LD2(g + 7);
      float a0 = AL2(g), a1 = AL2(g + 1), a2 = AL2(g + 2), a3 = AL2(g + 3);
      float2 f0 = __half22float2(c0);
      float2 f1 = __half22float2(c1);
      float2 f2 = __half22float2(c2);
      float2 f3 = __half22float2(c3);
      acc0 = fmaf(a0, f0.x, acc0); acc1 = fmaf(a0, f0.y, acc1);
      acc0 = fmaf(a1, f1.x, acc0); acc1 = fmaf(a1, f1.y, acc1);
      acc0 = fmaf(a2, f2.x, acc0); acc1 = fmaf(a2, f2.y, acc1);
      acc0 = fmaf(a3, f3.x, acc0); acc1 = fmaf(a3, f3.y, acc1);
      c0 = n0; c1 = n1; c2 = n2; c3 = n3;
    }
#undef LD2
#undef AL2
  } else {
    for (int j = eg; j < deg; j += 2) {
      int s;
      float p;
      if (j < 128) {
        s = sp[j];
        p = pp[j];
      } else {
        s = csr[beg + j];
        float t = a_src[s] + adn;
        t = t > 0.0f ? t : 0.2f * t;
        p = __expf(t);
      }
      float2 v = __half22float2(*(const __half2*)(gb + (size_t)s * 64));
      acc0 = fmaf(p, v.x, acc0);
      acc1 = fmaf(p, v.y, acc1);
    }
  }
  // combine the two edge-halves (lanes l and l^32 hold same cols)
  acc0 += __shfl_xor(acc0, 32);
  acc1 += __shfl_xor(acc1, 32);
  bool cact = li < 20;  // cols 2li, 2li+1 < 40
  float v0 = -INFINITY, v1 = -INFINITY;
  if (cact) {
    float2 bv = *(const float2*)(bias + 2 * li);
    v0 = acc0 * rd + bv.x;
    v1 = acc1 * rd + bv.y;
  }
  float mx = fmaxf(v0, v1);
  for (int m = 1; m < 64; m <<= 1) mx = fmaxf(mx, __shfl_xor(mx, m));
  float pe = (l < 20) ? __expf(v0 - mx) + __expf(v1 - mx) : 0.0f;
  float se = pe;
  for (int m = 1; m < 64; m <<= 1) se += __shfl_xor(se, m);
  float ls = logf(se);
  if (l < 20) {
    float* op = out + (size_t)n * OUTD + 2 * l;
    op[0] = v0 - mx - ls;
    op[1] = v1 - mx - ls;
  }
}

// ---------------------------------------------------------------------------
extern "C" void kernel_launch(void* const* d_in, const int* in_sizes, int n_in,
                              void* d_out, int out_size, void* d_ws,
                              size_t ws_size, hipStream_t stream) {
  const float* x = (const float*)d_in[0];
  const int* ei = (const int*)d_in[1];
  const float* mw1 = (const float*)d_in[2];
  const float* mb1 = (const float*)d_in[3];
  const float* mw2 = (const float*)d_in[4];
  const float* mb2 = (const float*)d_in[5];
  const float* W1 = (const float*)d_in[6];
  const float* as1w = (const float*)d_in[7];
  const float* ad1w = (const float*)d_in[8];
  const float* b1 = (const float*)d_in[9];
  const float* W2 = (const float*)d_in[10];
  const float* as2w = (const float*)d_in[11];
  const float* ad2w = (const float*)d_in[12];
  const float* b2 = (const float*)d_in[13];
  float* out = (float*)d_out;

  int N = in_sizes[0] / XDIM;
  int E = in_sizes[1] / 2;
  int ET = E + N;

  char* ws = (char*)d_ws;
  size_t off = 0;
  auto carve = [&](size_t bytes) -> void* {
    void* p = ws + off;
    off = (off + bytes + 255) & ~(size_t)255;
    return p;
  };
  float* stats = (float*)carve(64);
  int* deg = (int*)carve((size_t)N * 4);
  int* csum = (int*)carve((size_t)NCHUNK * 4);
  int* offs = (int*)carve((size_t)(N + 1) * 4);
  int* cur = (int*)carve((size_t)N * 4);
  int* csr = (int*)carve((size_t)ET * 4);
  float* scl = (float*)carve((size_t)N * 4);
  float* as1 = (float*)carve((size_t)N * NH * 4);
  float* ad1 = (float*)carve((size_t)N * NH * 4);
  __half* h1h = (__half*)carve((size_t)N * FEAT * 2);
  float* h2 = (float*)carve((size_t)N * FEAT * 4);
  __half* g16 = (__half*)carve((size_t)N * 64 * 2);
  float* as2 = (float*)carve((size_t)N * 4);
  float* ad2 = (float*)carve((size_t)N * 4);

  // zero stats + deg (adjacent at the start of ws)
  hipMemsetAsync(d_ws, 0, 256 + (size_t)N * 4, stream);

  k_stats<<<256, 256, 0, stream>>>(x, stats, N);
  k_scale<<<(N + 255) / 256, 256, 0, stream>>>(x, stats, mw1, mb1, mw2, mb2,
                                               scl, N);
  int hb = (E + 255) / 256;
  if (hb > 4096) hb = 4096;
  k_hist<<<hb, 256, 0, stream>>>(ei, deg, E);
  k_csum1<<<NCHUNK / 128, 128, 0, stream>>>(deg, csum, N);
  k_csum2<<<1, NCHUNK, 0, stream>>>(csum);
  k_csum3<<<NCHUNK / 128, 128, 0, stream>>>(deg, csum, offs, cur, csr, N, ET);
  k_scatter<<<hb, 256, 0, stream>>>(ei, cur, csr, E);
  k_gemm1<<<1280, 256, 0, stream>>>(x, scl, W1, as1w, ad1w, h1h, as1, ad1, N);
  k_agg1<<<(N + 3) / 4, 256, 0, stream>>>(offs, csr, as1, ad1, h1h, b1, h2, N);
  k_gemm2<<<1280, 256, 0, stream>>>(h2, W2, as2w, ad2w, g16, as2, ad2, N);
  k_agg2<<<(N + 3) / 4, 256, 0, stream>>>(offs, csr, as2, ad2, g16, b2, out, N);
}

// Round 5
// 492.430 us; speedup vs baseline: 1.7908x; 1.3191x over previous
//
#include <hip/hip_runtime.h>
#include <hip/hip_fp16.h>

#define XDIM 134
#define FEAT 128
#define AUGN 6
#define NH 8
#define HD 16
#define OUTD 40
#define PS 132       // per-head stride in plds (132 mod 32 = 4 -> conflict-free)
#define NCHUNK 1024
#define SB 256       // stats partial blocks

__device__ __forceinline__ float sel8(const float v[8], int h) {
  float r = v[0];
  r = (h == 1) ? v[1] : r; r = (h == 2) ? v[2] : r; r = (h == 3) ? v[3] : r;
  r = (h == 4) ? v[4] : r; r = (h == 5) ? v[5] : r; r = (h == 6) ? v[6] : r;
  r = (h == 7) ? v[7] : r;
  return r;
}
__device__ __forceinline__ float rlf(float v, int lane) {
  return __int_as_float(__builtin_amdgcn_readlane(__float_as_int(v), lane));
}

// ---------------- K0a: per-block partial sums/sumsq of aug columns ---------
// No atomics: wave-reduce -> LDS cross-wave -> part[block*12 + c].
__global__ __launch_bounds__(256) void k_stats1(const float* __restrict__ x,
                                                float* __restrict__ part,
                                                int N) {
  __shared__ float red[4][12];
  float s[AUGN] = {0, 0, 0, 0, 0, 0}, q[AUGN] = {0, 0, 0, 0, 0, 0};
  for (int n = blockIdx.x * blockDim.x + threadIdx.x; n < N;
       n += gridDim.x * blockDim.x) {
    const float* r = x + (size_t)n * XDIM + FEAT;
    float2 v0 = *(const float2*)r;
    float2 v1 = *(const float2*)(r + 2);
    float2 v2 = *(const float2*)(r + 4);
    float v[AUGN] = {v0.x, v0.y, v1.x, v1.y, v2.x, v2.y};
#pragma unroll
    for (int i = 0; i < AUGN; i++) {
      s[i] += v[i];
      q[i] += v[i] * v[i];
    }
  }
#pragma unroll
  for (int i = 0; i < AUGN; i++) {
    for (int m = 1; m < 64; m <<= 1) {
      s[i] += __shfl_xor(s[i], m);
      q[i] += __shfl_xor(q[i], m);
    }
  }
  int wv = threadIdx.x >> 6, l = threadIdx.x & 63;
  if (l == 0) {
#pragma unroll
    for (int i = 0; i < AUGN; i++) {
      red[wv][i] = s[i];
      red[wv][6 + i] = q[i];
    }
  }
  __syncthreads();
  int t = threadIdx.x;
  if (t < 12) {
    part[blockIdx.x * 12 + t] =
        red[0][t] + red[1][t] + red[2][t] + red[3][t];
  }
}

// ---------------- K0b: reduce SB partials -> stats[0..5], stats[8..13] -----
__global__ __launch_bounds__(256) void k_stats2(const float* __restrict__ part,
                                                float* __restrict__ stats) {
  __shared__ float red[4][12];
  int t = threadIdx.x;
  float v[12];
#pragma unroll
  for (int c = 0; c < 12; c++) v[c] = part[t * 12 + c];
#pragma unroll
  for (int c = 0; c < 12; c++)
    for (int m = 1; m < 64; m <<= 1) v[c] += __shfl_xor(v[c], m);
  int wv = t >> 6, l = t & 63;
  if (l == 0) {
#pragma unroll
    for (int c = 0; c < 12; c++) red[wv][c] = v[c];
  }
  __syncthreads();
  if (t < 12) {
    float s = red[0][t] + red[1][t] + red[2][t] + red[3][t];
    stats[t < 6 ? t : t + 2] = s;
  }
}

// ---------------- K1: per-node scale = 1 + sigmoid(MLP(norm(aug))) ----------
__global__ __launch_bounds__(256) void k_scale(
    const float* __restrict__ x, const float* __restrict__ stats,
    const float* __restrict__ w1, const float* __restrict__ b1,
    const float* __restrict__ w2, const float* __restrict__ b2,
    float* __restrict__ scl, int N) {
  int n = blockIdx.x * blockDim.x + threadIdx.x;
  if (n >= N) return;
  const float* r = x + (size_t)n * XDIM + FEAT;
  float a[AUGN];
  float invN = 1.0f / (float)N;
#pragma unroll
  for (int i = 0; i < AUGN; i++) {
    float sum = stats[i], sq = stats[8 + i];
    float mean = sum * invN;
    float var = (sq - sum * mean) / (float)(N - 1);
    a[i] = (r[i] - mean) / sqrtf(var);
  }
  float s2 = b2[0];
#pragma unroll
  for (int j = 0; j < 16; j++) {
    float z = b1[j];
#pragma unroll
    for (int i = 0; i < AUGN; i++) z = fmaf(a[i], w1[i * 16 + j], z);
    z = fmaxf(z, 0.0f);
    s2 = fmaf(z, w2[j], s2);
  }
  float sig = 1.0f / (1.0f + __expf(-s2));
  scl[n] = 1.0f + sig;
}

// ---------------- K2a: in-degree histogram (real edges only) ---------------
__global__ __launch_bounds__(256) void k_hist(const int* __restrict__ ei,
                                              int* __restrict__ deg, int E) {
  for (int e = blockIdx.x * blockDim.x + threadIdx.x; e < E;
       e += gridDim.x * blockDim.x)
    atomicAdd(&deg[ei[E + e]], 1);
}

// ---------------- K2b: 3-kernel deterministic scan of (deg+1) --------------
__global__ __launch_bounds__(128) void k_csum1(const int* __restrict__ deg,
                                               int* __restrict__ csum, int N) {
  int t = blockIdx.x * 128 + threadIdx.x;  // 8 blocks x 128 = 1024 chunks
  int chunk = (N + NCHUNK - 1) / NCHUNK;
  int lo = t * chunk, hi = min(lo + chunk, N);
  int sum = 0;
  for (int i = lo; i < hi; i++) sum += deg[i] + 1;
  csum[t] = sum;
}
__global__ __launch_bounds__(1024) void k_csum2(int* __restrict__ csum) {
  __shared__ int ps[NCHUNK];
  int t = threadIdx.x;
  ps[t] = csum[t];
  __syncthreads();
  for (int d = 1; d < NCHUNK; d <<= 1) {
    int v = (t >= d) ? ps[t - d] : 0;
    __syncthreads();
    ps[t] += v;
    __syncthreads();
  }
  csum[t] = (t == 0) ? 0 : ps[t - 1];  // exclusive
}
__global__ __launch_bounds__(128) void k_csum3(const int* __restrict__ deg,
                                               const int* __restrict__ csum,
                                               int* __restrict__ offs,
                                               int* __restrict__ cur,
                                               int* __restrict__ csr, int N,
                                               int ET) {
  int t = blockIdx.x * 128 + threadIdx.x;
  int chunk = (N + NCHUNK - 1) / NCHUNK;
  int lo = t * chunk, hi = min(lo + chunk, N);
  int run = csum[t];
  for (int i = lo; i < hi; i++) {
    offs[i] = run;
    cur[i] = run + 1;  // slot run is the self-loop
    csr[run] = i;
    run += deg[i] + 1;
  }
  if (t == 0) offs[N] = ET;
}

// ---------------- K2c: scatter src indices into CSR ------------------------
__global__ __launch_bounds__(256) void k_scatter(const int* __restrict__ ei,
                                                 int* __restrict__ cur,
                                                 int* __restrict__ csr, int E) {
  for (int e = blockIdx.x * blockDim.x + threadIdx.x; e < E;
       e += gridDim.x * blockDim.x) {
    int d = ei[E + e];
    int p = atomicAdd(&cur[d], 1);
    csr[p] = ei[e];
  }
}

// ---------------- K3: h1(fp16) = (x*scale) @ W1 ; a_src1/a_dst1 (fp32) -----
__global__ __launch_bounds__(256) void k_gemm1(
    const float* __restrict__ x, const float* __restrict__ scl,
    const float* __restrict__ W, const float* __restrict__ asv,
    const float* __restrict__ adv, __half* __restrict__ h1h,
    float* __restrict__ a_src, float* __restrict__ a_dst, int N) {
  __shared__ float WL[128 * 128];
  int tid = threadIdx.x;
#pragma unroll
  for (int i = 0; i < 16; i++)
    ((float4*)WL)[tid + i * 256] = ((const float4*)W)[tid + i * 256];
  __syncthreads();
  int wv = tid >> 6, l = tid & 63;
  int ngroups = gridDim.x * 4;
  for (int gI = blockIdx.x * 4 + wv; gI * 4 < N; gI += ngroups) {
    int base = gI * 4;
    float h0[4], h1r[4];
#pragma unroll
    for (int n = 0; n < 4; n++) {
      int node = base + n;
      if (node < N) {
        float2 v = *(const float2*)(x + (size_t)node * XDIM + 2 * l);
        h0[n] = v.x;
        h1r[n] = v.y;
      } else {
        h0[n] = 0.0f;
        h1r[n] = 0.0f;
      }
    }
    float a0[4] = {0, 0, 0, 0}, a1[4] = {0, 0, 0, 0};
#pragma unroll 8
    for (int k2 = 0; k2 < 64; k2++) {
      float2 we = *(const float2*)&WL[(2 * k2) * 128 + 2 * l];
      float2 wo = *(const float2*)&WL[(2 * k2 + 1) * 128 + 2 * l];
#pragma unroll
      for (int n = 0; n < 4; n++) {
        float he = rlf(h0[n], k2);
        float ho = rlf(h1r[n], k2);
        a0[n] = fmaf(he, we.x, fmaf(ho, wo.x, a0[n]));
        a1[n] = fmaf(he, we.y, fmaf(ho, wo.y, a1[n]));
      }
    }
    float asw0 = asv[2 * l], asw1 = asv[2 * l + 1];
    float adw0 = adv[2 * l], adw1 = adv[2 * l + 1];
#pragma unroll
    for (int n = 0; n < 4; n++) {
      int node = base + n;
      if (node >= N) break;
      float s = scl[node];
      float y0 = a0[n] * s, y1 = a1[n] * s;
      *(__half2*)(h1h + (size_t)node * FEAT + 2 * l) =
          __float22half2_rn(make_float2(y0, y1));
      float ps = y0 * asw0 + y1 * asw1;
      float pd = y0 * adw0 + y1 * adw1;
      ps += __shfl_xor(ps, 1); ps += __shfl_xor(ps, 2); ps += __shfl_xor(ps, 4);
      pd += __shfl_xor(pd, 1); pd += __shfl_xor(pd, 2); pd += __shfl_xor(pd, 4);
      if ((l & 7) == 0) {
        a_src[node * NH + (l >> 3)] = ps;
        a_dst[node * NH + (l >> 3)] = pd;
      }
    }
  }
}

// ---------------- K4: layer-1 softmax-aggregate; h2 = relu(out+bias) -------
// No max-subtraction (|e| bounded): sweep1 computes raw p=exp(e)->LDS + denom.
// sweep2 gathers fp16 h1 rows whole-wave (lane = ch pair), 4-deep clamped
// prefetch, normalize once at the end.
__global__ __launch_bounds__(256) void k_agg1(
    const int* __restrict__ offs, const int* __restrict__ csr,
    const float* __restrict__ a_src, const float* __restrict__ a_dst,
    const __half* __restrict__ h1h, const float* __restrict__ bias,
    float* __restrict__ h2, int N) {
  __shared__ float plds[4][8 * PS];
  __shared__ int slds[4][128];
  int wv = threadIdx.x >> 6, l = threadIdx.x & 63;
  int n = blockIdx.x * 4 + wv;
  if (n >= N) return;
  int beg = offs[n], end = offs[n + 1];
  int deg = end - beg;
  float ad[8];
#pragma unroll
  for (int h = 0; h < 8; h++) ad[h] = a_dst[(size_t)n * NH + h];
  // sweep 1: raw p = exp(leaky(e)) -> LDS (j<128), denom accumulate
  float sm[8] = {0, 0, 0, 0, 0, 0, 0, 0};
  for (int j0 = 0; j0 < deg; j0 += 64) {
    int j = j0 + l;
    if (j < deg) {
      int s = csr[beg + j];
      float4 v0 = *(const float4*)(a_src + (size_t)s * NH);
      float4 v1 = *(const float4*)(a_src + (size_t)s * NH + 4);
      float vs[8] = {v0.x, v0.y, v0.z, v0.w, v1.x, v1.y, v1.z, v1.w};
#pragma unroll
      for (int h = 0; h < 8; h++) {
        float t = vs[h] + ad[h];
        t = t > 0.0f ? t : 0.2f * t;
        float p = __expf(t);
        sm[h] += p;
        if (j < 128) plds[wv][h * PS + j] = p;
      }
      if (j < 128) slds[wv][j] = s;
    }
  }
#pragma unroll
  for (int h = 0; h < 8; h++)
    for (int m = 1; m < 64; m <<= 1) sm[h] += __shfl_xor(sm[h], m);
  // sweep 2: whole-wave fp16 rows, lane l owns channels {2l, 2l+1}
  int hl = l >> 3;
  float rd = 1.0f / sel8(sm, hl);
  const int* sp = slds[wv];
  const float* pp = &plds[wv][hl * PS];
  const __half* hb = h1h + 2 * l;
  float acc0 = 0.0f, acc1 = 0.0f;
  if (deg <= 128) {
    __half2 c0, c1, c2, c3;
#define LD1(J) (*(const __half2*)(hb + (size_t)sp[min((J), deg - 1)] * FEAT))
#define AL1(J) (((J) < deg) ? pp[(J)] : 0.0f)
    c0 = LD1(0); c1 = LD1(1); c2 = LD1(2); c3 = LD1(3);
    for (int jb = 0; jb < deg; jb += 4) {
      __half2 n0 = LD1(jb + 4), n1 = LD1(jb + 5), n2 = LD1(jb + 6),
              n3 = LD1(jb + 7);
      float a0 = AL1(jb), a1 = AL1(jb + 1), a2 = AL1(jb + 2), a3 = AL1(jb + 3);
      float2 f0 = __half22float2(c0);
      float2 f1 = __half22float2(c1);
      float2 f2 = __half22float2(c2);
      float2 f3 = __half22float2(c3);
      acc0 = fmaf(a0, f0.x, acc0); acc1 = fmaf(a0, f0.y, acc1);
      acc0 = fmaf(a1, f1.x, acc0); acc1 = fmaf(a1, f1.y, acc1);
      acc0 = fmaf(a2, f2.x, acc0); acc1 = fmaf(a2, f2.y, acc1);
      acc0 = fmaf(a3, f3.x, acc0); acc1 = fmaf(a3, f3.y, acc1);
      c0 = n0; c1 = n1; c2 = n2; c3 = n3;
    }
#undef LD1
#undef AL1
  } else {
    float adh = sel8(ad, hl);
    for (int j = 0; j < deg; j++) {
      int s;
      float p;
      if (j < 128) {
        s = sp[j];
        p = pp[j];
      } else {
        s = csr[beg + j];
        float t = a_src[(size_t)s * NH + hl] + adh;
        t = t > 0.0f ? t : 0.2f * t;
        p = __expf(t);
      }
      float2 v = __half22float2(*(const __half2*)(hb + (size_t)s * FEAT));
      acc0 = fmaf(p, v.x, acc0);
      acc1 = fmaf(p, v.y, acc1);
    }
  }
  acc0 *= rd;
  acc1 *= rd;
  float2 bv = *(const float2*)(bias + 2 * l);
  float o0 = fmaxf(acc0 + bv.x, 0.0f), o1 = fmaxf(acc1 + bv.y, 0.0f);
  *(float2*)(h2 + (size_t)n * FEAT + 2 * l) = make_float2(o0, o1);
}

// ---------------- K5: g16 = h2 @ W2 (fp16, padded 64); a_src2/a_dst2 -------
__global__ __launch_bounds__(256) void k_gemm2(
    const float* __restrict__ h2, const float* __restrict__ W,
    const float* __restrict__ asv, const float* __restrict__ adv,
    __half* __restrict__ g16, float* __restrict__ a_src,
    float* __restrict__ a_dst, int N) {
  __shared__ float WL[128 * OUTD];
  int tid = threadIdx.x;
  for (int i = tid; i < 128 * OUTD; i += 256) WL[i] = W[i];
  __syncthreads();
  int wv = tid >> 6, l = tid & 63;
  int cw = min(l, OUTD - 1);
  int ngroups = gridDim.x * 4;
  for (int gI = blockIdx.x * 4 + wv; gI * 4 < N; gI += ngroups) {
    int base = gI * 4;
    float h0[4], h1r[4];
#pragma unroll
    for (int n = 0; n < 4; n++) {
      int node = base + n;
      if (node < N) {
        float2 v = *(const float2*)(h2 + (size_t)node * FEAT + 2 * l);
        h0[n] = v.x;
        h1r[n] = v.y;
      } else {
        h0[n] = 0.0f;
        h1r[n] = 0.0f;
      }
    }
    float acc[4] = {0, 0, 0, 0};
#pragma unroll 8
    for (int k2 = 0; k2 < 64; k2++) {
      float we = WL[(2 * k2) * OUTD + cw];
      float wo = WL[(2 * k2 + 1) * OUTD + cw];
#pragma unroll
      for (int n = 0; n < 4; n++) {
        float he = rlf(h0[n], k2);
        float ho = rlf(h1r[n], k2);
        acc[n] = fmaf(he, we, fmaf(ho, wo, acc[n]));
      }
    }
    float asw = asv[cw], adw = adv[cw];
#pragma unroll
    for (int n = 0; n < 4; n++) {
      int node = base + n;
      if (node >= N) break;
      g16[(size_t)node * 64 + l] =
          (l < OUTD) ? __float2half(acc[n]) : __float2half(0.0f);
      float ps = (l < OUTD) ? acc[n] * asw : 0.0f;
      float pd = (l < OUTD) ? acc[n] * adw : 0.0f;
      for (int m = 1; m < 64; m <<= 1) {
        ps += __shfl_xor(ps, m);
        pd += __shfl_xor(pd, m);
      }
      if (l == 0) {
        a_src[node] = ps;
        a_dst[node] = pd;
      }
    }
  }
}

// ---------------- K6: layer-2 softmax-aggregate + log_softmax --------------
// No max-subtraction. Gather: 2 edges/wave (eg = l>>5), lanes li=l&31 own
// col pair {2li,2li+1} of fp16 g rows; xor-32 reduce; log_softmax in-wave.
__global__ __launch_bounds__(256) void k_agg2(
    const int* __restrict__ offs, const int* __restrict__ csr,
    const float* __restrict__ a_src, const float* __restrict__ a_dst,
    const __half* __restrict__ g16, const float* __restrict__ bias,
    float* __restrict__ out, int N) {
  __shared__ float plds[4][PS];
  __shared__ int slds[4][128];
  int wv = threadIdx.x >> 6, l = threadIdx.x & 63;
  int n = blockIdx.x * 4 + wv;
  if (n >= N) return;
  int beg = offs[n], end = offs[n + 1];
  int deg = end - beg;
  float adn = a_dst[n];
  float sm = 0.0f;
  for (int j0 = 0; j0 < deg; j0 += 64) {
    int j = j0 + l;
    if (j < deg) {
      int s = csr[beg + j];
      float t = a_src[s] + adn;
      t = t > 0.0f ? t : 0.2f * t;
      float p = __expf(t);
      sm += p;
      if (j < 128) {
        plds[wv][j] = p;
        slds[wv][j] = s;
      }
    }
  }
  for (int m = 1; m < 64; m <<= 1) sm += __shfl_xor(sm, m);
  float rd = 1.0f / sm;
  const int* sp = slds[wv];
  const float* pp = plds[wv];
  int li = l & 31, eg = l >> 5;
  const __half* gb = g16 + 2 * li;
  float acc0 = 0.0f, acc1 = 0.0f;
  if (deg <= 128) {
    int ng = (deg + 1) >> 1;
    __half2 c0, c1, c2, c3;
#define LD2(G) \
  (*(const __half2*)(gb + (size_t)sp[min(2 * (G) + eg, deg - 1)] * 64))
#define AL2(G) ((2 * (G) + eg < deg) ? pp[2 * (G) + eg] : 0.0f)
    c0 = LD2(0); c1 = LD2(1); c2 = LD2(2); c3 = LD2(3);
    for (int g = 0; g < ng; g += 4) {
      __half2 n0 = LD2(g + 4), n1 = LD2(g + 5), n2 = LD2(g + 6),
              n3 = LD2(g + 7);
      float a0 = AL2(g), a1 = AL2(g + 1), a2 = AL2(g + 2), a3 = AL2(g + 3);
      float2 f0 = __half22float2(c0);
      float2 f1 = __half22float2(c1);
      float2 f2 = __half22float2(c2);
      float2 f3 = __half22float2(c3);
      acc0 = fmaf(a0, f0.x, acc0); acc1 = fmaf(a0, f0.y, acc1);
      acc0 = fmaf(a1, f1.x, acc0); acc1 = fmaf(a1, f1.y, acc1);
      acc0 = fmaf(a2, f2.x, acc0); acc1 = fmaf(a2, f2.y, acc1);
      acc0 = fmaf(a3, f3.x, acc0); acc1 = fmaf(a3, f3.y, acc1);
      c0 = n0; c1 = n1; c2 = n2; c3 = n3;
    }
#undef LD2
#undef AL2
  } else {
    for (int j = eg; j < deg; j += 2) {
      int s;
      float p;
      if (j < 128) {
        s = sp[j];
        p = pp[j];
      } else {
        s = csr[beg + j];
        float t = a_src[s] + adn;
        t = t > 0.0f ? t : 0.2f * t;
        p = __expf(t);
      }
      float2 v = __half22float2(*(const __half2*)(gb + (size_t)s * 64));
      acc0 = fmaf(p, v.x, acc0);
      acc1 = fmaf(p, v.y, acc1);
    }
  }
  // combine the two edge-halves (lanes l and l^32 hold same cols)
  acc0 += __shfl_xor(acc0, 32);
  acc1 += __shfl_xor(acc1, 32);
  bool cact = li < 20;  // cols 2li, 2li+1 < 40
  float v0 = -INFINITY, v1 = -INFINITY;
  if (cact) {
    float2 bv = *(const float2*)(bias + 2 * li);
    v0 = acc0 * rd + bv.x;
    v1 = acc1 * rd + bv.y;
  }
  float mx = fmaxf(v0, v1);
  for (int m = 1; m < 64; m <<= 1) mx = fmaxf(mx, __shfl_xor(mx, m));
  float pe = (l < 20) ? __expf(v0 - mx) + __expf(v1 - mx) : 0.0f;
  float se = pe;
  for (int m = 1; m < 64; m <<= 1) se += __shfl_xor(se, m);
  float ls = logf(se);
  if (l < 20) {
    float* op = out + (size_t)n * OUTD + 2 * l;
    op[0] = v0 - mx - ls;
    op[1] = v1 - mx - ls;
  }
}

// ---------------------------------------------------------------------------
extern "C" void kernel_launch(void* const* d_in, const int* in_sizes, int n_in,
                              void* d_out, int out_size, void* d_ws,
                              size_t ws_size, hipStream_t stream) {
  const float* x = (const float*)d_in[0];
  const int* ei = (const int*)d_in[1];
  const float* mw1 = (const float*)d_in[2];
  const float* mb1 = (const float*)d_in[3];
  const float* mw2 = (const float*)d_in[4];
  const float* mb2 = (const float*)d_in[5];
  const float* W1 = (const float*)d_in[6];
  const float* as1w = (const float*)d_in[7];
  const float* ad1w = (const float*)d_in[8];
  const float* b1 = (const float*)d_in[9];
  const float* W2 = (const float*)d_in[10];
  const float* as2w = (const float*)d_in[11];
  const float* ad2w = (const float*)d_in[12];
  const float* b2 = (const float*)d_in[13];
  float* out = (float*)d_out;

  int N = in_sizes[0] / XDIM;
  int E = in_sizes[1] / 2;
  int ET = E + N;

  char* ws = (char*)d_ws;
  size_t off = 0;
  auto carve = [&](size_t bytes) -> void* {
    void* p = ws + off;
    off = (off + bytes + 255) & ~(size_t)255;
    return p;
  };
  float* stats = (float*)carve(64);
  int* deg = (int*)carve((size_t)N * 4);
  float* part = (float*)carve((size_t)SB * 12 * 4);
  int* csum = (int*)carve((size_t)NCHUNK * 4);
  int* offs = (int*)carve((size_t)(N + 1) * 4);
  int* cur = (int*)carve((size_t)N * 4);
  int* csr = (int*)carve((size_t)ET * 4);
  float* scl = (float*)carve((size_t)N * 4);
  float* as1 = (float*)carve((size_t)N * NH * 4);
  float* ad1 = (float*)carve((size_t)N * NH * 4);
  __half* h1h = (__half*)carve((size_t)N * FEAT * 2);
  float* h2 = (float*)carve((size_t)N * FEAT * 4);
  __half* g16 = (__half*)carve((size_t)N * 64 * 2);
  float* as2 = (float*)carve((size_t)N * 4);
  float* ad2 = (float*)carve((size_t)N * 4);

  // zero deg (stats no longer needs zeroing - k_stats2 overwrites)
  hipMemsetAsync(deg, 0, (size_t)N * 4, stream);

  k_stats1<<<SB, 256, 0, stream>>>(x, part, N);
  k_stats2<<<1, 256, 0, stream>>>(part, stats);
  k_scale<<<(N + 255) / 256, 256, 0, stream>>>(x, stats, mw1, mb1, mw2, mb2,
                                               scl, N);
  int hb = (E + 255) / 256;
  if (hb > 4096) hb = 4096;
  k_hist<<<hb, 256, 0, stream>>>(ei, deg, E);
  k_csum1<<<NCHUNK / 128, 128, 0, stream>>>(deg, csum, N);
  k_csum2<<<1, NCHUNK, 0, stream>>>(csum);
  k_csum3<<<NCHUNK / 128, 128, 0, stream>>>(deg, csum, offs, cur, csr, N, ET);
  k_scatter<<<hb, 256, 0, stream>>>(ei, cur, csr, E);
  k_gemm1<<<1280, 256, 0, stream>>>(x, scl, W1, as1w, ad1w, h1h, as1, ad1, N);
  k_agg1<<<(N + 3) / 4, 256, 0, stream>>>(offs, csr, as1, ad1, h1h, b1, h2, N);
  k_gemm2<<<1280, 256, 0, stream>>>(h2, W2, as2w, ad2w, g16, as2, ad2, N);
  k_agg2<<<(N + 3) / 4, 256, 0, stream>>>(offs, csr, as2, ad2, g16, b2, out, N);
}

// Round 6
// 386.755 us; speedup vs baseline: 2.2801x; 1.2732x over previous
//
#include <hip/hip_runtime.h>
#include <hip/hip_fp16.h>

#define XDIM 134
#define FEAT 128
#define AUGN 6
#define NH 8
#define HD 16
#define OUTD 40
#define PS 132       // per-head stride in plds (132 mod 32 = 4 -> conflict-free)
#define SB 256       // stats partial blocks
#define PB 256       // partition blocks
#define MAXNB 256    // max buckets (N <= 65536)

__device__ __forceinline__ float sel8(const float v[8], int h) {
  float r = v[0];
  r = (h == 1) ? v[1] : r; r = (h == 2) ? v[2] : r; r = (h == 3) ? v[3] : r;
  r = (h == 4) ? v[4] : r; r = (h == 5) ? v[5] : r; r = (h == 6) ? v[6] : r;
  r = (h == 7) ? v[7] : r;
  return r;
}
__device__ __forceinline__ float rlf(float v, int lane) {
  return __int_as_float(__builtin_amdgcn_readlane(__float_as_int(v), lane));
}

// ---------------- K0a: per-block partial sums/sumsq of aug columns ---------
__global__ __launch_bounds__(256) void k_stats1(const float* __restrict__ x,
                                                float* __restrict__ part,
                                                int N) {
  __shared__ float red[4][12];
  float s[AUGN] = {0, 0, 0, 0, 0, 0}, q[AUGN] = {0, 0, 0, 0, 0, 0};
  for (int n = blockIdx.x * blockDim.x + threadIdx.x; n < N;
       n += gridDim.x * blockDim.x) {
    const float* r = x + (size_t)n * XDIM + FEAT;
    float2 v0 = *(const float2*)r;
    float2 v1 = *(const float2*)(r + 2);
    float2 v2 = *(const float2*)(r + 4);
    float v[AUGN] = {v0.x, v0.y, v1.x, v1.y, v2.x, v2.y};
#pragma unroll
    for (int i = 0; i < AUGN; i++) {
      s[i] += v[i];
      q[i] += v[i] * v[i];
    }
  }
#pragma unroll
  for (int i = 0; i < AUGN; i++) {
    for (int m = 1; m < 64; m <<= 1) {
      s[i] += __shfl_xor(s[i], m);
      q[i] += __shfl_xor(q[i], m);
    }
  }
  int wv = threadIdx.x >> 6, l = threadIdx.x & 63;
  if (l == 0) {
#pragma unroll
    for (int i = 0; i < AUGN; i++) {
      red[wv][i] = s[i];
      red[wv][6 + i] = q[i];
    }
  }
  __syncthreads();
  int t = threadIdx.x;
  if (t < 12) {
    part[blockIdx.x * 12 + t] =
        red[0][t] + red[1][t] + red[2][t] + red[3][t];
  }
}

// ---------------- K0b: reduce SB partials -> stats[0..5], stats[8..13] -----
__global__ __launch_bounds__(256) void k_stats2(const float* __restrict__ part,
                                                float* __restrict__ stats) {
  __shared__ float red[4][12];
  int t = threadIdx.x;
  float v[12];
#pragma unroll
  for (int c = 0; c < 12; c++) v[c] = part[t * 12 + c];
#pragma unroll
  for (int c = 0; c < 12; c++)
    for (int m = 1; m < 64; m <<= 1) v[c] += __shfl_xor(v[c], m);
  int wv = t >> 6, l = t & 63;
  if (l == 0) {
#pragma unroll
    for (int c = 0; c < 12; c++) red[wv][c] = v[c];
  }
  __syncthreads();
  if (t < 12) {
    float s = red[0][t] + red[1][t] + red[2][t] + red[3][t];
    stats[t < 6 ? t : t + 2] = s;
  }
}

// ---------------- K1: per-node scale = 1 + sigmoid(MLP(norm(aug))) ----------
__global__ __launch_bounds__(256) void k_scale(
    const float* __restrict__ x, const float* __restrict__ stats,
    const float* __restrict__ w1, const float* __restrict__ b1,
    const float* __restrict__ w2, const float* __restrict__ b2,
    float* __restrict__ scl, int N) {
  int n = blockIdx.x * blockDim.x + threadIdx.x;
  if (n >= N) return;
  const float* r = x + (size_t)n * XDIM + FEAT;
  float a[AUGN];
  float invN = 1.0f / (float)N;
#pragma unroll
  for (int i = 0; i < AUGN; i++) {
    float sum = stats[i], sq = stats[8 + i];
    float mean = sum * invN;
    float var = (sq - sum * mean) / (float)(N - 1);
    a[i] = (r[i] - mean) / sqrtf(var);
  }
  float s2 = b2[0];
#pragma unroll
  for (int j = 0; j < 16; j++) {
    float z = b1[j];
#pragma unroll
    for (int i = 0; i < AUGN; i++) z = fmaf(a[i], w1[i * 16 + j], z);
    z = fmaxf(z, 0.0f);
    s2 = fmaf(z, w2[j], s2);
  }
  float sig = 1.0f / (1.0f + __expf(-s2));
  scl[n] = 1.0f + sig;
}

// ---------------- K2a: per-(block,bucket) histogram of dst>>8 --------------
__global__ __launch_bounds__(256) void k_bh(const int* __restrict__ ei,
                                            int* __restrict__ cnt, int E,
                                            int NB) {
  __shared__ int hist[MAXNB];
  int t = threadIdx.x;
  for (int b = t; b < NB; b += 256) hist[b] = 0;
  __syncthreads();
  int ch = (E + PB - 1) / PB;
  int lo = blockIdx.x * ch, hi = min(lo + ch, E);
  for (int e = lo + t; e < hi; e += 256)
    atomicAdd(&hist[ei[E + e] >> 8], 1);
  __syncthreads();
  for (int b = t; b < NB; b += 256)
    cnt[(size_t)b * PB + blockIdx.x] = hist[b];
}

// ---------------- K2b: one-block exclusive scan of cnt[NB*PB] --------------
__global__ __launch_bounds__(1024) void k_bscan(int* __restrict__ cnt,
                                                int total) {
  __shared__ int ps[1024];
  int t = threadIdx.x;
  int chunk = (total + 1023) >> 10;
  int lo = t * chunk, hi = min(lo + chunk, total);
  int sum = 0;
  for (int i = lo; i < hi; i++) sum += cnt[i];
  ps[t] = sum;
  __syncthreads();
  for (int d = 1; d < 1024; d <<= 1) {
    int v = (t >= d) ? ps[t - d] : 0;
    __syncthreads();
    ps[t] += v;
    __syncthreads();
  }
  int run = (t == 0) ? 0 : ps[t - 1];
  for (int i = lo; i < hi; i++) {
    int v = cnt[i];
    cnt[i] = run;
    run += v;
  }
}

// ---------------- K2c: partition edges into bucket-grouped (src,dst) pairs -
__global__ __launch_bounds__(256) void k_part(const int* __restrict__ ei,
                                              const int* __restrict__ cnt,
                                              int2* __restrict__ ebuf, int E,
                                              int NB) {
  __shared__ int cur[MAXNB];
  int t = threadIdx.x;
  for (int b = t; b < NB; b += 256) cur[b] = cnt[(size_t)b * PB + blockIdx.x];
  __syncthreads();
  int ch = (E + PB - 1) / PB;
  int lo = blockIdx.x * ch, hi = min(lo + ch, E);
  for (int e = lo + t; e < hi; e += 256) {
    int s = ei[e], d = ei[E + e];
    int pos = atomicAdd(&cur[d >> 8], 1);
    ebuf[pos] = make_int2(s, d);
  }
}

// ---------------- K2d: per-bucket CSR build (contiguous region writes) -----
__global__ __launch_bounds__(256) void k_bcsr(const int2* __restrict__ ebuf,
                                              const int* __restrict__ cnt,
                                              int* __restrict__ offs,
                                              int* __restrict__ csr, int N,
                                              int E, int NB) {
  __shared__ int dl[256];
  __shared__ int sc[256];
  __shared__ int cu[256];
  int b = blockIdx.x, t = threadIdx.x;
  int nn = min(256, N - b * 256);
  int rs = cnt[(size_t)b * PB];
  int re = (b + 1 < NB) ? cnt[(size_t)(b + 1) * PB] : E;
  int csrbase = rs + b * 256;
  dl[t] = 0;
  __syncthreads();
  for (int j = rs + t; j < re; j += 256)
    atomicAdd(&dl[ebuf[j].y & 255], 1);
  __syncthreads();
  int v = (t < nn) ? dl[t] + 1 : 0;
  sc[t] = v;
  __syncthreads();
  for (int d = 1; d < 256; d <<= 1) {
    int u = (t >= d) ? sc[t - d] : 0;
    __syncthreads();
    sc[t] += u;
    __syncthreads();
  }
  int excl = sc[t] - v;
  if (t < nn) {
    int node = b * 256 + t;
    offs[node] = csrbase + excl;
    csr[csrbase + excl] = node;  // self-loop slot
    cu[t] = excl + 1;
  }
  __syncthreads();
  for (int j = rs + t; j < re; j += 256) {
    int2 e = ebuf[j];
    int p = atomicAdd(&cu[e.y & 255], 1);
    csr[csrbase + p] = e.x;
  }
  if (b == 0 && t == 0) offs[N] = E + N;
}

// ---------------- K3: h1(fp16) = (x*scale) @ W1 ; a_src1/a_dst1 (fp32) -----
__global__ __launch_bounds__(256) void k_gemm1(
    const float* __restrict__ x, const float* __restrict__ scl,
    const float* __restrict__ W, const float* __restrict__ asv,
    const float* __restrict__ adv, __half* __restrict__ h1h,
    float* __restrict__ a_src, float* __restrict__ a_dst, int N) {
  __shared__ float WL[128 * 128];
  int tid = threadIdx.x;
#pragma unroll
  for (int i = 0; i < 16; i++)
    ((float4*)WL)[tid + i * 256] = ((const float4*)W)[tid + i * 256];
  __syncthreads();
  int wv = tid >> 6, l = tid & 63;
  int ngroups = gridDim.x * 4;
  for (int gI = blockIdx.x * 4 + wv; gI * 4 < N; gI += ngroups) {
    int base = gI * 4;
    float h0[4], h1r[4];
#pragma unroll
    for (int n = 0; n < 4; n++) {
      int node = base + n;
      if (node < N) {
        float2 v = *(const float2*)(x + (size_t)node * XDIM + 2 * l);
        h0[n] = v.x;
        h1r[n] = v.y;
      } else {
        h0[n] = 0.0f;
        h1r[n] = 0.0f;
      }
    }
    float a0[4] = {0, 0, 0, 0}, a1[4] = {0, 0, 0, 0};
#pragma unroll 8
    for (int k2 = 0; k2 < 64; k2++) {
      float2 we = *(const float2*)&WL[(2 * k2) * 128 + 2 * l];
      float2 wo = *(const float2*)&WL[(2 * k2 + 1) * 128 + 2 * l];
#pragma unroll
      for (int n = 0; n < 4; n++) {
        float he = rlf(h0[n], k2);
        float ho = rlf(h1r[n], k2);
        a0[n] = fmaf(he, we.x, fmaf(ho, wo.x, a0[n]));
        a1[n] = fmaf(he, we.y, fmaf(ho, wo.y, a1[n]));
      }
    }
    float asw0 = asv[2 * l], asw1 = asv[2 * l + 1];
    float adw0 = adv[2 * l], adw1 = adv[2 * l + 1];
#pragma unroll
    for (int n = 0; n < 4; n++) {
      int node = base + n;
      if (node >= N) break;
      float s = scl[node];
      float y0 = a0[n] * s, y1 = a1[n] * s;
      *(__half2*)(h1h + (size_t)node * FEAT + 2 * l) =
          __float22half2_rn(make_float2(y0, y1));
      float ps = y0 * asw0 + y1 * asw1;
      float pd = y0 * adw0 + y1 * adw1;
      ps += __shfl_xor(ps, 1); ps += __shfl_xor(ps, 2); ps += __shfl_xor(ps, 4);
      pd += __shfl_xor(pd, 1); pd += __shfl_xor(pd, 2); pd += __shfl_xor(pd, 4);
      if ((l & 7) == 0) {
        a_src[node * NH + (l >> 3)] = ps;
        a_dst[node * NH + (l >> 3)] = pd;
      }
    }
  }
}

// ---------------- K4: layer-1 softmax-aggregate; h2 = relu(out+bias) -------
__global__ __launch_bounds__(256) void k_agg1(
    const int* __restrict__ offs, const int* __restrict__ csr,
    const float* __restrict__ a_src, const float* __restrict__ a_dst,
    const __half* __restrict__ h1h, const float* __restrict__ bias,
    float* __restrict__ h2, int N) {
  __shared__ float plds[4][8 * PS];
  __shared__ int slds[4][128];
  int wv = threadIdx.x >> 6, l = threadIdx.x & 63;
  int n = blockIdx.x * 4 + wv;
  if (n >= N) return;
  int beg = offs[n], end = offs[n + 1];
  int deg = end - beg;
  float ad[8];
#pragma unroll
  for (int h = 0; h < 8; h++) ad[h] = a_dst[(size_t)n * NH + h];
  // sweep 1: raw p = exp(leaky(e)) -> LDS (j<128), denom accumulate
  float sm[8] = {0, 0, 0, 0, 0, 0, 0, 0};
  for (int j0 = 0; j0 < deg; j0 += 64) {
    int j = j0 + l;
    if (j < deg) {
      int s = csr[beg + j];
      float4 v0 = *(const float4*)(a_src + (size_t)s * NH);
      float4 v1 = *(const float4*)(a_src + (size_t)s * NH + 4);
      float vs[8] = {v0.x, v0.y, v0.z, v0.w, v1.x, v1.y, v1.z, v1.w};
#pragma unroll
      for (int h = 0; h < 8; h++) {
        float t = vs[h] + ad[h];
        t = t > 0.0f ? t : 0.2f * t;
        float p = __expf(t);
        sm[h] += p;
        if (j < 128) plds[wv][h * PS + j] = p;
      }
      if (j < 128) slds[wv][j] = s;
    }
  }
#pragma unroll
  for (int h = 0; h < 8; h++)
    for (int m = 1; m < 64; m <<= 1) sm[h] += __shfl_xor(sm[h], m);
  // sweep 2: whole-wave fp16 rows, lane l owns channels {2l, 2l+1}
  int hl = l >> 3;
  float rd = 1.0f / sel8(sm, hl);
  const int* sp = slds[wv];
  const float* pp = &plds[wv][hl * PS];
  const __half* hb = h1h + 2 * l;
  float acc0 = 0.0f, acc1 = 0.0f;
  if (deg <= 128) {
    __half2 c0, c1, c2, c3;
#define LD1(J) (*(const __half2*)(hb + (size_t)sp[min((J), deg - 1)] * FEAT))
#define AL1(J) (((J) < deg) ? pp[(J)] : 0.0f)
    c0 = LD1(0); c1 = LD1(1); c2 = LD1(2); c3 = LD1(3);
    for (int jb = 0; jb < deg; jb += 4) {
      __half2 n0 = LD1(jb + 4), n1 = LD1(jb + 5), n2 = LD1(jb + 6),
              n3 = LD1(jb + 7);
      float a0 = AL1(jb), a1 = AL1(jb + 1), a2 = AL1(jb + 2), a3 = AL1(jb + 3);
      float2 f0 = __half22float2(c0);
      float2 f1 = __half22float2(c1);
      float2 f2 = __half22float2(c2);
      float2 f3 = __half22float2(c3);
      acc0 = fmaf(a0, f0.x, acc0); acc1 = fmaf(a0, f0.y, acc1);
      acc0 = fmaf(a1, f1.x, acc0); acc1 = fmaf(a1, f1.y, acc1);
      acc0 = fmaf(a2, f2.x, acc0); acc1 = fmaf(a2, f2.y, acc1);
      acc0 = fmaf(a3, f3.x, acc0); acc1 = fmaf(a3, f3.y, acc1);
      c0 = n0; c1 = n1; c2 = n2; c3 = n3;
    }
#undef LD1
#undef AL1
  } else {
    float adh = sel8(ad, hl);
    for (int j = 0; j < deg; j++) {
      int s;
      float p;
      if (j < 128) {
        s = sp[j];
        p = pp[j];
      } else {
        s = csr[beg + j];
        float t = a_src[(size_t)s * NH + hl] + adh;
        t = t > 0.0f ? t : 0.2f * t;
        p = __expf(t);
      }
      float2 v = __half22float2(*(const __half2*)(hb + (size_t)s * FEAT));
      acc0 = fmaf(p, v.x, acc0);
      acc1 = fmaf(p, v.y, acc1);
    }
  }
  acc0 *= rd;
  acc1 *= rd;
  float2 bv = *(const float2*)(bias + 2 * l);
  float o0 = fmaxf(acc0 + bv.x, 0.0f), o1 = fmaxf(acc1 + bv.y, 0.0f);
  *(float2*)(h2 + (size_t)n * FEAT + 2 * l) = make_float2(o0, o1);
}

// ---------------- K5: g16 = h2 @ W2 (fp16, padded 64); a_src2/a_dst2 -------
__global__ __launch_bounds__(256) void k_gemm2(
    const float* __restrict__ h2, const float* __restrict__ W,
    const float* __restrict__ asv, const float* __restrict__ adv,
    __half* __restrict__ g16, float* __restrict__ a_src,
    float* __restrict__ a_dst, int N) {
  __shared__ float WL[128 * OUTD];
  int tid = threadIdx.x;
  for (int i = tid; i < 128 * OUTD; i += 256) WL[i] = W[i];
  __syncthreads();
  int wv = tid >> 6, l = tid & 63;
  int cw = min(l, OUTD - 1);
  int ngroups = gridDim.x * 4;
  for (int gI = blockIdx.x * 4 + wv; gI * 4 < N; gI += ngroups) {
    int base = gI * 4;
    float h0[4], h1r[4];
#pragma unroll
    for (int n = 0; n < 4; n++) {
      int node = base + n;
      if (node < N) {
        float2 v = *(const float2*)(h2 + (size_t)node * FEAT + 2 * l);
        h0[n] = v.x;
        h1r[n] = v.y;
      } else {
        h0[n] = 0.0f;
        h1r[n] = 0.0f;
      }
    }
    float acc[4] = {0, 0, 0, 0};
#pragma unroll 8
    for (int k2 = 0; k2 < 64; k2++) {
      float we = WL[(2 * k2) * OUTD + cw];
      float wo = WL[(2 * k2 + 1) * OUTD + cw];
#pragma unroll
      for (int n = 0; n < 4; n++) {
        float he = rlf(h0[n], k2);
        float ho = rlf(h1r[n], k2);
        acc[n] = fmaf(he, we, fmaf(ho, wo, acc[n]));
      }
    }
    float asw = asv[cw], adw = adv[cw];
#pragma unroll
    for (int n = 0; n < 4; n++) {
      int node = base + n;
      if (node >= N) break;
      g16[(size_t)node * 64 + l] =
          (l < OUTD) ? __float2half(acc[n]) : __float2half(0.0f);
      float ps = (l < OUTD) ? acc[n] * asw : 0.0f;
      float pd = (l < OUTD) ? acc[n] * adw : 0.0f;
      for (int m = 1; m < 64; m <<= 1) {
        ps += __shfl_xor(ps, m);
        pd += __shfl_xor(pd, m);
      }
      if (l == 0) {
        a_src[node] = ps;
        a_dst[node] = pd;
      }
    }
  }
}

// ---------------- K6: layer-2 softmax-aggregate + log_softmax --------------
__global__ __launch_bounds__(256) void k_agg2(
    const int* __restrict__ offs, const int* __restrict__ csr,
    const float* __restrict__ a_src, const float* __restrict__ a_dst,
    const __half* __restrict__ g16, const float* __restrict__ bias,
    float* __restrict__ out, int N) {
  __shared__ float plds[4][PS];
  __shared__ int slds[4][128];
  int wv = threadIdx.x >> 6, l = threadIdx.x & 63;
  int n = blockIdx.x * 4 + wv;
  if (n >= N) return;
  int beg = offs[n], end = offs[n + 1];
  int deg = end - beg;
  float adn = a_dst[n];
  float sm = 0.0f;
  for (int j0 = 0; j0 < deg; j0 += 64) {
    int j = j0 + l;
    if (j < deg) {
      int s = csr[beg + j];
      float t = a_src[s] + adn;
      t = t > 0.0f ? t : 0.2f * t;
      float p = __expf(t);
      sm += p;
      if (j < 128) {
        plds[wv][j] = p;
        slds[wv][j] = s;
      }
    }
  }
  for (int m = 1; m < 64; m <<= 1) sm += __shfl_xor(sm, m);
  float rd = 1.0f / sm;
  const int* sp = slds[wv];
  const float* pp = plds[wv];
  int li = l & 31, eg = l >> 5;
  const __half* gb = g16 + 2 * li;
  float acc0 = 0.0f, acc1 = 0.0f;
  if (deg <= 128) {
    int ng = (deg + 1) >> 1;
    __half2 c0, c1, c2, c3;
#define LD2(G) \
  (*(const __half2*)(gb + (size_t)sp[min(2 * (G) + eg, deg - 1)] * 64))
#define AL2(G) ((2 * (G) + eg < deg) ? pp[2 * (G) + eg] : 0.0f)
    c0 = LD2(0); c1 = LD2(1); c2 = LD2(2); c3 = LD2(3);
    for (int g = 0; g < ng; g += 4) {
      __half2 n0 = LD2(g + 4), n1 = LD2(g + 5), n2 = LD2(g + 6),
              n3 = LD2(g + 7);
      float a0 = AL2(g), a1 = AL2(g + 1), a2 = AL2(g + 2), a3 = AL2(g + 3);
      float2 f0 = __half22float2(c0);
      float2 f1 = __half22float2(c1);
      float2 f2 = __half22float2(c2);
      float2 f3 = __half22float2(c3);
      acc0 = fmaf(a0, f0.x, acc0); acc1 = fmaf(a0, f0.y, acc1);
      acc0 = fmaf(a1, f1.x, acc0); acc1 = fmaf(a1, f1.y, acc1);
      acc0 = fmaf(a2, f2.x, acc0); acc1 = fmaf(a2, f2.y, acc1);
      acc0 = fmaf(a3, f3.x, acc0); acc1 = fmaf(a3, f3.y, acc1);
      c0 = n0; c1 = n1; c2 = n2; c3 = n3;
    }
#undef LD2
#undef AL2
  } else {
    for (int j = eg; j < deg; j += 2) {
      int s;
      float p;
      if (j < 128) {
        s = sp[j];
        p = pp[j];
      } else {
        s = csr[beg + j];
        float t = a_src[s] + adn;
        t = t > 0.0f ? t : 0.2f * t;
        p = __expf(t);
      }
      float2 v = __half22float2(*(const __half2*)(gb + (size_t)s * 64));
      acc0 = fmaf(p, v.x, acc0);
      acc1 = fmaf(p, v.y, acc1);
    }
  }
  acc0 += __shfl_xor(acc0, 32);
  acc1 += __shfl_xor(acc1, 32);
  bool cact = li < 20;  // cols 2li, 2li+1 < 40
  float v0 = -INFINITY, v1 = -INFINITY;
  if (cact) {
    float2 bv = *(const float2*)(bias + 2 * li);
    v0 = acc0 * rd + bv.x;
    v1 = acc1 * rd + bv.y;
  }
  float mx = fmaxf(v0, v1);
  for (int m = 1; m < 64; m <<= 1) mx = fmaxf(mx, __shfl_xor(mx, m));
  float pe = (l < 20) ? __expf(v0 - mx) + __expf(v1 - mx) : 0.0f;
  float se = pe;
  for (int m = 1; m < 64; m <<= 1) se += __shfl_xor(se, m);
  float ls = logf(se);
  if (l < 20) {
    float* op = out + (size_t)n * OUTD + 2 * l;
    op[0] = v0 - mx - ls;
    op[1] = v1 - mx - ls;
  }
}

// ---------------------------------------------------------------------------
extern "C" void kernel_launch(void* const* d_in, const int* in_sizes, int n_in,
                              void* d_out, int out_size, void* d_ws,
                              size_t ws_size, hipStream_t stream) {
  const float* x = (const float*)d_in[0];
  const int* ei = (const int*)d_in[1];
  const float* mw1 = (const float*)d_in[2];
  const float* mb1 = (const float*)d_in[3];
  const float* mw2 = (const float*)d_in[4];
  const float* mb2 = (const float*)d_in[5];
  const float* W1 = (const float*)d_in[6];
  const float* as1w = (const float*)d_in[7];
  const float* ad1w = (const float*)d_in[8];
  const float* b1 = (const float*)d_in[9];
  const float* W2 = (const float*)d_in[10];
  const float* as2w = (const float*)d_in[11];
  const float* ad2w = (const float*)d_in[12];
  const float* b2 = (const float*)d_in[13];
  float* out = (float*)d_out;

  int N = in_sizes[0] / XDIM;
  int E = in_sizes[1] / 2;
  int ET = E + N;
  int NB = (N + 255) >> 8;  // dst buckets of 256 nodes

  char* ws = (char*)d_ws;
  size_t off = 0;
  auto carve = [&](size_t bytes) -> void* {
    void* p = ws + off;
    off = (off + bytes + 255) & ~(size_t)255;
    return p;
  };
  float* stats = (float*)carve(64);
  float* part = (float*)carve((size_t)SB * 12 * 4);
  int* cnt = (int*)carve((size_t)NB * PB * 4);
  int2* ebuf = (int2*)carve((size_t)E * 8);
  int* offs = (int*)carve((size_t)(N + 1) * 4);
  int* csr = (int*)carve((size_t)ET * 4);
  float* scl = (float*)carve((size_t)N * 4);
  float* as1 = (float*)carve((size_t)N * NH * 4);
  float* ad1 = (float*)carve((size_t)N * NH * 4);
  __half* h1h = (__half*)carve((size_t)N * FEAT * 2);
  float* h2 = (float*)carve((size_t)N * FEAT * 4);
  __half* g16 = (__half*)carve((size_t)N * 64 * 2);
  float* as2 = (float*)carve((size_t)N * 4);
  float* ad2 = (float*)carve((size_t)N * 4);

  k_stats1<<<SB, 256, 0, stream>>>(x, part, N);
  k_stats2<<<1, 256, 0, stream>>>(part, stats);
  k_scale<<<(N + 255) / 256, 256, 0, stream>>>(x, stats, mw1, mb1, mw2, mb2,
                                               scl, N);
  k_bh<<<PB, 256, 0, stream>>>(ei, cnt, E, NB);
  k_bscan<<<1, 1024, 0, stream>>>(cnt, NB * PB);
  k_part<<<PB, 256, 0, stream>>>(ei, cnt, ebuf, E, NB);
  k_bcsr<<<NB, 256, 0, stream>>>(ebuf, cnt, offs, csr, N, E, NB);
  k_gemm1<<<1280, 256, 0, stream>>>(x, scl, W1, as1w, ad1w, h1h, as1, ad1, N);
  k_agg1<<<(N + 3) / 4, 256, 0, stream>>>(offs, csr, as1, ad1, h1h, b1, h2, N);
  k_gemm2<<<1280, 256, 0, stream>>>(h2, W2, as2w, ad2w, g16, as2, ad2, N);
  k_agg2<<<(N + 3) / 4, 256, 0, stream>>>(offs, csr, as2, ad2, g16, b2, out, N);
}

// Round 7
// 351.455 us; speedup vs baseline: 2.5091x; 1.1004x over previous
//
#include <hip/hip_runtime.h>
#include <hip/hip_fp16.h>

#define XDIM 134
#define FEAT 128
#define AUGN 6
#define NH 8
#define HD 16
#define OUTD 40
#define PS 132       // per-head stride in plds (132 mod 32 = 4 -> conflict-free)
#define SB 256       // stats partial blocks
#define PB 256       // partition blocks
#define MAXNB 256    // max buckets (N <= 65536)
#define GST 40       // g row stride in halfs (80 B)

typedef float v2f __attribute__((ext_vector_type(2)));

__device__ __forceinline__ float sel8(const float v[8], int h) {
  float r = v[0];
  r = (h == 1) ? v[1] : r; r = (h == 2) ? v[2] : r; r = (h == 3) ? v[3] : r;
  r = (h == 4) ? v[4] : r; r = (h == 5) ? v[5] : r; r = (h == 6) ? v[6] : r;
  r = (h == 7) ? v[7] : r;
  return r;
}
__device__ __forceinline__ float rlf(float v, int lane) {
  return __int_as_float(__builtin_amdgcn_readlane(__float_as_int(v), lane));
}

// ---------------- K0a: per-block partial sums/sumsq of aug columns ---------
__global__ __launch_bounds__(256) void k_stats1(const float* __restrict__ x,
                                                float* __restrict__ part,
                                                int N) {
  __shared__ float red[4][12];
  float s[AUGN] = {0, 0, 0, 0, 0, 0}, q[AUGN] = {0, 0, 0, 0, 0, 0};
  for (int n = blockIdx.x * blockDim.x + threadIdx.x; n < N;
       n += gridDim.x * blockDim.x) {
    const float* r = x + (size_t)n * XDIM + FEAT;
    float2 v0 = *(const float2*)r;
    float2 v1 = *(const float2*)(r + 2);
    float2 v2 = *(const float2*)(r + 4);
    float v[AUGN] = {v0.x, v0.y, v1.x, v1.y, v2.x, v2.y};
#pragma unroll
    for (int i = 0; i < AUGN; i++) {
      s[i] += v[i];
      q[i] += v[i] * v[i];
    }
  }
#pragma unroll
  for (int i = 0; i < AUGN; i++) {
    for (int m = 1; m < 64; m <<= 1) {
      s[i] += __shfl_xor(s[i], m);
      q[i] += __shfl_xor(q[i], m);
    }
  }
  int wv = threadIdx.x >> 6, l = threadIdx.x & 63;
  if (l == 0) {
#pragma unroll
    for (int i = 0; i < AUGN; i++) {
      red[wv][i] = s[i];
      red[wv][6 + i] = q[i];
    }
  }
  __syncthreads();
  int t = threadIdx.x;
  if (t < 12) {
    part[blockIdx.x * 12 + t] =
        red[0][t] + red[1][t] + red[2][t] + red[3][t];
  }
}

// ---------------- K0b: reduce SB partials -> stats[0..5], stats[8..13] -----
__global__ __launch_bounds__(256) void k_stats2(const float* __restrict__ part,
                                                float* __restrict__ stats) {
  __shared__ float red[4][12];
  int t = threadIdx.x;
  float v[12];
#pragma unroll
  for (int c = 0; c < 12; c++) v[c] = part[t * 12 + c];
#pragma unroll
  for (int c = 0; c < 12; c++)
    for (int m = 1; m < 64; m <<= 1) v[c] += __shfl_xor(v[c], m);
  int wv = t >> 6, l = t & 63;
  if (l == 0) {
#pragma unroll
    for (int c = 0; c < 12; c++) red[wv][c] = v[c];
  }
  __syncthreads();
  if (t < 12) {
    float s = red[0][t] + red[1][t] + red[2][t] + red[3][t];
    stats[t < 6 ? t : t + 2] = s;
  }
}

// ---------------- K1: per-node scale = 1 + sigmoid(MLP(norm(aug))) ----------
__global__ __launch_bounds__(256) void k_scale(
    const float* __restrict__ x, const float* __restrict__ stats,
    const float* __restrict__ w1, const float* __restrict__ b1,
    const float* __restrict__ w2, const float* __restrict__ b2,
    float* __restrict__ scl, int N) {
  int n = blockIdx.x * blockDim.x + threadIdx.x;
  if (n >= N) return;
  const float* r = x + (size_t)n * XDIM + FEAT;
  float a[AUGN];
  float invN = 1.0f / (float)N;
#pragma unroll
  for (int i = 0; i < AUGN; i++) {
    float sum = stats[i], sq = stats[8 + i];
    float mean = sum * invN;
    float var = (sq - sum * mean) / (float)(N - 1);
    a[i] = (r[i] - mean) / sqrtf(var);
  }
  float s2 = b2[0];
#pragma unroll
  for (int j = 0; j < 16; j++) {
    float z = b1[j];
#pragma unroll
    for (int i = 0; i < AUGN; i++) z = fmaf(a[i], w1[i * 16 + j], z);
    z = fmaxf(z, 0.0f);
    s2 = fmaf(z, w2[j], s2);
  }
  float sig = 1.0f / (1.0f + __expf(-s2));
  scl[n] = 1.0f + sig;
}

// ---------------- K2a: per-(block,bucket) histogram of dst>>8 --------------
__global__ __launch_bounds__(256) void k_bh(const int* __restrict__ ei,
                                            int* __restrict__ cnt, int E,
                                            int NB) {
  __shared__ int hist[MAXNB];
  int t = threadIdx.x;
  for (int b = t; b < NB; b += 256) hist[b] = 0;
  __syncthreads();
  int ch = (E + PB - 1) / PB;
  int lo = blockIdx.x * ch, hi = min(lo + ch, E);
  for (int e = lo + t; e < hi; e += 256)
    atomicAdd(&hist[ei[E + e] >> 8], 1);
  __syncthreads();
  for (int b = t; b < NB; b += 256)
    cnt[(size_t)b * PB + blockIdx.x] = hist[b];
}

// ---------------- K2b: one-block exclusive scan of cnt[NB*PB] --------------
__global__ __launch_bounds__(1024) void k_bscan(int* __restrict__ cnt,
                                                int total) {
  __shared__ int ps[1024];
  int t = threadIdx.x;
  int chunk = (total + 1023) >> 10;
  int lo = t * chunk, hi = min(lo + chunk, total);
  int sum = 0;
  for (int i = lo; i < hi; i++) sum += cnt[i];
  ps[t] = sum;
  __syncthreads();
  for (int d = 1; d < 1024; d <<= 1) {
    int v = (t >= d) ? ps[t - d] : 0;
    __syncthreads();
    ps[t] += v;
    __syncthreads();
  }
  int run = (t == 0) ? 0 : ps[t - 1];
  for (int i = lo; i < hi; i++) {
    int v = cnt[i];
    cnt[i] = run;
    run += v;
  }
}

// ---------------- K2c: partition edges into bucket-grouped (src,dst) pairs -
__global__ __launch_bounds__(256) void k_part(const int* __restrict__ ei,
                                              const int* __restrict__ cnt,
                                              int2* __restrict__ ebuf, int E,
                                              int NB) {
  __shared__ int cur[MAXNB];
  int t = threadIdx.x;
  for (int b = t; b < NB; b += 256) cur[b] = cnt[(size_t)b * PB + blockIdx.x];
  __syncthreads();
  int ch = (E + PB - 1) / PB;
  int lo = blockIdx.x * ch, hi = min(lo + ch, E);
  for (int e = lo + t; e < hi; e += 256) {
    int s = ei[e], d = ei[E + e];
    int pos = atomicAdd(&cur[d >> 8], 1);
    ebuf[pos] = make_int2(s, d);
  }
}

// ---------------- K2d: per-bucket CSR build (contiguous region writes) -----
__global__ __launch_bounds__(256) void k_bcsr(const int2* __restrict__ ebuf,
                                              const int* __restrict__ cnt,
                                              int* __restrict__ offs,
                                              int* __restrict__ csr, int N,
                                              int E, int NB) {
  __shared__ int dl[256];
  __shared__ int sc[256];
  __shared__ int cu[256];
  int b = blockIdx.x, t = threadIdx.x;
  int nn = min(256, N - b * 256);
  int rs = cnt[(size_t)b * PB];
  int re = (b + 1 < NB) ? cnt[(size_t)(b + 1) * PB] : E;
  int csrbase = rs + b * 256;
  dl[t] = 0;
  __syncthreads();
  for (int j = rs + t; j < re; j += 256)
    atomicAdd(&dl[ebuf[j].y & 255], 1);
  __syncthreads();
  int v = (t < nn) ? dl[t] + 1 : 0;
  sc[t] = v;
  __syncthreads();
  for (int d = 1; d < 256; d <<= 1) {
    int u = (t >= d) ? sc[t - d] : 0;
    __syncthreads();
    sc[t] += u;
    __syncthreads();
  }
  int excl = sc[t] - v;
  if (t < nn) {
    int node = b * 256 + t;
    offs[node] = csrbase + excl;
    csr[csrbase + excl] = node;  // self-loop slot
    cu[t] = excl + 1;
  }
  __syncthreads();
  for (int j = rs + t; j < re; j += 256) {
    int2 e = ebuf[j];
    int p = atomicAdd(&cu[e.y & 255], 1);
    csr[csrbase + p] = e.x;
  }
  if (b == 0 && t == 0) offs[N] = E + N;
}

// ---------------- K3: h1(fp8 e4m3) = (x*scale) @ W1 ; scores fp32 ----------
__global__ __launch_bounds__(256) void k_gemm1(
    const float* __restrict__ x, const float* __restrict__ scl,
    const float* __restrict__ W, const float* __restrict__ asv,
    const float* __restrict__ adv, unsigned char* __restrict__ h8,
    float* __restrict__ a_src, float* __restrict__ a_dst, int N) {
  __shared__ float WL[128 * 128];
  int tid = threadIdx.x;
#pragma unroll
  for (int i = 0; i < 16; i++)
    ((float4*)WL)[tid + i * 256] = ((const float4*)W)[tid + i * 256];
  __syncthreads();
  int wv = tid >> 6, l = tid & 63;
  int ngroups = gridDim.x * 4;
  for (int gI = blockIdx.x * 4 + wv; gI * 4 < N; gI += ngroups) {
    int base = gI * 4;
    float h0[4], h1r[4];
#pragma unroll
    for (int n = 0; n < 4; n++) {
      int node = base + n;
      if (node < N) {
        float2 v = *(const float2*)(x + (size_t)node * XDIM + 2 * l);
        h0[n] = v.x;
        h1r[n] = v.y;
      } else {
        h0[n] = 0.0f;
        h1r[n] = 0.0f;
      }
    }
    float a0[4] = {0, 0, 0, 0}, a1[4] = {0, 0, 0, 0};
#pragma unroll 8
    for (int k2 = 0; k2 < 64; k2++) {
      float2 we = *(const float2*)&WL[(2 * k2) * 128 + 2 * l];
      float2 wo = *(const float2*)&WL[(2 * k2 + 1) * 128 + 2 * l];
#pragma unroll
      for (int n = 0; n < 4; n++) {
        float he = rlf(h0[n], k2);
        float ho = rlf(h1r[n], k2);
        a0[n] = fmaf(he, we.x, fmaf(ho, wo.x, a0[n]));
        a1[n] = fmaf(he, we.y, fmaf(ho, wo.y, a1[n]));
      }
    }
    float asw0 = asv[2 * l], asw1 = asv[2 * l + 1];
    float adw0 = adv[2 * l], adw1 = adv[2 * l + 1];
#pragma unroll
    for (int n = 0; n < 4; n++) {
      int node = base + n;
      if (node >= N) break;
      float s = scl[node];
      float y0 = a0[n] * s, y1 = a1[n] * s;
      int pk = __builtin_amdgcn_cvt_pk_fp8_f32(y0, y1, 0, false);
      ((unsigned short*)(h8 + (size_t)node * FEAT))[l] = (unsigned short)pk;
      float ps = y0 * asw0 + y1 * asw1;
      float pd = y0 * adw0 + y1 * adw1;
      ps += __shfl_xor(ps, 1); ps += __shfl_xor(ps, 2); ps += __shfl_xor(ps, 4);
      pd += __shfl_xor(pd, 1); pd += __shfl_xor(pd, 2); pd += __shfl_xor(pd, 4);
      if ((l & 7) == 0) {
        a_src[node * NH + (l >> 3)] = ps;
        a_dst[node * NH + (l >> 3)] = pd;
      }
    }
  }
}

// ---------------- K4: layer-1 softmax-aggregate; h2 = relu(out+bias) -------
// sweep1: raw p=exp(leaky(e)) -> LDS + denom. sweep2: fp8 row gather
// (lane = ch pair, 1 ushort/lane), 8-deep clamped prefetch, hw fp8 decode.
__global__ __launch_bounds__(256) void k_agg1(
    const int* __restrict__ offs, const int* __restrict__ csr,
    const float* __restrict__ a_src, const float* __restrict__ a_dst,
    const unsigned char* __restrict__ h8, const float* __restrict__ bias,
    float* __restrict__ h2, int N) {
  __shared__ float plds[4][8 * PS];
  __shared__ int slds[4][128];
  int wv = threadIdx.x >> 6, l = threadIdx.x & 63;
  int n = blockIdx.x * 4 + wv;
  if (n >= N) return;
  int beg = offs[n], end = offs[n + 1];
  int deg = end - beg;
  float ad[8];
#pragma unroll
  for (int h = 0; h < 8; h++) ad[h] = a_dst[(size_t)n * NH + h];
  // sweep 1
  float sm[8] = {0, 0, 0, 0, 0, 0, 0, 0};
  for (int j0 = 0; j0 < deg; j0 += 64) {
    int j = j0 + l;
    if (j < deg) {
      int s = csr[beg + j];
      float4 v0 = *(const float4*)(a_src + (size_t)s * NH);
      float4 v1 = *(const float4*)(a_src + (size_t)s * NH + 4);
      float vs[8] = {v0.x, v0.y, v0.z, v0.w, v1.x, v1.y, v1.z, v1.w};
#pragma unroll
      for (int h = 0; h < 8; h++) {
        float t = vs[h] + ad[h];
        t = t > 0.0f ? t : 0.2f * t;
        float p = __expf(t);
        sm[h] += p;
        if (j < 128) plds[wv][h * PS + j] = p;
      }
      if (j < 128) slds[wv][j] = s;
    }
  }
#pragma unroll
  for (int h = 0; h < 8; h++)
    for (int m = 1; m < 64; m <<= 1) sm[h] += __shfl_xor(sm[h], m);
  // sweep 2: fp8 rows, lane l owns channels {2l, 2l+1}
  int hl = l >> 3;
  float rd = 1.0f / sel8(sm, hl);
  const int* sp = slds[wv];
  const float* pp = &plds[wv][hl * PS];
  float acc0 = 0.0f, acc1 = 0.0f;
  if (deg <= 128) {
    int dm1 = deg - 1;
    unsigned short cur[8], nxt[8];
#define ROW(J) (((const unsigned short*)(h8 + (size_t)sp[min((J), dm1)] * FEAT))[l])
#pragma unroll
    for (int i = 0; i < 8; i++) cur[i] = ROW(i);
    for (int jb = 0; jb < deg; jb += 8) {
#pragma unroll
      for (int i = 0; i < 8; i++) nxt[i] = ROW(jb + 8 + i);
#pragma unroll
      for (int i = 0; i < 8; i++) {
        float a = (jb + i < deg) ? pp[jb + i] : 0.0f;
        v2f f = __builtin_amdgcn_cvt_pk_f32_fp8((int)cur[i], false);
        acc0 = fmaf(a, f[0], acc0);
        acc1 = fmaf(a, f[1], acc1);
        cur[i] = nxt[i];
      }
    }
#undef ROW
  } else {
    float adh = sel8(ad, hl);
    for (int j = 0; j < deg; j++) {
      int s;
      float p;
      if (j < 128) {
        s = sp[j];
        p = pp[j];
      } else {
        s = csr[beg + j];
        float t = a_src[(size_t)s * NH + hl] + adh;
        t = t > 0.0f ? t : 0.2f * t;
        p = __expf(t);
      }
      unsigned short w = ((const unsigned short*)(h8 + (size_t)s * FEAT))[l];
      v2f f = __builtin_amdgcn_cvt_pk_f32_fp8((int)w, false);
      acc0 = fmaf(p, f[0], acc0);
      acc1 = fmaf(p, f[1], acc1);
    }
  }
  acc0 *= rd;
  acc1 *= rd;
  float2 bv = *(const float2*)(bias + 2 * l);
  float o0 = fmaxf(acc0 + bv.x, 0.0f), o1 = fmaxf(acc1 + bv.y, 0.0f);
  *(float2*)(h2 + (size_t)n * FEAT + 2 * l) = make_float2(o0, o1);
}

// ---------------- K5: g40 = h2 @ W2 (fp16, packed 40); a_src2/a_dst2 -------
__global__ __launch_bounds__(256) void k_gemm2(
    const float* __restrict__ h2, const float* __restrict__ W,
    const float* __restrict__ asv, const float* __restrict__ adv,
    __half* __restrict__ g40, float* __restrict__ a_src,
    float* __restrict__ a_dst, int N) {
  __shared__ float WL[128 * OUTD];
  int tid = threadIdx.x;
  for (int i = tid; i < 128 * OUTD; i += 256) WL[i] = W[i];
  __syncthreads();
  int wv = tid >> 6, l = tid & 63;
  int cw = min(l, OUTD - 1);
  int ngroups = gridDim.x * 4;
  for (int gI = blockIdx.x * 4 + wv; gI * 4 < N; gI += ngroups) {
    int base = gI * 4;
    float h0[4], h1r[4];
#pragma unroll
    for (int n = 0; n < 4; n++) {
      int node = base + n;
      if (node < N) {
        float2 v = *(const float2*)(h2 + (size_t)node * FEAT + 2 * l);
        h0[n] = v.x;
        h1r[n] = v.y;
      } else {
        h0[n] = 0.0f;
        h1r[n] = 0.0f;
      }
    }
    float acc[4] = {0, 0, 0, 0};
#pragma unroll 8
    for (int k2 = 0; k2 < 64; k2++) {
      float we = WL[(2 * k2) * OUTD + cw];
      float wo = WL[(2 * k2 + 1) * OUTD + cw];
#pragma unroll
      for (int n = 0; n < 4; n++) {
        float he = rlf(h0[n], k2);
        float ho = rlf(h1r[n], k2);
        acc[n] = fmaf(he, we, fmaf(ho, wo, acc[n]));
      }
    }
    float asw = asv[cw], adw = adv[cw];
#pragma unroll
    for (int n = 0; n < 4; n++) {
      int node = base + n;
      if (node >= N) break;
      if (l < OUTD) g40[(size_t)node * GST + l] = __float2half(acc[n]);
      float ps = (l < OUTD) ? acc[n] * asw : 0.0f;
      float pd = (l < OUTD) ? acc[n] * adw : 0.0f;
      for (int m = 1; m < 64; m <<= 1) {
        ps += __shfl_xor(ps, m);
        pd += __shfl_xor(pd, m);
      }
      if (l == 0) {
        a_src[node] = ps;
        a_dst[node] = pd;
      }
    }
  }
}

// ---------------- K6: layer-2 softmax-aggregate + log_softmax --------------
// 2 edges/wave (eg=l>>5); lanes li<20 own col pair {2li,2li+1} of 80B rows.
__global__ __launch_bounds__(256) void k_agg2(
    const int* __restrict__ offs, const int* __restrict__ csr,
    const float* __restrict__ a_src, const float* __restrict__ a_dst,
    const __half* __restrict__ g40, const float* __restrict__ bias,
    float* __restrict__ out, int N) {
  __shared__ float plds[4][PS];
  __shared__ int slds[4][128];
  int wv = threadIdx.x >> 6, l = threadIdx.x & 63;
  int n = blockIdx.x * 4 + wv;
  if (n >= N) return;
  int beg = offs[n], end = offs[n + 1];
  int deg = end - beg;
  float adn = a_dst[n];
  float sm = 0.0f;
  for (int j0 = 0; j0 < deg; j0 += 64) {
    int j = j0 + l;
    if (j < deg) {
      int s = csr[beg + j];
      float t = a_src[s] + adn;
      t = t > 0.0f ? t : 0.2f * t;
      float p = __expf(t);
      sm += p;
      if (j < 128) {
        plds[wv][j] = p;
        slds[wv][j] = s;
      }
    }
  }
  for (int m = 1; m < 64; m <<= 1) sm += __shfl_xor(sm, m);
  float rd = 1.0f / sm;
  const int* sp = slds[wv];
  const float* pp = plds[wv];
  int li = l & 31, eg = l >> 5;
  bool cact = li < 20;  // cols 2li, 2li+1 < 40
  int lic = min(li, 19);
  const __half* gb = g40 + 2 * lic;
  float acc0 = 0.0f, acc1 = 0.0f;
  if (deg <= 128) {
    int ng = (deg + 1) >> 1;
    __half2 c0, c1, c2, c3;
#define LD2(G) \
  (*(const __half2*)(gb + (size_t)sp[min(2 * (G) + eg, deg - 1)] * GST))
#define AL2(G) ((2 * (G) + eg < deg) ? pp[2 * (G) + eg] : 0.0f)
    c0 = LD2(0); c1 = LD2(1); c2 = LD2(2); c3 = LD2(3);
    for (int g = 0; g < ng; g += 4) {
      __half2 n0 = LD2(g + 4), n1 = LD2(g + 5), n2 = LD2(g + 6),
              n3 = LD2(g + 7);
      float a0 = AL2(g), a1 = AL2(g + 1), a2 = AL2(g + 2), a3 = AL2(g + 3);
      float2 f0 = __half22float2(c0);
      float2 f1 = __half22float2(c1);
      float2 f2 = __half22float2(c2);
      float2 f3 = __half22float2(c3);
      acc0 = fmaf(a0, f0.x, acc0); acc1 = fmaf(a0, f0.y, acc1);
      acc0 = fmaf(a1, f1.x, acc0); acc1 = fmaf(a1, f1.y, acc1);
      acc0 = fmaf(a2, f2.x, acc0); acc1 = fmaf(a2, f2.y, acc1);
      acc0 = fmaf(a3, f3.x, acc0); acc1 = fmaf(a3, f3.y, acc1);
      c0 = n0; c1 = n1; c2 = n2; c3 = n3;
    }
#undef LD2
#undef AL2
  } else {
    for (int j = eg; j < deg; j += 2) {
      int s;
      float p;
      if (j < 128) {
        s = sp[j];
        p = pp[j];
      } else {
        s = csr[beg + j];
        float t = a_src[s] + adn;
        t = t > 0.0f ? t : 0.2f * t;
        p = __expf(t);
      }
      float2 v = __half22float2(*(const __half2*)(gb + (size_t)s * GST));
      acc0 = fmaf(p, v.x, acc0);
      acc1 = fmaf(p, v.y, acc1);
    }
  }
  acc0 += __shfl_xor(acc0, 32);
  acc1 += __shfl_xor(acc1, 32);
  float v0 = -INFINITY, v1 = -INFINITY;
  if (cact) {
    float2 bv = *(const float2*)(bias + 2 * li);
    v0 = acc0 * rd + bv.x;
    v1 = acc1 * rd + bv.y;
  }
  float mx = fmaxf(v0, v1);
  for (int m = 1; m < 64; m <<= 1) mx = fmaxf(mx, __shfl_xor(mx, m));
  float pe = (l < 20) ? __expf(v0 - mx) + __expf(v1 - mx) : 0.0f;
  float se = pe;
  for (int m = 1; m < 64; m <<= 1) se += __shfl_xor(se, m);
  float ls = logf(se);
  if (l < 20) {
    float* op = out + (size_t)n * OUTD + 2 * l;
    op[0] = v0 - mx - ls;
    op[1] = v1 - mx - ls;
  }
}

// ---------------------------------------------------------------------------
extern "C" void kernel_launch(void* const* d_in, const int* in_sizes, int n_in,
                              void* d_out, int out_size, void* d_ws,
                              size_t ws_size, hipStream_t stream) {
  const float* x = (const float*)d_in[0];
  const int* ei = (const int*)d_in[1];
  const float* mw1 = (const float*)d_in[2];
  const float* mb1 = (const float*)d_in[3];
  const float* mw2 = (const float*)d_in[4];
  const float* mb2 = (const float*)d_in[5];
  const float* W1 = (const float*)d_in[6];
  const float* as1w = (const float*)d_in[7];
  const float* ad1w = (const float*)d_in[8];
  const float* b1 = (const float*)d_in[9];
  const float* W2 = (const float*)d_in[10];
  const float* as2w = (const float*)d_in[11];
  const float* ad2w = (const float*)d_in[12];
  const float* b2 = (const float*)d_in[13];
  float* out = (float*)d_out;

  int N = in_sizes[0] / XDIM;
  int E = in_sizes[1] / 2;
  int ET = E + N;
  int NB = (N + 255) >> 8;  // dst buckets of 256 nodes

  char* ws = (char*)d_ws;
  size_t off = 0;
  auto carve = [&](size_t bytes) -> void* {
    void* p = ws + off;
    off = (off + bytes + 255) & ~(size_t)255;
    return p;
  };
  float* stats = (float*)carve(64);
  float* part = (float*)carve((size_t)SB * 12 * 4);
  int* cnt = (int*)carve((size_t)NB * PB * 4);
  int2* ebuf = (int2*)carve((size_t)E * 8);
  int* offs = (int*)carve((size_t)(N + 1) * 4);
  int* csr = (int*)carve((size_t)ET * 4);
  float* scl = (float*)carve((size_t)N * 4);
  float* as1 = (float*)carve((size_t)N * NH * 4);
  float* ad1 = (float*)carve((size_t)N * NH * 4);
  unsigned char* h8 = (unsigned char*)carve((size_t)N * FEAT);
  float* h2 = (float*)carve((size_t)N * FEAT * 4);
  __half* g40 = (__half*)carve((size_t)N * GST * 2);
  float* as2 = (float*)carve((size_t)N * 4);
  float* ad2 = (float*)carve((size_t)N * 4);

  k_stats1<<<SB, 256, 0, stream>>>(x, part, N);
  k_stats2<<<1, 256, 0, stream>>>(part, stats);
  k_scale<<<(N + 255) / 256, 256, 0, stream>>>(x, stats, mw1, mb1, mw2, mb2,
                                               scl, N);
  k_bh<<<PB, 256, 0, stream>>>(ei, cnt, E, NB);
  k_bscan<<<1, 1024, 0, stream>>>(cnt, NB * PB);
  k_part<<<PB, 256, 0, stream>>>(ei, cnt, ebuf, E, NB);
  k_bcsr<<<NB, 256, 0, stream>>>(ebuf, cnt, offs, csr, N, E, NB);
  k_gemm1<<<1280, 256, 0, stream>>>(x, scl, W1, as1w, ad1w, h8, as1, ad1, N);
  k_agg1<<<(N + 3) / 4, 256, 0, stream>>>(offs, csr, as1, ad1, h8, b1, h2, N);
  k_gemm2<<<1280, 256, 0, stream>>>(h2, W2, as2w, ad2w, g40, as2, ad2, N);
  k_agg2<<<(N + 3) / 4, 256, 0, stream>>>(offs, csr, as2, ad2, g40, b2, out, N);
}

// Round 9
// 314.955 us; speedup vs baseline: 2.7998x; 1.1159x over previous
//
#include <hip/hip_runtime.h>
#include <hip/hip_fp16.h>

#define XDIM 134
#define FEAT 128
#define AUGN 6
#define NH 8
#define HD 16
#define OUTD 40
#define PS 132       // per-head stride in plds (132 mod 32 = 4 -> conflict-free)
#define SB 256       // stats partial blocks
#define PB 256       // partition blocks
#define MAXNB 256    // max buckets (N <= 65536)
#define GST 40       // g row stride in halfs (80 B)

typedef float v2f __attribute__((ext_vector_type(2)));

__device__ __forceinline__ float rlf(float v, int lane) {
  return __int_as_float(__builtin_amdgcn_readlane(__float_as_int(v), lane));
}

// ---------------- K0a: per-block partial sums/sumsq of aug columns ---------
__global__ __launch_bounds__(256) void k_stats1(const float* __restrict__ x,
                                                float* __restrict__ part,
                                                int N) {
  __shared__ float red[4][12];
  float s[AUGN] = {0, 0, 0, 0, 0, 0}, q[AUGN] = {0, 0, 0, 0, 0, 0};
  for (int n = blockIdx.x * blockDim.x + threadIdx.x; n < N;
       n += gridDim.x * blockDim.x) {
    const float* r = x + (size_t)n * XDIM + FEAT;
    float2 v0 = *(const float2*)r;
    float2 v1 = *(const float2*)(r + 2);
    float2 v2 = *(const float2*)(r + 4);
    float v[AUGN] = {v0.x, v0.y, v1.x, v1.y, v2.x, v2.y};
#pragma unroll
    for (int i = 0; i < AUGN; i++) {
      s[i] += v[i];
      q[i] += v[i] * v[i];
    }
  }
#pragma unroll
  for (int i = 0; i < AUGN; i++) {
    for (int m = 1; m < 64; m <<= 1) {
      s[i] += __shfl_xor(s[i], m);
      q[i] += __shfl_xor(q[i], m);
    }
  }
  int wv = threadIdx.x >> 6, l = threadIdx.x & 63;
  if (l == 0) {
#pragma unroll
    for (int i = 0; i < AUGN; i++) {
      red[wv][i] = s[i];
      red[wv][6 + i] = q[i];
    }
  }
  __syncthreads();
  int t = threadIdx.x;
  if (t < 12) {
    part[blockIdx.x * 12 + t] =
        red[0][t] + red[1][t] + red[2][t] + red[3][t];
  }
}

// ---------------- K0b: reduce SB partials -> stats[0..5], stats[8..13] -----
__global__ __launch_bounds__(256) void k_stats2(const float* __restrict__ part,
                                                float* __restrict__ stats) {
  __shared__ float red[4][12];
  int t = threadIdx.x;
  float v[12];
#pragma unroll
  for (int c = 0; c < 12; c++) v[c] = part[t * 12 + c];
#pragma unroll
  for (int c = 0; c < 12; c++)
    for (int m = 1; m < 64; m <<= 1) v[c] += __shfl_xor(v[c], m);
  int wv = t >> 6, l = t & 63;
  if (l == 0) {
#pragma unroll
    for (int c = 0; c < 12; c++) red[wv][c] = v[c];
  }
  __syncthreads();
  if (t < 12) {
    float s = red[0][t] + red[1][t] + red[2][t] + red[3][t];
    stats[t < 6 ? t : t + 2] = s;
  }
}

// ---------------- K1: per-node scale = 1 + sigmoid(MLP(norm(aug))) ----------
__global__ __launch_bounds__(256) void k_scale(
    const float* __restrict__ x, const float* __restrict__ stats,
    const float* __restrict__ w1, const float* __restrict__ b1,
    const float* __restrict__ w2, const float* __restrict__ b2,
    float* __restrict__ scl, int N) {
  int n = blockIdx.x * blockDim.x + threadIdx.x;
  if (n >= N) return;
  const float* r = x + (size_t)n * XDIM + FEAT;
  float a[AUGN];
  float invN = 1.0f / (float)N;
#pragma unroll
  for (int i = 0; i < AUGN; i++) {
    float sum = stats[i], sq = stats[8 + i];
    float mean = sum * invN;
    float var = (sq - sum * mean) / (float)(N - 1);
    a[i] = (r[i] - mean) / sqrtf(var);
  }
  float s2 = b2[0];
#pragma unroll
  for (int j = 0; j < 16; j++) {
    float z = b1[j];
#pragma unroll
    for (int i = 0; i < AUGN; i++) z = fmaf(a[i], w1[i * 16 + j], z);
    z = fmaxf(z, 0.0f);
    s2 = fmaf(z, w2[j], s2);
  }
  float sig = 1.0f / (1.0f + __expf(-s2));
  scl[n] = 1.0f + sig;
}

// ---------------- K2a: per-(block,bucket) histogram of dst>>8 --------------
__global__ __launch_bounds__(256) void k_bh(const int* __restrict__ ei,
                                            int* __restrict__ cnt, int E,
                                            int NB) {
  __shared__ int hist[MAXNB];
  int t = threadIdx.x;
  for (int b = t; b < NB; b += 256) hist[b] = 0;
  __syncthreads();
  int ch = (E + PB - 1) / PB;
  int lo = blockIdx.x * ch, hi = min(lo + ch, E);
  for (int e = lo + t; e < hi; e += 256)
    atomicAdd(&hist[ei[E + e] >> 8], 1);
  __syncthreads();
  for (int b = t; b < NB; b += 256)
    cnt[(size_t)b * PB + blockIdx.x] = hist[b];
}

// ---------------- K2b: one-block exclusive scan of cnt[NB*PB] --------------
__global__ __launch_bounds__(1024) void k_bscan(int* __restrict__ cnt,
                                                int total) {
  __shared__ int ps[1024];
  int t = threadIdx.x;
  int chunk = (total + 1023) >> 10;
  int lo = t * chunk, hi = min(lo + chunk, total);
  int sum = 0;
  for (int i = lo; i < hi; i++) sum += cnt[i];
  ps[t] = sum;
  __syncthreads();
  for (int d = 1; d < 1024; d <<= 1) {
    int v = (t >= d) ? ps[t - d] : 0;
    __syncthreads();
    ps[t] += v;
    __syncthreads();
  }
  int run = (t == 0) ? 0 : ps[t - 1];
  for (int i = lo; i < hi; i++) {
    int v = cnt[i];
    cnt[i] = run;
    run += v;
  }
}

// ---------------- K2c: partition edges into bucket-grouped (src,dst) pairs -
__global__ __launch_bounds__(256) void k_part(const int* __restrict__ ei,
                                              const int* __restrict__ cnt,
                                              int2* __restrict__ ebuf, int E,
                                              int NB) {
  __shared__ int cur[MAXNB];
  int t = threadIdx.x;
  for (int b = t; b < NB; b += 256) cur[b] = cnt[(size_t)b * PB + blockIdx.x];
  __syncthreads();
  int ch = (E + PB - 1) / PB;
  int lo = blockIdx.x * ch, hi = min(lo + ch, E);
  for (int e = lo + t; e < hi; e += 256) {
    int s = ei[e], d = ei[E + e];
    int pos = atomicAdd(&cur[d >> 8], 1);
    ebuf[pos] = make_int2(s, d);
  }
}

// ---------------- K2d: per-bucket CSR build (contiguous region writes) -----
__global__ __launch_bounds__(256) void k_bcsr(const int2* __restrict__ ebuf,
                                              const int* __restrict__ cnt,
                                              int* __restrict__ offs,
                                              int* __restrict__ csr, int N,
                                              int E, int NB) {
  __shared__ int dl[256];
  __shared__ int sc[256];
  __shared__ int cu[256];
  int b = blockIdx.x, t = threadIdx.x;
  int nn = min(256, N - b * 256);
  int rs = cnt[(size_t)b * PB];
  int re = (b + 1 < NB) ? cnt[(size_t)(b + 1) * PB] : E;
  int csrbase = rs + b * 256;
  dl[t] = 0;
  __syncthreads();
  for (int j = rs + t; j < re; j += 256)
    atomicAdd(&dl[ebuf[j].y & 255], 1);
  __syncthreads();
  int v = (t < nn) ? dl[t] + 1 : 0;
  sc[t] = v;
  __syncthreads();
  for (int d = 1; d < 256; d <<= 1) {
    int u = (t >= d) ? sc[t - d] : 0;
    __syncthreads();
    sc[t] += u;
    __syncthreads();
  }
  int excl = sc[t] - v;
  if (t < nn) {
    int node = b * 256 + t;
    offs[node] = csrbase + excl;
    csr[csrbase + excl] = node;  // self-loop slot
    cu[t] = excl + 1;
  }
  __syncthreads();
  for (int j = rs + t; j < re; j += 256) {
    int2 e = ebuf[j];
    int p = atomicAdd(&cu[e.y & 255], 1);
    csr[csrbase + p] = e.x;
  }
  if (b == 0 && t == 0) offs[N] = E + N;
}

// ---------------- K3: h1(fp8 e4m3) = (x*scale) @ W1 ; scores fp32 ----------
__global__ __launch_bounds__(256) void k_gemm1(
    const float* __restrict__ x, const float* __restrict__ scl,
    const float* __restrict__ W, const float* __restrict__ asv,
    const float* __restrict__ adv, unsigned char* __restrict__ h8,
    float* __restrict__ a_src, float* __restrict__ a_dst, int N) {
  __shared__ float WL[128 * 128];
  int tid = threadIdx.x;
#pragma unroll
  for (int i = 0; i < 16; i++)
    ((float4*)WL)[tid + i * 256] = ((const float4*)W)[tid + i * 256];
  __syncthreads();
  int wv = tid >> 6, l = tid & 63;
  int ngroups = gridDim.x * 4;
  for (int gI = blockIdx.x * 4 + wv; gI * 4 < N; gI += ngroups) {
    int base = gI * 4;
    float h0[4], h1r[4];
#pragma unroll
    for (int n = 0; n < 4; n++) {
      int node = base + n;
      if (node < N) {
        float2 v = *(const float2*)(x + (size_t)node * XDIM + 2 * l);
        h0[n] = v.x;
        h1r[n] = v.y;
      } else {
        h0[n] = 0.0f;
        h1r[n] = 0.0f;
      }
    }
    float a0[4] = {0, 0, 0, 0}, a1[4] = {0, 0, 0, 0};
#pragma unroll 8
    for (int k2 = 0; k2 < 64; k2++) {
      float2 we = *(const float2*)&WL[(2 * k2) * 128 + 2 * l];
      float2 wo = *(const float2*)&WL[(2 * k2 + 1) * 128 + 2 * l];
#pragma unroll
      for (int n = 0; n < 4; n++) {
        float he = rlf(h0[n], k2);
        float ho = rlf(h1r[n], k2);
        a0[n] = fmaf(he, we.x, fmaf(ho, wo.x, a0[n]));
        a1[n] = fmaf(he, we.y, fmaf(ho, wo.y, a1[n]));
      }
    }
    float asw0 = asv[2 * l], asw1 = asv[2 * l + 1];
    float adw0 = adv[2 * l], adw1 = adv[2 * l + 1];
#pragma unroll
    for (int n = 0; n < 4; n++) {
      int node = base + n;
      if (node >= N) break;
      float s = scl[node];
      float y0 = a0[n] * s, y1 = a1[n] * s;
      int pk = __builtin_amdgcn_cvt_pk_fp8_f32(y0, y1, 0, false);
      ((unsigned short*)(h8 + (size_t)node * FEAT))[l] = (unsigned short)pk;
      float ps = y0 * asw0 + y1 * asw1;
      float pd = y0 * adw0 + y1 * adw1;
      ps += __shfl_xor(ps, 1); ps += __shfl_xor(ps, 2); ps += __shfl_xor(ps, 4);
      pd += __shfl_xor(pd, 1); pd += __shfl_xor(pd, 2); pd += __shfl_xor(pd, 4);
      if ((l & 7) == 0) {
        a_src[node * NH + (l >> 3)] = ps;
        a_dst[node * NH + (l >> 3)] = pd;
      }
    }
  }
}

// ---------------- K4: layer-1 softmax-aggregate; h2(fp16) ------------------
// sweep1: lane=(edge e8=l>>3, head h=l&7): 1 load + 1 exp/lane; 3-shfl reduce.
// sweep2: 2 edges/wave (eg=l>>5), lane li=l&31 owns 4 fp8 ch; 4-deep prefetch.
__global__ __launch_bounds__(256) void k_agg1(
    const int* __restrict__ offs, const int* __restrict__ csr,
    const float* __restrict__ a_src, const float* __restrict__ a_dst,
    const unsigned char* __restrict__ h8, const float* __restrict__ bias,
    __half* __restrict__ h2h, int N) {
  __shared__ float plds[4][8 * PS];
  __shared__ int slds[4][128];
  int wv = threadIdx.x >> 6, l = threadIdx.x & 63;
  int n = blockIdx.x * 4 + wv;
  if (n >= N) return;
  int beg = offs[n], end = offs[n + 1];
  int deg = end - beg;
  int h = l & 7, e8 = l >> 3;
  float adh = a_dst[(size_t)n * NH + h];
  // sweep 1: p = exp(leaky(a_src[s,h] + ad[h])) -> LDS, per-head denom
  float smh = 0.0f;
  for (int j0 = 0; j0 < deg; j0 += 8) {
    int j = j0 + e8;
    if (j < deg) {
      int s = csr[beg + j];
      if (h == 0 && j < 128) slds[wv][j] = s;
      float t = a_src[(size_t)s * NH + h] + adh;
      t = t > 0.0f ? t : 0.2f * t;
      float p = __expf(t);
      smh += p;
      if (j < 128) plds[wv][h * PS + j] = p;
    }
  }
  smh += __shfl_xor(smh, 8);
  smh += __shfl_xor(smh, 16);
  smh += __shfl_xor(smh, 32);  // lane k holds denom of head k&7
  __builtin_amdgcn_wave_barrier();
  // sweep 2: 2 edges/step; lane li owns channels {4li..4li+3}, head hh=li>>2
  int li = l & 31, eg = l >> 5;
  int hh = li >> 2;
  float rd = 1.0f / __shfl(smh, hh);
  const int* sp = slds[wv];
  const float* pp = &plds[wv][hh * PS];
  float acc0 = 0.0f, acc1 = 0.0f, acc2 = 0.0f, acc3 = 0.0f;
  if (deg <= 128) {
    int dm1 = deg - 1;
    int ng = (deg + 1) >> 1;  // steps of 2 edges
    unsigned int cur[4], nxt[4];
#define ROWA(G) \
  (*(const unsigned int*)(h8 + (size_t)sp[min(2 * (G) + eg, dm1)] * FEAT + 4 * li))
#pragma unroll
    for (int i = 0; i < 4; i++) cur[i] = ROWA(i);
    for (int g = 0; g < ng; g += 4) {
#pragma unroll
      for (int i = 0; i < 4; i++) nxt[i] = ROWA(g + 4 + i);
#pragma unroll
      for (int i = 0; i < 4; i++) {
        int j = 2 * (g + i) + eg;
        float a = (j < deg) ? pp[j] : 0.0f;
        v2f lo = __builtin_amdgcn_cvt_pk_f32_fp8((int)cur[i], false);
        v2f hi = __builtin_amdgcn_cvt_pk_f32_fp8((int)cur[i], true);
        acc0 = fmaf(a, lo[0], acc0);
        acc1 = fmaf(a, lo[1], acc1);
        acc2 = fmaf(a, hi[0], acc2);
        acc3 = fmaf(a, hi[1], acc3);
        cur[i] = nxt[i];
      }
    }
#undef ROWA
  } else {
    float adhh = __shfl(adh, hh);
    for (int j = eg; j < deg; j += 2) {
      int s;
      float p;
      if (j < 128) {
        s = sp[j];
        p = pp[j];
      } else {
        s = csr[beg + j];
        float t = a_src[(size_t)s * NH + hh] + adhh;
        t = t > 0.0f ? t : 0.2f * t;
        p = __expf(t);
      }
      unsigned int w =
          *(const unsigned int*)(h8 + (size_t)s * FEAT + 4 * li);
      v2f lo = __builtin_amdgcn_cvt_pk_f32_fp8((int)w, false);
      v2f hi = __builtin_amdgcn_cvt_pk_f32_fp8((int)w, true);
      acc0 = fmaf(p, lo[0], acc0);
      acc1 = fmaf(p, lo[1], acc1);
      acc2 = fmaf(p, hi[0], acc2);
      acc3 = fmaf(p, hi[1], acc3);
    }
  }
  acc0 += __shfl_xor(acc0, 32);
  acc1 += __shfl_xor(acc1, 32);
  acc2 += __shfl_xor(acc2, 32);
  acc3 += __shfl_xor(acc3, 32);
  if (l < 32) {
    float4 bv = *(const float4*)(bias + 4 * l);
    float o0 = fmaxf(acc0 * rd + bv.x, 0.0f);
    float o1 = fmaxf(acc1 * rd + bv.y, 0.0f);
    float o2 = fmaxf(acc2 * rd + bv.z, 0.0f);
    float o3 = fmaxf(acc3 * rd + bv.w, 0.0f);
    __half2 pa = __float22half2_rn(make_float2(o0, o1));
    __half2 pb = __float22half2_rn(make_float2(o2, o3));
    uint2 st;
    st.x = *(unsigned int*)&pa;
    st.y = *(unsigned int*)&pb;
    *(uint2*)(h2h + (size_t)n * FEAT + 4 * l) = st;
  }
}

// ---------------- K5: g40 = h2(fp16) @ W2 (fp16, packed 40) ----------------
__global__ __launch_bounds__(256) void k_gemm2(
    const __half* __restrict__ h2h, const float* __restrict__ W,
    const float* __restrict__ asv, const float* __restrict__ adv,
    __half* __restrict__ g40, float* __restrict__ a_src,
    float* __restrict__ a_dst, int N) {
  __shared__ float WL[128 * OUTD];
  int tid = threadIdx.x;
  for (int i = tid; i < 128 * OUTD; i += 256) WL[i] = W[i];
  __syncthreads();
  int wv = tid >> 6, l = tid & 63;
  int cw = min(l, OUTD - 1);
  int ngroups = gridDim.x * 4;
  for (int gI = blockIdx.x * 4 + wv; gI * 4 < N; gI += ngroups) {
    int base = gI * 4;
    float h0[4], h1r[4];
#pragma unroll
    for (int n = 0; n < 4; n++) {
      int node = base + n;
      if (node < N) {
        __half2 v = *(const __half2*)(h2h + (size_t)node * FEAT + 2 * l);
        float2 f = __half22float2(v);
        h0[n] = f.x;
        h1r[n] = f.y;
      } else {
        h0[n] = 0.0f;
        h1r[n] = 0.0f;
      }
    }
    float acc[4] = {0, 0, 0, 0};
#pragma unroll 8
    for (int k2 = 0; k2 < 64; k2++) {
      float we = WL[(2 * k2) * OUTD + cw];
      float wo = WL[(2 * k2 + 1) * OUTD + cw];
#pragma unroll
      for (int n = 0; n < 4; n++) {
        float he = rlf(h0[n], k2);
        float ho = rlf(h1r[n], k2);
        acc[n] = fmaf(he, we, fmaf(ho, wo, acc[n]));
      }
    }
    float asw = asv[cw], adw = adv[cw];
#pragma unroll
    for (int n = 0; n < 4; n++) {
      int node = base + n;
      if (node >= N) break;
      if (l < OUTD) g40[(size_t)node * GST + l] = __float2half(acc[n]);
      float ps = (l < OUTD) ? acc[n] * asw : 0.0f;
      float pd = (l < OUTD) ? acc[n] * adw : 0.0f;
      for (int m = 1; m < 64; m <<= 1) {
        ps += __shfl_xor(ps, m);
        pd += __shfl_xor(pd, m);
      }
      if (l == 0) {
        a_src[node] = ps;
        a_dst[node] = pd;
      }
    }
  }
}

// ---------------- K6: layer-2 softmax-aggregate + log_softmax --------------
// 4 edges/wave (eg=l>>4); lane li=l&15 (li<10) owns cols {4li..4li+3}.
__global__ __launch_bounds__(256) void k_agg2(
    const int* __restrict__ offs, const int* __restrict__ csr,
    const float* __restrict__ a_src, const float* __restrict__ a_dst,
    const __half* __restrict__ g40, const float* __restrict__ bias,
    float* __restrict__ out, int N) {
  __shared__ float plds[4][PS];
  __shared__ int slds[4][128];
  int wv = threadIdx.x >> 6, l = threadIdx.x & 63;
  int n = blockIdx.x * 4 + wv;
  if (n >= N) return;
  int beg = offs[n], end = offs[n + 1];
  int deg = end - beg;
  float adn = a_dst[n];
  float sm = 0.0f;
  for (int j0 = 0; j0 < deg; j0 += 64) {
    int j = j0 + l;
    if (j < deg) {
      int s = csr[beg + j];
      float t = a_src[s] + adn;
      t = t > 0.0f ? t : 0.2f * t;
      float p = __expf(t);
      sm += p;
      if (j < 128) {
        plds[wv][j] = p;
        slds[wv][j] = s;
      }
    }
  }
  for (int m = 1; m < 64; m <<= 1) sm += __shfl_xor(sm, m);
  float rd = 1.0f / sm;
  const int* sp = slds[wv];
  const float* pp = plds[wv];
  int li = l & 15, eg = l >> 4;
  int lic = min(li, 9);
  const __half* gb = g40 + 4 * lic;
  float acc0 = 0.0f, acc1 = 0.0f, acc2 = 0.0f, acc3 = 0.0f;
  if (deg <= 128) {
    int dm1 = deg - 1;
    int ns = (deg + 3) >> 2;  // steps of 4 edges
    uint2 cur[4], nxt[4];
#define ROWB(G) (*(const uint2*)(gb + (size_t)sp[min(4 * (G) + eg, dm1)] * GST))
#pragma unroll
    for (int i = 0; i < 4; i++) cur[i] = ROWB(i);
    for (int g = 0; g < ns; g += 4) {
#pragma unroll
      for (int i = 0; i < 4; i++) nxt[i] = ROWB(g + 4 + i);
#pragma unroll
      for (int i = 0; i < 4; i++) {
        int j = 4 * (g + i) + eg;
        float a = (j < deg) ? pp[j] : 0.0f;
        __half2 ha = *(__half2*)&cur[i].x;
        __half2 hb = *(__half2*)&cur[i].y;
        float2 fa = __half22float2(ha);
        float2 fb = __half22float2(hb);
        acc0 = fmaf(a, fa.x, acc0);
        acc1 = fmaf(a, fa.y, acc1);
        acc2 = fmaf(a, fb.x, acc2);
        acc3 = fmaf(a, fb.y, acc3);
        cur[i] = nxt[i];
      }
    }
#undef ROWB
  } else {
    for (int j = eg; j < deg; j += 4) {
      int s;
      float p;
      if (j < 128) {
        s = sp[j];
        p = pp[j];
      } else {
        s = csr[beg + j];
        float t = a_src[s] + adn;
        t = t > 0.0f ? t : 0.2f * t;
        p = __expf(t);
      }
      uint2 w = *(const uint2*)(gb + (size_t)s * GST);
      __half2 ha = *(__half2*)&w.x;
      __half2 hb = *(__half2*)&w.y;
      float2 fa = __half22float2(ha);
      float2 fb = __half22float2(hb);
      acc0 = fmaf(p, fa.x, acc0);
      acc1 = fmaf(p, fa.y, acc1);
      acc2 = fmaf(p, fb.x, acc2);
      acc3 = fmaf(p, fb.y, acc3);
    }
  }
#pragma unroll
  for (int m = 16; m < 64; m <<= 1) {
    acc0 += __shfl_xor(acc0, m);
    acc1 += __shfl_xor(acc1, m);
    acc2 += __shfl_xor(acc2, m);
    acc3 += __shfl_xor(acc3, m);
  }
  bool cact = li < 10;
  float v0 = -INFINITY, v1 = -INFINITY, v2 = -INFINITY, v3 = -INFINITY;
  if (cact) {
    float4 bv = *(const float4*)(bias + 4 * li);
    v0 = acc0 * rd + bv.x;
    v1 = acc1 * rd + bv.y;
    v2 = acc2 * rd + bv.z;
    v3 = acc3 * rd + bv.w;
  }
  float mx = fmaxf(fmaxf(v0, v1), fmaxf(v2, v3));
  for (int m = 1; m < 64; m <<= 1) mx = fmaxf(mx, __shfl_xor(mx, m));
  // FIX (round 8 bug): only eg==0 lanes contribute to the denominator —
  // lanes eg=1..3 hold identical post-reduce copies; counting them made
  // se 4x too large (ls off by log 4 = 1.386 -> absmax 1.41).
  float pe = (eg == 0 && cact) ? __expf(v0 - mx) + __expf(v1 - mx) +
                                     __expf(v2 - mx) + __expf(v3 - mx)
                               : 0.0f;
  float se = pe;
  for (int m = 1; m < 64; m <<= 1) se += __shfl_xor(se, m);
  float ls = logf(se);
  if (eg == 0 && cact) {
    float4 o;
    o.x = v0 - mx - ls;
    o.y = v1 - mx - ls;
    o.z = v2 - mx - ls;
    o.w = v3 - mx - ls;
    *(float4*)(out + (size_t)n * OUTD + 4 * li) = o;
  }
}

// ---------------------------------------------------------------------------
extern "C" void kernel_launch(void* const* d_in, const int* in_sizes, int n_in,
                              void* d_out, int out_size, void* d_ws,
                              size_t ws_size, hipStream_t stream) {
  const float* x = (const float*)d_in[0];
  const int* ei = (const int*)d_in[1];
  const float* mw1 = (const float*)d_in[2];
  const float* mb1 = (const float*)d_in[3];
  const float* mw2 = (const float*)d_in[4];
  const float* mb2 = (const float*)d_in[5];
  const float* W1 = (const float*)d_in[6];
  const float* as1w = (const float*)d_in[7];
  const float* ad1w = (const float*)d_in[8];
  const float* b1 = (const float*)d_in[9];
  const float* W2 = (const float*)d_in[10];
  const float* as2w = (const float*)d_in[11];
  const float* ad2w = (const float*)d_in[12];
  const float* b2 = (const float*)d_in[13];
  float* out = (float*)d_out;

  int N = in_sizes[0] / XDIM;
  int E = in_sizes[1] / 2;
  int ET = E + N;
  int NB = (N + 255) >> 8;  // dst buckets of 256 nodes

  char* ws = (char*)d_ws;
  size_t off = 0;
  auto carve = [&](size_t bytes) -> void* {
    void* p = ws + off;
    off = (off + bytes + 255) & ~(size_t)255;
    return p;
  };
  float* stats = (float*)carve(64);
  float* part = (float*)carve((size_t)SB * 12 * 4);
  int* cnt = (int*)carve((size_t)NB * PB * 4);
  int2* ebuf = (int2*)carve((size_t)E * 8);
  int* offs = (int*)carve((size_t)(N + 1) * 4);
  int* csr = (int*)carve((size_t)ET * 4);
  float* scl = (float*)carve((size_t)N * 4);
  float* as1 = (float*)carve((size_t)N * NH * 4);
  float* ad1 = (float*)carve((size_t)N * NH * 4);
  unsigned char* h8 = (unsigned char*)carve((size_t)N * FEAT);
  __half* h2h = (__half*)carve((size_t)N * FEAT * 2);
  __half* g40 = (__half*)carve((size_t)N * GST * 2);
  float* as2 = (float*)carve((size_t)N * 4);
  float* ad2 = (float*)carve((size_t)N * 4);

  k_stats1<<<SB, 256, 0, stream>>>(x, part, N);
  k_stats2<<<1, 256, 0, stream>>>(part, stats);
  k_scale<<<(N + 255) / 256, 256, 0, stream>>>(x, stats, mw1, mb1, mw2, mb2,
                                               scl, N);
  k_bh<<<PB, 256, 0, stream>>>(ei, cnt, E, NB);
  k_bscan<<<1, 1024, 0, stream>>>(cnt, NB * PB);
  k_part<<<PB, 256, 0, stream>>>(ei, cnt, ebuf, E, NB);
  k_bcsr<<<NB, 256, 0, stream>>>(ebuf, cnt, offs, csr, N, E, NB);
  k_gemm1<<<1280, 256, 0, stream>>>(x, scl, W1, as1w, ad1w, h8, as1, ad1, N);
  k_agg1<<<(N + 3) / 4, 256, 0, stream>>>(offs, csr, as1, ad1, h8, b1, h2h, N);
  k_gemm2<<<1280, 256, 0, stream>>>(h2h, W2, as2w, ad2w, g40, as2, ad2, N);
  k_agg2<<<(N + 3) / 4, 256, 0, stream>>>(offs, csr, as2, ad2, g40, b2, out, N);
}

// Round 10
// 243.391 us; speedup vs baseline: 3.6231x; 1.2940x over previous
//
#include <hip/hip_runtime.h>
#include <hip/hip_fp16.h>

#define XDIM 134
#define FEAT 128
#define AUGN 6
#define NH 8
#define HD 16
#define OUTD 40
#define PS 132       // per-head stride in plds (132 mod 32 = 4 -> conflict-free)
#define SB 256       // stats partial blocks
#define PB 256       // partition blocks
#define MAXNB 256    // max buckets (N <= 65536)
#define GST 40       // g row stride in halfs (80 B)

typedef float v2f __attribute__((ext_vector_type(2)));

__device__ __forceinline__ float rlf(float v, int lane) {
  return __int_as_float(__builtin_amdgcn_readlane(__float_as_int(v), lane));
}

// ---------------- K0a: per-block partial sums/sumsq of aug columns ---------
__global__ __launch_bounds__(256) void k_stats1(const float* __restrict__ x,
                                                float* __restrict__ part,
                                                int N) {
  __shared__ float red[4][12];
  float s[AUGN] = {0, 0, 0, 0, 0, 0}, q[AUGN] = {0, 0, 0, 0, 0, 0};
  for (int n = blockIdx.x * blockDim.x + threadIdx.x; n < N;
       n += gridDim.x * blockDim.x) {
    const float* r = x + (size_t)n * XDIM + FEAT;
    float2 v0 = *(const float2*)r;
    float2 v1 = *(const float2*)(r + 2);
    float2 v2 = *(const float2*)(r + 4);
    float v[AUGN] = {v0.x, v0.y, v1.x, v1.y, v2.x, v2.y};
#pragma unroll
    for (int i = 0; i < AUGN; i++) {
      s[i] += v[i];
      q[i] += v[i] * v[i];
    }
  }
#pragma unroll
  for (int i = 0; i < AUGN; i++) {
    for (int m = 1; m < 64; m <<= 1) {
      s[i] += __shfl_xor(s[i], m);
      q[i] += __shfl_xor(q[i], m);
    }
  }
  int wv = threadIdx.x >> 6, l = threadIdx.x & 63;
  if (l == 0) {
#pragma unroll
    for (int i = 0; i < AUGN; i++) {
      red[wv][i] = s[i];
      red[wv][6 + i] = q[i];
    }
  }
  __syncthreads();
  int t = threadIdx.x;
  if (t < 12) {
    part[blockIdx.x * 12 + t] =
        red[0][t] + red[1][t] + red[2][t] + red[3][t];
  }
}

// ---------------- K0b: reduce SB partials -> stats[0..5], stats[8..13] -----
__global__ __launch_bounds__(256) void k_stats2(const float* __restrict__ part,
                                                float* __restrict__ stats) {
  __shared__ float red[4][12];
  int t = threadIdx.x;
  float v[12];
#pragma unroll
  for (int c = 0; c < 12; c++) v[c] = part[t * 12 + c];
#pragma unroll
  for (int c = 0; c < 12; c++)
    for (int m = 1; m < 64; m <<= 1) v[c] += __shfl_xor(v[c], m);
  int wv = t >> 6, l = t & 63;
  if (l == 0) {
#pragma unroll
    for (int c = 0; c < 12; c++) red[wv][c] = v[c];
  }
  __syncthreads();
  if (t < 12) {
    float s = red[0][t] + red[1][t] + red[2][t] + red[3][t];
    stats[t < 6 ? t : t + 2] = s;
  }
}

// ---------------- K1: per-node scale = 1 + sigmoid(MLP(norm(aug))) ----------
__global__ __launch_bounds__(256) void k_scale(
    const float* __restrict__ x, const float* __restrict__ stats,
    const float* __restrict__ w1, const float* __restrict__ b1,
    const float* __restrict__ w2, const float* __restrict__ b2,
    float* __restrict__ scl, int N) {
  int n = blockIdx.x * blockDim.x + threadIdx.x;
  if (n >= N) return;
  const float* r = x + (size_t)n * XDIM + FEAT;
  float a[AUGN];
  float invN = 1.0f / (float)N;
#pragma unroll
  for (int i = 0; i < AUGN; i++) {
    float sum = stats[i], sq = stats[8 + i];
    float mean = sum * invN;
    float var = (sq - sum * mean) / (float)(N - 1);
    a[i] = (r[i] - mean) / sqrtf(var);
  }
  float s2 = b2[0];
#pragma unroll
  for (int j = 0; j < 16; j++) {
    float z = b1[j];
#pragma unroll
    for (int i = 0; i < AUGN; i++) z = fmaf(a[i], w1[i * 16 + j], z);
    z = fmaxf(z, 0.0f);
    s2 = fmaf(z, w2[j], s2);
  }
  float sig = 1.0f / (1.0f + __expf(-s2));
  scl[n] = 1.0f + sig;
}

// ---------------- K2a: per-(block,bucket) histogram of dst>>8 --------------
__global__ __launch_bounds__(256) void k_bh(const int* __restrict__ ei,
                                            int* __restrict__ cnt, int E,
                                            int NB) {
  __shared__ int hist[MAXNB];
  int t = threadIdx.x;
  for (int b = t; b < NB; b += 256) hist[b] = 0;
  __syncthreads();
  int ch = (E + PB - 1) / PB;
  int lo = blockIdx.x * ch, hi = min(lo + ch, E);
  for (int e = lo + t; e < hi; e += 256)
    atomicAdd(&hist[ei[E + e] >> 8], 1);
  __syncthreads();
  for (int b = t; b < NB; b += 256)
    cnt[(size_t)b * PB + blockIdx.x] = hist[b];
}

// ---------------- K2b-1: per-bucket exclusive scan of its 256 counts -------
// block b: coalesced LDS scan of cnt[b*PB .. b*PB+255] in place; total->bsum.
__global__ __launch_bounds__(256) void k_sc1(int* __restrict__ cnt,
                                             int* __restrict__ bsum) {
  __shared__ int ps[256];
  int b = blockIdx.x, t = threadIdx.x;
  int v = cnt[(size_t)b * PB + t];
  ps[t] = v;
  __syncthreads();
  for (int d = 1; d < 256; d <<= 1) {
    int u = (t >= d) ? ps[t - d] : 0;
    __syncthreads();
    ps[t] += u;
    __syncthreads();
  }
  cnt[(size_t)b * PB + t] = ps[t] - v;  // exclusive within bucket
  if (t == 255) bsum[b] = ps[255];
}

// ---------------- K2b-2: exclusive scan of bsum[NB] (NB <= 256) ------------
__global__ __launch_bounds__(256) void k_sc2(int* __restrict__ bsum, int NB) {
  __shared__ int ps[256];
  int t = threadIdx.x;
  int v = (t < NB) ? bsum[t] : 0;
  ps[t] = v;
  __syncthreads();
  for (int d = 1; d < 256; d <<= 1) {
    int u = (t >= d) ? ps[t - d] : 0;
    __syncthreads();
    ps[t] += u;
    __syncthreads();
  }
  if (t < NB) bsum[t] = ps[t] - v;  // global bucket start (edges only)
}

// ---------------- K2c: partition edges into bucket-grouped (src,dst) pairs -
__global__ __launch_bounds__(256) void k_part(const int* __restrict__ ei,
                                              const int* __restrict__ cnt,
                                              const int* __restrict__ bsum,
                                              int2* __restrict__ ebuf, int E,
                                              int NB) {
  __shared__ int cur[MAXNB];
  int t = threadIdx.x;
  for (int b = t; b < NB; b += 256)
    cur[b] = bsum[b] + cnt[(size_t)b * PB + blockIdx.x];
  __syncthreads();
  int ch = (E + PB - 1) / PB;
  int lo = blockIdx.x * ch, hi = min(lo + ch, E);
  for (int e = lo + t; e < hi; e += 256) {
    int s = ei[e], d = ei[E + e];
    int pos = atomicAdd(&cur[d >> 8], 1);
    ebuf[pos] = make_int2(s, d);
  }
}

// ---------------- K2d: per-bucket CSR build (contiguous region writes) -----
__global__ __launch_bounds__(256) void k_bcsr(const int2* __restrict__ ebuf,
                                              const int* __restrict__ bsum,
                                              int* __restrict__ offs,
                                              int* __restrict__ csr, int N,
                                              int E, int NB) {
  __shared__ int dl[256];
  __shared__ int sc[256];
  __shared__ int cu[256];
  int b = blockIdx.x, t = threadIdx.x;
  int nn = min(256, N - b * 256);
  int rs = bsum[b];
  int re = (b + 1 < NB) ? bsum[b + 1] : E;
  int csrbase = rs + b * 256;
  dl[t] = 0;
  __syncthreads();
  for (int j = rs + t; j < re; j += 256)
    atomicAdd(&dl[ebuf[j].y & 255], 1);
  __syncthreads();
  int v = (t < nn) ? dl[t] + 1 : 0;
  sc[t] = v;
  __syncthreads();
  for (int d = 1; d < 256; d <<= 1) {
    int u = (t >= d) ? sc[t - d] : 0;
    __syncthreads();
    sc[t] += u;
    __syncthreads();
  }
  int excl = sc[t] - v;
  if (t < nn) {
    int node = b * 256 + t;
    offs[node] = csrbase + excl;
    csr[csrbase + excl] = node;  // self-loop slot
    cu[t] = excl + 1;
  }
  __syncthreads();
  for (int j = rs + t; j < re; j += 256) {
    int2 e = ebuf[j];
    int p = atomicAdd(&cu[e.y & 255], 1);
    csr[csrbase + p] = e.x;
  }
  if (b == 0 && t == 0) offs[N] = E + N;
}

// ---------------- K3: h1(fp8 e4m3) = (x*scale) @ W1 ; scores fp32 ----------
__global__ __launch_bounds__(256) void k_gemm1(
    const float* __restrict__ x, const float* __restrict__ scl,
    const float* __restrict__ W, const float* __restrict__ asv,
    const float* __restrict__ adv, unsigned char* __restrict__ h8,
    float* __restrict__ a_src, float* __restrict__ a_dst, int N) {
  __shared__ float WL[128 * 128];
  int tid = threadIdx.x;
#pragma unroll
  for (int i = 0; i < 16; i++)
    ((float4*)WL)[tid + i * 256] = ((const float4*)W)[tid + i * 256];
  __syncthreads();
  int wv = tid >> 6, l = tid & 63;
  int ngroups = gridDim.x * 4;
  for (int gI = blockIdx.x * 4 + wv; gI * 4 < N; gI += ngroups) {
    int base = gI * 4;
    float h0[4], h1r[4];
#pragma unroll
    for (int n = 0; n < 4; n++) {
      int node = base + n;
      if (node < N) {
        float2 v = *(const float2*)(x + (size_t)node * XDIM + 2 * l);
        h0[n] = v.x;
        h1r[n] = v.y;
      } else {
        h0[n] = 0.0f;
        h1r[n] = 0.0f;
      }
    }
    float a0[4] = {0, 0, 0, 0}, a1[4] = {0, 0, 0, 0};
#pragma unroll 8
    for (int k2 = 0; k2 < 64; k2++) {
      float2 we = *(const float2*)&WL[(2 * k2) * 128 + 2 * l];
      float2 wo = *(const float2*)&WL[(2 * k2 + 1) * 128 + 2 * l];
#pragma unroll
      for (int n = 0; n < 4; n++) {
        float he = rlf(h0[n], k2);
        float ho = rlf(h1r[n], k2);
        a0[n] = fmaf(he, we.x, fmaf(ho, wo.x, a0[n]));
        a1[n] = fmaf(he, we.y, fmaf(ho, wo.y, a1[n]));
      }
    }
    float asw0 = asv[2 * l], asw1 = asv[2 * l + 1];
    float adw0 = adv[2 * l], adw1 = adv[2 * l + 1];
#pragma unroll
    for (int n = 0; n < 4; n++) {
      int node = base + n;
      if (node >= N) break;
      float s = scl[node];
      float y0 = a0[n] * s, y1 = a1[n] * s;
      int pk = __builtin_amdgcn_cvt_pk_fp8_f32(y0, y1, 0, false);
      ((unsigned short*)(h8 + (size_t)node * FEAT))[l] = (unsigned short)pk;
      float ps = y0 * asw0 + y1 * asw1;
      float pd = y0 * adw0 + y1 * adw1;
      ps += __shfl_xor(ps, 1); ps += __shfl_xor(ps, 2); ps += __shfl_xor(ps, 4);
      pd += __shfl_xor(pd, 1); pd += __shfl_xor(pd, 2); pd += __shfl_xor(pd, 4);
      if ((l & 7) == 0) {
        a_src[node * NH + (l >> 3)] = ps;
        a_dst[node * NH + (l >> 3)] = pd;
      }
    }
  }
}

// ---------------- K4: layer-1 softmax-aggregate; h2(fp16) ------------------
// sweep1: lane=(edge e8=l>>3, head h=l&7): 1 load + 1 exp/lane; 3-shfl reduce.
// sweep2: 2 edges/wave (eg=l>>5), lane li=l&31 owns 4 fp8 ch; 4-deep prefetch.
__global__ __launch_bounds__(256) void k_agg1(
    const int* __restrict__ offs, const int* __restrict__ csr,
    const float* __restrict__ a_src, const float* __restrict__ a_dst,
    const unsigned char* __restrict__ h8, const float* __restrict__ bias,
    __half* __restrict__ h2h, int N) {
  __shared__ float plds[4][8 * PS];
  __shared__ int slds[4][128];
  int wv = threadIdx.x >> 6, l = threadIdx.x & 63;
  int n = blockIdx.x * 4 + wv;
  if (n >= N) return;
  int beg = offs[n], end = offs[n + 1];
  int deg = end - beg;
  int h = l & 7, e8 = l >> 3;
  float adh = a_dst[(size_t)n * NH + h];
  // sweep 1: p = exp(leaky(a_src[s,h] + ad[h])) -> LDS, per-head denom
  float smh = 0.0f;
  for (int j0 = 0; j0 < deg; j0 += 8) {
    int j = j0 + e8;
    if (j < deg) {
      int s = csr[beg + j];
      if (h == 0 && j < 128) slds[wv][j] = s;
      float t = a_src[(size_t)s * NH + h] + adh;
      t = t > 0.0f ? t : 0.2f * t;
      float p = __expf(t);
      smh += p;
      if (j < 128) plds[wv][h * PS + j] = p;
    }
  }
  smh += __shfl_xor(smh, 8);
  smh += __shfl_xor(smh, 16);
  smh += __shfl_xor(smh, 32);  // lane k holds denom of head k&7
  __builtin_amdgcn_wave_barrier();
  // sweep 2: 2 edges/step; lane li owns channels {4li..4li+3}, head hh=li>>2
  int li = l & 31, eg = l >> 5;
  int hh = li >> 2;
  float rd = 1.0f / __shfl(smh, hh);
  const int* sp = slds[wv];
  const float* pp = &plds[wv][hh * PS];
  float acc0 = 0.0f, acc1 = 0.0f, acc2 = 0.0f, acc3 = 0.0f;
  if (deg <= 128) {
    int dm1 = deg - 1;
    int ng = (deg + 1) >> 1;  // steps of 2 edges
    unsigned int cur[4], nxt[4];
#define ROWA(G) \
  (*(const unsigned int*)(h8 + (size_t)sp[min(2 * (G) + eg, dm1)] * FEAT + 4 * li))
#pragma unroll
    for (int i = 0; i < 4; i++) cur[i] = ROWA(i);
    for (int g = 0; g < ng; g += 4) {
#pragma unroll
      for (int i = 0; i < 4; i++) nxt[i] = ROWA(g + 4 + i);
#pragma unroll
      for (int i = 0; i < 4; i++) {
        int j = 2 * (g + i) + eg;
        float a = (j < deg) ? pp[j] : 0.0f;
        v2f lo = __builtin_amdgcn_cvt_pk_f32_fp8((int)cur[i], false);
        v2f hi = __builtin_amdgcn_cvt_pk_f32_fp8((int)cur[i], true);
        acc0 = fmaf(a, lo[0], acc0);
        acc1 = fmaf(a, lo[1], acc1);
        acc2 = fmaf(a, hi[0], acc2);
        acc3 = fmaf(a, hi[1], acc3);
        cur[i] = nxt[i];
      }
    }
#undef ROWA
  } else {
    float adhh = __shfl(adh, hh);
    for (int j = eg; j < deg; j += 2) {
      int s;
      float p;
      if (j < 128) {
        s = sp[j];
        p = pp[j];
      } else {
        s = csr[beg + j];
        float t = a_src[(size_t)s * NH + hh] + adhh;
        t = t > 0.0f ? t : 0.2f * t;
        p = __expf(t);
      }
      unsigned int w =
          *(const unsigned int*)(h8 + (size_t)s * FEAT + 4 * li);
      v2f lo = __builtin_amdgcn_cvt_pk_f32_fp8((int)w, false);
      v2f hi = __builtin_amdgcn_cvt_pk_f32_fp8((int)w, true);
      acc0 = fmaf(p, lo[0], acc0);
      acc1 = fmaf(p, lo[1], acc1);
      acc2 = fmaf(p, hi[0], acc2);
      acc3 = fmaf(p, hi[1], acc3);
    }
  }
  acc0 += __shfl_xor(acc0, 32);
  acc1 += __shfl_xor(acc1, 32);
  acc2 += __shfl_xor(acc2, 32);
  acc3 += __shfl_xor(acc3, 32);
  if (l < 32) {
    float4 bv = *(const float4*)(bias + 4 * l);
    float o0 = fmaxf(acc0 * rd + bv.x, 0.0f);
    float o1 = fmaxf(acc1 * rd + bv.y, 0.0f);
    float o2 = fmaxf(acc2 * rd + bv.z, 0.0f);
    float o3 = fmaxf(acc3 * rd + bv.w, 0.0f);
    __half2 pa = __float22half2_rn(make_float2(o0, o1));
    __half2 pb = __float22half2_rn(make_float2(o2, o3));
    uint2 st;
    st.x = *(unsigned int*)&pa;
    st.y = *(unsigned int*)&pb;
    *(uint2*)(h2h + (size_t)n * FEAT + 4 * l) = st;
  }
}

// ---------------- K5: g40 = h2(fp16) @ W2 (fp16, packed 40) ----------------
__global__ __launch_bounds__(256) void k_gemm2(
    const __half* __restrict__ h2h, const float* __restrict__ W,
    const float* __restrict__ asv, const float* __restrict__ adv,
    __half* __restrict__ g40, float* __restrict__ a_src,
    float* __restrict__ a_dst, int N) {
  __shared__ float WL[128 * OUTD];
  int tid = threadIdx.x;
  for (int i = tid; i < 128 * OUTD; i += 256) WL[i] = W[i];
  __syncthreads();
  int wv = tid >> 6, l = tid & 63;
  int cw = min(l, OUTD - 1);
  int ngroups = gridDim.x * 4;
  for (int gI = blockIdx.x * 4 + wv; gI * 4 < N; gI += ngroups) {
    int base = gI * 4;
    float h0[4], h1r[4];
#pragma unroll
    for (int n = 0; n < 4; n++) {
      int node = base + n;
      if (node < N) {
        __half2 v = *(const __half2*)(h2h + (size_t)node * FEAT + 2 * l);
        float2 f = __half22float2(v);
        h0[n] = f.x;
        h1r[n] = f.y;
      } else {
        h0[n] = 0.0f;
        h1r[n] = 0.0f;
      }
    }
    float acc[4] = {0, 0, 0, 0};
#pragma unroll 8
    for (int k2 = 0; k2 < 64; k2++) {
      float we = WL[(2 * k2) * OUTD + cw];
      float wo = WL[(2 * k2 + 1) * OUTD + cw];
#pragma unroll
      for (int n = 0; n < 4; n++) {
        float he = rlf(h0[n], k2);
        float ho = rlf(h1r[n], k2);
        acc[n] = fmaf(he, we, fmaf(ho, wo, acc[n]));
      }
    }
    float asw = asv[cw], adw = adv[cw];
#pragma unroll
    for (int n = 0; n < 4; n++) {
      int node = base + n;
      if (node >= N) break;
      if (l < OUTD) g40[(size_t)node * GST + l] = __float2half(acc[n]);
      float ps = (l < OUTD) ? acc[n] * asw : 0.0f;
      float pd = (l < OUTD) ? acc[n] * adw : 0.0f;
      for (int m = 1; m < 64; m <<= 1) {
        ps += __shfl_xor(ps, m);
        pd += __shfl_xor(pd, m);
      }
      if (l == 0) {
        a_src[node] = ps;
        a_dst[node] = pd;
      }
    }
  }
}

// ---------------- K6: layer-2 softmax-aggregate + log_softmax --------------
// 4 edges/wave (eg=l>>4); lane li=l&15 (li<10) owns cols {4li..4li+3}.
__global__ __launch_bounds__(256) void k_agg2(
    const int* __restrict__ offs, const int* __restrict__ csr,
    const float* __restrict__ a_src, const float* __restrict__ a_dst,
    const __half* __restrict__ g40, const float* __restrict__ bias,
    float* __restrict__ out, int N) {
  __shared__ float plds[4][PS];
  __shared__ int slds[4][128];
  int wv = threadIdx.x >> 6, l = threadIdx.x & 63;
  int n = blockIdx.x * 4 + wv;
  if (n >= N) return;
  int beg = offs[n], end = offs[n + 1];
  int deg = end - beg;
  float adn = a_dst[n];
  float sm = 0.0f;
  for (int j0 = 0; j0 < deg; j0 += 64) {
    int j = j0 + l;
    if (j < deg) {
      int s = csr[beg + j];
      float t = a_src[s] + adn;
      t = t > 0.0f ? t : 0.2f * t;
      float p = __expf(t);
      sm += p;
      if (j < 128) {
        plds[wv][j] = p;
        slds[wv][j] = s;
      }
    }
  }
  for (int m = 1; m < 64; m <<= 1) sm += __shfl_xor(sm, m);
  float rd = 1.0f / sm;
  const int* sp = slds[wv];
  const float* pp = plds[wv];
  int li = l & 15, eg = l >> 4;
  int lic = min(li, 9);
  const __half* gb = g40 + 4 * lic;
  float acc0 = 0.0f, acc1 = 0.0f, acc2 = 0.0f, acc3 = 0.0f;
  if (deg <= 128) {
    int dm1 = deg - 1;
    int ns = (deg + 3) >> 2;  // steps of 4 edges
    uint2 cur[4], nxt[4];
#define ROWB(G) (*(const uint2*)(gb + (size_t)sp[min(4 * (G) + eg, dm1)] * GST))
#pragma unroll
    for (int i = 0; i < 4; i++) cur[i] = ROWB(i);
    for (int g = 0; g < ns; g += 4) {
#pragma unroll
      for (int i = 0; i < 4; i++) nxt[i] = ROWB(g + 4 + i);
#pragma unroll
      for (int i = 0; i < 4; i++) {
        int j = 4 * (g + i) + eg;
        float a = (j < deg) ? pp[j] : 0.0f;
        __half2 ha = *(__half2*)&cur[i].x;
        __half2 hb = *(__half2*)&cur[i].y;
        float2 fa = __half22float2(ha);
        float2 fb = __half22float2(hb);
        acc0 = fmaf(a, fa.x, acc0);
        acc1 = fmaf(a, fa.y, acc1);
        acc2 = fmaf(a, fb.x, acc2);
        acc3 = fmaf(a, fb.y, acc3);
        cur[i] = nxt[i];
      }
    }
#undef ROWB
  } else {
    for (int j = eg; j < deg; j += 4) {
      int s;
      float p;
      if (j < 128) {
        s = sp[j];
        p = pp[j];
      } else {
        s = csr[beg + j];
        float t = a_src[s] + adn;
        t = t > 0.0f ? t : 0.2f * t;
        p = __expf(t);
      }
      uint2 w = *(const uint2*)(gb + (size_t)s * GST);
      __half2 ha = *(__half2*)&w.x;
      __half2 hb = *(__half2*)&w.y;
      float2 fa = __half22float2(ha);
      float2 fb = __half22float2(hb);
      acc0 = fmaf(p, fa.x, acc0);
      acc1 = fmaf(p, fa.y, acc1);
      acc2 = fmaf(p, fb.x, acc2);
      acc3 = fmaf(p, fb.y, acc3);
    }
  }
#pragma unroll
  for (int m = 16; m < 64; m <<= 1) {
    acc0 += __shfl_xor(acc0, m);
    acc1 += __shfl_xor(acc1, m);
    acc2 += __shfl_xor(acc2, m);
    acc3 += __shfl_xor(acc3, m);
  }
  bool cact = li < 10;
  float v0 = -INFINITY, v1 = -INFINITY, v2 = -INFINITY, v3 = -INFINITY;
  if (cact) {
    float4 bv = *(const float4*)(bias + 4 * li);
    v0 = acc0 * rd + bv.x;
    v1 = acc1 * rd + bv.y;
    v2 = acc2 * rd + bv.z;
    v3 = acc3 * rd + bv.w;
  }
  float mx = fmaxf(fmaxf(v0, v1), fmaxf(v2, v3));
  for (int m = 1; m < 64; m <<= 1) mx = fmaxf(mx, __shfl_xor(mx, m));
  // only eg==0 lanes contribute to the denominator (eg=1..3 hold copies)
  float pe = (eg == 0 && cact) ? __expf(v0 - mx) + __expf(v1 - mx) +
                                     __expf(v2 - mx) + __expf(v3 - mx)
                               : 0.0f;
  float se = pe;
  for (int m = 1; m < 64; m <<= 1) se += __shfl_xor(se, m);
  float ls = logf(se);
  if (eg == 0 && cact) {
    float4 o;
    o.x = v0 - mx - ls;
    o.y = v1 - mx - ls;
    o.z = v2 - mx - ls;
    o.w = v3 - mx - ls;
    *(float4*)(out + (size_t)n * OUTD + 4 * li) = o;
  }
}

// ---------------------------------------------------------------------------
extern "C" void kernel_launch(void* const* d_in, const int* in_sizes, int n_in,
                              void* d_out, int out_size, void* d_ws,
                              size_t ws_size, hipStream_t stream) {
  const float* x = (const float*)d_in[0];
  const int* ei = (const int*)d_in[1];
  const float* mw1 = (const float*)d_in[2];
  const float* mb1 = (const float*)d_in[3];
  const float* mw2 = (const float*)d_in[4];
  const float* mb2 = (const float*)d_in[5];
  const float* W1 = (const float*)d_in[6];
  const float* as1w = (const float*)d_in[7];
  const float* ad1w = (const float*)d_in[8];
  const float* b1 = (const float*)d_in[9];
  const float* W2 = (const float*)d_in[10];
  const float* as2w = (const float*)d_in[11];
  const float* ad2w = (const float*)d_in[12];
  const float* b2 = (const float*)d_in[13];
  float* out = (float*)d_out;

  int N = in_sizes[0] / XDIM;
  int E = in_sizes[1] / 2;
  int ET = E + N;
  int NB = (N + 255) >> 8;  // dst buckets of 256 nodes

  char* ws = (char*)d_ws;
  size_t off = 0;
  auto carve = [&](size_t bytes) -> void* {
    void* p = ws + off;
    off = (off + bytes + 255) & ~(size_t)255;
    return p;
  };
  float* stats = (float*)carve(64);
  float* part = (float*)carve((size_t)SB * 12 * 4);
  int* cnt = (int*)carve((size_t)NB * PB * 4);
  int* bsum = (int*)carve((size_t)MAXNB * 4);
  int2* ebuf = (int2*)carve((size_t)E * 8);
  int* offs = (int*)carve((size_t)(N + 1) * 4);
  int* csr = (int*)carve((size_t)ET * 4);
  float* scl = (float*)carve((size_t)N * 4);
  float* as1 = (float*)carve((size_t)N * NH * 4);
  float* ad1 = (float*)carve((size_t)N * NH * 4);
  unsigned char* h8 = (unsigned char*)carve((size_t)N * FEAT);
  __half* h2h = (__half*)carve((size_t)N * FEAT * 2);
  __half* g40 = (__half*)carve((size_t)N * GST * 2);
  float* as2 = (float*)carve((size_t)N * 4);
  float* ad2 = (float*)carve((size_t)N * 4);

  k_stats1<<<SB, 256, 0, stream>>>(x, part, N);
  k_stats2<<<1, 256, 0, stream>>>(part, stats);
  k_scale<<<(N + 255) / 256, 256, 0, stream>>>(x, stats, mw1, mb1, mw2, mb2,
                                               scl, N);
  k_bh<<<PB, 256, 0, stream>>>(ei, cnt, E, NB);
  k_sc1<<<NB, 256, 0, stream>>>(cnt, bsum);
  k_sc2<<<1, 256, 0, stream>>>(bsum, NB);
  k_part<<<PB, 256, 0, stream>>>(ei, cnt, bsum, ebuf, E, NB);
  k_bcsr<<<NB, 256, 0, stream>>>(ebuf, bsum, offs, csr, N, E, NB);
  k_gemm1<<<1280, 256, 0, stream>>>(x, scl, W1, as1w, ad1w, h8, as1, ad1, N);
  k_agg1<<<(N + 3) / 4, 256, 0, stream>>>(offs, csr, as1, ad1, h8, b1, h2h, N);
  k_gemm2<<<1280, 256, 0, stream>>>(h2h, W2, as2w, ad2w, g40, as2, ad2, N);
  k_agg2<<<(N + 3) / 4, 256, 0, stream>>>(offs, csr, as2, ad2, g40, b2, out, N);
}

// Round 11
// 218.335 us; speedup vs baseline: 4.0389x; 1.1148x over previous
//
#include <hip/hip_runtime.h>
#include <hip/hip_fp16.h>

#define XDIM 134
#define FEAT 128
#define AUGN 6
#define NH 8
#define HD 16
#define OUTD 40
#define PS 132       // per-head stride in plds (132 mod 32 = 4 -> conflict-free)
#define SB 256       // stats partial blocks
#define PB 256       // partition blocks
#define MAXNB 256    // max buckets (N <= 65536)
#define GST 40       // g row stride in halfs (80 B)
#define WTS 130      // W^T LDS stride in halves (bank-spread, b32-aligned)
#define DST 132      // D LDS stride in halves

typedef float v2f __attribute__((ext_vector_type(2)));
typedef _Float16 h8t __attribute__((ext_vector_type(8)));
typedef float f32x4 __attribute__((ext_vector_type(4)));

__device__ __forceinline__ float rlf(float v, int lane) {
  return __int_as_float(__builtin_amdgcn_readlane(__float_as_int(v), lane));
}

// ---------------- K0a: per-block partial sums/sumsq of aug columns ---------
__global__ __launch_bounds__(256) void k_stats1(const float* __restrict__ x,
                                                float* __restrict__ part,
                                                int N) {
  __shared__ float red[4][12];
  float s[AUGN] = {0, 0, 0, 0, 0, 0}, q[AUGN] = {0, 0, 0, 0, 0, 0};
  for (int n = blockIdx.x * blockDim.x + threadIdx.x; n < N;
       n += gridDim.x * blockDim.x) {
    const float* r = x + (size_t)n * XDIM + FEAT;
    float2 v0 = *(const float2*)r;
    float2 v1 = *(const float2*)(r + 2);
    float2 v2 = *(const float2*)(r + 4);
    float v[AUGN] = {v0.x, v0.y, v1.x, v1.y, v2.x, v2.y};
#pragma unroll
    for (int i = 0; i < AUGN; i++) {
      s[i] += v[i];
      q[i] += v[i] * v[i];
    }
  }
#pragma unroll
  for (int i = 0; i < AUGN; i++) {
    for (int m = 1; m < 64; m <<= 1) {
      s[i] += __shfl_xor(s[i], m);
      q[i] += __shfl_xor(q[i], m);
    }
  }
  int wv = threadIdx.x >> 6, l = threadIdx.x & 63;
  if (l == 0) {
#pragma unroll
    for (int i = 0; i < AUGN; i++) {
      red[wv][i] = s[i];
      red[wv][6 + i] = q[i];
    }
  }
  __syncthreads();
  int t = threadIdx.x;
  if (t < 12) {
    part[blockIdx.x * 12 + t] =
        red[0][t] + red[1][t] + red[2][t] + red[3][t];
  }
}

// ---------------- K0b: reduce SB partials -> stats[0..5], stats[8..13] -----
__global__ __launch_bounds__(256) void k_stats2(const float* __restrict__ part,
                                                float* __restrict__ stats) {
  __shared__ float red[4][12];
  int t = threadIdx.x;
  float v[12];
#pragma unroll
  for (int c = 0; c < 12; c++) v[c] = part[t * 12 + c];
#pragma unroll
  for (int c = 0; c < 12; c++)
    for (int m = 1; m < 64; m <<= 1) v[c] += __shfl_xor(v[c], m);
  int wv = t >> 6, l = t & 63;
  if (l == 0) {
#pragma unroll
    for (int c = 0; c < 12; c++) red[wv][c] = v[c];
  }
  __syncthreads();
  if (t < 12) {
    float s = red[0][t] + red[1][t] + red[2][t] + red[3][t];
    stats[t < 6 ? t : t + 2] = s;
  }
}

// ---------------- K1: per-node scale = 1 + sigmoid(MLP(norm(aug))) ----------
__global__ __launch_bounds__(256) void k_scale(
    const float* __restrict__ x, const float* __restrict__ stats,
    const float* __restrict__ w1, const float* __restrict__ b1,
    const float* __restrict__ w2, const float* __restrict__ b2,
    float* __restrict__ scl, int N) {
  int n = blockIdx.x * blockDim.x + threadIdx.x;
  if (n >= N) return;
  const float* r = x + (size_t)n * XDIM + FEAT;
  float a[AUGN];
  float invN = 1.0f / (float)N;
#pragma unroll
  for (int i = 0; i < AUGN; i++) {
    float sum = stats[i], sq = stats[8 + i];
    float mean = sum * invN;
    float var = (sq - sum * mean) / (float)(N - 1);
    a[i] = (r[i] - mean) / sqrtf(var);
  }
  float s2 = b2[0];
#pragma unroll
  for (int j = 0; j < 16; j++) {
    float z = b1[j];
#pragma unroll
    for (int i = 0; i < AUGN; i++) z = fmaf(a[i], w1[i * 16 + j], z);
    z = fmaxf(z, 0.0f);
    s2 = fmaf(z, w2[j], s2);
  }
  float sig = 1.0f / (1.0f + __expf(-s2));
  scl[n] = 1.0f + sig;
}

// ---------------- K2a: per-(block,bucket) histogram of dst>>8 --------------
__global__ __launch_bounds__(256) void k_bh(const int* __restrict__ ei,
                                            int* __restrict__ cnt, int E,
                                            int NB) {
  __shared__ int hist[MAXNB];
  int t = threadIdx.x;
  for (int b = t; b < NB; b += 256) hist[b] = 0;
  __syncthreads();
  int ch = (E + PB - 1) / PB;
  int lo = blockIdx.x * ch, hi = min(lo + ch, E);
  for (int e = lo + t; e < hi; e += 256)
    atomicAdd(&hist[ei[E + e] >> 8], 1);
  __syncthreads();
  for (int b = t; b < NB; b += 256)
    cnt[(size_t)b * PB + blockIdx.x] = hist[b];
}

// ---------------- K2b-1: per-bucket exclusive scan of its 256 counts -------
__global__ __launch_bounds__(256) void k_sc1(int* __restrict__ cnt,
                                             int* __restrict__ bsum) {
  __shared__ int ps[256];
  int b = blockIdx.x, t = threadIdx.x;
  int v = cnt[(size_t)b * PB + t];
  ps[t] = v;
  __syncthreads();
  for (int d = 1; d < 256; d <<= 1) {
    int u = (t >= d) ? ps[t - d] : 0;
    __syncthreads();
    ps[t] += u;
    __syncthreads();
  }
  cnt[(size_t)b * PB + t] = ps[t] - v;  // exclusive within bucket
  if (t == 255) bsum[b] = ps[255];
}

// ---------------- K2b-2: exclusive scan of bsum[NB] (NB <= 256) ------------
__global__ __launch_bounds__(256) void k_sc2(int* __restrict__ bsum, int NB) {
  __shared__ int ps[256];
  int t = threadIdx.x;
  int v = (t < NB) ? bsum[t] : 0;
  ps[t] = v;
  __syncthreads();
  for (int d = 1; d < 256; d <<= 1) {
    int u = (t >= d) ? ps[t - d] : 0;
    __syncthreads();
    ps[t] += u;
    __syncthreads();
  }
  if (t < NB) bsum[t] = ps[t] - v;  // global bucket start (edges only)
}

// ---------------- K2c: partition edges into bucket-grouped (src,dst) pairs -
__global__ __launch_bounds__(256) void k_part(const int* __restrict__ ei,
                                              const int* __restrict__ cnt,
                                              const int* __restrict__ bsum,
                                              int2* __restrict__ ebuf, int E,
                                              int NB) {
  __shared__ int cur[MAXNB];
  int t = threadIdx.x;
  for (int b = t; b < NB; b += 256)
    cur[b] = bsum[b] + cnt[(size_t)b * PB + blockIdx.x];
  __syncthreads();
  int ch = (E + PB - 1) / PB;
  int lo = blockIdx.x * ch, hi = min(lo + ch, E);
  for (int e = lo + t; e < hi; e += 256) {
    int s = ei[e], d = ei[E + e];
    int pos = atomicAdd(&cur[d >> 8], 1);
    ebuf[pos] = make_int2(s, d);
  }
}

// ---------------- K2d: per-bucket CSR build (contiguous region writes) -----
__global__ __launch_bounds__(256) void k_bcsr(const int2* __restrict__ ebuf,
                                              const int* __restrict__ bsum,
                                              int* __restrict__ offs,
                                              int* __restrict__ csr, int N,
                                              int E, int NB) {
  __shared__ int dl[256];
  __shared__ int sc[256];
  __shared__ int cu[256];
  int b = blockIdx.x, t = threadIdx.x;
  int nn = min(256, N - b * 256);
  int rs = bsum[b];
  int re = (b + 1 < NB) ? bsum[b + 1] : E;
  int csrbase = rs + b * 256;
  dl[t] = 0;
  __syncthreads();
  for (int j = rs + t; j < re; j += 256)
    atomicAdd(&dl[ebuf[j].y & 255], 1);
  __syncthreads();
  int v = (t < nn) ? dl[t] + 1 : 0;
  sc[t] = v;
  __syncthreads();
  for (int d = 1; d < 256; d <<= 1) {
    int u = (t >= d) ? sc[t - d] : 0;
    __syncthreads();
    sc[t] += u;
    __syncthreads();
  }
  int excl = sc[t] - v;
  if (t < nn) {
    int node = b * 256 + t;
    offs[node] = csrbase + excl;
    csr[csrbase + excl] = node;  // self-loop slot
    cu[t] = excl + 1;
  }
  __syncthreads();
  for (int j = rs + t; j < re; j += 256) {
    int2 e = ebuf[j];
    int p = atomicAdd(&cu[e.y & 255], 1);
    csr[csrbase + p] = e.x;
  }
  if (b == 0 && t == 0) offs[N] = E + N;
}

// ---------------- K3: MFMA h1(fp8) = (x*scale) @ W1 ; scores fp32 ----------
// Block = 4 waves = one 64-node x 128-col tile, K=128 via 4x mfma 16x16x32.
// W^T staged fp16 in LDS (stride 130: coalesced read, conflict-free write).
// Wave w owns cols [32w,32w+32): 8 B-frags in regs. D -> LDS fp16 -> epilogue.
__global__ __launch_bounds__(256) void k_gemm1(
    const float* __restrict__ x, const float* __restrict__ scl,
    const float* __restrict__ W, const float* __restrict__ asv,
    const float* __restrict__ adv, unsigned char* __restrict__ h8,
    float* __restrict__ a_src, float* __restrict__ a_dst, int N) {
  __shared__ __half WT[128 * WTS];  // 33280 B
  __shared__ __half D16[64 * DST];  // 16896 B
  int tid = threadIdx.x;
  int wv = tid >> 6, l = tid & 63;
  int q = l >> 4, c = l & 15;
  // stage W^T as fp16: coalesced global read, bank-spread LDS write
  for (int idx = tid; idx < 128 * 128; idx += 256) {
    int k = idx >> 7, n = idx & 127;
    WT[n * WTS + k] = __float2half(W[idx]);
  }
  __syncthreads();
  // B fragments: bf[ct][kk][j] = W[k = kk*32+8q+j][col = 32wv+16ct+c]
  int colBase = wv * 32;
  h8t bf[2][4];
  const unsigned short* wtp = (const unsigned short*)WT;
#pragma unroll
  for (int ct = 0; ct < 2; ct++) {
#pragma unroll
    for (int kk = 0; kk < 4; kk++) {
      unsigned int* bu = (unsigned int*)&bf[ct][kk];
      int base = (colBase + ct * 16 + c) * WTS + kk * 32 + 8 * q;
#pragma unroll
      for (int p = 0; p < 4; p++)
        bu[p] = *(const unsigned int*)(wtp + base + 2 * p);
    }
  }
  int nodeBase = blockIdx.x * 64;
#pragma unroll
  for (int nt = 0; nt < 4; nt++) {
    int node = nodeBase + nt * 16 + c;
    const float* xr = x + (size_t)min(node, N - 1) * XDIM;
    h8t af[4];
#pragma unroll
    for (int kk = 0; kk < 4; kk++) {
      int k0 = kk * 32 + 8 * q;
#pragma unroll
      for (int p = 0; p < 4; p++) {
        float2 v = *(const float2*)(xr + k0 + 2 * p);
        af[kk][2 * p] = (_Float16)v.x;
        af[kk][2 * p + 1] = (_Float16)v.y;
      }
    }
    f32x4 a0 = {0.f, 0.f, 0.f, 0.f}, a1 = {0.f, 0.f, 0.f, 0.f};
#pragma unroll
    for (int kk = 0; kk < 4; kk++) {
      a0 = __builtin_amdgcn_mfma_f32_16x16x32_f16(af[kk], bf[0][kk], a0, 0, 0, 0);
      a1 = __builtin_amdgcn_mfma_f32_16x16x32_f16(af[kk], bf[1][kk], a1, 0, 0, 0);
    }
    // D layout: row = 4q + r, col = c (per 16x16 tile)
#pragma unroll
    for (int r = 0; r < 4; r++) {
      int row = nt * 16 + 4 * q + r;
      D16[row * DST + colBase + c] = __float2half(a0[r]);
      D16[row * DST + colBase + 16 + c] = __float2half(a1[r]);
    }
  }
  __syncthreads();
  // epilogue: wave wv handles nodes nodeBase+16wv .. +15; lane owns ch 2l,2l+1
  float asw0 = asv[2 * l], asw1 = asv[2 * l + 1];
  float adw0 = adv[2 * l], adw1 = adv[2 * l + 1];
  for (int i = 0; i < 16; i++) {
    int node = nodeBase + wv * 16 + i;
    if (node >= N) break;
    float s = scl[node];
    __half2 yh = *(const __half2*)&D16[(wv * 16 + i) * DST + 2 * l];
    float2 yf = __half22float2(yh);
    float y0 = yf.x * s, y1 = yf.y * s;
    int pk = __builtin_amdgcn_cvt_pk_fp8_f32(y0, y1, 0, false);
    ((unsigned short*)(h8 + (size_t)node * FEAT))[l] = (unsigned short)pk;
    float ps = y0 * asw0 + y1 * asw1;
    float pd = y0 * adw0 + y1 * adw1;
    ps += __shfl_xor(ps, 1); ps += __shfl_xor(ps, 2); ps += __shfl_xor(ps, 4);
    pd += __shfl_xor(pd, 1); pd += __shfl_xor(pd, 2); pd += __shfl_xor(pd, 4);
    if ((l & 7) == 0) {
      a_src[node * NH + (l >> 3)] = ps;
      a_dst[node * NH + (l >> 3)] = pd;
    }
  }
}

// ---------------- K4: layer-1 softmax-aggregate; h2(fp16) ------------------
// sweep1: lane=(edge e8=l>>3, head h=l&7): 1 load + 1 exp/lane; 3-shfl reduce.
// sweep2: 2 edges/wave (eg=l>>5), lane li=l&31 owns 4 fp8 ch; 4-deep prefetch.
__global__ __launch_bounds__(256) void k_agg1(
    const int* __restrict__ offs, const int* __restrict__ csr,
    const float* __restrict__ a_src, const float* __restrict__ a_dst,
    const unsigned char* __restrict__ h8, const float* __restrict__ bias,
    __half* __restrict__ h2h, int N) {
  __shared__ float plds[4][8 * PS];
  __shared__ int slds[4][128];
  int wv = threadIdx.x >> 6, l = threadIdx.x & 63;
  int n = blockIdx.x * 4 + wv;
  if (n >= N) return;
  int beg = offs[n], end = offs[n + 1];
  int deg = end - beg;
  int h = l & 7, e8 = l >> 3;
  float adh = a_dst[(size_t)n * NH + h];
  // sweep 1: p = exp(leaky(a_src[s,h] + ad[h])) -> LDS, per-head denom
  float smh = 0.0f;
  for (int j0 = 0; j0 < deg; j0 += 8) {
    int j = j0 + e8;
    if (j < deg) {
      int s = csr[beg + j];
      if (h == 0 && j < 128) slds[wv][j] = s;
      float t = a_src[(size_t)s * NH + h] + adh;
      t = t > 0.0f ? t : 0.2f * t;
      float p = __expf(t);
      smh += p;
      if (j < 128) plds[wv][h * PS + j] = p;
    }
  }
  smh += __shfl_xor(smh, 8);
  smh += __shfl_xor(smh, 16);
  smh += __shfl_xor(smh, 32);  // lane k holds denom of head k&7
  __builtin_amdgcn_wave_barrier();
  // sweep 2: 2 edges/step; lane li owns channels {4li..4li+3}, head hh=li>>2
  int li = l & 31, eg = l >> 5;
  int hh = li >> 2;
  float rd = 1.0f / __shfl(smh, hh);
  const int* sp = slds[wv];
  const float* pp = &plds[wv][hh * PS];
  float acc0 = 0.0f, acc1 = 0.0f, acc2 = 0.0f, acc3 = 0.0f;
  if (deg <= 128) {
    int dm1 = deg - 1;
    int ng = (deg + 1) >> 1;  // steps of 2 edges
    unsigned int cur[4], nxt[4];
#define ROWA(G) \
  (*(const unsigned int*)(h8 + (size_t)sp[min(2 * (G) + eg, dm1)] * FEAT + 4 * li))
#pragma unroll
    for (int i = 0; i < 4; i++) cur[i] = ROWA(i);
    for (int g = 0; g < ng; g += 4) {
#pragma unroll
      for (int i = 0; i < 4; i++) nxt[i] = ROWA(g + 4 + i);
#pragma unroll
      for (int i = 0; i < 4; i++) {
        int j = 2 * (g + i) + eg;
        float a = (j < deg) ? pp[j] : 0.0f;
        v2f lo = __builtin_amdgcn_cvt_pk_f32_fp8((int)cur[i], false);
        v2f hi = __builtin_amdgcn_cvt_pk_f32_fp8((int)cur[i], true);
        acc0 = fmaf(a, lo[0], acc0);
        acc1 = fmaf(a, lo[1], acc1);
        acc2 = fmaf(a, hi[0], acc2);
        acc3 = fmaf(a, hi[1], acc3);
        cur[i] = nxt[i];
      }
    }
#undef ROWA
  } else {
    float adhh = __shfl(adh, hh);
    for (int j = eg; j < deg; j += 2) {
      int s;
      float p;
      if (j < 128) {
        s = sp[j];
        p = pp[j];
      } else {
        s = csr[beg + j];
        float t = a_src[(size_t)s * NH + hh] + adhh;
        t = t > 0.0f ? t : 0.2f * t;
        p = __expf(t);
      }
      unsigned int w =
          *(const unsigned int*)(h8 + (size_t)s * FEAT + 4 * li);
      v2f lo = __builtin_amdgcn_cvt_pk_f32_fp8((int)w, false);
      v2f hi = __builtin_amdgcn_cvt_pk_f32_fp8((int)w, true);
      acc0 = fmaf(p, lo[0], acc0);
      acc1 = fmaf(p, lo[1], acc1);
      acc2 = fmaf(p, hi[0], acc2);
      acc3 = fmaf(p, hi[1], acc3);
    }
  }
  acc0 += __shfl_xor(acc0, 32);
  acc1 += __shfl_xor(acc1, 32);
  acc2 += __shfl_xor(acc2, 32);
  acc3 += __shfl_xor(acc3, 32);
  if (l < 32) {
    float4 bv = *(const float4*)(bias + 4 * l);
    float o0 = fmaxf(acc0 * rd + bv.x, 0.0f);
    float o1 = fmaxf(acc1 * rd + bv.y, 0.0f);
    float o2 = fmaxf(acc2 * rd + bv.z, 0.0f);
    float o3 = fmaxf(acc3 * rd + bv.w, 0.0f);
    __half2 pa = __float22half2_rn(make_float2(o0, o1));
    __half2 pb = __float22half2_rn(make_float2(o2, o3));
    uint2 st;
    st.x = *(unsigned int*)&pa;
    st.y = *(unsigned int*)&pb;
    *(uint2*)(h2h + (size_t)n * FEAT + 4 * l) = st;
  }
}

// ---------------- K5: g40 = h2(fp16) @ W2 (fp16, packed 40) ----------------
__global__ __launch_bounds__(256) void k_gemm2(
    const __half* __restrict__ h2h, const float* __restrict__ W,
    const float* __restrict__ asv, const float* __restrict__ adv,
    __half* __restrict__ g40, float* __restrict__ a_src,
    float* __restrict__ a_dst, int N) {
  __shared__ float WL[128 * OUTD];
  int tid = threadIdx.x;
  for (int i = tid; i < 128 * OUTD; i += 256) WL[i] = W[i];
  __syncthreads();
  int wv = tid >> 6, l = tid & 63;
  int cw = min(l, OUTD - 1);
  int ngroups = gridDim.x * 4;
  for (int gI = blockIdx.x * 4 + wv; gI * 4 < N; gI += ngroups) {
    int base = gI * 4;
    float h0[4], h1r[4];
#pragma unroll
    for (int n = 0; n < 4; n++) {
      int node = base + n;
      if (node < N) {
        __half2 v = *(const __half2*)(h2h + (size_t)node * FEAT + 2 * l);
        float2 f = __half22float2(v);
        h0[n] = f.x;
        h1r[n] = f.y;
      } else {
        h0[n] = 0.0f;
        h1r[n] = 0.0f;
      }
    }
    float acc[4] = {0, 0, 0, 0};
#pragma unroll 8
    for (int k2 = 0; k2 < 64; k2++) {
      float we = WL[(2 * k2) * OUTD + cw];
      float wo = WL[(2 * k2 + 1) * OUTD + cw];
#pragma unroll
      for (int n = 0; n < 4; n++) {
        float he = rlf(h0[n], k2);
        float ho = rlf(h1r[n], k2);
        acc[n] = fmaf(he, we, fmaf(ho, wo, acc[n]));
      }
    }
    float asw = asv[cw], adw = adv[cw];
#pragma unroll
    for (int n = 0; n < 4; n++) {
      int node = base + n;
      if (node >= N) break;
      if (l < OUTD) g40[(size_t)node * GST + l] = __float2half(acc[n]);
      float ps = (l < OUTD) ? acc[n] * asw : 0.0f;
      float pd = (l < OUTD) ? acc[n] * adw : 0.0f;
      for (int m = 1; m < 64; m <<= 1) {
        ps += __shfl_xor(ps, m);
        pd += __shfl_xor(pd, m);
      }
      if (l == 0) {
        a_src[node] = ps;
        a_dst[node] = pd;
      }
    }
  }
}

// ---------------- K6: layer-2 softmax-aggregate + log_softmax --------------
// 4 edges/wave (eg=l>>4); lane li=l&15 (li<10) owns cols {4li..4li+3}.
__global__ __launch_bounds__(256) void k_agg2(
    const int* __restrict__ offs, const int* __restrict__ csr,
    const float* __restrict__ a_src, const float* __restrict__ a_dst,
    const __half* __restrict__ g40, const float* __restrict__ bias,
    float* __restrict__ out, int N) {
  __shared__ float plds[4][PS];
  __shared__ int slds[4][128];
  int wv = threadIdx.x >> 6, l = threadIdx.x & 63;
  int n = blockIdx.x * 4 + wv;
  if (n >= N) return;
  int beg = offs[n], end = offs[n + 1];
  int deg = end - beg;
  float adn = a_dst[n];
  float sm = 0.0f;
  for (int j0 = 0; j0 < deg; j0 += 64) {
    int j = j0 + l;
    if (j < deg) {
      int s = csr[beg + j];
      float t = a_src[s] + adn;
      t = t > 0.0f ? t : 0.2f * t;
      float p = __expf(t);
      sm += p;
      if (j < 128) {
        plds[wv][j] = p;
        slds[wv][j] = s;
      }
    }
  }
  for (int m = 1; m < 64; m <<= 1) sm += __shfl_xor(sm, m);
  float rd = 1.0f / sm;
  const int* sp = slds[wv];
  const float* pp = plds[wv];
  int li = l & 15, eg = l >> 4;
  int lic = min(li, 9);
  const __half* gb = g40 + 4 * lic;
  float acc0 = 0.0f, acc1 = 0.0f, acc2 = 0.0f, acc3 = 0.0f;
  if (deg <= 128) {
    int dm1 = deg - 1;
    int ns = (deg + 3) >> 2;  // steps of 4 edges
    uint2 cur[4], nxt[4];
#define ROWB(G) (*(const uint2*)(gb + (size_t)sp[min(4 * (G) + eg, dm1)] * GST))
#pragma unroll
    for (int i = 0; i < 4; i++) cur[i] = ROWB(i);
    for (int g = 0; g < ns; g += 4) {
#pragma unroll
      for (int i = 0; i < 4; i++) nxt[i] = ROWB(g + 4 + i);
#pragma unroll
      for (int i = 0; i < 4; i++) {
        int j = 4 * (g + i) + eg;
        float a = (j < deg) ? pp[j] : 0.0f;
        __half2 ha = *(__half2*)&cur[i].x;
        __half2 hb = *(__half2*)&cur[i].y;
        float2 fa = __half22float2(ha);
        float2 fb = __half22float2(hb);
        acc0 = fmaf(a, fa.x, acc0);
        acc1 = fmaf(a, fa.y, acc1);
        acc2 = fmaf(a, fb.x, acc2);
        acc3 = fmaf(a, fb.y, acc3);
        cur[i] = nxt[i];
      }
    }
#undef ROWB
  } else {
    for (int j = eg; j < deg; j += 4) {
      int s;
      float p;
      if (j < 128) {
        s = sp[j];
        p = pp[j];
      } else {
        s = csr[beg + j];
        float t = a_src[s] + adn;
        t = t > 0.0f ? t : 0.2f * t;
        p = __expf(t);
      }
      uint2 w = *(const uint2*)(gb + (size_t)s * GST);
      __half2 ha = *(__half2*)&w.x;
      __half2 hb = *(__half2*)&w.y;
      float2 fa = __half22float2(ha);
      float2 fb = __half22float2(hb);
      acc0 = fmaf(p, fa.x, acc0);
      acc1 = fmaf(p, fa.y, acc1);
      acc2 = fmaf(p, fb.x, acc2);
      acc3 = fmaf(p, fb.y, acc3);
    }
  }
#pragma unroll
  for (int m = 16; m < 64; m <<= 1) {
    acc0 += __shfl_xor(acc0, m);
    acc1 += __shfl_xor(acc1, m);
    acc2 += __shfl_xor(acc2, m);
    acc3 += __shfl_xor(acc3, m);
  }
  bool cact = li < 10;
  float v0 = -INFINITY, v1 = -INFINITY, v2 = -INFINITY, v3 = -INFINITY;
  if (cact) {
    float4 bv = *(const float4*)(bias + 4 * li);
    v0 = acc0 * rd + bv.x;
    v1 = acc1 * rd + bv.y;
    v2 = acc2 * rd + bv.z;
    v3 = acc3 * rd + bv.w;
  }
  float mx = fmaxf(fmaxf(v0, v1), fmaxf(v2, v3));
  for (int m = 1; m < 64; m <<= 1) mx = fmaxf(mx, __shfl_xor(mx, m));
  // only eg==0 lanes contribute to the denominator (eg=1..3 hold copies)
  float pe = (eg == 0 && cact) ? __expf(v0 - mx) + __expf(v1 - mx) +
                                     __expf(v2 - mx) + __expf(v3 - mx)
                               : 0.0f;
  float se = pe;
  for (int m = 1; m < 64; m <<= 1) se += __shfl_xor(se, m);
  float ls = logf(se);
  if (eg == 0 && cact) {
    float4 o;
    o.x = v0 - mx - ls;
    o.y = v1 - mx - ls;
    o.z = v2 - mx - ls;
    o.w = v3 - mx - ls;
    *(float4*)(out + (size_t)n * OUTD + 4 * li) = o;
  }
}

// ---------------------------------------------------------------------------
extern "C" void kernel_launch(void* const* d_in, const int* in_sizes, int n_in,
                              void* d_out, int out_size, void* d_ws,
                              size_t ws_size, hipStream_t stream) {
  const float* x = (const float*)d_in[0];
  const int* ei = (const int*)d_in[1];
  const float* mw1 = (const float*)d_in[2];
  const float* mb1 = (const float*)d_in[3];
  const float* mw2 = (const float*)d_in[4];
  const float* mb2 = (const float*)d_in[5];
  const float* W1 = (const float*)d_in[6];
  const float* as1w = (const float*)d_in[7];
  const float* ad1w = (const float*)d_in[8];
  const float* b1 = (const float*)d_in[9];
  const float* W2 = (const float*)d_in[10];
  const float* as2w = (const float*)d_in[11];
  const float* ad2w = (const float*)d_in[12];
  const float* b2 = (const float*)d_in[13];
  float* out = (float*)d_out;

  int N = in_sizes[0] / XDIM;
  int E = in_sizes[1] / 2;
  int ET = E + N;
  int NB = (N + 255) >> 8;  // dst buckets of 256 nodes

  char* ws = (char*)d_ws;
  size_t off = 0;
  auto carve = [&](size_t bytes) -> void* {
    void* p = ws + off;
    off = (off + bytes + 255) & ~(size_t)255;
    return p;
  };
  float* stats = (float*)carve(64);
  float* part = (float*)carve((size_t)SB * 12 * 4);
  int* cnt = (int*)carve((size_t)NB * PB * 4);
  int* bsum = (int*)carve((size_t)MAXNB * 4);
  int2* ebuf = (int2*)carve((size_t)E * 8);
  int* offs = (int*)carve((size_t)(N + 1) * 4);
  int* csr = (int*)carve((size_t)ET * 4);
  float* scl = (float*)carve((size_t)N * 4);
  float* as1 = (float*)carve((size_t)N * NH * 4);
  float* ad1 = (float*)carve((size_t)N * NH * 4);
  unsigned char* h8 = (unsigned char*)carve((size_t)N * FEAT);
  __half* h2h = (__half*)carve((size_t)N * FEAT * 2);
  __half* g40 = (__half*)carve((size_t)N * GST * 2);
  float* as2 = (float*)carve((size_t)N * 4);
  float* ad2 = (float*)carve((size_t)N * 4);

  k_stats1<<<SB, 256, 0, stream>>>(x, part, N);
  k_stats2<<<1, 256, 0, stream>>>(part, stats);
  k_scale<<<(N + 255) / 256, 256, 0, stream>>>(x, stats, mw1, mb1, mw2, mb2,
                                               scl, N);
  k_bh<<<PB, 256, 0, stream>>>(ei, cnt, E, NB);
  k_sc1<<<NB, 256, 0, stream>>>(cnt, bsum);
  k_sc2<<<1, 256, 0, stream>>>(bsum, NB);
  k_part<<<PB, 256, 0, stream>>>(ei, cnt, bsum, ebuf, E, NB);
  k_bcsr<<<NB, 256, 0, stream>>>(ebuf, bsum, offs, csr, N, E, NB);
  int NB2 = (N + 63) / 64;
  k_gemm1<<<NB2, 256, 0, stream>>>(x, scl, W1, as1w, ad1w, h8, as1, ad1, N);
  k_agg1<<<(N + 3) / 4, 256, 0, stream>>>(offs, csr, as1, ad1, h8, b1, h2h, N);
  k_gemm2<<<1280, 256, 0, stream>>>(h2h, W2, as2w, ad2w, g40, as2, ad2, N);
  k_agg2<<<(N + 3) / 4, 256, 0, stream>>>(offs, csr, as2, ad2, g40, b2, out, N);
}

// Round 12
// 185.931 us; speedup vs baseline: 4.7428x; 1.1743x over previous
//
#include <hip/hip_runtime.h>
#include <hip/hip_fp16.h>

#define XDIM 134
#define FEAT 128
#define AUGN 6
#define NH 8
#define HD 16
#define OUTD 40
#define PS 132       // per-head stride in plds (132 mod 32 = 4 -> conflict-free)
#define SB 256       // stats partial blocks
#define PB 256       // partition blocks
#define MAXNB 256    // max buckets (N <= 65536)
#define GST 40       // g row stride in halfs (80 B)
#define WTS 130      // W^T LDS stride in halves (bank-spread, b32-aligned)
#define DST 132      // gemm1 D LDS stride in halves
#define W2C 48       // gemm2 padded cols
#define DST2 52      // gemm2 D LDS stride in floats

typedef float v2f __attribute__((ext_vector_type(2)));
typedef _Float16 h8t __attribute__((ext_vector_type(8)));
typedef float f32x4 __attribute__((ext_vector_type(4)));

__device__ __forceinline__ float rlf(float v, int lane) {
  return __int_as_float(__builtin_amdgcn_readlane(__float_as_int(v), lane));
}

// ---------------- K0a: per-block partial sums/sumsq of aug columns ---------
__global__ __launch_bounds__(256) void k_stats1(const float* __restrict__ x,
                                                float* __restrict__ part,
                                                int N) {
  __shared__ float red[4][12];
  float s[AUGN] = {0, 0, 0, 0, 0, 0}, q[AUGN] = {0, 0, 0, 0, 0, 0};
  for (int n = blockIdx.x * blockDim.x + threadIdx.x; n < N;
       n += gridDim.x * blockDim.x) {
    const float* r = x + (size_t)n * XDIM + FEAT;
    float2 v0 = *(const float2*)r;
    float2 v1 = *(const float2*)(r + 2);
    float2 v2 = *(const float2*)(r + 4);
    float v[AUGN] = {v0.x, v0.y, v1.x, v1.y, v2.x, v2.y};
#pragma unroll
    for (int i = 0; i < AUGN; i++) {
      s[i] += v[i];
      q[i] += v[i] * v[i];
    }
  }
#pragma unroll
  for (int i = 0; i < AUGN; i++) {
    for (int m = 1; m < 64; m <<= 1) {
      s[i] += __shfl_xor(s[i], m);
      q[i] += __shfl_xor(q[i], m);
    }
  }
  int wv = threadIdx.x >> 6, l = threadIdx.x & 63;
  if (l == 0) {
#pragma unroll
    for (int i = 0; i < AUGN; i++) {
      red[wv][i] = s[i];
      red[wv][6 + i] = q[i];
    }
  }
  __syncthreads();
  int t = threadIdx.x;
  if (t < 12) {
    part[blockIdx.x * 12 + t] =
        red[0][t] + red[1][t] + red[2][t] + red[3][t];
  }
}

// ---------------- K1: scale = 1 + sigmoid(MLP(norm(aug))) ------------------
// stats2 folded in: every block reduces part[SB*12] (3 KB) redundantly.
__global__ __launch_bounds__(256) void k_scale(
    const float* __restrict__ x, const float* __restrict__ part,
    const float* __restrict__ w1, const float* __restrict__ b1,
    const float* __restrict__ w2, const float* __restrict__ b2,
    float* __restrict__ scl, int N) {
  __shared__ float red[4][12];
  __shared__ float sred[12];
  int t = threadIdx.x;
  {
    float v[12];
#pragma unroll
    for (int c = 0; c < 12; c++) v[c] = part[t * 12 + c];
#pragma unroll
    for (int c = 0; c < 12; c++)
      for (int m = 1; m < 64; m <<= 1) v[c] += __shfl_xor(v[c], m);
    int wv = t >> 6, l = t & 63;
    if (l == 0) {
#pragma unroll
      for (int c = 0; c < 12; c++) red[wv][c] = v[c];
    }
    __syncthreads();
    if (t < 12) sred[t] = red[0][t] + red[1][t] + red[2][t] + red[3][t];
    __syncthreads();
  }
  int n = blockIdx.x * 256 + t;
  if (n >= N) return;
  const float* r = x + (size_t)n * XDIM + FEAT;
  float a[AUGN];
  float invN = 1.0f / (float)N;
#pragma unroll
  for (int i = 0; i < AUGN; i++) {
    float sum = sred[i], sq = sred[6 + i];
    float mean = sum * invN;
    float var = (sq - sum * mean) / (float)(N - 1);
    a[i] = (r[i] - mean) / sqrtf(var);
  }
  float s2 = b2[0];
#pragma unroll
  for (int j = 0; j < 16; j++) {
    float z = b1[j];
#pragma unroll
    for (int i = 0; i < AUGN; i++) z = fmaf(a[i], w1[i * 16 + j], z);
    z = fmaxf(z, 0.0f);
    s2 = fmaf(z, w2[j], s2);
  }
  float sig = 1.0f / (1.0f + __expf(-s2));
  scl[n] = 1.0f + sig;
}

// ---------------- K2a: per-(block,bucket) histogram of dst>>8 --------------
__global__ __launch_bounds__(256) void k_bh(const int* __restrict__ ei,
                                            int* __restrict__ cnt, int E,
                                            int NB) {
  __shared__ int hist[MAXNB];
  int t = threadIdx.x;
  for (int b = t; b < NB; b += 256) hist[b] = 0;
  __syncthreads();
  int ch = (E + PB - 1) / PB;
  int lo = blockIdx.x * ch, hi = min(lo + ch, E);
  for (int e = lo + t; e < hi; e += 256)
    atomicAdd(&hist[ei[E + e] >> 8], 1);
  __syncthreads();
  for (int b = t; b < NB; b += 256)
    cnt[(size_t)b * PB + blockIdx.x] = hist[b];
}

// ---------------- K2b: per-bucket exclusive scan of its 256 counts ---------
// cnt[b][*] -> exclusive in place; bsum[b] = bucket total (raw).
__global__ __launch_bounds__(256) void k_sc1(int* __restrict__ cnt,
                                             int* __restrict__ bsum) {
  __shared__ int ps[256];
  int b = blockIdx.x, t = threadIdx.x;
  int v = cnt[(size_t)b * PB + t];
  ps[t] = v;
  __syncthreads();
  for (int d = 1; d < 256; d <<= 1) {
    int u = (t >= d) ? ps[t - d] : 0;
    __syncthreads();
    ps[t] += u;
    __syncthreads();
  }
  cnt[(size_t)b * PB + t] = ps[t] - v;  // exclusive within bucket
  if (t == 255) bsum[b] = ps[255];
}

// ---------------- K2c: partition edges into bucket-grouped packed ints -----
// sc2 folded: scan raw bsum in LDS. ebuf word = (src<<8) | (dst&255).
__global__ __launch_bounds__(256) void k_part(const int* __restrict__ ei,
                                              const int* __restrict__ cnt,
                                              const int* __restrict__ bsum,
                                              int* __restrict__ ebuf, int E,
                                              int NB) {
  __shared__ int bex[MAXNB];
  __shared__ int cur[MAXNB];
  int t = threadIdx.x;
  int v = (t < NB) ? bsum[t] : 0;
  bex[t] = v;
  __syncthreads();
  for (int d = 1; d < 256; d <<= 1) {
    int u = (t >= d) ? bex[t - d] : 0;
    __syncthreads();
    bex[t] += u;
    __syncthreads();
  }
  if (t < NB) cur[t] = (bex[t] - v) + cnt[(size_t)t * PB + blockIdx.x];
  __syncthreads();
  int ch = (E + PB - 1) / PB;
  int lo = blockIdx.x * ch, hi = min(lo + ch, E);
  for (int e = lo + t; e < hi; e += 256) {
    int s = ei[e], d = ei[E + e];
    int pos = atomicAdd(&cur[d >> 8], 1);
    ebuf[pos] = (s << 8) | (d & 255);
  }
}

// ---------------- K2d: per-bucket CSR build (contiguous region writes) -----
__global__ __launch_bounds__(256) void k_bcsr(const int* __restrict__ ebuf,
                                              const int* __restrict__ bsum,
                                              int* __restrict__ offs,
                                              int* __restrict__ csr, int N,
                                              int E, int NB) {
  __shared__ int bex[MAXNB];
  __shared__ int dl[256];
  __shared__ int sc[256];
  __shared__ int cu[256];
  int b = blockIdx.x, t = threadIdx.x;
  {
    int v = (t < NB) ? bsum[t] : 0;
    bex[t] = v;
    __syncthreads();
    for (int d = 1; d < 256; d <<= 1) {
      int u = (t >= d) ? bex[t - d] : 0;
      __syncthreads();
      bex[t] += u;
      __syncthreads();
    }
    int incl = bex[t];
    __syncthreads();
    bex[t] = incl - v;  // exclusive
    __syncthreads();
  }
  int nn = min(256, N - b * 256);
  int rs = bex[b];
  int re = (b + 1 < NB) ? bex[b + 1] : E;
  int csrbase = rs + b * 256;
  dl[t] = 0;
  __syncthreads();
  for (int j = rs + t; j < re; j += 256)
    atomicAdd(&dl[ebuf[j] & 255], 1);
  __syncthreads();
  int v = (t < nn) ? dl[t] + 1 : 0;
  sc[t] = v;
  __syncthreads();
  for (int d = 1; d < 256; d <<= 1) {
    int u = (t >= d) ? sc[t - d] : 0;
    __syncthreads();
    sc[t] += u;
    __syncthreads();
  }
  int excl = sc[t] - v;
  if (t < nn) {
    int node = b * 256 + t;
    offs[node] = csrbase + excl;
    csr[csrbase + excl] = node;  // self-loop slot
    cu[t] = excl + 1;
  }
  __syncthreads();
  for (int j = rs + t; j < re; j += 256) {
    int pk = ebuf[j];
    int p = atomicAdd(&cu[pk & 255], 1);
    csr[csrbase + p] = pk >> 8;
  }
  if (b == 0 && t == 0) offs[N] = E + N;
}

// ---------------- K3: MFMA h1(fp8) = (x*scale) @ W1 ; scores fp32 ----------
__global__ __launch_bounds__(256) void k_gemm1(
    const float* __restrict__ x, const float* __restrict__ scl,
    const float* __restrict__ W, const float* __restrict__ asv,
    const float* __restrict__ adv, unsigned char* __restrict__ h8,
    float* __restrict__ a_src, float* __restrict__ a_dst, int N) {
  __shared__ __half WT[128 * WTS];  // 33280 B
  __shared__ __half D16[64 * DST];  // 16896 B
  int tid = threadIdx.x;
  int wv = tid >> 6, l = tid & 63;
  int q = l >> 4, c = l & 15;
  for (int idx = tid; idx < 128 * 128; idx += 256) {
    int k = idx >> 7, n = idx & 127;
    WT[n * WTS + k] = __float2half(W[idx]);
  }
  __syncthreads();
  int colBase = wv * 32;
  h8t bf[2][4];
  const unsigned short* wtp = (const unsigned short*)WT;
#pragma unroll
  for (int ct = 0; ct < 2; ct++) {
#pragma unroll
    for (int kk = 0; kk < 4; kk++) {
      unsigned int* bu = (unsigned int*)&bf[ct][kk];
      int base = (colBase + ct * 16 + c) * WTS + kk * 32 + 8 * q;
#pragma unroll
      for (int p = 0; p < 4; p++)
        bu[p] = *(const unsigned int*)(wtp + base + 2 * p);
    }
  }
  int nodeBase = blockIdx.x * 64;
#pragma unroll
  for (int nt = 0; nt < 4; nt++) {
    int node = nodeBase + nt * 16 + c;
    const float* xr = x + (size_t)min(node, N - 1) * XDIM;
    h8t af[4];
#pragma unroll
    for (int kk = 0; kk < 4; kk++) {
      int k0 = kk * 32 + 8 * q;
#pragma unroll
      for (int p = 0; p < 4; p++) {
        float2 v = *(const float2*)(xr + k0 + 2 * p);
        af[kk][2 * p] = (_Float16)v.x;
        af[kk][2 * p + 1] = (_Float16)v.y;
      }
    }
    f32x4 a0 = {0.f, 0.f, 0.f, 0.f}, a1 = {0.f, 0.f, 0.f, 0.f};
#pragma unroll
    for (int kk = 0; kk < 4; kk++) {
      a0 = __builtin_amdgcn_mfma_f32_16x16x32_f16(af[kk], bf[0][kk], a0, 0, 0, 0);
      a1 = __builtin_amdgcn_mfma_f32_16x16x32_f16(af[kk], bf[1][kk], a1, 0, 0, 0);
    }
#pragma unroll
    for (int r = 0; r < 4; r++) {
      int row = nt * 16 + 4 * q + r;
      D16[row * DST + colBase + c] = __float2half(a0[r]);
      D16[row * DST + colBase + 16 + c] = __float2half(a1[r]);
    }
  }
  __syncthreads();
  float asw0 = asv[2 * l], asw1 = asv[2 * l + 1];
  float adw0 = adv[2 * l], adw1 = adv[2 * l + 1];
  for (int i = 0; i < 16; i++) {
    int node = nodeBase + wv * 16 + i;
    if (node >= N) break;
    float s = scl[node];
    __half2 yh = *(const __half2*)&D16[(wv * 16 + i) * DST + 2 * l];
    float2 yf = __half22float2(yh);
    float y0 = yf.x * s, y1 = yf.y * s;
    int pk = __builtin_amdgcn_cvt_pk_fp8_f32(y0, y1, 0, false);
    ((unsigned short*)(h8 + (size_t)node * FEAT))[l] = (unsigned short)pk;
    float ps = y0 * asw0 + y1 * asw1;
    float pd = y0 * adw0 + y1 * adw1;
    ps += __shfl_xor(ps, 1); ps += __shfl_xor(ps, 2); ps += __shfl_xor(ps, 4);
    pd += __shfl_xor(pd, 1); pd += __shfl_xor(pd, 2); pd += __shfl_xor(pd, 4);
    if ((l & 7) == 0) {
      a_src[node * NH + (l >> 3)] = ps;
      a_dst[node * NH + (l >> 3)] = pd;
    }
  }
}

// ---------------- K4: layer-1 softmax-aggregate; h2(fp16) ------------------
// sweep1: lane=(edge e8, head h): 1 load + 1 exp/lane; 3-shfl reduce.
// sweep2: 4 edges/wave (eg=l>>4), lane li=l&15 owns 8 fp8 ch (uint2).
__global__ __launch_bounds__(256) void k_agg1(
    const int* __restrict__ offs, const int* __restrict__ csr,
    const float* __restrict__ a_src, const float* __restrict__ a_dst,
    const unsigned char* __restrict__ h8, const float* __restrict__ bias,
    __half* __restrict__ h2h, int N) {
  __shared__ float plds[4][8 * PS];
  __shared__ int slds[4][128];
  int wv = threadIdx.x >> 6, l = threadIdx.x & 63;
  int n = blockIdx.x * 4 + wv;
  if (n >= N) return;
  int beg = offs[n], end = offs[n + 1];
  int deg = end - beg;
  int h = l & 7, e8 = l >> 3;
  float adh = a_dst[(size_t)n * NH + h];
  float smh = 0.0f;
  for (int j0 = 0; j0 < deg; j0 += 8) {
    int j = j0 + e8;
    if (j < deg) {
      int s = csr[beg + j];
      if (h == 0 && j < 128) slds[wv][j] = s;
      float t = a_src[(size_t)s * NH + h] + adh;
      t = t > 0.0f ? t : 0.2f * t;
      float p = __expf(t);
      smh += p;
      if (j < 128) plds[wv][h * PS + j] = p;
    }
  }
  smh += __shfl_xor(smh, 8);
  smh += __shfl_xor(smh, 16);
  smh += __shfl_xor(smh, 32);  // lane k holds denom of head k&7
  __builtin_amdgcn_wave_barrier();
  // sweep 2: 4 edges/step; lane li owns channels {8li..8li+7}, head hh=li>>1
  int li = l & 15, eg = l >> 4;
  int hh = li >> 1;
  float rd = 1.0f / __shfl(smh, hh);
  const int* sp = slds[wv];
  const float* pp = &plds[wv][hh * PS];
  float acc0 = 0.f, acc1 = 0.f, acc2 = 0.f, acc3 = 0.f;
  float acc4 = 0.f, acc5 = 0.f, acc6 = 0.f, acc7 = 0.f;
  if (deg <= 128) {
    int dm1 = deg - 1;
    int ns = (deg + 3) >> 2;  // steps of 4 edges
    uint2 cur[4], nxt[4];
#define ROWA(G) \
  (*(const uint2*)(h8 + (size_t)sp[min(4 * (G) + eg, dm1)] * FEAT + 8 * li))
#pragma unroll
    for (int i = 0; i < 4; i++) cur[i] = ROWA(i);
    for (int g = 0; g < ns; g += 4) {
#pragma unroll
      for (int i = 0; i < 4; i++) nxt[i] = ROWA(g + 4 + i);
#pragma unroll
      for (int i = 0; i < 4; i++) {
        int j = 4 * (g + i) + eg;
        float a = (j < deg) ? pp[j] : 0.0f;
        v2f l0 = __builtin_amdgcn_cvt_pk_f32_fp8((int)cur[i].x, false);
        v2f h0 = __builtin_amdgcn_cvt_pk_f32_fp8((int)cur[i].x, true);
        v2f l1 = __builtin_amdgcn_cvt_pk_f32_fp8((int)cur[i].y, false);
        v2f h1 = __builtin_amdgcn_cvt_pk_f32_fp8((int)cur[i].y, true);
        acc0 = fmaf(a, l0[0], acc0); acc1 = fmaf(a, l0[1], acc1);
        acc2 = fmaf(a, h0[0], acc2); acc3 = fmaf(a, h0[1], acc3);
        acc4 = fmaf(a, l1[0], acc4); acc5 = fmaf(a, l1[1], acc5);
        acc6 = fmaf(a, h1[0], acc6); acc7 = fmaf(a, h1[1], acc7);
        cur[i] = nxt[i];
      }
    }
#undef ROWA
  } else {
    float adhh = __shfl(adh, hh);
    for (int j = eg; j < deg; j += 4) {
      int s;
      float p;
      if (j < 128) {
        s = sp[j];
        p = pp[j];
      } else {
        s = csr[beg + j];
        float t = a_src[(size_t)s * NH + hh] + adhh;
        t = t > 0.0f ? t : 0.2f * t;
        p = __expf(t);
      }
      uint2 w = *(const uint2*)(h8 + (size_t)s * FEAT + 8 * li);
      v2f l0 = __builtin_amdgcn_cvt_pk_f32_fp8((int)w.x, false);
      v2f h0 = __builtin_amdgcn_cvt_pk_f32_fp8((int)w.x, true);
      v2f l1 = __builtin_amdgcn_cvt_pk_f32_fp8((int)w.y, false);
      v2f h1 = __builtin_amdgcn_cvt_pk_f32_fp8((int)w.y, true);
      acc0 = fmaf(p, l0[0], acc0); acc1 = fmaf(p, l0[1], acc1);
      acc2 = fmaf(p, h0[0], acc2); acc3 = fmaf(p, h0[1], acc3);
      acc4 = fmaf(p, l1[0], acc4); acc5 = fmaf(p, l1[1], acc5);
      acc6 = fmaf(p, h1[0], acc6); acc7 = fmaf(p, h1[1], acc7);
    }
  }
#pragma unroll
  for (int m = 16; m < 64; m <<= 1) {
    acc0 += __shfl_xor(acc0, m); acc1 += __shfl_xor(acc1, m);
    acc2 += __shfl_xor(acc2, m); acc3 += __shfl_xor(acc3, m);
    acc4 += __shfl_xor(acc4, m); acc5 += __shfl_xor(acc5, m);
    acc6 += __shfl_xor(acc6, m); acc7 += __shfl_xor(acc7, m);
  }
  if (l < 16) {
    float4 b0 = *(const float4*)(bias + 8 * l);
    float4 b1v = *(const float4*)(bias + 8 * l + 4);
    float o0 = fmaxf(acc0 * rd + b0.x, 0.0f);
    float o1 = fmaxf(acc1 * rd + b0.y, 0.0f);
    float o2 = fmaxf(acc2 * rd + b0.z, 0.0f);
    float o3 = fmaxf(acc3 * rd + b0.w, 0.0f);
    float o4 = fmaxf(acc4 * rd + b1v.x, 0.0f);
    float o5 = fmaxf(acc5 * rd + b1v.y, 0.0f);
    float o6 = fmaxf(acc6 * rd + b1v.z, 0.0f);
    float o7 = fmaxf(acc7 * rd + b1v.w, 0.0f);
    __half2 pa = __float22half2_rn(make_float2(o0, o1));
    __half2 pb = __float22half2_rn(make_float2(o2, o3));
    __half2 pc = __float22half2_rn(make_float2(o4, o5));
    __half2 pd2 = __float22half2_rn(make_float2(o6, o7));
    uint4 st;
    st.x = *(unsigned int*)&pa;
    st.y = *(unsigned int*)&pb;
    st.z = *(unsigned int*)&pc;
    st.w = *(unsigned int*)&pd2;
    *(uint4*)(h2h + (size_t)n * FEAT + 8 * l) = st;
  }
}

// ---------------- K5: MFMA g40 = h2(fp16) @ W2 ; a_src2/a_dst2 -------------
// Block = 4 waves x 16 nodes; 3 col-tiles (40->48) x 4 K-steps = 12 MFMA/wave.
__global__ __launch_bounds__(256) void k_gemm2(
    const __half* __restrict__ h2h, const float* __restrict__ W,
    const float* __restrict__ asv, const float* __restrict__ adv,
    __half* __restrict__ g40, float* __restrict__ a_src,
    float* __restrict__ a_dst, int N) {
  __shared__ __half WT2[W2C * WTS];  // 12480 B
  __shared__ float DL[64 * DST2];    // 13312 B
  int tid = threadIdx.x;
  int wv = tid >> 6, l = tid & 63;
  int q = l >> 4, c = l & 15;
  for (int idx = tid; idx < W2C * 128; idx += 256) {
    int col = idx >> 7, k = idx & 127;
    float v = (col < OUTD) ? W[k * OUTD + col] : 0.0f;
    WT2[col * WTS + k] = __float2half(v);
  }
  __syncthreads();
  h8t bf[3][4];
  const unsigned short* wtp = (const unsigned short*)WT2;
#pragma unroll
  for (int ct = 0; ct < 3; ct++) {
#pragma unroll
    for (int kk = 0; kk < 4; kk++) {
      unsigned int* bu = (unsigned int*)&bf[ct][kk];
      int base = (ct * 16 + c) * WTS + kk * 32 + 8 * q;
#pragma unroll
      for (int p = 0; p < 4; p++)
        bu[p] = *(const unsigned int*)(wtp + base + 2 * p);
    }
  }
  int nodeBase = blockIdx.x * 64;
  int node = nodeBase + wv * 16 + c;
  const __half* hr = h2h + (size_t)min(node, N - 1) * FEAT;
  h8t af[4];
#pragma unroll
  for (int kk = 0; kk < 4; kk++) {
    uint4 v = *(const uint4*)(hr + kk * 32 + 8 * q);
    *(uint4*)&af[kk] = v;
  }
  f32x4 d0 = {0.f, 0.f, 0.f, 0.f}, d1 = {0.f, 0.f, 0.f, 0.f},
        d2 = {0.f, 0.f, 0.f, 0.f};
#pragma unroll
  for (int kk = 0; kk < 4; kk++) {
    d0 = __builtin_amdgcn_mfma_f32_16x16x32_f16(af[kk], bf[0][kk], d0, 0, 0, 0);
    d1 = __builtin_amdgcn_mfma_f32_16x16x32_f16(af[kk], bf[1][kk], d1, 0, 0, 0);
    d2 = __builtin_amdgcn_mfma_f32_16x16x32_f16(af[kk], bf[2][kk], d2, 0, 0, 0);
  }
#pragma unroll
  for (int r = 0; r < 4; r++) {
    int row = wv * 16 + 4 * q + r;
    DL[row * DST2 + c] = d0[r];
    DL[row * DST2 + 16 + c] = d1[r];
    DL[row * DST2 + 32 + c] = d2[r];
  }
  __syncthreads();
  // scores: lane (i=l&15, cg=l>>4) sums cols cg*10..cg*10+9 of node row i
  int i = l & 15, cg = l >> 4;
  int row = wv * 16 + i;
  float ps = 0.0f, pd = 0.0f;
#pragma unroll
  for (int k = 0; k < 10; k++) {
    int col = cg * 10 + k;
    float gv = DL[row * DST2 + col];
    ps = fmaf(gv, asv[col], ps);
    pd = fmaf(gv, adv[col], pd);
  }
  ps += __shfl_xor(ps, 16); ps += __shfl_xor(ps, 32);
  pd += __shfl_xor(pd, 16); pd += __shfl_xor(pd, 32);
  int snode = nodeBase + wv * 16 + i;
  if (cg == 0 && snode < N) {
    a_src[snode] = ps;
    a_dst[snode] = pd;
  }
  // g40 write: 16 nodes x 20 uint words, coalesced from DL
  for (int idx = l; idx < 16 * 20; idx += 64) {
    int ni = idx / 20, w = idx - ni * 20;
    int rr = wv * 16 + ni;
    int wnode = nodeBase + rr;
    if (wnode < N) {
      float2 f = make_float2(DL[rr * DST2 + 2 * w], DL[rr * DST2 + 2 * w + 1]);
      *(__half2*)(g40 + (size_t)wnode * GST + 2 * w) = __float22half2_rn(f);
    }
  }
}

// ---------------- K6: layer-2 softmax-aggregate + log_softmax --------------
__global__ __launch_bounds__(256) void k_agg2(
    const int* __restrict__ offs, const int* __restrict__ csr,
    const float* __restrict__ a_src, const float* __restrict__ a_dst,
    const __half* __restrict__ g40, const float* __restrict__ bias,
    float* __restrict__ out, int N) {
  __shared__ float plds[4][PS];
  __shared__ int slds[4][128];
  int wv = threadIdx.x >> 6, l = threadIdx.x & 63;
  int n = blockIdx.x * 4 + wv;
  if (n >= N) return;
  int beg = offs[n], end = offs[n + 1];
  int deg = end - beg;
  float adn = a_dst[n];
  float sm = 0.0f;
  for (int j0 = 0; j0 < deg; j0 += 64) {
    int j = j0 + l;
    if (j < deg) {
      int s = csr[beg + j];
      float t = a_src[s] + adn;
      t = t > 0.0f ? t : 0.2f * t;
      float p = __expf(t);
      sm += p;
      if (j < 128) {
        plds[wv][j] = p;
        slds[wv][j] = s;
      }
    }
  }
  for (int m = 1; m < 64; m <<= 1) sm += __shfl_xor(sm, m);
  float rd = 1.0f / sm;
  const int* sp = slds[wv];
  const float* pp = plds[wv];
  int li = l & 15, eg = l >> 4;
  int lic = min(li, 9);
  const __half* gb = g40 + 4 * lic;
  float acc0 = 0.0f, acc1 = 0.0f, acc2 = 0.0f, acc3 = 0.0f;
  if (deg <= 128) {
    int dm1 = deg - 1;
    int ns = (deg + 3) >> 2;  // steps of 4 edges
    uint2 cur[4], nxt[4];
#define ROWB(G) (*(const uint2*)(gb + (size_t)sp[min(4 * (G) + eg, dm1)] * GST))
#pragma unroll
    for (int i = 0; i < 4; i++) cur[i] = ROWB(i);
    for (int g = 0; g < ns; g += 4) {
#pragma unroll
      for (int i = 0; i < 4; i++) nxt[i] = ROWB(g + 4 + i);
#pragma unroll
      for (int i = 0; i < 4; i++) {
        int j = 4 * (g + i) + eg;
        float a = (j < deg) ? pp[j] : 0.0f;
        __half2 ha = *(__half2*)&cur[i].x;
        __half2 hb = *(__half2*)&cur[i].y;
        float2 fa = __half22float2(ha);
        float2 fb = __half22float2(hb);
        acc0 = fmaf(a, fa.x, acc0);
        acc1 = fmaf(a, fa.y, acc1);
        acc2 = fmaf(a, fb.x, acc2);
        acc3 = fmaf(a, fb.y, acc3);
        cur[i] = nxt[i];
      }
    }
#undef ROWB
  } else {
    for (int j = eg; j < deg; j += 4) {
      int s;
      float p;
      if (j < 128) {
        s = sp[j];
        p = pp[j];
      } else {
        s = csr[beg + j];
        float t = a_src[s] + adn;
        t = t > 0.0f ? t : 0.2f * t;
        p = __expf(t);
      }
      uint2 w = *(const uint2*)(gb + (size_t)s * GST);
      __half2 ha = *(__half2*)&w.x;
      __half2 hb = *(__half2*)&w.y;
      float2 fa = __half22float2(ha);
      float2 fb = __half22float2(hb);
      acc0 = fmaf(p, fa.x, acc0);
      acc1 = fmaf(p, fa.y, acc1);
      acc2 = fmaf(p, fb.x, acc2);
      acc3 = fmaf(p, fb.y, acc3);
    }
  }
#pragma unroll
  for (int m = 16; m < 64; m <<= 1) {
    acc0 += __shfl_xor(acc0, m);
    acc1 += __shfl_xor(acc1, m);
    acc2 += __shfl_xor(acc2, m);
    acc3 += __shfl_xor(acc3, m);
  }
  bool cact = li < 10;
  float v0 = -INFINITY, v1 = -INFINITY, v2 = -INFINITY, v3 = -INFINITY;
  if (cact) {
    float4 bv = *(const float4*)(bias + 4 * li);
    v0 = acc0 * rd + bv.x;
    v1 = acc1 * rd + bv.y;
    v2 = acc2 * rd + bv.z;
    v3 = acc3 * rd + bv.w;
  }
  float mx = fmaxf(fmaxf(v0, v1), fmaxf(v2, v3));
  for (int m = 1; m < 64; m <<= 1) mx = fmaxf(mx, __shfl_xor(mx, m));
  // only eg==0 lanes contribute to the denominator (eg=1..3 hold copies)
  float pe = (eg == 0 && cact) ? __expf(v0 - mx) + __expf(v1 - mx) +
                                     __expf(v2 - mx) + __expf(v3 - mx)
                               : 0.0f;
  float se = pe;
  for (int m = 1; m < 64; m <<= 1) se += __shfl_xor(se, m);
  float ls = logf(se);
  if (eg == 0 && cact) {
    float4 o;
    o.x = v0 - mx - ls;
    o.y = v1 - mx - ls;
    o.z = v2 - mx - ls;
    o.w = v3 - mx - ls;
    *(float4*)(out + (size_t)n * OUTD + 4 * li) = o;
  }
}

// ---------------------------------------------------------------------------
extern "C" void kernel_launch(void* const* d_in, const int* in_sizes, int n_in,
                              void* d_out, int out_size, void* d_ws,
                              size_t ws_size, hipStream_t stream) {
  const float* x = (const float*)d_in[0];
  const int* ei = (const int*)d_in[1];
  const float* mw1 = (const float*)d_in[2];
  const float* mb1 = (const float*)d_in[3];
  const float* mw2 = (const float*)d_in[4];
  const float* mb2 = (const float*)d_in[5];
  const float* W1 = (const float*)d_in[6];
  const float* as1w = (const float*)d_in[7];
  const float* ad1w = (const float*)d_in[8];
  const float* b1 = (const float*)d_in[9];
  const float* W2 = (const float*)d_in[10];
  const float* as2w = (const float*)d_in[11];
  const float* ad2w = (const float*)d_in[12];
  const float* b2 = (const float*)d_in[13];
  float* out = (float*)d_out;

  int N = in_sizes[0] / XDIM;
  int E = in_sizes[1] / 2;
  int ET = E + N;
  int NB = (N + 255) >> 8;  // dst buckets of 256 nodes

  char* ws = (char*)d_ws;
  size_t off = 0;
  auto carve = [&](size_t bytes) -> void* {
    void* p = ws + off;
    off = (off + bytes + 255) & ~(size_t)255;
    return p;
  };
  float* part = (float*)carve((size_t)SB * 12 * 4);
  int* cnt = (int*)carve((size_t)NB * PB * 4);
  int* bsum = (int*)carve((size_t)MAXNB * 4);
  int* ebuf = (int*)carve((size_t)E * 4);
  int* offs = (int*)carve((size_t)(N + 1) * 4);
  int* csr = (int*)carve((size_t)ET * 4);
  float* scl = (float*)carve((size_t)N * 4);
  float* as1 = (float*)carve((size_t)N * NH * 4);
  float* ad1 = (float*)carve((size_t)N * NH * 4);
  unsigned char* h8 = (unsigned char*)carve((size_t)N * FEAT);
  __half* h2h = (__half*)carve((size_t)N * FEAT * 2);
  __half* g40 = (__half*)carve((size_t)N * GST * 2);
  float* as2 = (float*)carve((size_t)N * 4);
  float* ad2 = (float*)carve((size_t)N * 4);

  k_stats1<<<SB, 256, 0, stream>>>(x, part, N);
  k_scale<<<(N + 255) / 256, 256, 0, stream>>>(x, part, mw1, mb1, mw2, mb2,
                                               scl, N);
  k_bh<<<PB, 256, 0, stream>>>(ei, cnt, E, NB);
  k_sc1<<<NB, 256, 0, stream>>>(cnt, bsum);
  k_part<<<PB, 256, 0, stream>>>(ei, cnt, bsum, ebuf, E, NB);
  k_bcsr<<<NB, 256, 0, stream>>>(ebuf, bsum, offs, csr, N, E, NB);
  int NG = (N + 63) / 64;
  k_gemm1<<<NG, 256, 0, stream>>>(x, scl, W1, as1w, ad1w, h8, as1, ad1, N);
  k_agg1<<<(N + 3) / 4, 256, 0, stream>>>(offs, csr, as1, ad1, h8, b1, h2h, N);
  k_gemm2<<<NG, 256, 0, stream>>>(h2h, W2, as2w, ad2w, g40, as2, ad2, N);
  k_agg2<<<(N + 3) / 4, 256, 0, stream>>>(offs, csr, as2, ad2, g40, b2, out, N);
}

// Round 13
// 184.614 us; speedup vs baseline: 4.7766x; 1.0071x over previous
//
#include <hip/hip_runtime.h>
#include <hip/hip_fp16.h>

#define XDIM 134
#define FEAT 128
#define AUGN 6
#define NH 8
#define HD 16
#define OUTD 40
#define PS 132       // per-head stride in plds (132 mod 32 = 4 -> conflict-free)
#define SB 256       // stats partial blocks
#define PB 256       // partition blocks
#define MAXNB 256    // max buckets (N <= 65536)
#define G8S 64       // g8 row stride in bytes (one cache line)
#define WTS 130      // W^T LDS stride in halves (bank-spread, b32-aligned)
#define DST 132      // gemm1 D LDS stride in halves
#define W2C 48       // gemm2 padded cols
#define DST2 52      // gemm2 D LDS stride in floats

typedef float v2f __attribute__((ext_vector_type(2)));
typedef _Float16 h8t __attribute__((ext_vector_type(8)));
typedef float f32x4 __attribute__((ext_vector_type(4)));

__device__ __forceinline__ float rlf(float v, int lane) {
  return __int_as_float(__builtin_amdgcn_readlane(__float_as_int(v), lane));
}

// ---------------- K0a: per-block partial sums/sumsq of aug columns ---------
__global__ __launch_bounds__(256) void k_stats1(const float* __restrict__ x,
                                                float* __restrict__ part,
                                                int N) {
  __shared__ float red[4][12];
  float s[AUGN] = {0, 0, 0, 0, 0, 0}, q[AUGN] = {0, 0, 0, 0, 0, 0};
  for (int n = blockIdx.x * blockDim.x + threadIdx.x; n < N;
       n += gridDim.x * blockDim.x) {
    const float* r = x + (size_t)n * XDIM + FEAT;
    float2 v0 = *(const float2*)r;
    float2 v1 = *(const float2*)(r + 2);
    float2 v2 = *(const float2*)(r + 4);
    float v[AUGN] = {v0.x, v0.y, v1.x, v1.y, v2.x, v2.y};
#pragma unroll
    for (int i = 0; i < AUGN; i++) {
      s[i] += v[i];
      q[i] += v[i] * v[i];
    }
  }
#pragma unroll
  for (int i = 0; i < AUGN; i++) {
    for (int m = 1; m < 64; m <<= 1) {
      s[i] += __shfl_xor(s[i], m);
      q[i] += __shfl_xor(q[i], m);
    }
  }
  int wv = threadIdx.x >> 6, l = threadIdx.x & 63;
  if (l == 0) {
#pragma unroll
    for (int i = 0; i < AUGN; i++) {
      red[wv][i] = s[i];
      red[wv][6 + i] = q[i];
    }
  }
  __syncthreads();
  int t = threadIdx.x;
  if (t < 12) {
    part[blockIdx.x * 12 + t] =
        red[0][t] + red[1][t] + red[2][t] + red[3][t];
  }
}

// ---------------- K1: scale = 1 + sigmoid(MLP(norm(aug))) ------------------
__global__ __launch_bounds__(256) void k_scale(
    const float* __restrict__ x, const float* __restrict__ part,
    const float* __restrict__ w1, const float* __restrict__ b1,
    const float* __restrict__ w2, const float* __restrict__ b2,
    float* __restrict__ scl, int N) {
  __shared__ float red[4][12];
  __shared__ float sred[12];
  int t = threadIdx.x;
  {
    float v[12];
#pragma unroll
    for (int c = 0; c < 12; c++) v[c] = part[t * 12 + c];
#pragma unroll
    for (int c = 0; c < 12; c++)
      for (int m = 1; m < 64; m <<= 1) v[c] += __shfl_xor(v[c], m);
    int wv = t >> 6, l = t & 63;
    if (l == 0) {
#pragma unroll
      for (int c = 0; c < 12; c++) red[wv][c] = v[c];
    }
    __syncthreads();
    if (t < 12) sred[t] = red[0][t] + red[1][t] + red[2][t] + red[3][t];
    __syncthreads();
  }
  int n = blockIdx.x * 256 + t;
  if (n >= N) return;
  const float* r = x + (size_t)n * XDIM + FEAT;
  float a[AUGN];
  float invN = 1.0f / (float)N;
#pragma unroll
  for (int i = 0; i < AUGN; i++) {
    float sum = sred[i], sq = sred[6 + i];
    float mean = sum * invN;
    float var = (sq - sum * mean) / (float)(N - 1);
    a[i] = (r[i] - mean) / sqrtf(var);
  }
  float s2 = b2[0];
#pragma unroll
  for (int j = 0; j < 16; j++) {
    float z = b1[j];
#pragma unroll
    for (int i = 0; i < AUGN; i++) z = fmaf(a[i], w1[i * 16 + j], z);
    z = fmaxf(z, 0.0f);
    s2 = fmaf(z, w2[j], s2);
  }
  float sig = 1.0f / (1.0f + __expf(-s2));
  scl[n] = 1.0f + sig;
}

// ---------------- K2a: per-(block,bucket) histogram of dst>>8 --------------
__global__ __launch_bounds__(256) void k_bh(const int* __restrict__ ei,
                                            int* __restrict__ cnt, int E,
                                            int NB) {
  __shared__ int hist[MAXNB];
  int t = threadIdx.x;
  for (int b = t; b < NB; b += 256) hist[b] = 0;
  __syncthreads();
  int ch = (E + PB - 1) / PB;
  int lo = blockIdx.x * ch, hi = min(lo + ch, E);
  for (int e = lo + t; e < hi; e += 256)
    atomicAdd(&hist[ei[E + e] >> 8], 1);
  __syncthreads();
  for (int b = t; b < NB; b += 256)
    cnt[(size_t)b * PB + blockIdx.x] = hist[b];
}

// ---------------- K2b: per-bucket exclusive scan of its 256 counts ---------
__global__ __launch_bounds__(256) void k_sc1(int* __restrict__ cnt,
                                             int* __restrict__ bsum) {
  __shared__ int ps[256];
  int b = blockIdx.x, t = threadIdx.x;
  int v = cnt[(size_t)b * PB + t];
  ps[t] = v;
  __syncthreads();
  for (int d = 1; d < 256; d <<= 1) {
    int u = (t >= d) ? ps[t - d] : 0;
    __syncthreads();
    ps[t] += u;
    __syncthreads();
  }
  cnt[(size_t)b * PB + t] = ps[t] - v;  // exclusive within bucket
  if (t == 255) bsum[b] = ps[255];
}

// ---------------- K2c: partition edges into bucket-grouped packed ints -----
__global__ __launch_bounds__(256) void k_part(const int* __restrict__ ei,
                                              const int* __restrict__ cnt,
                                              const int* __restrict__ bsum,
                                              int* __restrict__ ebuf, int E,
                                              int NB) {
  __shared__ int bex[MAXNB];
  __shared__ int cur[MAXNB];
  int t = threadIdx.x;
  int v = (t < NB) ? bsum[t] : 0;
  bex[t] = v;
  __syncthreads();
  for (int d = 1; d < 256; d <<= 1) {
    int u = (t >= d) ? bex[t - d] : 0;
    __syncthreads();
    bex[t] += u;
    __syncthreads();
  }
  if (t < NB) cur[t] = (bex[t] - v) + cnt[(size_t)t * PB + blockIdx.x];
  __syncthreads();
  int ch = (E + PB - 1) / PB;
  int lo = blockIdx.x * ch, hi = min(lo + ch, E);
  for (int e = lo + t; e < hi; e += 256) {
    int s = ei[e], d = ei[E + e];
    int pos = atomicAdd(&cur[d >> 8], 1);
    ebuf[pos] = (s << 8) | (d & 255);
  }
}

// ---------------- K2d: per-bucket CSR build (contiguous region writes) -----
__global__ __launch_bounds__(256) void k_bcsr(const int* __restrict__ ebuf,
                                              const int* __restrict__ bsum,
                                              int* __restrict__ offs,
                                              int* __restrict__ csr, int N,
                                              int E, int NB) {
  __shared__ int bex[MAXNB];
  __shared__ int dl[256];
  __shared__ int sc[256];
  __shared__ int cu[256];
  int b = blockIdx.x, t = threadIdx.x;
  {
    int v = (t < NB) ? bsum[t] : 0;
    bex[t] = v;
    __syncthreads();
    for (int d = 1; d < 256; d <<= 1) {
      int u = (t >= d) ? bex[t - d] : 0;
      __syncthreads();
      bex[t] += u;
      __syncthreads();
    }
    int incl = bex[t];
    __syncthreads();
    bex[t] = incl - v;  // exclusive
    __syncthreads();
  }
  int nn = min(256, N - b * 256);
  int rs = bex[b];
  int re = (b + 1 < NB) ? bex[b + 1] : E;
  int csrbase = rs + b * 256;
  dl[t] = 0;
  __syncthreads();
  for (int j = rs + t; j < re; j += 256)
    atomicAdd(&dl[ebuf[j] & 255], 1);
  __syncthreads();
  int v = (t < nn) ? dl[t] + 1 : 0;
  sc[t] = v;
  __syncthreads();
  for (int d = 1; d < 256; d <<= 1) {
    int u = (t >= d) ? sc[t - d] : 0;
    __syncthreads();
    sc[t] += u;
    __syncthreads();
  }
  int excl = sc[t] - v;
  if (t < nn) {
    int node = b * 256 + t;
    offs[node] = csrbase + excl;
    csr[csrbase + excl] = node;  // self-loop slot
    cu[t] = excl + 1;
  }
  __syncthreads();
  for (int j = rs + t; j < re; j += 256) {
    int pk = ebuf[j];
    int p = atomicAdd(&cu[pk & 255], 1);
    csr[csrbase + p] = pk >> 8;
  }
  if (b == 0 && t == 0) offs[N] = E + N;
}

// ---------------- K3: MFMA h1(fp8) = (x*scale) @ W1 ; scores fp32 ----------
__global__ __launch_bounds__(256) void k_gemm1(
    const float* __restrict__ x, const float* __restrict__ scl,
    const float* __restrict__ W, const float* __restrict__ asv,
    const float* __restrict__ adv, unsigned char* __restrict__ h8,
    float* __restrict__ a_src, float* __restrict__ a_dst, int N) {
  __shared__ __half WT[128 * WTS];  // 33280 B
  __shared__ __half D16[64 * DST];  // 16896 B
  int tid = threadIdx.x;
  int wv = tid >> 6, l = tid & 63;
  int q = l >> 4, c = l & 15;
  for (int idx = tid; idx < 128 * 128; idx += 256) {
    int k = idx >> 7, n = idx & 127;
    WT[n * WTS + k] = __float2half(W[idx]);
  }
  __syncthreads();
  int colBase = wv * 32;
  h8t bf[2][4];
  const unsigned short* wtp = (const unsigned short*)WT;
#pragma unroll
  for (int ct = 0; ct < 2; ct++) {
#pragma unroll
    for (int kk = 0; kk < 4; kk++) {
      unsigned int* bu = (unsigned int*)&bf[ct][kk];
      int base = (colBase + ct * 16 + c) * WTS + kk * 32 + 8 * q;
#pragma unroll
      for (int p = 0; p < 4; p++)
        bu[p] = *(const unsigned int*)(wtp + base + 2 * p);
    }
  }
  int nodeBase = blockIdx.x * 64;
#pragma unroll
  for (int nt = 0; nt < 4; nt++) {
    int node = nodeBase + nt * 16 + c;
    const float* xr = x + (size_t)min(node, N - 1) * XDIM;
    h8t af[4];
#pragma unroll
    for (int kk = 0; kk < 4; kk++) {
      int k0 = kk * 32 + 8 * q;
#pragma unroll
      for (int p = 0; p < 4; p++) {
        float2 v = *(const float2*)(xr + k0 + 2 * p);
        af[kk][2 * p] = (_Float16)v.x;
        af[kk][2 * p + 1] = (_Float16)v.y;
      }
    }
    f32x4 a0 = {0.f, 0.f, 0.f, 0.f}, a1 = {0.f, 0.f, 0.f, 0.f};
#pragma unroll
    for (int kk = 0; kk < 4; kk++) {
      a0 = __builtin_amdgcn_mfma_f32_16x16x32_f16(af[kk], bf[0][kk], a0, 0, 0, 0);
      a1 = __builtin_amdgcn_mfma_f32_16x16x32_f16(af[kk], bf[1][kk], a1, 0, 0, 0);
    }
#pragma unroll
    for (int r = 0; r < 4; r++) {
      int row = nt * 16 + 4 * q + r;
      D16[row * DST + colBase + c] = __float2half(a0[r]);
      D16[row * DST + colBase + 16 + c] = __float2half(a1[r]);
    }
  }
  __syncthreads();
  float asw0 = asv[2 * l], asw1 = asv[2 * l + 1];
  float adw0 = adv[2 * l], adw1 = adv[2 * l + 1];
  for (int i = 0; i < 16; i++) {
    int node = nodeBase + wv * 16 + i;
    if (node >= N) break;
    float s = scl[node];
    __half2 yh = *(const __half2*)&D16[(wv * 16 + i) * DST + 2 * l];
    float2 yf = __half22float2(yh);
    float y0 = yf.x * s, y1 = yf.y * s;
    int pk = __builtin_amdgcn_cvt_pk_fp8_f32(y0, y1, 0, false);
    ((unsigned short*)(h8 + (size_t)node * FEAT))[l] = (unsigned short)pk;
    float ps = y0 * asw0 + y1 * asw1;
    float pd = y0 * adw0 + y1 * adw1;
    ps += __shfl_xor(ps, 1); ps += __shfl_xor(ps, 2); ps += __shfl_xor(ps, 4);
    pd += __shfl_xor(pd, 1); pd += __shfl_xor(pd, 2); pd += __shfl_xor(pd, 4);
    if ((l & 7) == 0) {
      a_src[node * NH + (l >> 3)] = ps;
      a_dst[node * NH + (l >> 3)] = pd;
    }
  }
}

// ---------------- K4: layer-1 softmax-aggregate; h2(fp16) ------------------
// sweep1: lane=(edge e8, head h). sweep2: 4 edges/wave, lane li owns 8 fp8 ch;
// A/B-banked prefetch: 8 wave-loads in flight (consume A, shift B->A, load B).
__global__ __launch_bounds__(256) void k_agg1(
    const int* __restrict__ offs, const int* __restrict__ csr,
    const float* __restrict__ a_src, const float* __restrict__ a_dst,
    const unsigned char* __restrict__ h8, const float* __restrict__ bias,
    __half* __restrict__ h2h, int N) {
  __shared__ float plds[4][8 * PS];
  __shared__ int slds[4][128];
  int wv = threadIdx.x >> 6, l = threadIdx.x & 63;
  int n = blockIdx.x * 4 + wv;
  if (n >= N) return;
  int beg = offs[n], end = offs[n + 1];
  int deg = end - beg;
  int h = l & 7, e8 = l >> 3;
  float adh = a_dst[(size_t)n * NH + h];
  float smh = 0.0f;
  for (int j0 = 0; j0 < deg; j0 += 8) {
    int j = j0 + e8;
    if (j < deg) {
      int s = csr[beg + j];
      if (h == 0 && j < 128) slds[wv][j] = s;
      float t = a_src[(size_t)s * NH + h] + adh;
      t = t > 0.0f ? t : 0.2f * t;
      float p = __expf(t);
      smh += p;
      if (j < 128) plds[wv][h * PS + j] = p;
    }
  }
  smh += __shfl_xor(smh, 8);
  smh += __shfl_xor(smh, 16);
  smh += __shfl_xor(smh, 32);  // lane k holds denom of head k&7
  __builtin_amdgcn_wave_barrier();
  // sweep 2: 4 edges/step; lane li owns channels {8li..8li+7}, head hh=li>>1
  int li = l & 15, eg = l >> 4;
  int hh = li >> 1;
  float rd = 1.0f / __shfl(smh, hh);
  const int* sp = slds[wv];
  const float* pp = &plds[wv][hh * PS];
  float acc0 = 0.f, acc1 = 0.f, acc2 = 0.f, acc3 = 0.f;
  float acc4 = 0.f, acc5 = 0.f, acc6 = 0.f, acc7 = 0.f;
  if (deg <= 128) {
    int dm1 = deg - 1;
    int ns = (deg + 3) >> 2;  // steps of 4 edges
    uint2 A[4], B[4];
#define ROWA(G) \
  (*(const uint2*)(h8 + (size_t)sp[min(4 * (G) + eg, dm1)] * FEAT + 8 * li))
#pragma unroll
    for (int i = 0; i < 4; i++) A[i] = ROWA(i);
#pragma unroll
    for (int i = 0; i < 4; i++) B[i] = ROWA(4 + i);
    for (int g = 0; g < ns; g += 4) {
#pragma unroll
      for (int i = 0; i < 4; i++) {
        uint2 w = A[i];
        A[i] = B[i];
        B[i] = ROWA(g + 8 + i);
        int j = 4 * (g + i) + eg;
        float a = (j < deg) ? pp[j] : 0.0f;
        v2f l0 = __builtin_amdgcn_cvt_pk_f32_fp8((int)w.x, false);
        v2f h0 = __builtin_amdgcn_cvt_pk_f32_fp8((int)w.x, true);
        v2f l1 = __builtin_amdgcn_cvt_pk_f32_fp8((int)w.y, false);
        v2f h1 = __builtin_amdgcn_cvt_pk_f32_fp8((int)w.y, true);
        acc0 = fmaf(a, l0[0], acc0); acc1 = fmaf(a, l0[1], acc1);
        acc2 = fmaf(a, h0[0], acc2); acc3 = fmaf(a, h0[1], acc3);
        acc4 = fmaf(a, l1[0], acc4); acc5 = fmaf(a, l1[1], acc5);
        acc6 = fmaf(a, h1[0], acc6); acc7 = fmaf(a, h1[1], acc7);
      }
    }
#undef ROWA
  } else {
    float adhh = __shfl(adh, hh);
    for (int j = eg; j < deg; j += 4) {
      int s;
      float p;
      if (j < 128) {
        s = sp[j];
        p = pp[j];
      } else {
        s = csr[beg + j];
        float t = a_src[(size_t)s * NH + hh] + adhh;
        t = t > 0.0f ? t : 0.2f * t;
        p = __expf(t);
      }
      uint2 w = *(const uint2*)(h8 + (size_t)s * FEAT + 8 * li);
      v2f l0 = __builtin_amdgcn_cvt_pk_f32_fp8((int)w.x, false);
      v2f h0 = __builtin_amdgcn_cvt_pk_f32_fp8((int)w.x, true);
      v2f l1 = __builtin_amdgcn_cvt_pk_f32_fp8((int)w.y, false);
      v2f h1 = __builtin_amdgcn_cvt_pk_f32_fp8((int)w.y, true);
      acc0 = fmaf(p, l0[0], acc0); acc1 = fmaf(p, l0[1], acc1);
      acc2 = fmaf(p, h0[0], acc2); acc3 = fmaf(p, h0[1], acc3);
      acc4 = fmaf(p, l1[0], acc4); acc5 = fmaf(p, l1[1], acc5);
      acc6 = fmaf(p, h1[0], acc6); acc7 = fmaf(p, h1[1], acc7);
    }
  }
#pragma unroll
  for (int m = 16; m < 64; m <<= 1) {
    acc0 += __shfl_xor(acc0, m); acc1 += __shfl_xor(acc1, m);
    acc2 += __shfl_xor(acc2, m); acc3 += __shfl_xor(acc3, m);
    acc4 += __shfl_xor(acc4, m); acc5 += __shfl_xor(acc5, m);
    acc6 += __shfl_xor(acc6, m); acc7 += __shfl_xor(acc7, m);
  }
  if (l < 16) {
    float4 b0 = *(const float4*)(bias + 8 * l);
    float4 b1v = *(const float4*)(bias + 8 * l + 4);
    float o0 = fmaxf(acc0 * rd + b0.x, 0.0f);
    float o1 = fmaxf(acc1 * rd + b0.y, 0.0f);
    float o2 = fmaxf(acc2 * rd + b0.z, 0.0f);
    float o3 = fmaxf(acc3 * rd + b0.w, 0.0f);
    float o4 = fmaxf(acc4 * rd + b1v.x, 0.0f);
    float o5 = fmaxf(acc5 * rd + b1v.y, 0.0f);
    float o6 = fmaxf(acc6 * rd + b1v.z, 0.0f);
    float o7 = fmaxf(acc7 * rd + b1v.w, 0.0f);
    __half2 pa = __float22half2_rn(make_float2(o0, o1));
    __half2 pb = __float22half2_rn(make_float2(o2, o3));
    __half2 pc = __float22half2_rn(make_float2(o4, o5));
    __half2 pd2 = __float22half2_rn(make_float2(o6, o7));
    uint4 st;
    st.x = *(unsigned int*)&pa;
    st.y = *(unsigned int*)&pb;
    st.z = *(unsigned int*)&pc;
    st.w = *(unsigned int*)&pd2;
    *(uint4*)(h2h + (size_t)n * FEAT + 8 * l) = st;
  }
}

// ---------------- K5: MFMA g8(fp8, 64B rows) = h2(fp16) @ W2 ---------------
__global__ __launch_bounds__(256) void k_gemm2(
    const __half* __restrict__ h2h, const float* __restrict__ W,
    const float* __restrict__ asv, const float* __restrict__ adv,
    unsigned char* __restrict__ g8, float* __restrict__ a_src,
    float* __restrict__ a_dst, int N) {
  __shared__ __half WT2[W2C * WTS];  // 12480 B
  __shared__ float DL[64 * DST2];    // 13312 B
  int tid = threadIdx.x;
  int wv = tid >> 6, l = tid & 63;
  int q = l >> 4, c = l & 15;
  for (int idx = tid; idx < W2C * 128; idx += 256) {
    int col = idx >> 7, k = idx & 127;
    float v = (col < OUTD) ? W[k * OUTD + col] : 0.0f;
    WT2[col * WTS + k] = __float2half(v);
  }
  __syncthreads();
  h8t bf[3][4];
  const unsigned short* wtp = (const unsigned short*)WT2;
#pragma unroll
  for (int ct = 0; ct < 3; ct++) {
#pragma unroll
    for (int kk = 0; kk < 4; kk++) {
      unsigned int* bu = (unsigned int*)&bf[ct][kk];
      int base = (ct * 16 + c) * WTS + kk * 32 + 8 * q;
#pragma unroll
      for (int p = 0; p < 4; p++)
        bu[p] = *(const unsigned int*)(wtp + base + 2 * p);
    }
  }
  int nodeBase = blockIdx.x * 64;
  int node = nodeBase + wv * 16 + c;
  const __half* hr = h2h + (size_t)min(node, N - 1) * FEAT;
  h8t af[4];
#pragma unroll
  for (int kk = 0; kk < 4; kk++) {
    uint4 v = *(const uint4*)(hr + kk * 32 + 8 * q);
    *(uint4*)&af[kk] = v;
  }
  f32x4 d0 = {0.f, 0.f, 0.f, 0.f}, d1 = {0.f, 0.f, 0.f, 0.f},
        d2 = {0.f, 0.f, 0.f, 0.f};
#pragma unroll
  for (int kk = 0; kk < 4; kk++) {
    d0 = __builtin_amdgcn_mfma_f32_16x16x32_f16(af[kk], bf[0][kk], d0, 0, 0, 0);
    d1 = __builtin_amdgcn_mfma_f32_16x16x32_f16(af[kk], bf[1][kk], d1, 0, 0, 0);
    d2 = __builtin_amdgcn_mfma_f32_16x16x32_f16(af[kk], bf[2][kk], d2, 0, 0, 0);
  }
#pragma unroll
  for (int r = 0; r < 4; r++) {
    int row = wv * 16 + 4 * q + r;
    DL[row * DST2 + c] = d0[r];
    DL[row * DST2 + 16 + c] = d1[r];
    DL[row * DST2 + 32 + c] = d2[r];
  }
  __syncthreads();
  // scores: lane (i=l&15, cg=l>>4) sums cols cg*10..cg*10+9 of node row i
  int i = l & 15, cg = l >> 4;
  int row = wv * 16 + i;
  float ps = 0.0f, pd = 0.0f;
#pragma unroll
  for (int k = 0; k < 10; k++) {
    int col = cg * 10 + k;
    float gv = DL[row * DST2 + col];
    ps = fmaf(gv, asv[col], ps);
    pd = fmaf(gv, adv[col], pd);
  }
  ps += __shfl_xor(ps, 16); ps += __shfl_xor(ps, 32);
  pd += __shfl_xor(pd, 16); pd += __shfl_xor(pd, 32);
  int snode = nodeBase + wv * 16 + i;
  if (cg == 0 && snode < N) {
    a_src[snode] = ps;
    a_dst[snode] = pd;
  }
  // g8 write: 16 nodes x 16 uint words (64B rows), fp8-packed from DL
  for (int idx = l; idx < 16 * 16; idx += 64) {
    int ni = idx >> 4, w = idx & 15;
    int rr = wv * 16 + ni;
    int wnode = nodeBase + rr;
    if (wnode < N) {
      unsigned int u = 0;
      if (w < 10) {
        float c0 = DL[rr * DST2 + 4 * w];
        float c1 = DL[rr * DST2 + 4 * w + 1];
        float c2 = DL[rr * DST2 + 4 * w + 2];
        float c3 = DL[rr * DST2 + 4 * w + 3];
        u = __builtin_amdgcn_cvt_pk_fp8_f32(c0, c1, 0, false);
        u = __builtin_amdgcn_cvt_pk_fp8_f32(c2, c3, u, true);
      }
      *(unsigned int*)(g8 + (size_t)wnode * G8S + 4 * w) = u;
    }
  }
}

// ---------------- K6: layer-2 softmax-aggregate + log_softmax --------------
// 4 edges/wave (eg=l>>4); lane li (li<10) owns cols {4li..4li+3} of fp8 rows.
__global__ __launch_bounds__(256) void k_agg2(
    const int* __restrict__ offs, const int* __restrict__ csr,
    const float* __restrict__ a_src, const float* __restrict__ a_dst,
    const unsigned char* __restrict__ g8, const float* __restrict__ bias,
    float* __restrict__ out, int N) {
  __shared__ float plds[4][PS];
  __shared__ int slds[4][128];
  int wv = threadIdx.x >> 6, l = threadIdx.x & 63;
  int n = blockIdx.x * 4 + wv;
  if (n >= N) return;
  int beg = offs[n], end = offs[n + 1];
  int deg = end - beg;
  float adn = a_dst[n];
  float sm = 0.0f;
  for (int j0 = 0; j0 < deg; j0 += 64) {
    int j = j0 + l;
    if (j < deg) {
      int s = csr[beg + j];
      float t = a_src[s] + adn;
      t = t > 0.0f ? t : 0.2f * t;
      float p = __expf(t);
      sm += p;
      if (j < 128) {
        plds[wv][j] = p;
        slds[wv][j] = s;
      }
    }
  }
  for (int m = 1; m < 64; m <<= 1) sm += __shfl_xor(sm, m);
  float rd = 1.0f / sm;
  const int* sp = slds[wv];
  const float* pp = plds[wv];
  int li = l & 15, eg = l >> 4;
  int lic = min(li, 9);
  const unsigned char* gb = g8 + 4 * lic;
  float acc0 = 0.0f, acc1 = 0.0f, acc2 = 0.0f, acc3 = 0.0f;
  if (deg <= 128) {
    int dm1 = deg - 1;
    int ns = (deg + 3) >> 2;  // steps of 4 edges
    unsigned int cur[4], nxt[4];
#define ROWB(G) \
  (*(const unsigned int*)(gb + (size_t)sp[min(4 * (G) + eg, dm1)] * G8S))
#pragma unroll
    for (int i = 0; i < 4; i++) cur[i] = ROWB(i);
    for (int g = 0; g < ns; g += 4) {
#pragma unroll
      for (int i = 0; i < 4; i++) nxt[i] = ROWB(g + 4 + i);
#pragma unroll
      for (int i = 0; i < 4; i++) {
        int j = 4 * (g + i) + eg;
        float a = (j < deg) ? pp[j] : 0.0f;
        v2f lo = __builtin_amdgcn_cvt_pk_f32_fp8((int)cur[i], false);
        v2f hi = __builtin_amdgcn_cvt_pk_f32_fp8((int)cur[i], true);
        acc0 = fmaf(a, lo[0], acc0);
        acc1 = fmaf(a, lo[1], acc1);
        acc2 = fmaf(a, hi[0], acc2);
        acc3 = fmaf(a, hi[1], acc3);
        cur[i] = nxt[i];
      }
    }
#undef ROWB
  } else {
    for (int j = eg; j < deg; j += 4) {
      int s;
      float p;
      if (j < 128) {
        s = sp[j];
        p = pp[j];
      } else {
        s = csr[beg + j];
        float t = a_src[s] + adn;
        t = t > 0.0f ? t : 0.2f * t;
        p = __expf(t);
      }
      unsigned int w = *(const unsigned int*)(gb + (size_t)s * G8S);
      v2f lo = __builtin_amdgcn_cvt_pk_f32_fp8((int)w, false);
      v2f hi = __builtin_amdgcn_cvt_pk_f32_fp8((int)w, true);
      acc0 = fmaf(p, lo[0], acc0);
      acc1 = fmaf(p, lo[1], acc1);
      acc2 = fmaf(p, hi[0], acc2);
      acc3 = fmaf(p, hi[1], acc3);
    }
  }
#pragma unroll
  for (int m = 16; m < 64; m <<= 1) {
    acc0 += __shfl_xor(acc0, m);
    acc1 += __shfl_xor(acc1, m);
    acc2 += __shfl_xor(acc2, m);
    acc3 += __shfl_xor(acc3, m);
  }
  bool cact = li < 10;
  float v0 = -INFINITY, v1 = -INFINITY, v2 = -INFINITY, v3 = -INFINITY;
  if (cact) {
    float4 bv = *(const float4*)(bias + 4 * li);
    v0 = acc0 * rd + bv.x;
    v1 = acc1 * rd + bv.y;
    v2 = acc2 * rd + bv.z;
    v3 = acc3 * rd + bv.w;
  }
  float mx = fmaxf(fmaxf(v0, v1), fmaxf(v2, v3));
  for (int m = 1; m < 64; m <<= 1) mx = fmaxf(mx, __shfl_xor(mx, m));
  // only eg==0 lanes contribute to the denominator (eg=1..3 hold copies)
  float pe = (eg == 0 && cact) ? __expf(v0 - mx) + __expf(v1 - mx) +
                                     __expf(v2 - mx) + __expf(v3 - mx)
                               : 0.0f;
  float se = pe;
  for (int m = 1; m < 64; m <<= 1) se += __shfl_xor(se, m);
  float ls = logf(se);
  if (eg == 0 && cact) {
    float4 o;
    o.x = v0 - mx - ls;
    o.y = v1 - mx - ls;
    o.z = v2 - mx - ls;
    o.w = v3 - mx - ls;
    *(float4*)(out + (size_t)n * OUTD + 4 * li) = o;
  }
}

// ---------------------------------------------------------------------------
extern "C" void kernel_launch(void* const* d_in, const int* in_sizes, int n_in,
                              void* d_out, int out_size, void* d_ws,
                              size_t ws_size, hipStream_t stream) {
  const float* x = (const float*)d_in[0];
  const int* ei = (const int*)d_in[1];
  const float* mw1 = (const float*)d_in[2];
  const float* mb1 = (const float*)d_in[3];
  const float* mw2 = (const float*)d_in[4];
  const float* mb2 = (const float*)d_in[5];
  const float* W1 = (const float*)d_in[6];
  const float* as1w = (const float*)d_in[7];
  const float* ad1w = (const float*)d_in[8];
  const float* b1 = (const float*)d_in[9];
  const float* W2 = (const float*)d_in[10];
  const float* as2w = (const float*)d_in[11];
  const float* ad2w = (const float*)d_in[12];
  const float* b2 = (const float*)d_in[13];
  float* out = (float*)d_out;

  int N = in_sizes[0] / XDIM;
  int E = in_sizes[1] / 2;
  int ET = E + N;
  int NB = (N + 255) >> 8;  // dst buckets of 256 nodes

  char* ws = (char*)d_ws;
  size_t off = 0;
  auto carve = [&](size_t bytes) -> void* {
    void* p = ws + off;
    off = (off + bytes + 255) & ~(size_t)255;
    return p;
  };
  float* part = (float*)carve((size_t)SB * 12 * 4);
  int* cnt = (int*)carve((size_t)NB * PB * 4);
  int* bsum = (int*)carve((size_t)MAXNB * 4);
  int* ebuf = (int*)carve((size_t)E * 4);
  int* offs = (int*)carve((size_t)(N + 1) * 4);
  int* csr = (int*)carve((size_t)ET * 4);
  float* scl = (float*)carve((size_t)N * 4);
  float* as1 = (float*)carve((size_t)N * NH * 4);
  float* ad1 = (float*)carve((size_t)N * NH * 4);
  unsigned char* h8 = (unsigned char*)carve((size_t)N * FEAT);
  __half* h2h = (__half*)carve((size_t)N * FEAT * 2);
  unsigned char* g8 = (unsigned char*)carve((size_t)N * G8S);
  float* as2 = (float*)carve((size_t)N * 4);
  float* ad2 = (float*)carve((size_t)N * 4);

  k_stats1<<<SB, 256, 0, stream>>>(x, part, N);
  k_scale<<<(N + 255) / 256, 256, 0, stream>>>(x, part, mw1, mb1, mw2, mb2,
                                               scl, N);
  k_bh<<<PB, 256, 0, stream>>>(ei, cnt, E, NB);
  k_sc1<<<NB, 256, 0, stream>>>(cnt, bsum);
  k_part<<<PB, 256, 0, stream>>>(ei, cnt, bsum, ebuf, E, NB);
  k_bcsr<<<NB, 256, 0, stream>>>(ebuf, bsum, offs, csr, N, E, NB);
  int NG = (N + 63) / 64;
  k_gemm1<<<NG, 256, 0, stream>>>(x, scl, W1, as1w, ad1w, h8, as1, ad1, N);
  k_agg1<<<(N + 3) / 4, 256, 0, stream>>>(offs, csr, as1, ad1, h8, b1, h2h, N);
  k_gemm2<<<NG, 256, 0, stream>>>(h2h, W2, as2w, ad2w, g8, as2, ad2, N);
  k_agg2<<<(N + 3) / 4, 256, 0, stream>>>(offs, csr, as2, ad2, g8, b2, out, N);
}

// Round 14
// 182.186 us; speedup vs baseline: 4.8402x; 1.0133x over previous
//
#include <hip/hip_runtime.h>
#include <hip/hip_fp16.h>

#define XDIM 134
#define FEAT 128
#define AUGN 6
#define NH 8
#define HD 16
#define OUTD 40
#define PS 132       // per-head stride in plds (132 mod 32 = 4 -> conflict-free)
#define SB 256       // stats partial blocks
#define PB 256       // partition blocks
#define MAXNB 256    // max buckets (N <= 65536)
#define G8S 64       // g8 row stride in bytes (one cache line)
#define WTS 130      // W^T LDS stride in halves (bank-spread, b32-aligned)
#define DST 132      // gemm1 D LDS stride in halves
#define W2C 48       // gemm2 padded cols
#define DST2 52      // gemm2 D LDS stride in floats

typedef float v2f __attribute__((ext_vector_type(2)));
typedef _Float16 h8t __attribute__((ext_vector_type(8)));
typedef float f32x4 __attribute__((ext_vector_type(4)));

__device__ __forceinline__ float rlf(float v, int lane) {
  return __int_as_float(__builtin_amdgcn_readlane(__float_as_int(v), lane));
}

// ---------------- K0a: per-block partial sums/sumsq of aug columns ---------
__global__ __launch_bounds__(256) void k_stats1(const float* __restrict__ x,
                                                float* __restrict__ part,
                                                int N) {
  __shared__ float red[4][12];
  float s[AUGN] = {0, 0, 0, 0, 0, 0}, q[AUGN] = {0, 0, 0, 0, 0, 0};
  for (int n = blockIdx.x * blockDim.x + threadIdx.x; n < N;
       n += gridDim.x * blockDim.x) {
    const float* r = x + (size_t)n * XDIM + FEAT;
    float2 v0 = *(const float2*)r;
    float2 v1 = *(const float2*)(r + 2);
    float2 v2 = *(const float2*)(r + 4);
    float v[AUGN] = {v0.x, v0.y, v1.x, v1.y, v2.x, v2.y};
#pragma unroll
    for (int i = 0; i < AUGN; i++) {
      s[i] += v[i];
      q[i] += v[i] * v[i];
    }
  }
#pragma unroll
  for (int i = 0; i < AUGN; i++) {
    for (int m = 1; m < 64; m <<= 1) {
      s[i] += __shfl_xor(s[i], m);
      q[i] += __shfl_xor(q[i], m);
    }
  }
  int wv = threadIdx.x >> 6, l = threadIdx.x & 63;
  if (l == 0) {
#pragma unroll
    for (int i = 0; i < AUGN; i++) {
      red[wv][i] = s[i];
      red[wv][6 + i] = q[i];
    }
  }
  __syncthreads();
  int t = threadIdx.x;
  if (t < 12) {
    part[blockIdx.x * 12 + t] =
        red[0][t] + red[1][t] + red[2][t] + red[3][t];
  }
}

// ---------------- K1: scale = 1 + sigmoid(MLP(norm(aug))) ------------------
__global__ __launch_bounds__(256) void k_scale(
    const float* __restrict__ x, const float* __restrict__ part,
    const float* __restrict__ w1, const float* __restrict__ b1,
    const float* __restrict__ w2, const float* __restrict__ b2,
    float* __restrict__ scl, int N) {
  __shared__ float red[4][12];
  __shared__ float sred[12];
  int t = threadIdx.x;
  {
    float v[12];
#pragma unroll
    for (int c = 0; c < 12; c++) v[c] = part[t * 12 + c];
#pragma unroll
    for (int c = 0; c < 12; c++)
      for (int m = 1; m < 64; m <<= 1) v[c] += __shfl_xor(v[c], m);
    int wv = t >> 6, l = t & 63;
    if (l == 0) {
#pragma unroll
      for (int c = 0; c < 12; c++) red[wv][c] = v[c];
    }
    __syncthreads();
    if (t < 12) sred[t] = red[0][t] + red[1][t] + red[2][t] + red[3][t];
    __syncthreads();
  }
  int n = blockIdx.x * 256 + t;
  if (n >= N) return;
  const float* r = x + (size_t)n * XDIM + FEAT;
  float a[AUGN];
  float invN = 1.0f / (float)N;
#pragma unroll
  for (int i = 0; i < AUGN; i++) {
    float sum = sred[i], sq = sred[6 + i];
    float mean = sum * invN;
    float var = (sq - sum * mean) / (float)(N - 1);
    a[i] = (r[i] - mean) / sqrtf(var);
  }
  float s2 = b2[0];
#pragma unroll
  for (int j = 0; j < 16; j++) {
    float z = b1[j];
#pragma unroll
    for (int i = 0; i < AUGN; i++) z = fmaf(a[i], w1[i * 16 + j], z);
    z = fmaxf(z, 0.0f);
    s2 = fmaf(z, w2[j], s2);
  }
  float sig = 1.0f / (1.0f + __expf(-s2));
  scl[n] = 1.0f + sig;
}

// ---------------- K2a: per-(block,bucket) histogram of dst>>8 --------------
__global__ __launch_bounds__(256) void k_bh(const int* __restrict__ ei,
                                            int* __restrict__ cnt, int E,
                                            int NB) {
  __shared__ int hist[MAXNB];
  int t = threadIdx.x;
  for (int b = t; b < NB; b += 256) hist[b] = 0;
  __syncthreads();
  int ch = (E + PB - 1) / PB;
  int lo = blockIdx.x * ch, hi = min(lo + ch, E);
  for (int e = lo + t; e < hi; e += 256)
    atomicAdd(&hist[ei[E + e] >> 8], 1);
  __syncthreads();
  for (int b = t; b < NB; b += 256)
    cnt[(size_t)b * PB + blockIdx.x] = hist[b];
}

// ---------------- K2b: per-bucket exclusive scan of its 256 counts ---------
__global__ __launch_bounds__(256) void k_sc1(int* __restrict__ cnt,
                                             int* __restrict__ bsum) {
  __shared__ int ps[256];
  int b = blockIdx.x, t = threadIdx.x;
  int v = cnt[(size_t)b * PB + t];
  ps[t] = v;
  __syncthreads();
  for (int d = 1; d < 256; d <<= 1) {
    int u = (t >= d) ? ps[t - d] : 0;
    __syncthreads();
    ps[t] += u;
    __syncthreads();
  }
  cnt[(size_t)b * PB + t] = ps[t] - v;  // exclusive within bucket
  if (t == 255) bsum[b] = ps[255];
}

// ---------------- K2c: partition edges into bucket-grouped packed ints -----
__global__ __launch_bounds__(256) void k_part(const int* __restrict__ ei,
                                              const int* __restrict__ cnt,
                                              const int* __restrict__ bsum,
                                              int* __restrict__ ebuf, int E,
                                              int NB) {
  __shared__ int bex[MAXNB];
  __shared__ int cur[MAXNB];
  int t = threadIdx.x;
  int v = (t < NB) ? bsum[t] : 0;
  bex[t] = v;
  __syncthreads();
  for (int d = 1; d < 256; d <<= 1) {
    int u = (t >= d) ? bex[t - d] : 0;
    __syncthreads();
    bex[t] += u;
    __syncthreads();
  }
  if (t < NB) cur[t] = (bex[t] - v) + cnt[(size_t)t * PB + blockIdx.x];
  __syncthreads();
  int ch = (E + PB - 1) / PB;
  int lo = blockIdx.x * ch, hi = min(lo + ch, E);
  for (int e = lo + t; e < hi; e += 256) {
    int s = ei[e], d = ei[E + e];
    int pos = atomicAdd(&cur[d >> 8], 1);
    ebuf[pos] = (s << 8) | (d & 255);
  }
}

// ---------------- K2d: per-bucket CSR build (contiguous region writes) -----
__global__ __launch_bounds__(256) void k_bcsr(const int* __restrict__ ebuf,
                                              const int* __restrict__ bsum,
                                              int* __restrict__ offs,
                                              int* __restrict__ csr, int N,
                                              int E, int NB) {
  __shared__ int bex[MAXNB];
  __shared__ int dl[256];
  __shared__ int sc[256];
  __shared__ int cu[256];
  int b = blockIdx.x, t = threadIdx.x;
  {
    int v = (t < NB) ? bsum[t] : 0;
    bex[t] = v;
    __syncthreads();
    for (int d = 1; d < 256; d <<= 1) {
      int u = (t >= d) ? bex[t - d] : 0;
      __syncthreads();
      bex[t] += u;
      __syncthreads();
    }
    int incl = bex[t];
    __syncthreads();
    bex[t] = incl - v;  // exclusive
    __syncthreads();
  }
  int nn = min(256, N - b * 256);
  int rs = bex[b];
  int re = (b + 1 < NB) ? bex[b + 1] : E;
  int csrbase = rs + b * 256;
  dl[t] = 0;
  __syncthreads();
  for (int j = rs + t; j < re; j += 256)
    atomicAdd(&dl[ebuf[j] & 255], 1);
  __syncthreads();
  int v = (t < nn) ? dl[t] + 1 : 0;
  sc[t] = v;
  __syncthreads();
  for (int d = 1; d < 256; d <<= 1) {
    int u = (t >= d) ? sc[t - d] : 0;
    __syncthreads();
    sc[t] += u;
    __syncthreads();
  }
  int excl = sc[t] - v;
  if (t < nn) {
    int node = b * 256 + t;
    offs[node] = csrbase + excl;
    csr[csrbase + excl] = node;  // self-loop slot
    cu[t] = excl + 1;
  }
  __syncthreads();
  for (int j = rs + t; j < re; j += 256) {
    int pk = ebuf[j];
    int p = atomicAdd(&cu[pk & 255], 1);
    csr[csrbase + p] = pk >> 8;
  }
  if (b == 0 && t == 0) offs[N] = E + N;
}

// ---------------- K3: MFMA h1(fp8) = (x*scale) @ W1 ; scores fp16 ----------
__global__ __launch_bounds__(256) void k_gemm1(
    const float* __restrict__ x, const float* __restrict__ scl,
    const float* __restrict__ W, const float* __restrict__ asv,
    const float* __restrict__ adv, unsigned char* __restrict__ h8,
    __half* __restrict__ as1h, __half* __restrict__ ad1h, int N) {
  __shared__ __half WT[128 * WTS];  // 33280 B
  __shared__ __half D16[64 * DST];  // 16896 B
  int tid = threadIdx.x;
  int wv = tid >> 6, l = tid & 63;
  int q = l >> 4, c = l & 15;
  // stage W^T fp16: float4 global reads (consecutive n, fixed k)
  for (int idx = tid * 4; idx < 128 * 128; idx += 256 * 4) {
    int k = idx >> 7, n = idx & 127;
    float4 v = *(const float4*)(W + idx);
    WT[(n + 0) * WTS + k] = __float2half(v.x);
    WT[(n + 1) * WTS + k] = __float2half(v.y);
    WT[(n + 2) * WTS + k] = __float2half(v.z);
    WT[(n + 3) * WTS + k] = __float2half(v.w);
  }
  __syncthreads();
  int colBase = wv * 32;
  h8t bf[2][4];
  const unsigned short* wtp = (const unsigned short*)WT;
#pragma unroll
  for (int ct = 0; ct < 2; ct++) {
#pragma unroll
    for (int kk = 0; kk < 4; kk++) {
      unsigned int* bu = (unsigned int*)&bf[ct][kk];
      int base = (colBase + ct * 16 + c) * WTS + kk * 32 + 8 * q;
#pragma unroll
      for (int p = 0; p < 4; p++)
        bu[p] = *(const unsigned int*)(wtp + base + 2 * p);
    }
  }
  int nodeBase = blockIdx.x * 64;
#pragma unroll
  for (int nt = 0; nt < 4; nt++) {
    int node = nodeBase + nt * 16 + c;
    const float* xr = x + (size_t)min(node, N - 1) * XDIM;
    h8t af[4];
#pragma unroll
    for (int kk = 0; kk < 4; kk++) {
      int k0 = kk * 32 + 8 * q;
#pragma unroll
      for (int p = 0; p < 4; p++) {
        float2 v = *(const float2*)(xr + k0 + 2 * p);
        af[kk][2 * p] = (_Float16)v.x;
        af[kk][2 * p + 1] = (_Float16)v.y;
      }
    }
    f32x4 a0 = {0.f, 0.f, 0.f, 0.f}, a1 = {0.f, 0.f, 0.f, 0.f};
#pragma unroll
    for (int kk = 0; kk < 4; kk++) {
      a0 = __builtin_amdgcn_mfma_f32_16x16x32_f16(af[kk], bf[0][kk], a0, 0, 0, 0);
      a1 = __builtin_amdgcn_mfma_f32_16x16x32_f16(af[kk], bf[1][kk], a1, 0, 0, 0);
    }
#pragma unroll
    for (int r = 0; r < 4; r++) {
      int row = nt * 16 + 4 * q + r;
      D16[row * DST + colBase + c] = __float2half(a0[r]);
      D16[row * DST + colBase + 16 + c] = __float2half(a1[r]);
    }
  }
  __syncthreads();
  float asw0 = asv[2 * l], asw1 = asv[2 * l + 1];
  float adw0 = adv[2 * l], adw1 = adv[2 * l + 1];
  for (int i = 0; i < 16; i++) {
    int node = nodeBase + wv * 16 + i;
    if (node >= N) break;
    float s = scl[node];
    __half2 yh = *(const __half2*)&D16[(wv * 16 + i) * DST + 2 * l];
    float2 yf = __half22float2(yh);
    float y0 = yf.x * s, y1 = yf.y * s;
    int pk = __builtin_amdgcn_cvt_pk_fp8_f32(y0, y1, 0, false);
    ((unsigned short*)(h8 + (size_t)node * FEAT))[l] = (unsigned short)pk;
    float ps = y0 * asw0 + y1 * asw1;
    float pd = y0 * adw0 + y1 * adw1;
    ps += __shfl_xor(ps, 1); ps += __shfl_xor(ps, 2); ps += __shfl_xor(ps, 4);
    pd += __shfl_xor(pd, 1); pd += __shfl_xor(pd, 2); pd += __shfl_xor(pd, 4);
    if ((l & 7) == 0) {
      as1h[node * NH + (l >> 3)] = __float2half(ps);
      ad1h[node * NH + (l >> 3)] = __float2half(pd);
    }
  }
}

// ---------------- K4: layer-1 softmax-aggregate; h2(fp16) ------------------
// sweep1: lane=(edge e8, head h), fp16 score gather (16B rows).
// sweep2: 4 edges/wave (eg=l>>4), lane li owns 8 fp8 ch (uint2), 4-deep.
__global__ __launch_bounds__(256) void k_agg1(
    const int* __restrict__ offs, const int* __restrict__ csr,
    const __half* __restrict__ as1h, const __half* __restrict__ ad1h,
    const unsigned char* __restrict__ h8, const float* __restrict__ bias,
    __half* __restrict__ h2h, int N) {
  __shared__ float plds[4][8 * PS];
  __shared__ int slds[4][128];
  int wv = threadIdx.x >> 6, l = threadIdx.x & 63;
  int n = blockIdx.x * 4 + wv;
  if (n >= N) return;
  int beg = offs[n], end = offs[n + 1];
  int deg = end - beg;
  int h = l & 7, e8 = l >> 3;
  float adh = __half2float(ad1h[(size_t)n * NH + h]);
  float smh = 0.0f;
  for (int j0 = 0; j0 < deg; j0 += 8) {
    int j = j0 + e8;
    if (j < deg) {
      int s = csr[beg + j];
      if (h == 0 && j < 128) slds[wv][j] = s;
      float t = __half2float(as1h[(size_t)s * NH + h]) + adh;
      t = t > 0.0f ? t : 0.2f * t;
      float p = __expf(t);
      smh += p;
      if (j < 128) plds[wv][h * PS + j] = p;
    }
  }
  smh += __shfl_xor(smh, 8);
  smh += __shfl_xor(smh, 16);
  smh += __shfl_xor(smh, 32);  // lane k holds denom of head k&7
  __builtin_amdgcn_wave_barrier();
  // sweep 2: 4 edges/step; lane li owns channels {8li..8li+7}, head hh=li>>1
  int li = l & 15, eg = l >> 4;
  int hh = li >> 1;
  float rd = 1.0f / __shfl(smh, hh);
  const int* sp = slds[wv];
  const float* pp = &plds[wv][hh * PS];
  float acc0 = 0.f, acc1 = 0.f, acc2 = 0.f, acc3 = 0.f;
  float acc4 = 0.f, acc5 = 0.f, acc6 = 0.f, acc7 = 0.f;
  if (deg <= 128) {
    int dm1 = deg - 1;
    int ns = (deg + 3) >> 2;  // steps of 4 edges
    uint2 cur[4], nxt[4];
#define ROWA(G) \
  (*(const uint2*)(h8 + (size_t)sp[min(4 * (G) + eg, dm1)] * FEAT + 8 * li))
#pragma unroll
    for (int i = 0; i < 4; i++) cur[i] = ROWA(i);
    for (int g = 0; g < ns; g += 4) {
#pragma unroll
      for (int i = 0; i < 4; i++) nxt[i] = ROWA(g + 4 + i);
#pragma unroll
      for (int i = 0; i < 4; i++) {
        int j = 4 * (g + i) + eg;
        float a = (j < deg) ? pp[j] : 0.0f;
        v2f l0 = __builtin_amdgcn_cvt_pk_f32_fp8((int)cur[i].x, false);
        v2f h0 = __builtin_amdgcn_cvt_pk_f32_fp8((int)cur[i].x, true);
        v2f l1 = __builtin_amdgcn_cvt_pk_f32_fp8((int)cur[i].y, false);
        v2f h1 = __builtin_amdgcn_cvt_pk_f32_fp8((int)cur[i].y, true);
        acc0 = fmaf(a, l0[0], acc0); acc1 = fmaf(a, l0[1], acc1);
        acc2 = fmaf(a, h0[0], acc2); acc3 = fmaf(a, h0[1], acc3);
        acc4 = fmaf(a, l1[0], acc4); acc5 = fmaf(a, l1[1], acc5);
        acc6 = fmaf(a, h1[0], acc6); acc7 = fmaf(a, h1[1], acc7);
        cur[i] = nxt[i];
      }
    }
#undef ROWA
  } else {
    float adhh = __shfl(adh, hh);
    for (int j = eg; j < deg; j += 4) {
      int s;
      float p;
      if (j < 128) {
        s = sp[j];
        p = pp[j];
      } else {
        s = csr[beg + j];
        float t = __half2float(as1h[(size_t)s * NH + hh]) + adhh;
        t = t > 0.0f ? t : 0.2f * t;
        p = __expf(t);
      }
      uint2 w = *(const uint2*)(h8 + (size_t)s * FEAT + 8 * li);
      v2f l0 = __builtin_amdgcn_cvt_pk_f32_fp8((int)w.x, false);
      v2f h0 = __builtin_amdgcn_cvt_pk_f32_fp8((int)w.x, true);
      v2f l1 = __builtin_amdgcn_cvt_pk_f32_fp8((int)w.y, false);
      v2f h1 = __builtin_amdgcn_cvt_pk_f32_fp8((int)w.y, true);
      acc0 = fmaf(p, l0[0], acc0); acc1 = fmaf(p, l0[1], acc1);
      acc2 = fmaf(p, h0[0], acc2); acc3 = fmaf(p, h0[1], acc3);
      acc4 = fmaf(p, l1[0], acc4); acc5 = fmaf(p, l1[1], acc5);
      acc6 = fmaf(p, h1[0], acc6); acc7 = fmaf(p, h1[1], acc7);
    }
  }
#pragma unroll
  for (int m = 16; m < 64; m <<= 1) {
    acc0 += __shfl_xor(acc0, m); acc1 += __shfl_xor(acc1, m);
    acc2 += __shfl_xor(acc2, m); acc3 += __shfl_xor(acc3, m);
    acc4 += __shfl_xor(acc4, m); acc5 += __shfl_xor(acc5, m);
    acc6 += __shfl_xor(acc6, m); acc7 += __shfl_xor(acc7, m);
  }
  if (l < 16) {
    float4 b0 = *(const float4*)(bias + 8 * l);
    float4 b1v = *(const float4*)(bias + 8 * l + 4);
    float o0 = fmaxf(acc0 * rd + b0.x, 0.0f);
    float o1 = fmaxf(acc1 * rd + b0.y, 0.0f);
    float o2 = fmaxf(acc2 * rd + b0.z, 0.0f);
    float o3 = fmaxf(acc3 * rd + b0.w, 0.0f);
    float o4 = fmaxf(acc4 * rd + b1v.x, 0.0f);
    float o5 = fmaxf(acc5 * rd + b1v.y, 0.0f);
    float o6 = fmaxf(acc6 * rd + b1v.z, 0.0f);
    float o7 = fmaxf(acc7 * rd + b1v.w, 0.0f);
    __half2 pa = __float22half2_rn(make_float2(o0, o1));
    __half2 pb = __float22half2_rn(make_float2(o2, o3));
    __half2 pc = __float22half2_rn(make_float2(o4, o5));
    __half2 pd2 = __float22half2_rn(make_float2(o6, o7));
    uint4 st;
    st.x = *(unsigned int*)&pa;
    st.y = *(unsigned int*)&pb;
    st.z = *(unsigned int*)&pc;
    st.w = *(unsigned int*)&pd2;
    *(uint4*)(h2h + (size_t)n * FEAT + 8 * l) = st;
  }
}

// ---------------- K5: MFMA g8(fp8, 64B rows) = h2(fp16) @ W2 ---------------
__global__ __launch_bounds__(256) void k_gemm2(
    const __half* __restrict__ h2h, const float* __restrict__ W,
    const float* __restrict__ asv, const float* __restrict__ adv,
    unsigned char* __restrict__ g8, float* __restrict__ a_src,
    float* __restrict__ a_dst, int N) {
  __shared__ __half WT2[W2C * WTS];  // 12480 B
  __shared__ float DL[64 * DST2];    // 13312 B
  int tid = threadIdx.x;
  int wv = tid >> 6, l = tid & 63;
  int q = l >> 4, c = l & 15;
  for (int idx = tid; idx < W2C * 128; idx += 256) {
    int col = idx >> 7, k = idx & 127;
    float v = (col < OUTD) ? W[k * OUTD + col] : 0.0f;
    WT2[col * WTS + k] = __float2half(v);
  }
  __syncthreads();
  h8t bf[3][4];
  const unsigned short* wtp = (const unsigned short*)WT2;
#pragma unroll
  for (int ct = 0; ct < 3; ct++) {
#pragma unroll
    for (int kk = 0; kk < 4; kk++) {
      unsigned int* bu = (unsigned int*)&bf[ct][kk];
      int base = (ct * 16 + c) * WTS + kk * 32 + 8 * q;
#pragma unroll
      for (int p = 0; p < 4; p++)
        bu[p] = *(const unsigned int*)(wtp + base + 2 * p);
    }
  }
  int nodeBase = blockIdx.x * 64;
  int node = nodeBase + wv * 16 + c;
  const __half* hr = h2h + (size_t)min(node, N - 1) * FEAT;
  h8t af[4];
#pragma unroll
  for (int kk = 0; kk < 4; kk++) {
    uint4 v = *(const uint4*)(hr + kk * 32 + 8 * q);
    *(uint4*)&af[kk] = v;
  }
  f32x4 d0 = {0.f, 0.f, 0.f, 0.f}, d1 = {0.f, 0.f, 0.f, 0.f},
        d2 = {0.f, 0.f, 0.f, 0.f};
#pragma unroll
  for (int kk = 0; kk < 4; kk++) {
    d0 = __builtin_amdgcn_mfma_f32_16x16x32_f16(af[kk], bf[0][kk], d0, 0, 0, 0);
    d1 = __builtin_amdgcn_mfma_f32_16x16x32_f16(af[kk], bf[1][kk], d1, 0, 0, 0);
    d2 = __builtin_amdgcn_mfma_f32_16x16x32_f16(af[kk], bf[2][kk], d2, 0, 0, 0);
  }
#pragma unroll
  for (int r = 0; r < 4; r++) {
    int row = wv * 16 + 4 * q + r;
    DL[row * DST2 + c] = d0[r];
    DL[row * DST2 + 16 + c] = d1[r];
    DL[row * DST2 + 32 + c] = d2[r];
  }
  __syncthreads();
  // scores: lane (i=l&15, cg=l>>4) sums cols cg*10..cg*10+9 of node row i
  int i = l & 15, cg = l >> 4;
  int row = wv * 16 + i;
  float ps = 0.0f, pd = 0.0f;
#pragma unroll
  for (int k = 0; k < 10; k++) {
    int col = cg * 10 + k;
    float gv = DL[row * DST2 + col];
    ps = fmaf(gv, asv[col], ps);
    pd = fmaf(gv, adv[col], pd);
  }
  ps += __shfl_xor(ps, 16); ps += __shfl_xor(ps, 32);
  pd += __shfl_xor(pd, 16); pd += __shfl_xor(pd, 32);
  int snode = nodeBase + wv * 16 + i;
  if (cg == 0 && snode < N) {
    a_src[snode] = ps;
    a_dst[snode] = pd;
  }
  // g8 write: 16 nodes x 16 uint words (64B rows), fp8-packed from DL
  for (int idx = l; idx < 16 * 16; idx += 64) {
    int ni = idx >> 4, w = idx & 15;
    int rr = wv * 16 + ni;
    int wnode = nodeBase + rr;
    if (wnode < N) {
      unsigned int u = 0;
      if (w < 10) {
        float c0 = DL[rr * DST2 + 4 * w];
        float c1 = DL[rr * DST2 + 4 * w + 1];
        float c2 = DL[rr * DST2 + 4 * w + 2];
        float c3 = DL[rr * DST2 + 4 * w + 3];
        u = __builtin_amdgcn_cvt_pk_fp8_f32(c0, c1, 0, false);
        u = __builtin_amdgcn_cvt_pk_fp8_f32(c2, c3, u, true);
      }
      *(unsigned int*)(g8 + (size_t)wnode * G8S + 4 * w) = u;
    }
  }
}

// ---------------- K6: layer-2 softmax-aggregate + log_softmax --------------
// 4 edges/wave (eg=l>>4); lane li (li<10) owns cols {4li..4li+3} of fp8 rows.
__global__ __launch_bounds__(256) void k_agg2(
    const int* __restrict__ offs, const int* __restrict__ csr,
    const float* __restrict__ a_src, const float* __restrict__ a_dst,
    const unsigned char* __restrict__ g8, const float* __restrict__ bias,
    float* __restrict__ out, int N) {
  __shared__ float plds[4][PS];
  __shared__ int slds[4][128];
  int wv = threadIdx.x >> 6, l = threadIdx.x & 63;
  int n = blockIdx.x * 4 + wv;
  if (n >= N) return;
  int beg = offs[n], end = offs[n + 1];
  int deg = end - beg;
  float adn = a_dst[n];
  float sm = 0.0f;
  for (int j0 = 0; j0 < deg; j0 += 64) {
    int j = j0 + l;
    if (j < deg) {
      int s = csr[beg + j];
      float t = a_src[s] + adn;
      t = t > 0.0f ? t : 0.2f * t;
      float p = __expf(t);
      sm += p;
      if (j < 128) {
        plds[wv][j] = p;
        slds[wv][j] = s;
      }
    }
  }
  for (int m = 1; m < 64; m <<= 1) sm += __shfl_xor(sm, m);
  float rd = 1.0f / sm;
  const int* sp = slds[wv];
  const float* pp = plds[wv];
  int li = l & 15, eg = l >> 4;
  int lic = min(li, 9);
  const unsigned char* gb = g8 + 4 * lic;
  float acc0 = 0.0f, acc1 = 0.0f, acc2 = 0.0f, acc3 = 0.0f;
  if (deg <= 128) {
    int dm1 = deg - 1;
    int ns = (deg + 3) >> 2;  // steps of 4 edges
    unsigned int cur[4], nxt[4];
#define ROWB(G) \
  (*(const unsigned int*)(gb + (size_t)sp[min(4 * (G) + eg, dm1)] * G8S))
#pragma unroll
    for (int i = 0; i < 4; i++) cur[i] = ROWB(i);
    for (int g = 0; g < ns; g += 4) {
#pragma unroll
      for (int i = 0; i < 4; i++) nxt[i] = ROWB(g + 4 + i);
#pragma unroll
      for (int i = 0; i < 4; i++) {
        int j = 4 * (g + i) + eg;
        float a = (j < deg) ? pp[j] : 0.0f;
        v2f lo = __builtin_amdgcn_cvt_pk_f32_fp8((int)cur[i], false);
        v2f hi = __builtin_amdgcn_cvt_pk_f32_fp8((int)cur[i], true);
        acc0 = fmaf(a, lo[0], acc0);
        acc1 = fmaf(a, lo[1], acc1);
        acc2 = fmaf(a, hi[0], acc2);
        acc3 = fmaf(a, hi[1], acc3);
        cur[i] = nxt[i];
      }
    }
#undef ROWB
  } else {
    for (int j = eg; j < deg; j += 4) {
      int s;
      float p;
      if (j < 128) {
        s = sp[j];
        p = pp[j];
      } else {
        s = csr[beg + j];
        float t = a_src[s] + adn;
        t = t > 0.0f ? t : 0.2f * t;
        p = __expf(t);
      }
      unsigned int w = *(const unsigned int*)(gb + (size_t)s * G8S);
      v2f lo = __builtin_amdgcn_cvt_pk_f32_fp8((int)w, false);
      v2f hi = __builtin_amdgcn_cvt_pk_f32_fp8((int)w, true);
      acc0 = fmaf(p, lo[0], acc0);
      acc1 = fmaf(p, lo[1], acc1);
      acc2 = fmaf(p, hi[0], acc2);
      acc3 = fmaf(p, hi[1], acc3);
    }
  }
#pragma unroll
  for (int m = 16; m < 64; m <<= 1) {
    acc0 += __shfl_xor(acc0, m);
    acc1 += __shfl_xor(acc1, m);
    acc2 += __shfl_xor(acc2, m);
    acc3 += __shfl_xor(acc3, m);
  }
  bool cact = li < 10;
  float v0 = -INFINITY, v1 = -INFINITY, v2 = -INFINITY, v3 = -INFINITY;
  if (cact) {
    float4 bv = *(const float4*)(bias + 4 * li);
    v0 = acc0 * rd + bv.x;
    v1 = acc1 * rd + bv.y;
    v2 = acc2 * rd + bv.z;
    v3 = acc3 * rd + bv.w;
  }
  float mx = fmaxf(fmaxf(v0, v1), fmaxf(v2, v3));
  for (int m = 1; m < 64; m <<= 1) mx = fmaxf(mx, __shfl_xor(mx, m));
  // only eg==0 lanes contribute to the denominator (eg=1..3 hold copies)
  float pe = (eg == 0 && cact) ? __expf(v0 - mx) + __expf(v1 - mx) +
                                     __expf(v2 - mx) + __expf(v3 - mx)
                               : 0.0f;
  float se = pe;
  for (int m = 1; m < 64; m <<= 1) se += __shfl_xor(se, m);
  float ls = logf(se);
  if (eg == 0 && cact) {
    float4 o;
    o.x = v0 - mx - ls;
    o.y = v1 - mx - ls;
    o.z = v2 - mx - ls;
    o.w = v3 - mx - ls;
    *(float4*)(out + (size_t)n * OUTD + 4 * li) = o;
  }
}

// ---------------------------------------------------------------------------
extern "C" void kernel_launch(void* const* d_in, const int* in_sizes, int n_in,
                              void* d_out, int out_size, void* d_ws,
                              size_t ws_size, hipStream_t stream) {
  const float* x = (const float*)d_in[0];
  const int* ei = (const int*)d_in[1];
  const float* mw1 = (const float*)d_in[2];
  const float* mb1 = (const float*)d_in[3];
  const float* mw2 = (const float*)d_in[4];
  const float* mb2 = (const float*)d_in[5];
  const float* W1 = (const float*)d_in[6];
  const float* as1w = (const float*)d_in[7];
  const float* ad1w = (const float*)d_in[8];
  const float* b1 = (const float*)d_in[9];
  const float* W2 = (const float*)d_in[10];
  const float* as2w = (const float*)d_in[11];
  const float* ad2w = (const float*)d_in[12];
  const float* b2 = (const float*)d_in[13];
  float* out = (float*)d_out;

  int N = in_sizes[0] / XDIM;
  int E = in_sizes[1] / 2;
  int ET = E + N;
  int NB = (N + 255) >> 8;  // dst buckets of 256 nodes

  char* ws = (char*)d_ws;
  size_t off = 0;
  auto carve = [&](size_t bytes) -> void* {
    void* p = ws + off;
    off = (off + bytes + 255) & ~(size_t)255;
    return p;
  };
  float* part = (float*)carve((size_t)SB * 12 * 4);
  int* cnt = (int*)carve((size_t)NB * PB * 4);
  int* bsum = (int*)carve((size_t)MAXNB * 4);
  int* ebuf = (int*)carve((size_t)E * 4);
  int* offs = (int*)carve((size_t)(N + 1) * 4);
  int* csr = (int*)carve((size_t)ET * 4);
  float* scl = (float*)carve((size_t)N * 4);
  __half* as1h = (__half*)carve((size_t)N * NH * 2);
  __half* ad1h = (__half*)carve((size_t)N * NH * 2);
  unsigned char* h8 = (unsigned char*)carve((size_t)N * FEAT);
  __half* h2h = (__half*)carve((size_t)N * FEAT * 2);
  unsigned char* g8 = (unsigned char*)carve((size_t)N * G8S);
  float* as2 = (float*)carve((size_t)N * 4);
  float* ad2 = (float*)carve((size_t)N * 4);

  k_stats1<<<SB, 256, 0, stream>>>(x, part, N);
  k_scale<<<(N + 255) / 256, 256, 0, stream>>>(x, part, mw1, mb1, mw2, mb2,
                                               scl, N);
  k_bh<<<PB, 256, 0, stream>>>(ei, cnt, E, NB);
  k_sc1<<<NB, 256, 0, stream>>>(cnt, bsum);
  k_part<<<PB, 256, 0, stream>>>(ei, cnt, bsum, ebuf, E, NB);
  k_bcsr<<<NB, 256, 0, stream>>>(ebuf, bsum, offs, csr, N, E, NB);
  int NG = (N + 63) / 64;
  k_gemm1<<<NG, 256, 0, stream>>>(x, scl, W1, as1w, ad1w, h8, as1h, ad1h, N);
  k_agg1<<<(N + 3) / 4, 256, 0, stream>>>(offs, csr, as1h, ad1h, h8, b1, h2h,
                                          N);
  k_gemm2<<<NG, 256, 0, stream>>>(h2h, W2, as2w, ad2w, g8, as2, ad2, N);
  k_agg2<<<(N + 3) / 4, 256, 0, stream>>>(offs, csr, as2, ad2, g8, b2, out, N);
}

// Round 15
// 166.739 us; speedup vs baseline: 5.2887x; 1.0926x over previous
//
#include <hip/hip_runtime.h>
#include <hip/hip_fp16.h>

#define XDIM 134
#define FEAT 128
#define AUGN 6
#define NH 8
#define HD 16
#define OUTD 40
#define PS 132       // per-head stride in plds (132 mod 32 = 4 -> conflict-free)
#define SB 256       // stats partial blocks
#define PB 256       // partition blocks
#define MAXNB 256    // max buckets (N <= 65536)
#define G8S 64       // g8 row stride in bytes (one cache line)
#define WTS 130      // W^T LDS stride in halves (bank-spread, b32-aligned)
#define DST 132      // gemm1 D LDS stride in halves
#define W2C 48       // gemm2 padded cols
#define DST2 52      // gemm2 D LDS stride in floats

typedef float v2f __attribute__((ext_vector_type(2)));
typedef _Float16 h8t __attribute__((ext_vector_type(8)));
typedef float f32x4 __attribute__((ext_vector_type(4)));

__device__ __forceinline__ float rlf(float v, int lane) {
  return __int_as_float(__builtin_amdgcn_readlane(__float_as_int(v), lane));
}

// ---------------- F1: stats1 (blocks [0,SB)) || bh (blocks [SB,SB+PB)) -----
__global__ __launch_bounds__(256) void k_f1(const float* __restrict__ x,
                                            float* __restrict__ part,
                                            const int* __restrict__ ei,
                                            int* __restrict__ cnt, int N,
                                            int E, int NB) {
  __shared__ float red[4][12];
  __shared__ int hist[MAXNB];
  int t = threadIdx.x;
  if (blockIdx.x < SB) {
    int bb = blockIdx.x;
    float s[AUGN] = {0, 0, 0, 0, 0, 0}, q[AUGN] = {0, 0, 0, 0, 0, 0};
    for (int n = bb * 256 + t; n < N; n += SB * 256) {
      const float* r = x + (size_t)n * XDIM + FEAT;
      float2 v0 = *(const float2*)r;
      float2 v1 = *(const float2*)(r + 2);
      float2 v2 = *(const float2*)(r + 4);
      float v[AUGN] = {v0.x, v0.y, v1.x, v1.y, v2.x, v2.y};
#pragma unroll
      for (int i = 0; i < AUGN; i++) {
        s[i] += v[i];
        q[i] += v[i] * v[i];
      }
    }
#pragma unroll
    for (int i = 0; i < AUGN; i++) {
      for (int m = 1; m < 64; m <<= 1) {
        s[i] += __shfl_xor(s[i], m);
        q[i] += __shfl_xor(q[i], m);
      }
    }
    int wv = t >> 6, l = t & 63;
    if (l == 0) {
#pragma unroll
      for (int i = 0; i < AUGN; i++) {
        red[wv][i] = s[i];
        red[wv][6 + i] = q[i];
      }
    }
    __syncthreads();
    if (t < 12)
      part[bb * 12 + t] = red[0][t] + red[1][t] + red[2][t] + red[3][t];
  } else {
    int bb = blockIdx.x - SB;
    for (int b = t; b < NB; b += 256) hist[b] = 0;
    __syncthreads();
    int ch = (E + PB - 1) / PB;
    int lo = bb * ch, hi = min(lo + ch, E);
    for (int e = lo + t; e < hi; e += 256)
      atomicAdd(&hist[ei[E + e] >> 8], 1);
    __syncthreads();
    for (int b = t; b < NB; b += 256)
      cnt[(size_t)b * PB + bb] = hist[b];
  }
}

// ---------------- F2: scale (blocks [0,NSC)) || sc1 (blocks [NSC,NSC+NB)) --
__global__ __launch_bounds__(256) void k_f2(
    const float* __restrict__ x, const float* __restrict__ part,
    const float* __restrict__ w1, const float* __restrict__ b1,
    const float* __restrict__ w2, const float* __restrict__ b2,
    float* __restrict__ scl, int* __restrict__ cnt, int* __restrict__ bsum,
    int N, int NSC) {
  __shared__ float red[4][12];
  __shared__ float sred[12];
  __shared__ int ps[256];
  int t = threadIdx.x;
  if ((int)blockIdx.x < NSC) {
    {
      float v[12];
#pragma unroll
      for (int c = 0; c < 12; c++) v[c] = part[t * 12 + c];
#pragma unroll
      for (int c = 0; c < 12; c++)
        for (int m = 1; m < 64; m <<= 1) v[c] += __shfl_xor(v[c], m);
      int wv = t >> 6, l = t & 63;
      if (l == 0) {
#pragma unroll
        for (int c = 0; c < 12; c++) red[wv][c] = v[c];
      }
      __syncthreads();
      if (t < 12) sred[t] = red[0][t] + red[1][t] + red[2][t] + red[3][t];
      __syncthreads();
    }
    int n = blockIdx.x * 256 + t;
    if (n >= N) return;
    const float* r = x + (size_t)n * XDIM + FEAT;
    float a[AUGN];
    float invN = 1.0f / (float)N;
#pragma unroll
    for (int i = 0; i < AUGN; i++) {
      float sum = sred[i], sq = sred[6 + i];
      float mean = sum * invN;
      float var = (sq - sum * mean) / (float)(N - 1);
      a[i] = (r[i] - mean) / sqrtf(var);
    }
    float s2 = b2[0];
#pragma unroll
    for (int j = 0; j < 16; j++) {
      float z = b1[j];
#pragma unroll
      for (int i = 0; i < AUGN; i++) z = fmaf(a[i], w1[i * 16 + j], z);
      z = fmaxf(z, 0.0f);
      s2 = fmaf(z, w2[j], s2);
    }
    float sig = 1.0f / (1.0f + __expf(-s2));
    scl[n] = 1.0f + sig;
  } else {
    int b = blockIdx.x - NSC;
    int v = cnt[(size_t)b * PB + t];
    ps[t] = v;
    __syncthreads();
    for (int d = 1; d < 256; d <<= 1) {
      int u = (t >= d) ? ps[t - d] : 0;
      __syncthreads();
      ps[t] += u;
      __syncthreads();
    }
    cnt[(size_t)b * PB + t] = ps[t] - v;  // exclusive within bucket
    if (t == 255) bsum[b] = ps[255];
  }
}

// ---------------- F3: gemm1 (blocks [0,NG)) || part (blocks [NG,NG+PB)) ----
__global__ __launch_bounds__(256) void k_f3(
    const float* __restrict__ x, const float* __restrict__ scl,
    const float* __restrict__ W, const float* __restrict__ asv,
    const float* __restrict__ adv, unsigned char* __restrict__ h8,
    __half* __restrict__ as1h, __half* __restrict__ ad1h,
    const int* __restrict__ ei, const int* __restrict__ cnt,
    const int* __restrict__ bsum, int* __restrict__ ebuf, int N, int E,
    int NB, int NG) {
  __shared__ __align__(16) char smem[128 * WTS * 2 + 64 * DST * 2];
  int tid = threadIdx.x;
  if ((int)blockIdx.x < NG) {
    __half* WT = (__half*)smem;                       // 128*WTS halves
    __half* D16 = (__half*)(smem + 128 * WTS * 2);    // 64*DST halves
    int wv = tid >> 6, l = tid & 63;
    int q = l >> 4, c = l & 15;
    for (int idx = tid * 4; idx < 128 * 128; idx += 256 * 4) {
      int k = idx >> 7, n = idx & 127;
      float4 v = *(const float4*)(W + idx);
      WT[(n + 0) * WTS + k] = __float2half(v.x);
      WT[(n + 1) * WTS + k] = __float2half(v.y);
      WT[(n + 2) * WTS + k] = __float2half(v.z);
      WT[(n + 3) * WTS + k] = __float2half(v.w);
    }
    __syncthreads();
    int colBase = wv * 32;
    h8t bf[2][4];
    const unsigned short* wtp = (const unsigned short*)WT;
#pragma unroll
    for (int ct = 0; ct < 2; ct++) {
#pragma unroll
      for (int kk = 0; kk < 4; kk++) {
        unsigned int* bu = (unsigned int*)&bf[ct][kk];
        int base = (colBase + ct * 16 + c) * WTS + kk * 32 + 8 * q;
#pragma unroll
        for (int p = 0; p < 4; p++)
          bu[p] = *(const unsigned int*)(wtp + base + 2 * p);
      }
    }
    int nodeBase = blockIdx.x * 64;
#pragma unroll
    for (int nt = 0; nt < 4; nt++) {
      int node = nodeBase + nt * 16 + c;
      const float* xr = x + (size_t)min(node, N - 1) * XDIM;
      h8t af[4];
#pragma unroll
      for (int kk = 0; kk < 4; kk++) {
        int k0 = kk * 32 + 8 * q;
#pragma unroll
        for (int p = 0; p < 4; p++) {
          float2 v = *(const float2*)(xr + k0 + 2 * p);
          af[kk][2 * p] = (_Float16)v.x;
          af[kk][2 * p + 1] = (_Float16)v.y;
        }
      }
      f32x4 a0 = {0.f, 0.f, 0.f, 0.f}, a1 = {0.f, 0.f, 0.f, 0.f};
#pragma unroll
      for (int kk = 0; kk < 4; kk++) {
        a0 = __builtin_amdgcn_mfma_f32_16x16x32_f16(af[kk], bf[0][kk], a0, 0,
                                                    0, 0);
        a1 = __builtin_amdgcn_mfma_f32_16x16x32_f16(af[kk], bf[1][kk], a1, 0,
                                                    0, 0);
      }
#pragma unroll
      for (int r = 0; r < 4; r++) {
        int row = nt * 16 + 4 * q + r;
        D16[row * DST + colBase + c] = __float2half(a0[r]);
        D16[row * DST + colBase + 16 + c] = __float2half(a1[r]);
      }
    }
    __syncthreads();
    float asw0 = asv[2 * l], asw1 = asv[2 * l + 1];
    float adw0 = adv[2 * l], adw1 = adv[2 * l + 1];
    for (int i = 0; i < 16; i++) {
      int node = nodeBase + wv * 16 + i;
      if (node >= N) break;
      float s = scl[node];
      __half2 yh = *(const __half2*)&D16[(wv * 16 + i) * DST + 2 * l];
      float2 yf = __half22float2(yh);
      float y0 = yf.x * s, y1 = yf.y * s;
      int pk = __builtin_amdgcn_cvt_pk_fp8_f32(y0, y1, 0, false);
      ((unsigned short*)(h8 + (size_t)node * FEAT))[l] = (unsigned short)pk;
      float ps2 = y0 * asw0 + y1 * asw1;
      float pd = y0 * adw0 + y1 * adw1;
      ps2 += __shfl_xor(ps2, 1);
      ps2 += __shfl_xor(ps2, 2);
      ps2 += __shfl_xor(ps2, 4);
      pd += __shfl_xor(pd, 1);
      pd += __shfl_xor(pd, 2);
      pd += __shfl_xor(pd, 4);
      if ((l & 7) == 0) {
        as1h[node * NH + (l >> 3)] = __float2half(ps2);
        ad1h[node * NH + (l >> 3)] = __float2half(pd);
      }
    }
  } else {
    int bb = blockIdx.x - NG;
    int* bex = (int*)smem;
    int* cur = (int*)(smem + 1024);
    int t = tid;
    int v = (t < NB) ? bsum[t] : 0;
    bex[t] = v;
    __syncthreads();
    for (int d = 1; d < 256; d <<= 1) {
      int u = (t >= d) ? bex[t - d] : 0;
      __syncthreads();
      bex[t] += u;
      __syncthreads();
    }
    if (t < NB) cur[t] = (bex[t] - v) + cnt[(size_t)t * PB + bb];
    __syncthreads();
    int ch = (E + PB - 1) / PB;
    int lo = bb * ch, hi = min(lo + ch, E);
    for (int e = lo + t; e < hi; e += 256) {
      int s = ei[e], d = ei[E + e];
      int pos = atomicAdd(&cur[d >> 8], 1);
      ebuf[pos] = (s << 8) | (d & 255);
    }
  }
}

// ---------------- K2d: per-bucket CSR build (contiguous region writes) -----
__global__ __launch_bounds__(256) void k_bcsr(const int* __restrict__ ebuf,
                                              const int* __restrict__ bsum,
                                              int* __restrict__ offs,
                                              int* __restrict__ csr, int N,
                                              int E, int NB) {
  __shared__ int bex[MAXNB];
  __shared__ int dl[256];
  __shared__ int sc[256];
  __shared__ int cu[256];
  int b = blockIdx.x, t = threadIdx.x;
  {
    int v = (t < NB) ? bsum[t] : 0;
    bex[t] = v;
    __syncthreads();
    for (int d = 1; d < 256; d <<= 1) {
      int u = (t >= d) ? bex[t - d] : 0;
      __syncthreads();
      bex[t] += u;
      __syncthreads();
    }
    int incl = bex[t];
    __syncthreads();
    bex[t] = incl - v;  // exclusive
    __syncthreads();
  }
  int nn = min(256, N - b * 256);
  int rs = bex[b];
  int re = (b + 1 < NB) ? bex[b + 1] : E;
  int csrbase = rs + b * 256;
  dl[t] = 0;
  __syncthreads();
  for (int j = rs + t; j < re; j += 256)
    atomicAdd(&dl[ebuf[j] & 255], 1);
  __syncthreads();
  int v = (t < nn) ? dl[t] + 1 : 0;
  sc[t] = v;
  __syncthreads();
  for (int d = 1; d < 256; d <<= 1) {
    int u = (t >= d) ? sc[t - d] : 0;
    __syncthreads();
    sc[t] += u;
    __syncthreads();
  }
  int excl = sc[t] - v;
  if (t < nn) {
    int node = b * 256 + t;
    offs[node] = csrbase + excl;
    csr[csrbase + excl] = node;  // self-loop slot
    cu[t] = excl + 1;
  }
  __syncthreads();
  for (int j = rs + t; j < re; j += 256) {
    int pk = ebuf[j];
    int p = atomicAdd(&cu[pk & 255], 1);
    csr[csrbase + p] = pk >> 8;
  }
  if (b == 0 && t == 0) offs[N] = E + N;
}

// ---------------- K4: layer-1 softmax-aggregate; h2(fp16) ------------------
__global__ __launch_bounds__(256) void k_agg1(
    const int* __restrict__ offs, const int* __restrict__ csr,
    const __half* __restrict__ as1h, const __half* __restrict__ ad1h,
    const unsigned char* __restrict__ h8, const float* __restrict__ bias,
    __half* __restrict__ h2h, int N) {
  __shared__ float plds[4][8 * PS];
  __shared__ int slds[4][128];
  int wv = threadIdx.x >> 6, l = threadIdx.x & 63;
  int n = blockIdx.x * 4 + wv;
  if (n >= N) return;
  int beg = offs[n], end = offs[n + 1];
  int deg = end - beg;
  int h = l & 7, e8 = l >> 3;
  float adh = __half2float(ad1h[(size_t)n * NH + h]);
  float smh = 0.0f;
  for (int j0 = 0; j0 < deg; j0 += 8) {
    int j = j0 + e8;
    if (j < deg) {
      int s = csr[beg + j];
      if (h == 0 && j < 128) slds[wv][j] = s;
      float t = __half2float(as1h[(size_t)s * NH + h]) + adh;
      t = t > 0.0f ? t : 0.2f * t;
      float p = __expf(t);
      smh += p;
      if (j < 128) plds[wv][h * PS + j] = p;
    }
  }
  smh += __shfl_xor(smh, 8);
  smh += __shfl_xor(smh, 16);
  smh += __shfl_xor(smh, 32);  // lane k holds denom of head k&7
  __builtin_amdgcn_wave_barrier();
  // sweep 2: 4 edges/step; lane li owns channels {8li..8li+7}, head hh=li>>1
  int li = l & 15, eg = l >> 4;
  int hh = li >> 1;
  float rd = 1.0f / __shfl(smh, hh);
  const int* sp = slds[wv];
  const float* pp = &plds[wv][hh * PS];
  float acc0 = 0.f, acc1 = 0.f, acc2 = 0.f, acc3 = 0.f;
  float acc4 = 0.f, acc5 = 0.f, acc6 = 0.f, acc7 = 0.f;
  if (deg <= 128) {
    int dm1 = deg - 1;
    int ns = (deg + 3) >> 2;  // steps of 4 edges
    uint2 cur[4], nxt[4];
#define ROWA(G) \
  (*(const uint2*)(h8 + (size_t)sp[min(4 * (G) + eg, dm1)] * FEAT + 8 * li))
#pragma unroll
    for (int i = 0; i < 4; i++) cur[i] = ROWA(i);
    for (int g = 0; g < ns; g += 4) {
#pragma unroll
      for (int i = 0; i < 4; i++) nxt[i] = ROWA(g + 4 + i);
#pragma unroll
      for (int i = 0; i < 4; i++) {
        int j = 4 * (g + i) + eg;
        float a = (j < deg) ? pp[j] : 0.0f;
        v2f l0 = __builtin_amdgcn_cvt_pk_f32_fp8((int)cur[i].x, false);
        v2f h0 = __builtin_amdgcn_cvt_pk_f32_fp8((int)cur[i].x, true);
        v2f l1 = __builtin_amdgcn_cvt_pk_f32_fp8((int)cur[i].y, false);
        v2f h1 = __builtin_amdgcn_cvt_pk_f32_fp8((int)cur[i].y, true);
        acc0 = fmaf(a, l0[0], acc0); acc1 = fmaf(a, l0[1], acc1);
        acc2 = fmaf(a, h0[0], acc2); acc3 = fmaf(a, h0[1], acc3);
        acc4 = fmaf(a, l1[0], acc4); acc5 = fmaf(a, l1[1], acc5);
        acc6 = fmaf(a, h1[0], acc6); acc7 = fmaf(a, h1[1], acc7);
        cur[i] = nxt[i];
      }
    }
#undef ROWA
  } else {
    float adhh = __shfl(adh, hh);
    for (int j = eg; j < deg; j += 4) {
      int s;
      float p;
      if (j < 128) {
        s = sp[j];
        p = pp[j];
      } else {
        s = csr[beg + j];
        float t = __half2float(as1h[(size_t)s * NH + hh]) + adhh;
        t = t > 0.0f ? t : 0.2f * t;
        p = __expf(t);
      }
      uint2 w = *(const uint2*)(h8 + (size_t)s * FEAT + 8 * li);
      v2f l0 = __builtin_amdgcn_cvt_pk_f32_fp8((int)w.x, false);
      v2f h0 = __builtin_amdgcn_cvt_pk_f32_fp8((int)w.x, true);
      v2f l1 = __builtin_amdgcn_cvt_pk_f32_fp8((int)w.y, false);
      v2f h1 = __builtin_amdgcn_cvt_pk_f32_fp8((int)w.y, true);
      acc0 = fmaf(p, l0[0], acc0); acc1 = fmaf(p, l0[1], acc1);
      acc2 = fmaf(p, h0[0], acc2); acc3 = fmaf(p, h0[1], acc3);
      acc4 = fmaf(p, l1[0], acc4); acc5 = fmaf(p, l1[1], acc5);
      acc6 = fmaf(p, h1[0], acc6); acc7 = fmaf(p, h1[1], acc7);
    }
  }
#pragma unroll
  for (int m = 16; m < 64; m <<= 1) {
    acc0 += __shfl_xor(acc0, m); acc1 += __shfl_xor(acc1, m);
    acc2 += __shfl_xor(acc2, m); acc3 += __shfl_xor(acc3, m);
    acc4 += __shfl_xor(acc4, m); acc5 += __shfl_xor(acc5, m);
    acc6 += __shfl_xor(acc6, m); acc7 += __shfl_xor(acc7, m);
  }
  if (l < 16) {
    float4 b0 = *(const float4*)(bias + 8 * l);
    float4 b1v = *(const float4*)(bias + 8 * l + 4);
    float o0 = fmaxf(acc0 * rd + b0.x, 0.0f);
    float o1 = fmaxf(acc1 * rd + b0.y, 0.0f);
    float o2 = fmaxf(acc2 * rd + b0.z, 0.0f);
    float o3 = fmaxf(acc3 * rd + b0.w, 0.0f);
    float o4 = fmaxf(acc4 * rd + b1v.x, 0.0f);
    float o5 = fmaxf(acc5 * rd + b1v.y, 0.0f);
    float o6 = fmaxf(acc6 * rd + b1v.z, 0.0f);
    float o7 = fmaxf(acc7 * rd + b1v.w, 0.0f);
    __half2 pa = __float22half2_rn(make_float2(o0, o1));
    __half2 pb = __float22half2_rn(make_float2(o2, o3));
    __half2 pc = __float22half2_rn(make_float2(o4, o5));
    __half2 pd2 = __float22half2_rn(make_float2(o6, o7));
    uint4 st;
    st.x = *(unsigned int*)&pa;
    st.y = *(unsigned int*)&pb;
    st.z = *(unsigned int*)&pc;
    st.w = *(unsigned int*)&pd2;
    *(uint4*)(h2h + (size_t)n * FEAT + 8 * l) = st;
  }
}

// ---------------- K5: MFMA g8(fp8, 64B rows) = h2(fp16) @ W2 ---------------
__global__ __launch_bounds__(256) void k_gemm2(
    const __half* __restrict__ h2h, const float* __restrict__ W,
    const float* __restrict__ asv, const float* __restrict__ adv,
    unsigned char* __restrict__ g8, float* __restrict__ a_src,
    float* __restrict__ a_dst, int N) {
  __shared__ __half WT2[W2C * WTS];  // 12480 B
  __shared__ float DL[64 * DST2];    // 13312 B
  int tid = threadIdx.x;
  int wv = tid >> 6, l = tid & 63;
  int q = l >> 4, c = l & 15;
  for (int idx = tid; idx < W2C * 128; idx += 256) {
    int col = idx >> 7, k = idx & 127;
    float v = (col < OUTD) ? W[k * OUTD + col] : 0.0f;
    WT2[col * WTS + k] = __float2half(v);
  }
  __syncthreads();
  h8t bf[3][4];
  const unsigned short* wtp = (const unsigned short*)WT2;
#pragma unroll
  for (int ct = 0; ct < 3; ct++) {
#pragma unroll
    for (int kk = 0; kk < 4; kk++) {
      unsigned int* bu = (unsigned int*)&bf[ct][kk];
      int base = (ct * 16 + c) * WTS + kk * 32 + 8 * q;
#pragma unroll
      for (int p = 0; p < 4; p++)
        bu[p] = *(const unsigned int*)(wtp + base + 2 * p);
    }
  }
  int nodeBase = blockIdx.x * 64;
  int node = nodeBase + wv * 16 + c;
  const __half* hr = h2h + (size_t)min(node, N - 1) * FEAT;
  h8t af[4];
#pragma unroll
  for (int kk = 0; kk < 4; kk++) {
    uint4 v = *(const uint4*)(hr + kk * 32 + 8 * q);
    *(uint4*)&af[kk] = v;
  }
  f32x4 d0 = {0.f, 0.f, 0.f, 0.f}, d1 = {0.f, 0.f, 0.f, 0.f},
        d2 = {0.f, 0.f, 0.f, 0.f};
#pragma unroll
  for (int kk = 0; kk < 4; kk++) {
    d0 = __builtin_amdgcn_mfma_f32_16x16x32_f16(af[kk], bf[0][kk], d0, 0, 0, 0);
    d1 = __builtin_amdgcn_mfma_f32_16x16x32_f16(af[kk], bf[1][kk], d1, 0, 0, 0);
    d2 = __builtin_amdgcn_mfma_f32_16x16x32_f16(af[kk], bf[2][kk], d2, 0, 0, 0);
  }
#pragma unroll
  for (int r = 0; r < 4; r++) {
    int row = wv * 16 + 4 * q + r;
    DL[row * DST2 + c] = d0[r];
    DL[row * DST2 + 16 + c] = d1[r];
    DL[row * DST2 + 32 + c] = d2[r];
  }
  __syncthreads();
  // scores: lane (i=l&15, cg=l>>4) sums cols cg*10..cg*10+9 of node row i
  int i = l & 15, cg = l >> 4;
  int row = wv * 16 + i;
  float ps = 0.0f, pd = 0.0f;
#pragma unroll
  for (int k = 0; k < 10; k++) {
    int col = cg * 10 + k;
    float gv = DL[row * DST2 + col];
    ps = fmaf(gv, asv[col], ps);
    pd = fmaf(gv, adv[col], pd);
  }
  ps += __shfl_xor(ps, 16); ps += __shfl_xor(ps, 32);
  pd += __shfl_xor(pd, 16); pd += __shfl_xor(pd, 32);
  int snode = nodeBase + wv * 16 + i;
  if (cg == 0 && snode < N) {
    a_src[snode] = ps;
    a_dst[snode] = pd;
  }
  // g8 write: 16 nodes x 16 uint words (64B rows), fp8-packed from DL
  for (int idx = l; idx < 16 * 16; idx += 64) {
    int ni = idx >> 4, w = idx & 15;
    int rr = wv * 16 + ni;
    int wnode = nodeBase + rr;
    if (wnode < N) {
      unsigned int u = 0;
      if (w < 10) {
        float c0 = DL[rr * DST2 + 4 * w];
        float c1 = DL[rr * DST2 + 4 * w + 1];
        float c2 = DL[rr * DST2 + 4 * w + 2];
        float c3 = DL[rr * DST2 + 4 * w + 3];
        u = __builtin_amdgcn_cvt_pk_fp8_f32(c0, c1, 0, false);
        u = __builtin_amdgcn_cvt_pk_fp8_f32(c2, c3, u, true);
      }
      *(unsigned int*)(g8 + (size_t)wnode * G8S + 4 * w) = u;
    }
  }
}

// ---------------- K6: layer-2 softmax-aggregate + log_softmax --------------
__global__ __launch_bounds__(256) void k_agg2(
    const int* __restrict__ offs, const int* __restrict__ csr,
    const float* __restrict__ a_src, const float* __restrict__ a_dst,
    const unsigned char* __restrict__ g8, const float* __restrict__ bias,
    float* __restrict__ out, int N) {
  __shared__ float plds[4][PS];
  __shared__ int slds[4][128];
  int wv = threadIdx.x >> 6, l = threadIdx.x & 63;
  int n = blockIdx.x * 4 + wv;
  if (n >= N) return;
  int beg = offs[n], end = offs[n + 1];
  int deg = end - beg;
  float adn = a_dst[n];
  float sm = 0.0f;
  for (int j0 = 0; j0 < deg; j0 += 64) {
    int j = j0 + l;
    if (j < deg) {
      int s = csr[beg + j];
      float t = a_src[s] + adn;
      t = t > 0.0f ? t : 0.2f * t;
      float p = __expf(t);
      sm += p;
      if (j < 128) {
        plds[wv][j] = p;
        slds[wv][j] = s;
      }
    }
  }
  for (int m = 1; m < 64; m <<= 1) sm += __shfl_xor(sm, m);
  float rd = 1.0f / sm;
  const int* sp = slds[wv];
  const float* pp = plds[wv];
  int li = l & 15, eg = l >> 4;
  int lic = min(li, 9);
  const unsigned char* gb = g8 + 4 * lic;
  float acc0 = 0.0f, acc1 = 0.0f, acc2 = 0.0f, acc3 = 0.0f;
  if (deg <= 128) {
    int dm1 = deg - 1;
    int ns = (deg + 3) >> 2;  // steps of 4 edges
    unsigned int cur[4], nxt[4];
#define ROWB(G) \
  (*(const unsigned int*)(gb + (size_t)sp[min(4 * (G) + eg, dm1)] * G8S))
#pragma unroll
    for (int i = 0; i < 4; i++) cur[i] = ROWB(i);
    for (int g = 0; g < ns; g += 4) {
#pragma unroll
      for (int i = 0; i < 4; i++) nxt[i] = ROWB(g + 4 + i);
#pragma unroll
      for (int i = 0; i < 4; i++) {
        int j = 4 * (g + i) + eg;
        float a = (j < deg) ? pp[j] : 0.0f;
        v2f lo = __builtin_amdgcn_cvt_pk_f32_fp8((int)cur[i], false);
        v2f hi = __builtin_amdgcn_cvt_pk_f32_fp8((int)cur[i], true);
        acc0 = fmaf(a, lo[0], acc0);
        acc1 = fmaf(a, lo[1], acc1);
        acc2 = fmaf(a, hi[0], acc2);
        acc3 = fmaf(a, hi[1], acc3);
        cur[i] = nxt[i];
      }
    }
#undef ROWB
  } else {
    for (int j = eg; j < deg; j += 4) {
      int s;
      float p;
      if (j < 128) {
        s = sp[j];
        p = pp[j];
      } else {
        s = csr[beg + j];
        float t = a_src[s] + adn;
        t = t > 0.0f ? t : 0.2f * t;
        p = __expf(t);
      }
      unsigned int w = *(const unsigned int*)(gb + (size_t)s * G8S);
      v2f lo = __builtin_amdgcn_cvt_pk_f32_fp8((int)w, false);
      v2f hi = __builtin_amdgcn_cvt_pk_f32_fp8((int)w, true);
      acc0 = fmaf(p, lo[0], acc0);
      acc1 = fmaf(p, lo[1], acc1);
      acc2 = fmaf(p, hi[0], acc2);
      acc3 = fmaf(p, hi[1], acc3);
    }
  }
#pragma unroll
  for (int m = 16; m < 64; m <<= 1) {
    acc0 += __shfl_xor(acc0, m);
    acc1 += __shfl_xor(acc1, m);
    acc2 += __shfl_xor(acc2, m);
    acc3 += __shfl_xor(acc3, m);
  }
  bool cact = li < 10;
  float v0 = -INFINITY, v1 = -INFINITY, v2 = -INFINITY, v3 = -INFINITY;
  if (cact) {
    float4 bv = *(const float4*)(bias + 4 * li);
    v0 = acc0 * rd + bv.x;
    v1 = acc1 * rd + bv.y;
    v2 = acc2 * rd + bv.z;
    v3 = acc3 * rd + bv.w;
  }
  float mx = fmaxf(fmaxf(v0, v1), fmaxf(v2, v3));
  for (int m = 1; m < 64; m <<= 1) mx = fmaxf(mx, __shfl_xor(mx, m));
  // only eg==0 lanes contribute to the denominator (eg=1..3 hold copies)
  float pe = (eg == 0 && cact) ? __expf(v0 - mx) + __expf(v1 - mx) +
                                     __expf(v2 - mx) + __expf(v3 - mx)
                               : 0.0f;
  float se = pe;
  for (int m = 1; m < 64; m <<= 1) se += __shfl_xor(se, m);
  float ls = logf(se);
  if (eg == 0 && cact) {
    float4 o;
    o.x = v0 - mx - ls;
    o.y = v1 - mx - ls;
    o.z = v2 - mx - ls;
    o.w = v3 - mx - ls;
    *(float4*)(out + (size_t)n * OUTD + 4 * li) = o;
  }
}

// ---------------------------------------------------------------------------
extern "C" void kernel_launch(void* const* d_in, const int* in_sizes, int n_in,
                              void* d_out, int out_size, void* d_ws,
                              size_t ws_size, hipStream_t stream) {
  const float* x = (const float*)d_in[0];
  const int* ei = (const int*)d_in[1];
  const float* mw1 = (const float*)d_in[2];
  const float* mb1 = (const float*)d_in[3];
  const float* mw2 = (const float*)d_in[4];
  const float* mb2 = (const float*)d_in[5];
  const float* W1 = (const float*)d_in[6];
  const float* as1w = (const float*)d_in[7];
  const float* ad1w = (const float*)d_in[8];
  const float* b1 = (const float*)d_in[9];
  const float* W2 = (const float*)d_in[10];
  const float* as2w = (const float*)d_in[11];
  const float* ad2w = (const float*)d_in[12];
  const float* b2 = (const float*)d_in[13];
  float* out = (float*)d_out;

  int N = in_sizes[0] / XDIM;
  int E = in_sizes[1] / 2;
  int ET = E + N;
  int NB = (N + 255) >> 8;  // dst buckets of 256 nodes

  char* ws = (char*)d_ws;
  size_t off = 0;
  auto carve = [&](size_t bytes) -> void* {
    void* p = ws + off;
    off = (off + bytes + 255) & ~(size_t)255;
    return p;
  };
  float* part = (float*)carve((size_t)SB * 12 * 4);
  int* cnt = (int*)carve((size_t)NB * PB * 4);
  int* bsum = (int*)carve((size_t)MAXNB * 4);
  int* ebuf = (int*)carve((size_t)E * 4);
  int* offs = (int*)carve((size_t)(N + 1) * 4);
  int* csr = (int*)carve((size_t)ET * 4);
  float* scl = (float*)carve((size_t)N * 4);
  __half* as1h = (__half*)carve((size_t)N * NH * 2);
  __half* ad1h = (__half*)carve((size_t)N * NH * 2);
  unsigned char* h8 = (unsigned char*)carve((size_t)N * FEAT);
  __half* h2h = (__half*)carve((size_t)N * FEAT * 2);
  unsigned char* g8 = (unsigned char*)carve((size_t)N * G8S);
  float* as2 = (float*)carve((size_t)N * 4);
  float* ad2 = (float*)carve((size_t)N * 4);

  int NSC = (N + 255) / 256;
  int NG = (N + 63) / 64;
  k_f1<<<SB + PB, 256, 0, stream>>>(x, part, ei, cnt, N, E, NB);
  k_f2<<<NSC + NB, 256, 0, stream>>>(x, part, mw1, mb1, mw2, mb2, scl, cnt,
                                     bsum, N, NSC);
  k_f3<<<NG + PB, 256, 0, stream>>>(x, scl, W1, as1w, ad1w, h8, as1h, ad1h,
                                    ei, cnt, bsum, ebuf, N, E, NB, NG);
  k_bcsr<<<NB, 256, 0, stream>>>(ebuf, bsum, offs, csr, N, E, NB);
  k_agg1<<<(N + 3) / 4, 256, 0, stream>>>(offs, csr, as1h, ad1h, h8, b1, h2h,
                                          N);
  k_gemm2<<<NG, 256, 0, stream>>>(h2h, W2, as2w, ad2w, g8, as2, ad2, N);
  k_agg2<<<(N + 3) / 4, 256, 0, stream>>>(offs, csr, as2, ad2, g8, b2, out, N);
}

// Round 16
// 166.628 us; speedup vs baseline: 5.2922x; 1.0007x over previous
//
#include <hip/hip_runtime.h>
#include <hip/hip_fp16.h>

#define XDIM 134
#define FEAT 128
#define AUGN 6
#define NH 8
#define HD 16
#define OUTD 40
#define PS 132       // per-head stride in plds (132 mod 32 = 4 -> conflict-free)
#define SB 256       // stats partial blocks
#define PB 256       // partition blocks
#define MAXNB 256    // max buckets (N <= 65536)
#define G8S 64       // g8 row stride in bytes (one cache line)
#define WTS 130      // W^T LDS stride in halves (bank-spread, b32-aligned)
#define DST 132      // gemm1 D LDS stride in halves
#define W2C 48       // gemm2 padded cols
#define DST2 52      // gemm2 D LDS stride in floats

typedef float v2f __attribute__((ext_vector_type(2)));
typedef _Float16 h8t __attribute__((ext_vector_type(8)));
typedef float f32x4 __attribute__((ext_vector_type(4)));

__device__ __forceinline__ float rlf(float v, int lane) {
  return __int_as_float(__builtin_amdgcn_readlane(__float_as_int(v), lane));
}

// ---------------- F1: stats1 (blocks [0,SB)) || bh (blocks [SB,SB+PB)) -----
__global__ __launch_bounds__(256) void k_f1(const float* __restrict__ x,
                                            float* __restrict__ part,
                                            const int* __restrict__ ei,
                                            int* __restrict__ cnt, int N,
                                            int E, int NB) {
  __shared__ float red[4][12];
  __shared__ int hist[MAXNB];
  int t = threadIdx.x;
  if (blockIdx.x < SB) {
    int bb = blockIdx.x;
    float s[AUGN] = {0, 0, 0, 0, 0, 0}, q[AUGN] = {0, 0, 0, 0, 0, 0};
    for (int n = bb * 256 + t; n < N; n += SB * 256) {
      const float* r = x + (size_t)n * XDIM + FEAT;
      float2 v0 = *(const float2*)r;
      float2 v1 = *(const float2*)(r + 2);
      float2 v2 = *(const float2*)(r + 4);
      float v[AUGN] = {v0.x, v0.y, v1.x, v1.y, v2.x, v2.y};
#pragma unroll
      for (int i = 0; i < AUGN; i++) {
        s[i] += v[i];
        q[i] += v[i] * v[i];
      }
    }
#pragma unroll
    for (int i = 0; i < AUGN; i++) {
      for (int m = 1; m < 64; m <<= 1) {
        s[i] += __shfl_xor(s[i], m);
        q[i] += __shfl_xor(q[i], m);
      }
    }
    int wv = t >> 6, l = t & 63;
    if (l == 0) {
#pragma unroll
      for (int i = 0; i < AUGN; i++) {
        red[wv][i] = s[i];
        red[wv][6 + i] = q[i];
      }
    }
    __syncthreads();
    if (t < 12)
      part[bb * 12 + t] = red[0][t] + red[1][t] + red[2][t] + red[3][t];
  } else {
    int bb = blockIdx.x - SB;
    for (int b = t; b < NB; b += 256) hist[b] = 0;
    __syncthreads();
    int ch = (E + PB - 1) / PB;
    int lo = bb * ch, hi = min(lo + ch, E);
    for (int e = lo + t; e < hi; e += 256)
      atomicAdd(&hist[ei[E + e] >> 8], 1);
    __syncthreads();
    for (int b = t; b < NB; b += 256)
      cnt[(size_t)b * PB + bb] = hist[b];
  }
}

// ---------------- F2: scale (blocks [0,NSC)) || sc1 (blocks [NSC,NSC+NB)) --
__global__ __launch_bounds__(256) void k_f2(
    const float* __restrict__ x, const float* __restrict__ part,
    const float* __restrict__ w1, const float* __restrict__ b1,
    const float* __restrict__ w2, const float* __restrict__ b2,
    float* __restrict__ scl, int* __restrict__ cnt, int* __restrict__ bsum,
    int N, int NSC) {
  __shared__ float red[4][12];
  __shared__ float sred[12];
  __shared__ int ps[256];
  int t = threadIdx.x;
  if ((int)blockIdx.x < NSC) {
    {
      float v[12];
#pragma unroll
      for (int c = 0; c < 12; c++) v[c] = part[t * 12 + c];
#pragma unroll
      for (int c = 0; c < 12; c++)
        for (int m = 1; m < 64; m <<= 1) v[c] += __shfl_xor(v[c], m);
      int wv = t >> 6, l = t & 63;
      if (l == 0) {
#pragma unroll
        for (int c = 0; c < 12; c++) red[wv][c] = v[c];
      }
      __syncthreads();
      if (t < 12) sred[t] = red[0][t] + red[1][t] + red[2][t] + red[3][t];
      __syncthreads();
    }
    int n = blockIdx.x * 256 + t;
    if (n >= N) return;
    const float* r = x + (size_t)n * XDIM + FEAT;
    float a[AUGN];
    float invN = 1.0f / (float)N;
#pragma unroll
    for (int i = 0; i < AUGN; i++) {
      float sum = sred[i], sq = sred[6 + i];
      float mean = sum * invN;
      float var = (sq - sum * mean) / (float)(N - 1);
      a[i] = (r[i] - mean) / sqrtf(var);
    }
    float s2 = b2[0];
#pragma unroll
    for (int j = 0; j < 16; j++) {
      float z = b1[j];
#pragma unroll
      for (int i = 0; i < AUGN; i++) z = fmaf(a[i], w1[i * 16 + j], z);
      z = fmaxf(z, 0.0f);
      s2 = fmaf(z, w2[j], s2);
    }
    float sig = 1.0f / (1.0f + __expf(-s2));
    scl[n] = 1.0f + sig;
  } else {
    int b = blockIdx.x - NSC;
    int v = cnt[(size_t)b * PB + t];
    ps[t] = v;
    __syncthreads();
    for (int d = 1; d < 256; d <<= 1) {
      int u = (t >= d) ? ps[t - d] : 0;
      __syncthreads();
      ps[t] += u;
      __syncthreads();
    }
    cnt[(size_t)b * PB + t] = ps[t] - v;  // exclusive within bucket
    if (t == 255) bsum[b] = ps[255];
  }
}

// ---------------- F3: gemm1 (blocks [0,NG)) || part (blocks [NG,NG+PB)) ----
__global__ __launch_bounds__(256) void k_f3(
    const float* __restrict__ x, const float* __restrict__ scl,
    const float* __restrict__ W, const float* __restrict__ asv,
    const float* __restrict__ adv, unsigned char* __restrict__ h8,
    __half* __restrict__ as1h, __half* __restrict__ ad1h,
    const int* __restrict__ ei, const int* __restrict__ cnt,
    const int* __restrict__ bsum, int* __restrict__ ebuf, int N, int E,
    int NB, int NG) {
  __shared__ __align__(16) char smem[128 * WTS * 2 + 64 * DST * 2];
  int tid = threadIdx.x;
  if ((int)blockIdx.x < NG) {
    __half* WT = (__half*)smem;                       // 128*WTS halves
    __half* D16 = (__half*)(smem + 128 * WTS * 2);    // 64*DST halves
    int wv = tid >> 6, l = tid & 63;
    int q = l >> 4, c = l & 15;
    for (int idx = tid * 4; idx < 128 * 128; idx += 256 * 4) {
      int k = idx >> 7, n = idx & 127;
      float4 v = *(const float4*)(W + idx);
      WT[(n + 0) * WTS + k] = __float2half(v.x);
      WT[(n + 1) * WTS + k] = __float2half(v.y);
      WT[(n + 2) * WTS + k] = __float2half(v.z);
      WT[(n + 3) * WTS + k] = __float2half(v.w);
    }
    __syncthreads();
    int colBase = wv * 32;
    h8t bf[2][4];
    const unsigned short* wtp = (const unsigned short*)WT;
#pragma unroll
    for (int ct = 0; ct < 2; ct++) {
#pragma unroll
      for (int kk = 0; kk < 4; kk++) {
        unsigned int* bu = (unsigned int*)&bf[ct][kk];
        int base = (colBase + ct * 16 + c) * WTS + kk * 32 + 8 * q;
#pragma unroll
        for (int p = 0; p < 4; p++)
          bu[p] = *(const unsigned int*)(wtp + base + 2 * p);
      }
    }
    int nodeBase = blockIdx.x * 64;
#pragma unroll
    for (int nt = 0; nt < 4; nt++) {
      int node = nodeBase + nt * 16 + c;
      const float* xr = x + (size_t)min(node, N - 1) * XDIM;
      h8t af[4];
#pragma unroll
      for (int kk = 0; kk < 4; kk++) {
        int k0 = kk * 32 + 8 * q;
#pragma unroll
        for (int p = 0; p < 4; p++) {
          float2 v = *(const float2*)(xr + k0 + 2 * p);
          af[kk][2 * p] = (_Float16)v.x;
          af[kk][2 * p + 1] = (_Float16)v.y;
        }
      }
      f32x4 a0 = {0.f, 0.f, 0.f, 0.f}, a1 = {0.f, 0.f, 0.f, 0.f};
#pragma unroll
      for (int kk = 0; kk < 4; kk++) {
        a0 = __builtin_amdgcn_mfma_f32_16x16x32_f16(af[kk], bf[0][kk], a0, 0,
                                                    0, 0);
        a1 = __builtin_amdgcn_mfma_f32_16x16x32_f16(af[kk], bf[1][kk], a1, 0,
                                                    0, 0);
      }
#pragma unroll
      for (int r = 0; r < 4; r++) {
        int row = nt * 16 + 4 * q + r;
        D16[row * DST + colBase + c] = __float2half(a0[r]);
        D16[row * DST + colBase + 16 + c] = __float2half(a1[r]);
      }
    }
    __syncthreads();
    float asw0 = asv[2 * l], asw1 = asv[2 * l + 1];
    float adw0 = adv[2 * l], adw1 = adv[2 * l + 1];
    for (int i = 0; i < 16; i++) {
      int node = nodeBase + wv * 16 + i;
      if (node >= N) break;
      float s = scl[node];
      __half2 yh = *(const __half2*)&D16[(wv * 16 + i) * DST + 2 * l];
      float2 yf = __half22float2(yh);
      float y0 = yf.x * s, y1 = yf.y * s;
      int pk = __builtin_amdgcn_cvt_pk_fp8_f32(y0, y1, 0, false);
      ((unsigned short*)(h8 + (size_t)node * FEAT))[l] = (unsigned short)pk;
      float ps2 = y0 * asw0 + y1 * asw1;
      float pd = y0 * adw0 + y1 * adw1;
      ps2 += __shfl_xor(ps2, 1);
      ps2 += __shfl_xor(ps2, 2);
      ps2 += __shfl_xor(ps2, 4);
      pd += __shfl_xor(pd, 1);
      pd += __shfl_xor(pd, 2);
      pd += __shfl_xor(pd, 4);
      if ((l & 7) == 0) {
        as1h[node * NH + (l >> 3)] = __float2half(ps2);
        ad1h[node * NH + (l >> 3)] = __float2half(pd);
      }
    }
  } else {
    int bb = blockIdx.x - NG;
    int* bex = (int*)smem;
    int* cur = (int*)(smem + 1024);
    int t = tid;
    int v = (t < NB) ? bsum[t] : 0;
    bex[t] = v;
    __syncthreads();
    for (int d = 1; d < 256; d <<= 1) {
      int u = (t >= d) ? bex[t - d] : 0;
      __syncthreads();
      bex[t] += u;
      __syncthreads();
    }
    if (t < NB) cur[t] = (bex[t] - v) + cnt[(size_t)t * PB + bb];
    __syncthreads();
    int ch = (E + PB - 1) / PB;
    int lo = bb * ch, hi = min(lo + ch, E);
    for (int e = lo + t; e < hi; e += 256) {
      int s = ei[e], d = ei[E + e];
      int pos = atomicAdd(&cur[d >> 8], 1);
      ebuf[pos] = (s << 8) | (d & 255);
    }
  }
}

// ---------------- K2d: per-bucket CSR build (contiguous region writes) -----
__global__ __launch_bounds__(256) void k_bcsr(const int* __restrict__ ebuf,
                                              const int* __restrict__ bsum,
                                              int* __restrict__ offs,
                                              int* __restrict__ csr, int N,
                                              int E, int NB) {
  __shared__ int bex[MAXNB];
  __shared__ int dl[256];
  __shared__ int sc[256];
  __shared__ int cu[256];
  int b = blockIdx.x, t = threadIdx.x;
  {
    int v = (t < NB) ? bsum[t] : 0;
    bex[t] = v;
    __syncthreads();
    for (int d = 1; d < 256; d <<= 1) {
      int u = (t >= d) ? bex[t - d] : 0;
      __syncthreads();
      bex[t] += u;
      __syncthreads();
    }
    int incl = bex[t];
    __syncthreads();
    bex[t] = incl - v;  // exclusive
    __syncthreads();
  }
  int nn = min(256, N - b * 256);
  int rs = bex[b];
  int re = (b + 1 < NB) ? bex[b + 1] : E;
  int csrbase = rs + b * 256;
  dl[t] = 0;
  __syncthreads();
  for (int j = rs + t; j < re; j += 256)
    atomicAdd(&dl[ebuf[j] & 255], 1);
  __syncthreads();
  int v = (t < nn) ? dl[t] + 1 : 0;
  sc[t] = v;
  __syncthreads();
  for (int d = 1; d < 256; d <<= 1) {
    int u = (t >= d) ? sc[t - d] : 0;
    __syncthreads();
    sc[t] += u;
    __syncthreads();
  }
  int excl = sc[t] - v;
  if (t < nn) {
    int node = b * 256 + t;
    offs[node] = csrbase + excl;
    csr[csrbase + excl] = node;  // self-loop slot
    cu[t] = excl + 1;
  }
  __syncthreads();
  for (int j = rs + t; j < re; j += 256) {
    int pk = ebuf[j];
    int p = atomicAdd(&cu[pk & 255], 1);
    csr[csrbase + p] = pk >> 8;
  }
  if (b == 0 && t == 0) offs[N] = E + N;
}

// ---------------- K4: layer-1 softmax-aggregate; h2(fp8, 128B rows) --------
__global__ __launch_bounds__(256) void k_agg1(
    const int* __restrict__ offs, const int* __restrict__ csr,
    const __half* __restrict__ as1h, const __half* __restrict__ ad1h,
    const unsigned char* __restrict__ h8, const float* __restrict__ bias,
    unsigned char* __restrict__ h2c, int N) {
  __shared__ float plds[4][8 * PS];
  __shared__ int slds[4][128];
  int wv = threadIdx.x >> 6, l = threadIdx.x & 63;
  int n = blockIdx.x * 4 + wv;
  if (n >= N) return;
  int beg = offs[n], end = offs[n + 1];
  int deg = end - beg;
  int h = l & 7, e8 = l >> 3;
  float adh = __half2float(ad1h[(size_t)n * NH + h]);
  float smh = 0.0f;
  for (int j0 = 0; j0 < deg; j0 += 8) {
    int j = j0 + e8;
    if (j < deg) {
      int s = csr[beg + j];
      if (h == 0 && j < 128) slds[wv][j] = s;
      float t = __half2float(as1h[(size_t)s * NH + h]) + adh;
      t = t > 0.0f ? t : 0.2f * t;
      float p = __expf(t);
      smh += p;
      if (j < 128) plds[wv][h * PS + j] = p;
    }
  }
  smh += __shfl_xor(smh, 8);
  smh += __shfl_xor(smh, 16);
  smh += __shfl_xor(smh, 32);  // lane k holds denom of head k&7
  __builtin_amdgcn_wave_barrier();
  // sweep 2: 4 edges/step; lane li owns channels {8li..8li+7}, head hh=li>>1
  int li = l & 15, eg = l >> 4;
  int hh = li >> 1;
  float rd = 1.0f / __shfl(smh, hh);
  const int* sp = slds[wv];
  const float* pp = &plds[wv][hh * PS];
  float acc0 = 0.f, acc1 = 0.f, acc2 = 0.f, acc3 = 0.f;
  float acc4 = 0.f, acc5 = 0.f, acc6 = 0.f, acc7 = 0.f;
  if (deg <= 128) {
    int dm1 = deg - 1;
    int ns = (deg + 3) >> 2;  // steps of 4 edges
    uint2 cur[4], nxt[4];
#define ROWA(G) \
  (*(const uint2*)(h8 + (size_t)sp[min(4 * (G) + eg, dm1)] * FEAT + 8 * li))
#pragma unroll
    for (int i = 0; i < 4; i++) cur[i] = ROWA(i);
    for (int g = 0; g < ns; g += 4) {
#pragma unroll
      for (int i = 0; i < 4; i++) nxt[i] = ROWA(g + 4 + i);
#pragma unroll
      for (int i = 0; i < 4; i++) {
        int j = 4 * (g + i) + eg;
        float a = (j < deg) ? pp[j] : 0.0f;
        v2f l0 = __builtin_amdgcn_cvt_pk_f32_fp8((int)cur[i].x, false);
        v2f h0 = __builtin_amdgcn_cvt_pk_f32_fp8((int)cur[i].x, true);
        v2f l1 = __builtin_amdgcn_cvt_pk_f32_fp8((int)cur[i].y, false);
        v2f h1 = __builtin_amdgcn_cvt_pk_f32_fp8((int)cur[i].y, true);
        acc0 = fmaf(a, l0[0], acc0); acc1 = fmaf(a, l0[1], acc1);
        acc2 = fmaf(a, h0[0], acc2); acc3 = fmaf(a, h0[1], acc3);
        acc4 = fmaf(a, l1[0], acc4); acc5 = fmaf(a, l1[1], acc5);
        acc6 = fmaf(a, h1[0], acc6); acc7 = fmaf(a, h1[1], acc7);
        cur[i] = nxt[i];
      }
    }
#undef ROWA
  } else {
    float adhh = __shfl(adh, hh);
    for (int j = eg; j < deg; j += 4) {
      int s;
      float p;
      if (j < 128) {
        s = sp[j];
        p = pp[j];
      } else {
        s = csr[beg + j];
        float t = __half2float(as1h[(size_t)s * NH + hh]) + adhh;
        t = t > 0.0f ? t : 0.2f * t;
        p = __expf(t);
      }
      uint2 w = *(const uint2*)(h8 + (size_t)s * FEAT + 8 * li);
      v2f l0 = __builtin_amdgcn_cvt_pk_f32_fp8((int)w.x, false);
      v2f h0 = __builtin_amdgcn_cvt_pk_f32_fp8((int)w.x, true);
      v2f l1 = __builtin_amdgcn_cvt_pk_f32_fp8((int)w.y, false);
      v2f h1 = __builtin_amdgcn_cvt_pk_f32_fp8((int)w.y, true);
      acc0 = fmaf(p, l0[0], acc0); acc1 = fmaf(p, l0[1], acc1);
      acc2 = fmaf(p, h0[0], acc2); acc3 = fmaf(p, h0[1], acc3);
      acc4 = fmaf(p, l1[0], acc4); acc5 = fmaf(p, l1[1], acc5);
      acc6 = fmaf(p, h1[0], acc6); acc7 = fmaf(p, h1[1], acc7);
    }
  }
#pragma unroll
  for (int m = 16; m < 64; m <<= 1) {
    acc0 += __shfl_xor(acc0, m); acc1 += __shfl_xor(acc1, m);
    acc2 += __shfl_xor(acc2, m); acc3 += __shfl_xor(acc3, m);
    acc4 += __shfl_xor(acc4, m); acc5 += __shfl_xor(acc5, m);
    acc6 += __shfl_xor(acc6, m); acc7 += __shfl_xor(acc7, m);
  }
  if (l < 16) {
    float4 b0 = *(const float4*)(bias + 8 * l);
    float4 b1v = *(const float4*)(bias + 8 * l + 4);
    float o0 = fmaxf(acc0 * rd + b0.x, 0.0f);
    float o1 = fmaxf(acc1 * rd + b0.y, 0.0f);
    float o2 = fmaxf(acc2 * rd + b0.z, 0.0f);
    float o3 = fmaxf(acc3 * rd + b0.w, 0.0f);
    float o4 = fmaxf(acc4 * rd + b1v.x, 0.0f);
    float o5 = fmaxf(acc5 * rd + b1v.y, 0.0f);
    float o6 = fmaxf(acc6 * rd + b1v.z, 0.0f);
    float o7 = fmaxf(acc7 * rd + b1v.w, 0.0f);
    unsigned int ua = __builtin_amdgcn_cvt_pk_fp8_f32(o0, o1, 0, false);
    ua = __builtin_amdgcn_cvt_pk_fp8_f32(o2, o3, ua, true);
    unsigned int ub = __builtin_amdgcn_cvt_pk_fp8_f32(o4, o5, 0, false);
    ub = __builtin_amdgcn_cvt_pk_fp8_f32(o6, o7, ub, true);
    uint2 st;
    st.x = ua;
    st.y = ub;
    *(uint2*)(h2c + (size_t)n * FEAT + 8 * l) = st;
  }
}

// ---------------- K5: MFMA g8(fp8, 64B rows) = h2(fp8) @ W2 ----------------
__global__ __launch_bounds__(256) void k_gemm2(
    const unsigned char* __restrict__ h2c, const float* __restrict__ W,
    const float* __restrict__ asv, const float* __restrict__ adv,
    unsigned char* __restrict__ g8, float* __restrict__ a_src,
    float* __restrict__ a_dst, int N) {
  __shared__ __half WT2[W2C * WTS];  // 12480 B
  __shared__ float DL[64 * DST2];    // 13312 B
  int tid = threadIdx.x;
  int wv = tid >> 6, l = tid & 63;
  int q = l >> 4, c = l & 15;
  for (int idx = tid; idx < W2C * 128; idx += 256) {
    int col = idx >> 7, k = idx & 127;
    float v = (col < OUTD) ? W[k * OUTD + col] : 0.0f;
    WT2[col * WTS + k] = __float2half(v);
  }
  __syncthreads();
  h8t bf[3][4];
  const unsigned short* wtp = (const unsigned short*)WT2;
#pragma unroll
  for (int ct = 0; ct < 3; ct++) {
#pragma unroll
    for (int kk = 0; kk < 4; kk++) {
      unsigned int* bu = (unsigned int*)&bf[ct][kk];
      int base = (ct * 16 + c) * WTS + kk * 32 + 8 * q;
#pragma unroll
      for (int p = 0; p < 4; p++)
        bu[p] = *(const unsigned int*)(wtp + base + 2 * p);
    }
  }
  int nodeBase = blockIdx.x * 64;
  int node = nodeBase + wv * 16 + c;
  const unsigned char* hr = h2c + (size_t)min(node, N - 1) * FEAT;
  h8t af[4];
#pragma unroll
  for (int kk = 0; kk < 4; kk++) {
    uint2 v = *(const uint2*)(hr + kk * 32 + 8 * q);
    v2f f0 = __builtin_amdgcn_cvt_pk_f32_fp8((int)v.x, false);
    v2f f1 = __builtin_amdgcn_cvt_pk_f32_fp8((int)v.x, true);
    v2f f2 = __builtin_amdgcn_cvt_pk_f32_fp8((int)v.y, false);
    v2f f3 = __builtin_amdgcn_cvt_pk_f32_fp8((int)v.y, true);
    af[kk][0] = (_Float16)f0[0]; af[kk][1] = (_Float16)f0[1];
    af[kk][2] = (_Float16)f1[0]; af[kk][3] = (_Float16)f1[1];
    af[kk][4] = (_Float16)f2[0]; af[kk][5] = (_Float16)f2[1];
    af[kk][6] = (_Float16)f3[0]; af[kk][7] = (_Float16)f3[1];
  }
  f32x4 d0 = {0.f, 0.f, 0.f, 0.f}, d1 = {0.f, 0.f, 0.f, 0.f},
        d2 = {0.f, 0.f, 0.f, 0.f};
#pragma unroll
  for (int kk = 0; kk < 4; kk++) {
    d0 = __builtin_amdgcn_mfma_f32_16x16x32_f16(af[kk], bf[0][kk], d0, 0, 0, 0);
    d1 = __builtin_amdgcn_mfma_f32_16x16x32_f16(af[kk], bf[1][kk], d1, 0, 0, 0);
    d2 = __builtin_amdgcn_mfma_f32_16x16x32_f16(af[kk], bf[2][kk], d2, 0, 0, 0);
  }
#pragma unroll
  for (int r = 0; r < 4; r++) {
    int row = wv * 16 + 4 * q + r;
    DL[row * DST2 + c] = d0[r];
    DL[row * DST2 + 16 + c] = d1[r];
    DL[row * DST2 + 32 + c] = d2[r];
  }
  __syncthreads();
  // scores: lane (i=l&15, cg=l>>4) sums cols cg*10..cg*10+9 of node row i
  int i = l & 15, cg = l >> 4;
  int row = wv * 16 + i;
  float ps = 0.0f, pd = 0.0f;
#pragma unroll
  for (int k = 0; k < 10; k++) {
    int col = cg * 10 + k;
    float gv = DL[row * DST2 + col];
    ps = fmaf(gv, asv[col], ps);
    pd = fmaf(gv, adv[col], pd);
  }
  ps += __shfl_xor(ps, 16); ps += __shfl_xor(ps, 32);
  pd += __shfl_xor(pd, 16); pd += __shfl_xor(pd, 32);
  int snode = nodeBase + wv * 16 + i;
  if (cg == 0 && snode < N) {
    a_src[snode] = ps;
    a_dst[snode] = pd;
  }
  // g8 write: 16 nodes x 16 uint words (64B rows), fp8-packed from DL
  for (int idx = l; idx < 16 * 16; idx += 64) {
    int ni = idx >> 4, w = idx & 15;
    int rr = wv * 16 + ni;
    int wnode = nodeBase + rr;
    if (wnode < N) {
      unsigned int u = 0;
      if (w < 10) {
        float c0 = DL[rr * DST2 + 4 * w];
        float c1 = DL[rr * DST2 + 4 * w + 1];
        float c2 = DL[rr * DST2 + 4 * w + 2];
        float c3 = DL[rr * DST2 + 4 * w + 3];
        u = __builtin_amdgcn_cvt_pk_fp8_f32(c0, c1, 0, false);
        u = __builtin_amdgcn_cvt_pk_fp8_f32(c2, c3, u, true);
      }
      *(unsigned int*)(g8 + (size_t)wnode * G8S + 4 * w) = u;
    }
  }
}

// ---------------- K6: layer-2 softmax-aggregate + log_softmax --------------
__global__ __launch_bounds__(256) void k_agg2(
    const int* __restrict__ offs, const int* __restrict__ csr,
    const float* __restrict__ a_src, const float* __restrict__ a_dst,
    const unsigned char* __restrict__ g8, const float* __restrict__ bias,
    float* __restrict__ out, int N) {
  __shared__ float plds[4][PS];
  __shared__ int slds[4][128];
  int wv = threadIdx.x >> 6, l = threadIdx.x & 63;
  int n = blockIdx.x * 4 + wv;
  if (n >= N) return;
  int beg = offs[n], end = offs[n + 1];
  int deg = end - beg;
  float adn = a_dst[n];
  float sm = 0.0f;
  for (int j0 = 0; j0 < deg; j0 += 64) {
    int j = j0 + l;
    if (j < deg) {
      int s = csr[beg + j];
      float t = a_src[s] + adn;
      t = t > 0.0f ? t : 0.2f * t;
      float p = __expf(t);
      sm += p;
      if (j < 128) {
        plds[wv][j] = p;
        slds[wv][j] = s;
      }
    }
  }
  for (int m = 1; m < 64; m <<= 1) sm += __shfl_xor(sm, m);
  float rd = 1.0f / sm;
  const int* sp = slds[wv];
  const float* pp = plds[wv];
  int li = l & 15, eg = l >> 4;
  int lic = min(li, 9);
  const unsigned char* gb = g8 + 4 * lic;
  float acc0 = 0.0f, acc1 = 0.0f, acc2 = 0.0f, acc3 = 0.0f;
  if (deg <= 128) {
    int dm1 = deg - 1;
    int ns = (deg + 3) >> 2;  // steps of 4 edges
    unsigned int cur[4], nxt[4];
#define ROWB(G) \
  (*(const unsigned int*)(gb + (size_t)sp[min(4 * (G) + eg, dm1)] * G8S))
#pragma unroll
    for (int i = 0; i < 4; i++) cur[i] = ROWB(i);
    for (int g = 0; g < ns; g += 4) {
#pragma unroll
      for (int i = 0; i < 4; i++) nxt[i] = ROWB(g + 4 + i);
#pragma unroll
      for (int i = 0; i < 4; i++) {
        int j = 4 * (g + i) + eg;
        float a = (j < deg) ? pp[j] : 0.0f;
        v2f lo = __builtin_amdgcn_cvt_pk_f32_fp8((int)cur[i], false);
        v2f hi = __builtin_amdgcn_cvt_pk_f32_fp8((int)cur[i], true);
        acc0 = fmaf(a, lo[0], acc0);
        acc1 = fmaf(a, lo[1], acc1);
        acc2 = fmaf(a, hi[0], acc2);
        acc3 = fmaf(a, hi[1], acc3);
        cur[i] = nxt[i];
      }
    }
#undef ROWB
  } else {
    for (int j = eg; j < deg; j += 4) {
      int s;
      float p;
      if (j < 128) {
        s = sp[j];
        p = pp[j];
      } else {
        s = csr[beg + j];
        float t = a_src[s] + adn;
        t = t > 0.0f ? t : 0.2f * t;
        p = __expf(t);
      }
      unsigned int w = *(const unsigned int*)(gb + (size_t)s * G8S);
      v2f lo = __builtin_amdgcn_cvt_pk_f32_fp8((int)w, false);
      v2f hi = __builtin_amdgcn_cvt_pk_f32_fp8((int)w, true);
      acc0 = fmaf(p, lo[0], acc0);
      acc1 = fmaf(p, lo[1], acc1);
      acc2 = fmaf(p, hi[0], acc2);
      acc3 = fmaf(p, hi[1], acc3);
    }
  }
#pragma unroll
  for (int m = 16; m < 64; m <<= 1) {
    acc0 += __shfl_xor(acc0, m);
    acc1 += __shfl_xor(acc1, m);
    acc2 += __shfl_xor(acc2, m);
    acc3 += __shfl_xor(acc3, m);
  }
  bool cact = li < 10;
  float v0 = -INFINITY, v1 = -INFINITY, v2 = -INFINITY, v3 = -INFINITY;
  if (cact) {
    float4 bv = *(const float4*)(bias + 4 * li);
    v0 = acc0 * rd + bv.x;
    v1 = acc1 * rd + bv.y;
    v2 = acc2 * rd + bv.z;
    v3 = acc3 * rd + bv.w;
  }
  float mx = fmaxf(fmaxf(v0, v1), fmaxf(v2, v3));
  for (int m = 1; m < 64; m <<= 1) mx = fmaxf(mx, __shfl_xor(mx, m));
  // only eg==0 lanes contribute to the denominator (eg=1..3 hold copies)
  float pe = (eg == 0 && cact) ? __expf(v0 - mx) + __expf(v1 - mx) +
                                     __expf(v2 - mx) + __expf(v3 - mx)
                               : 0.0f;
  float se = pe;
  for (int m = 1; m < 64; m <<= 1) se += __shfl_xor(se, m);
  float ls = logf(se);
  if (eg == 0 && cact) {
    float4 o;
    o.x = v0 - mx - ls;
    o.y = v1 - mx - ls;
    o.z = v2 - mx - ls;
    o.w = v3 - mx - ls;
    *(float4*)(out + (size_t)n * OUTD + 4 * li) = o;
  }
}

// ---------------------------------------------------------------------------
extern "C" void kernel_launch(void* const* d_in, const int* in_sizes, int n_in,
                              void* d_out, int out_size, void* d_ws,
                              size_t ws_size, hipStream_t stream) {
  const float* x = (const float*)d_in[0];
  const int* ei = (const int*)d_in[1];
  const float* mw1 = (const float*)d_in[2];
  const float* mb1 = (const float*)d_in[3];
  const float* mw2 = (const float*)d_in[4];
  const float* mb2 = (const float*)d_in[5];
  const float* W1 = (const float*)d_in[6];
  const float* as1w = (const float*)d_in[7];
  const float* ad1w = (const float*)d_in[8];
  const float* b1 = (const float*)d_in[9];
  const float* W2 = (const float*)d_in[10];
  const float* as2w = (const float*)d_in[11];
  const float* ad2w = (const float*)d_in[12];
  const float* b2 = (const float*)d_in[13];
  float* out = (float*)d_out;

  int N = in_sizes[0] / XDIM;
  int E = in_sizes[1] / 2;
  int ET = E + N;
  int NB = (N + 255) >> 8;  // dst buckets of 256 nodes

  char* ws = (char*)d_ws;
  size_t off = 0;
  auto carve = [&](size_t bytes) -> void* {
    void* p = ws + off;
    off = (off + bytes + 255) & ~(size_t)255;
    return p;
  };
  float* part = (float*)carve((size_t)SB * 12 * 4);
  int* cnt = (int*)carve((size_t)NB * PB * 4);
  int* bsum = (int*)carve((size_t)MAXNB * 4);
  int* ebuf = (int*)carve((size_t)E * 4);
  int* offs = (int*)carve((size_t)(N + 1) * 4);
  int* csr = (int*)carve((size_t)ET * 4);
  float* scl = (float*)carve((size_t)N * 4);
  __half* as1h = (__half*)carve((size_t)N * NH * 2);
  __half* ad1h = (__half*)carve((size_t)N * NH * 2);
  unsigned char* h8 = (unsigned char*)carve((size_t)N * FEAT);
  unsigned char* h2c = (unsigned char*)carve((size_t)N * FEAT);
  unsigned char* g8 = (unsigned char*)carve((size_t)N * G8S);
  float* as2 = (float*)carve((size_t)N * 4);
  float* ad2 = (float*)carve((size_t)N * 4);

  int NSC = (N + 255) / 256;
  int NG = (N + 63) / 64;
  k_f1<<<SB + PB, 256, 0, stream>>>(x, part, ei, cnt, N, E, NB);
  k_f2<<<NSC + NB, 256, 0, stream>>>(x, part, mw1, mb1, mw2, mb2, scl, cnt,
                                     bsum, N, NSC);
  k_f3<<<NG + PB, 256, 0, stream>>>(x, scl, W1, as1w, ad1w, h8, as1h, ad1h,
                                    ei, cnt, bsum, ebuf, N, E, NB, NG);
  k_bcsr<<<NB, 256, 0, stream>>>(ebuf, bsum, offs, csr, N, E, NB);
  k_agg1<<<(N + 3) / 4, 256, 0, stream>>>(offs, csr, as1h, ad1h, h8, b1, h2c,
                                          N);
  k_gemm2<<<NG, 256, 0, stream>>>(h2c, W2, as2w, ad2w, g8, as2, ad2, N);
  k_agg2<<<(N + 3) / 4, 256, 0, stream>>>(offs, csr, as2, ad2, g8, b2, out, N);
}